// Round 14
// baseline (20371.010 us; speedup 1.0000x reference)
//
#include <hip/hip_runtime.h>
#include <math.h>
#include <stdint.h>

typedef unsigned int u32;
typedef _Float16 f16;
typedef __attribute__((ext_vector_type(8))) _Float16 f16x8;
typedef __attribute__((ext_vector_type(4))) float f32x4;

// ---------------- Threefry-2x32 (20 rounds), matches JAX ----------------
__host__ __device__ __forceinline__ u32 rotl32(u32 x, int r) { return (x << r) | (x >> (32 - r)); }
__host__ __device__ __forceinline__ void tf_round(u32& x0, u32& x1, int r) {
  x0 += x1; x1 = rotl32(x1, r); x1 ^= x0;
}
__host__ __device__ __forceinline__ void tf_block(u32 k0, u32 k1, u32 x0, u32 x1, u32& o0, u32& o1) {
  u32 k2 = k0 ^ k1 ^ 0x1BD11BDAu;
  x0 += k0; x1 += k1;
  tf_round(x0,x1,13); tf_round(x0,x1,15); tf_round(x0,x1,26); tf_round(x0,x1,6);
  x0 += k1; x1 += k2 + 1u;
  tf_round(x0,x1,17); tf_round(x0,x1,29); tf_round(x0,x1,16); tf_round(x0,x1,24);
  x0 += k2; x1 += k0 + 2u;
  tf_round(x0,x1,13); tf_round(x0,x1,15); tf_round(x0,x1,26); tf_round(x0,x1,6);
  x0 += k0; x1 += k1 + 3u;
  tf_round(x0,x1,17); tf_round(x0,x1,29); tf_round(x0,x1,16); tf_round(x0,x1,24);
  x0 += k1; x1 += k2 + 4u;
  tf_round(x0,x1,13); tf_round(x0,x1,15); tf_round(x0,x1,26); tf_round(x0,x1,6);
  x0 += k2; x1 += k0 + 5u;
  o0 = x0; o1 = x1;
}

__global__ void k_idx(u32 ka, u32 kb, int n, int mask, int* __restrict__ idx) {
  int i = blockIdx.x * 256 + threadIdx.x;
  if (i >= n) return;
  u32 b1, b2; tf_block(ka, kb, 0u, (u32)i, b1, b2);
  idx[i] = (int)((b1 ^ b2) & (u32)mask);
}

__device__ __forceinline__ void emit_split(float v, f16* __restrict__ oh,
                                           f16* __restrict__ ol, size_t o) {
  f16 h = (f16)v;
  oh[o] = h;
  ol[o] = (f16)((v - (float)h) * 2048.0f);
}
__device__ __forceinline__ float rsplit(const f16* __restrict__ h,
                                        const f16* __restrict__ l, size_t o) {
  return (float)h[o] + (float)l[o] * (1.0f / 2048.0f);
}

// ---------------- positional embedding ----------------
__global__ void k_pe(float* __restrict__ pe) {
  int i = blockIdx.x * 256 + threadIdx.x;
  if (i >= 2048 * 512) return;
  int t = i >> 9, o = i & 511;
  float arg = (float)((o >> 1) * 2) * (float)(-(log(10000.0) / 512.0));
  float div = (float)exp((double)arg);
  float ang32 = (float)t * div;
  double ang = (double)ang32;
  pe[i] = (float)((o & 1) ? cos(ang) : sin(ang));
}

// ---------------- embedding (split-only output) ----------------
__global__ __launch_bounds__(256) void k_embed(
    const float* __restrict__ x, const float* __restrict__ mark,
    const float* __restrict__ tw, const float* __restrict__ mw,
    const float* __restrict__ pe, f16* __restrict__ oh, f16* __restrict__ ol,
    int L, int total) {
  int i = blockIdx.x * 256 + threadIdx.x;
  if (i >= total) return;
  int oo = i & 511;
  int bt = i >> 9;
  int t = bt % L;
  int b = bt / L;
  float acc = pe[(t << 9) + oo];
  #pragma unroll
  for (int k = 0; k < 3; ++k) {
    int st = t + k - 1; if (st < 0) st += L; else if (st >= L) st -= L;
    const float* xr = x + (size_t)(b * L + st) * 7;
    const float* wr = tw + oo * 21 + k;
    #pragma unroll
    for (int ii = 0; ii < 7; ++ii) acc += xr[ii] * wr[ii * 3];
  }
  const float* mr = mark + (size_t)bt * 4;
  #pragma unroll
  for (int m = 0; m < 4; ++m) acc += mr[m] * mw[(m << 9) + oo];
  emit_split(acc, oh, ol, ((size_t)bt << 9) + oo);
}

// ---------------- weight transpose + f16 split (z = matrix index) ----------------
__global__ __launch_bounds__(256) void k_wsplit(const float* __restrict__ W,
    f16* __restrict__ Wh, f16* __restrict__ Wl, int K, int N) {
  size_t zo = (size_t)blockIdx.z * K * N;
  W += zo; Wh += zo; Wl += zo;
  __shared__ float tile[32][33];
  int kb = blockIdx.x << 5, nb = blockIdx.y << 5;
  int t = threadIdx.x;
  int tr = t >> 5, tc = t & 31;
  #pragma unroll
  for (int p = 0; p < 4; ++p)
    tile[tr + p * 8][tc] = W[(size_t)(kb + tr + p * 8) * N + nb + tc];
  __syncthreads();
  #pragma unroll
  for (int p = 0; p < 4; ++p) {
    int n = tr + p * 8, k = tc;
    float v = tile[k][n];
    f16 h = (f16)v;
    size_t o = (size_t)(nb + n) * K + kb + k;
    Wh[o] = h;
    Wl[o] = (f16)((v - (float)h) * 2048.0f);
  }
}

__global__ void k_wsplit_conv(const float* __restrict__ w, f16* __restrict__ Wh, f16* __restrict__ Wl) {
  int i = blockIdx.x * 256 + threadIdx.x;
  if (i >= 512 * 1536) return;
  int o = i / 1536, k = i - o * 1536;
  float v = w[(size_t)o * 1536 + (k & 511) * 3 + (k >> 9)];
  f16 h = (f16)v;
  Wh[i] = h;
  Wl[i] = (f16)((v - (float)h) * 2048.0f);
}

__device__ __forceinline__ int swz_x(int r) { return ((((r >> 1) & 3) ^ ((r >> 3) & 3)) << 4); }

__device__ __forceinline__ void gload16(const void* g, void* l) {
  __builtin_amdgcn_global_load_lds(
      (const __attribute__((address_space(1))) void*)g,
      (__attribute__((address_space(3))) void*)l, 16, 0, 0);
}

// ---------------- MFMA GEMM v2: pre-split f16 A/B, async LDS, dbuf, 16x16x32 ----------------
// ACT: 0 none, 1 gelu, 2 bn+elu. OSPLIT: C as split pair. GATHER: circular distil rows.
// RESID: add residual reconstructed from split pair Rh/Rl.
// Block->tile mapping is XCD-swizzled (bijective when nwg%8==0) for L2 locality.
template<int ACT, int OSPLIT, int GATHER, int RESID>
__global__ __launch_bounds__(256, 2) void k_mgemm2(
    const f16* __restrict__ Ah, const f16* __restrict__ Al,
    const f16* __restrict__ Bh, const f16* __restrict__ Bl,
    const float* __restrict__ bias,
    const f16* __restrict__ Rh, const f16* __restrict__ Rl,
    const float* __restrict__ bns, const float* __restrict__ bnb,
    float* __restrict__ C, f16* __restrict__ Ch, f16* __restrict__ Cl,
    int M, int N, int K, int lgL) {
  __shared__ char lds[65536];
  const int t = threadIdx.x;
  int nwg = gridDim.x * gridDim.y;
  int bid = blockIdx.y * gridDim.x + blockIdx.x;
  if ((nwg & 7) == 0) {
    int cpx = nwg >> 3;
    bid = (bid & 7) * cpx + (bid >> 3);
  }
  const int bm = (bid / gridDim.x) << 7, bn = (bid % gridDim.x) << 7;
  const int w = t >> 6, l = t & 63;
  const int lr = l >> 2;
  const int qx = (l & 3) << 4;
  const int wr = (w >> 1) << 6, wc = (w & 1) << 6;
  const int fr = l & 15;
  const int fkB = (l >> 4) << 4;
  const f32x4 zero = {0.f, 0.f, 0.f, 0.f};
  f32x4 acc1[4][4], acc2[4][4];
  #pragma unroll
  for (int i = 0; i < 4; ++i)
    #pragma unroll
    for (int j = 0; j < 4; ++j) { acc1[i][j] = zero; acc2[i][j] = zero; }

  auto stage = [&](int k0, int bufo) {
    #pragma unroll
    for (int c = 0; c < 2; ++c) {
      int r = w * 32 + c * 16 + lr;
      int sx = qx ^ swz_x(r);
      const char *gAh, *gAl;
      if (GATHER) {
        int m = bm + r;
        int Lm = 1 << lgL;
        int ab = m >> lgL, at = m & (Lm - 1);
        int ke = k0 + (sx >> 1);
        int tap = ke >> 9, ii = ke & 511;
        int st = at + tap - 1; if (st < 0) st += Lm; else if (st >= Lm) st -= Lm;
        size_t aoff = (((size_t)((ab << lgL) + st)) << 9) + ii;
        gAh = (const char*)(Ah + aoff);
        gAl = (const char*)(Al + aoff);
      } else {
        gAh = (const char*)(Ah + (size_t)(bm + r) * K + k0) + sx;
        gAl = (const char*)(Al + (size_t)(bm + r) * K + k0) + sx;
      }
      const char* gBh = (const char*)(Bh + (size_t)(bn + r) * K + k0) + sx;
      const char* gBl = (const char*)(Bl + (size_t)(bn + r) * K + k0) + sx;
      char* base = lds + bufo + w * 2048 + c * 1024;
      gload16(gAh, base);
      gload16(gAl, base + 8192);
      gload16(gBh, base + 16384);
      gload16(gBl, base + 24576);
    }
  };

  int nt = K >> 5;
  stage(0, 0);
  __syncthreads();
  int bufo = 0;
  for (int tt = 0; tt < nt; ++tt) {
    int nb = bufo ^ 32768;
    if (tt + 1 < nt) stage((tt + 1) << 5, nb);
    char* pAh = lds + bufo;
    char* pAl = pAh + 8192;
    char* pBh = pAh + 16384;
    char* pBl = pAh + 24576;
    f16x8 ah4[4], al4[4];
    #pragma unroll
    for (int i = 0; i < 4; ++i) {
      int r = wr + i * 16 + fr;
      int ob = r * 64 + (fkB ^ swz_x(r));
      ah4[i] = *(f16x8*)(pAh + ob);
      al4[i] = *(f16x8*)(pAl + ob);
    }
    #pragma unroll
    for (int j = 0; j < 4; ++j) {
      int r = wc + j * 16 + fr;
      int ob = r * 64 + (fkB ^ swz_x(r));
      f16x8 bh_ = *(f16x8*)(pBh + ob);
      f16x8 bl_ = *(f16x8*)(pBl + ob);
      #pragma unroll
      for (int i = 0; i < 4; ++i) {
        acc1[i][j] = __builtin_amdgcn_mfma_f32_16x16x32_f16(ah4[i], bh_, acc1[i][j], 0, 0, 0);
        acc2[i][j] = __builtin_amdgcn_mfma_f32_16x16x32_f16(ah4[i], bl_, acc2[i][j], 0, 0, 0);
        acc2[i][j] = __builtin_amdgcn_mfma_f32_16x16x32_f16(al4[i], bh_, acc2[i][j], 0, 0, 0);
      }
    }
    __syncthreads();
    bufo = nb;
  }
  #pragma unroll
  for (int j = 0; j < 4; ++j) {
    int col = bn + wc + j * 16 + fr;
    float bsv = bias[col];
    float g2 = 0.f, b2 = 0.f;
    if (ACT == 2) { g2 = bns[col] * 0.9999950000375f; b2 = bnb[col]; }
    #pragma unroll
    for (int i = 0; i < 4; ++i) {
      #pragma unroll
      for (int r = 0; r < 4; ++r) {
        int row = bm + wr + i * 16 + ((l >> 4) << 2) + r;
        float v = acc1[i][j][r] + acc2[i][j][r] * (1.0f / 2048.0f) + bsv;
        if (ACT == 1) v = 0.5f * v * (1.0f + erff(v * 0.70710678118654752f));
        if (ACT == 2) { v = v * g2 + b2; v = v > 0.f ? v : expm1f(v); }
        size_t oi = (size_t)row * N + col;
        if (RESID) v += rsplit(Rh, Rl, oi);
        if (OSPLIT) emit_split(v, Ch, Cl, oi);
        else        C[oi] = v;
      }
    }
  }
}

// ---------------- LayerNorm on split input; optional split / f32 outputs ----------------
__global__ __launch_bounds__(256) void k_ln(const f16* __restrict__ xh, const f16* __restrict__ xl,
    const float* __restrict__ g, const float* __restrict__ b,
    float* __restrict__ of32, f16* __restrict__ oh, f16* __restrict__ ol) {
  int row = blockIdx.x, t = threadIdx.x;
  size_t base = (size_t)row << 9;
  float v0 = rsplit(xh, xl, base + t);
  float v1 = rsplit(xh, xl, base + t + 256);
  float s = v0 + v1;
  #pragma unroll
  for (int off = 32; off; off >>= 1) s += __shfl_down(s, off);
  __shared__ float ls[4];
  if ((t & 63) == 0) ls[t >> 6] = s;
  __syncthreads();
  float mean = (ls[0] + ls[1] + ls[2] + ls[3]) * (1.f / 512.f);
  __syncthreads();
  float d0 = v0 - mean, d1 = v1 - mean;
  float q = d0 * d0 + d1 * d1;
  #pragma unroll
  for (int off = 32; off; off >>= 1) q += __shfl_down(q, off);
  if ((t & 63) == 0) ls[t >> 6] = q;
  __syncthreads();
  float var = (ls[0] + ls[1] + ls[2] + ls[3]) * (1.f / 512.f);
  float rs = rsqrtf(var + 1e-5f);
  float r0 = d0 * rs * g[t] + b[t];
  float r1 = d1 * rs * g[t + 256] + b[t + 256];
  if (of32) { of32[base + t] = r0; of32[base + t + 256] = r1; }
  if (oh) {
    emit_split(r0, oh, ol, base + t);
    emit_split(r1, oh, ol, base + t + 256);
  }
}

// ---------------- chunked M-scoring: K chunk staged in LDS, 40x less K traffic ----------------
// grid: (nch = Lk/256, bs*8). Partial max/sum per (chunk, bh, l); dots bit-identical
// to the original per-float4 expression; combine reassociates only the cross-sample sum.
__global__ __launch_bounds__(256) void k_qkM2(const float* __restrict__ Q, int qstr,
    const float* __restrict__ Kp, int kstr, const int* __restrict__ idx,
    float* __restrict__ MPmax, float* __restrict__ MPsum, int Lq, int Lk, int U) {
  __shared__ float ks[16384];          // 256 rows x 16 float4 slots (xor-swizzled), 64 KB
  int ch = blockIdx.x, bh = blockIdx.y;
  int b = bh >> 3, h = bh & 7;
  int c0 = ch << 8;
  int t = threadIdx.x;
  for (int i = t; i < 4096; i += 256) {
    int r = i >> 4, c4 = i & 15;
    float4 v = *(const float4*)(Kp + (size_t)(b * Lk + c0 + r) * kstr + (h << 6) + (c4 << 2));
    *(float4*)(ks + r * 64 + ((c4 ^ (r & 15)) << 2)) = v;
  }
  __syncthreads();
  int w = t >> 6, lane = t & 63;
  for (int l = w; l < Lq; l += 4) {
    float dot = 0.f;
    bool act = false;
    if (lane < U) {
      int kr = idx[l * U + lane];
      int rr = kr - c0;
      if (rr >= 0 && rr < 256) {
        act = true;
        const float4* q4 = (const float4*)(Q + (size_t)(b * Lq + l) * qstr + (h << 6));
        const float* krow = ks + rr * 64;
        int sw = rr & 15;
        #pragma unroll
        for (int e = 0; e < 16; ++e) {
          float4 a = q4[e];
          float4 c = *(const float4*)(krow + ((e ^ sw) << 2));
          dot += a.x * c.x + a.y * c.y + a.z * c.z + a.w * c.w;
        }
      }
    }
    float mx = act ? dot : -INFINITY;
    float sm = act ? dot : 0.f;
    #pragma unroll
    for (int off = 32; off; off >>= 1) {
      mx = fmaxf(mx, __shfl_xor(mx, off));
      sm += __shfl_xor(sm, off);
    }
    if (lane == 0) {
      size_t o = ((size_t)ch * gridDim.y + bh) * Lq + l;
      MPmax[o] = mx; MPsum[o] = sm;
    }
  }
}
__global__ void k_qkMc(const float* __restrict__ MPmax, const float* __restrict__ MPsum,
                       float* __restrict__ M, int nch, int total, int Lk) {
  int i = blockIdx.x * 256 + threadIdx.x;
  if (i >= total) return;
  float mx = -INFINITY, sm = 0.f;
  for (int ch = 0; ch < nch; ++ch) {
    mx = fmaxf(mx, MPmax[(size_t)ch * total + i]);
    sm += MPsum[(size_t)ch * total + i];
  }
  M[i] = mx - sm / (float)Lk;
}

// ---------------- single-wave top-u per (b,h), ties -> lower index ----------------
__global__ void k_topk64(const float* __restrict__ M, int* __restrict__ mtop, int Lq, int u) {
  __shared__ float vals[2048];
  int bh = blockIdx.x, l = threadIdx.x;
  const float* Mr = M + (size_t)bh * Lq;
  for (int i = l; i < Lq; i += 64) vals[i] = Mr[i];
  __syncthreads();
  for (int it = 0; it < u; ++it) {
    float bv = -INFINITY; int bi = 0x7fffffff;
    for (int i = l; i < Lq; i += 64) {
      float v = vals[i];
      if (v > bv || (v == bv && i < bi)) { bv = v; bi = i; }
    }
    #pragma unroll
    for (int off = 32; off; off >>= 1) {
      float vv = __shfl_xor(bv, off); int ii = __shfl_xor(bi, off);
      if (vv > bv || (vv == bv && ii < bi)) { bv = vv; bi = ii; }
    }
    if (l == 0) { mtop[bh * u + it] = bi; vals[bi] = -INFINITY; }
    __syncthreads();
  }
}

// ---------------- ctx mean (AO split) ----------------
__global__ void k_cm1(const float* __restrict__ V, int vstr, float* __restrict__ PS,
                      int Lk, int rows) {
  int bid = blockIdx.x;
  int bh = bid >> 4, seg = bid & 15, d = threadIdx.x;
  int b = bh >> 3, h = bh & 7;
  const float* vp = V + (size_t)(b * Lk + seg * rows) * vstr + (h << 6) + d;
  float acc = 0.f;
  for (int r = 0; r < rows; ++r) acc += vp[(size_t)r * vstr];
  PS[(bid << 6) + d] = acc;
}
__global__ void k_cm2(const float* __restrict__ PS, f16* __restrict__ AOh,
                      f16* __restrict__ AOl, float invLk, int Lq, int total) {
  int i = blockIdx.x * 256 + threadIdx.x;
  if (i >= total) return;
  int c = i & 511; int h = c >> 6; int d = c & 63;
  int r = i >> 9; int b = r / Lq;
  float acc = 0.f;
  #pragma unroll
  for (int s = 0; s < 16; ++s) acc += PS[(((((b << 3) + h) << 4) + s) << 6) + d];
  emit_split(acc * invLk, AOh, AOl, (size_t)i);
}

// ---------------- cumsum (masked ctx; per-block prefix, AO split) ----------------
__global__ void k_cs1(const float* __restrict__ V, int vstr, float* __restrict__ PS,
                      int Lq, int rows) {
  int bid = blockIdx.x;
  int bh = bid >> 3, seg = bid & 7, d = threadIdx.x;
  int b = bh >> 3, h = bh & 7;
  const float* vp = V + (size_t)(b * Lq + seg * rows) * vstr + (h << 6) + d;
  float acc = 0.f;
  for (int r = 0; r < rows; ++r) acc += vp[(size_t)r * vstr];
  PS[(bid << 6) + d] = acc;
}
__global__ void k_cs3(const float* __restrict__ V, int vstr, const float* __restrict__ PS,
                      f16* __restrict__ AOh, f16* __restrict__ AOl, int Lq, int rows) {
  int bid = blockIdx.x;
  int bh = bid >> 3, seg = bid & 7, d = threadIdx.x;
  int b = bh >> 3, h = bh & 7;
  float acc = 0.f;
  for (int s2 = 0; s2 < seg; ++s2) acc += PS[(((bh << 3) + s2) << 6) + d];
  const float* vp = V + (size_t)(b * Lq + seg * rows) * vstr + (h << 6) + d;
  size_t ob = ((size_t)(b * Lq + seg * rows) << 9) + (h << 6) + d;
  for (int r = 0; r < rows; ++r) {
    acc += vp[(size_t)r * vstr];
    emit_split(acc, AOh, AOl, ob + ((size_t)r << 9));
  }
}

// ---------------- sparse attn: 4 selected rows per block (AO split) ----------------
__global__ __launch_bounds__(256) void k_sattn4(
    const float* __restrict__ Q, int qstr, const float* __restrict__ Kp, int kstr,
    const float* __restrict__ Vp, int vstr, const int* __restrict__ mtop,
    f16* __restrict__ AOh, f16* __restrict__ AOl, int Lq, int Lk, int u, int masked) {
  __shared__ float sc[4][2048];
  __shared__ float qs[4][64];
  __shared__ float red[4][256];
  __shared__ float pv[4][4][64];
  __shared__ int rowsh[4];
  __shared__ float mxs[4], sss[4];
  int nb = (u + 3) >> 2;
  int ub = blockIdx.x % nb, bh = blockIdx.x / nb;
  int b = bh >> 3, h = bh & 7;
  int t = threadIdx.x;
  if (t < 4) {
    int ui = ub * 4 + t;
    rowsh[t] = (ui < u) ? mtop[bh * u + ui] : -1;
  }
  __syncthreads();
  {
    int r = t >> 6, d = t & 63;
    int row = rowsh[r];
    qs[r][d] = (row >= 0) ? Q[(size_t)(b * Lq + row) * qstr + (h << 6) + d] : 0.f;
  }
  __syncthreads();
  float lm0 = -INFINITY, lm1 = -INFINITY, lm2 = -INFINITY, lm3 = -INFINITY;
  for (int c = t; c < Lk; c += 256) {
    const float4* kr = (const float4*)(Kp + (size_t)(b * Lk + c) * kstr + (h << 6));
    float d0 = 0.f, d1 = 0.f, d2 = 0.f, d3 = 0.f;
    #pragma unroll
    for (int e = 0; e < 16; ++e) {
      float4 kk = kr[e];
      d0 += qs[0][4*e]*kk.x + qs[0][4*e+1]*kk.y + qs[0][4*e+2]*kk.z + qs[0][4*e+3]*kk.w;
      d1 += qs[1][4*e]*kk.x + qs[1][4*e+1]*kk.y + qs[1][4*e+2]*kk.z + qs[1][4*e+3]*kk.w;
      d2 += qs[2][4*e]*kk.x + qs[2][4*e+1]*kk.y + qs[2][4*e+2]*kk.z + qs[2][4*e+3]*kk.w;
      d3 += qs[3][4*e]*kk.x + qs[3][4*e+1]*kk.y + qs[3][4*e+2]*kk.z + qs[3][4*e+3]*kk.w;
    }
    float dd[4] = {d0, d1, d2, d3};
    #pragma unroll
    for (int r = 0; r < 4; ++r) {
      float v = dd[r] * 0.125f;
      if (masked && c > rowsh[r]) v = -INFINITY;
      sc[r][c] = v;
    }
    lm0 = fmaxf(lm0, sc[0][c]); lm1 = fmaxf(lm1, sc[1][c]);
    lm2 = fmaxf(lm2, sc[2][c]); lm3 = fmaxf(lm3, sc[3][c]);
  }
  red[0][t] = lm0; red[1][t] = lm1; red[2][t] = lm2; red[3][t] = lm3;
  __syncthreads();
  {
    int w = t >> 6, lane = t & 63;
    float m = fmaxf(fmaxf(red[w][lane], red[w][lane + 64]),
                    fmaxf(red[w][lane + 128], red[w][lane + 192]));
    #pragma unroll
    for (int off = 32; off; off >>= 1) m = fmaxf(m, __shfl_xor(m, off));
    if (lane == 0) mxs[w] = m;
  }
  __syncthreads();
  float ls0 = 0.f, ls1 = 0.f, ls2 = 0.f, ls3 = 0.f;
  float m0 = mxs[0], m1 = mxs[1], m2 = mxs[2], m3 = mxs[3];
  for (int c = t; c < Lk; c += 256) {
    float e0 = expf(sc[0][c] - m0); sc[0][c] = e0; ls0 += e0;
    float e1 = expf(sc[1][c] - m1); sc[1][c] = e1; ls1 += e1;
    float e2 = expf(sc[2][c] - m2); sc[2][c] = e2; ls2 += e2;
    float e3 = expf(sc[3][c] - m3); sc[3][c] = e3; ls3 += e3;
  }
  red[0][t] = ls0; red[1][t] = ls1; red[2][t] = ls2; red[3][t] = ls3;
  __syncthreads();
  {
    int w = t >> 6, lane = t & 63;
    float s = red[w][lane] + red[w][lane + 64] + red[w][lane + 128] + red[w][lane + 192];
    #pragma unroll
    for (int off = 32; off; off >>= 1) s += __shfl_xor(s, off);
    if (lane == 0) sss[w] = s;
  }
  __syncthreads();
  {
    int g = t >> 6, d = t & 63;
    float a0 = 0.f, a1 = 0.f, a2 = 0.f, a3 = 0.f;
    for (int c = g; c < Lk; c += 4) {
      float v = Vp[(size_t)(b * Lk + c) * vstr + (h << 6) + d];
      a0 += sc[0][c] * v; a1 += sc[1][c] * v; a2 += sc[2][c] * v; a3 += sc[3][c] * v;
    }
    pv[g][0][d] = a0; pv[g][1][d] = a1; pv[g][2][d] = a2; pv[g][3][d] = a3;
  }
  __syncthreads();
  {
    int r = t >> 6, d = t & 63;
    int row = rowsh[r];
    if (row >= 0) {
      float s = (pv[0][r][d] + pv[1][r][d] + pv[2][r][d] + pv[3][r][d]) / sss[r];
      emit_split(s, AOh, AOl, ((size_t)(b * Lq + row) << 9) + (h << 6) + d);
    }
  }
}

// ---------------- maxpool w3 s2 p1 along L (split-only output) ----------------
__global__ void k_maxpool(const float* __restrict__ y, f16* __restrict__ oh,
                          f16* __restrict__ ol, int L) {
  int Lo = L >> 1;
  int i = blockIdx.x * 256 + threadIdx.x;
  int c = i & 511; int bj = i >> 9;
  int j = bj % Lo; int b = bj / Lo;
  float m = -INFINITY;
  int t0 = 2 * j - 1;
  #pragma unroll
  for (int k = 0; k < 3; ++k) {
    int tt = t0 + k;
    if (tt >= 0 && tt < L) m = fmaxf(m, y[((size_t)(b * L + tt) << 9) + c]);
  }
  emit_split(m, oh, ol, ((size_t)(b * Lo + j) << 9) + c);
}

// ---------------- final projection 512->7 (reads f32 from Y) ----------------
__global__ void k_proj(const float* __restrict__ Xn, const float* __restrict__ pw,
                       const float* __restrict__ pb, float* __restrict__ out) {
  int i = blockIdx.x * 256 + threadIdx.x;
  if (i >= 16 * 512 * 7) return;
  int c = i % 7; int r = i / 7;
  int b = r >> 9; int j = r & 511;
  const float* xr = Xn + ((size_t)(b * 1024 + 512 + j) << 9);
  float acc = pb[c];
  for (int d2 = 0; d2 < 512; ++d2) acc += xr[d2] * pw[d2 * 7 + c];
  out[i] = acc;
}

// =====================================================================
extern "C" void kernel_launch(void* const* d_in, const int* in_sizes, int n_in,
                              void* d_out, int out_size, void* d_ws, size_t ws_size,
                              hipStream_t stream) {
  const float* x_enc      = (const float*)d_in[0];
  const float* x_mark_enc = (const float*)d_in[1];
  const float* x_dec      = (const float*)d_in[2];
  const float* x_mark_dec = (const float*)d_in[3];
  const float* enc_tok_w  = (const float*)d_in[4];
  const float* enc_mark_w = (const float*)d_in[5];
  const float* dec_tok_w  = (const float*)d_in[6];
  const float* dec_mark_w = (const float*)d_in[7];
  const float* enc_attn_w = (const float*)d_in[8];
  const float* enc_attn_b = (const float*)d_in[9];
  const float* enc_ffn1_w = (const float*)d_in[10];
  const float* enc_ffn1_b = (const float*)d_in[11];
  const float* enc_ffn2_w = (const float*)d_in[12];
  const float* enc_ffn2_b = (const float*)d_in[13];
  const float* enc_ln_g   = (const float*)d_in[14];
  const float* enc_ln_b   = (const float*)d_in[15];
  const float* distil_w   = (const float*)d_in[16];
  const float* distil_b   = (const float*)d_in[17];
  const float* distil_bn_g= (const float*)d_in[18];
  const float* distil_bn_b= (const float*)d_in[19];
  const float* enc_norm_g = (const float*)d_in[20];
  const float* enc_norm_b = (const float*)d_in[21];
  const float* dec_self_w = (const float*)d_in[22];
  const float* dec_self_b = (const float*)d_in[23];
  const float* dec_cross_w= (const float*)d_in[24];
  const float* dec_cross_b= (const float*)d_in[25];
  const float* dec_ffn1_w = (const float*)d_in[26];
  const float* dec_ffn1_b = (const float*)d_in[27];
  const float* dec_ffn2_w = (const float*)d_in[28];
  const float* dec_ffn2_b = (const float*)d_in[29];
  const float* dec_ln_g   = (const float*)d_in[30];
  const float* dec_ln_b   = (const float*)d_in[31];
  const float* dec_norm_g = (const float*)d_in[32];
  const float* dec_norm_b = (const float*)d_in[33];
  const float* proj_w     = (const float*)d_in[34];
  const float* proj_b     = (const float*)d_in[35];

  // -------- workspace layout: split-only activations, ~168 MB --------
  float* ws = (float*)d_ws;
  size_t off = 0;
  f16* Xh   = (f16*)(ws + off); off += 16777216;
  f16* Xl   = Xh + 16777216;
  f16* ENCh = (f16*)(ws + off); off += 4194304;
  f16* ENCl = ENCh + 4194304;
  float* PE = ws + off; off += 1048576;
  float* Mb = ws + off; off += 65536;
  float* PS = ws + off; off += 32768;
  float* MPm = ws + off; off += 524288;
  float* MPs = ws + off; off += 524288;
  f16* WSP  = (f16*)(ws + off); off += 2097152;
  int* IDXi = (int*)(ws + off); off += 83200;
  float* Y  = ws + off; off += 16777216;
  int* MTi  = IDXi + 81920;
  if (ws_size < off * 4) return;
  f16* Yh = (f16*)Y;
  f16* Yl = Yh + 16777216;
  const int bs = 4;

  auto ln = [&](const f16* xh, const f16* xl, const float* g, const float* b, int rows,
                float* of32, f16* oh, f16* ol) {
    k_ln<<<rows, 256, 0, stream>>>(xh, xl, g, b, of32, oh, ol);
  };
  auto wsplit = [&](const float* W, f16* Wh, f16* Wl, int K, int N, int nmat) {
    dim3 g(K >> 5, N >> 5, nmat);
    k_wsplit<<<g, 256, 0, stream>>>(W, Wh, Wl, K, N);
  };
  auto mgQ = [&](const f16* Ah, const f16* Al, const f16* Wh, const f16* Wl,
                 const float* bias, float* C, int M, int N, int K) {
    dim3 g(N >> 7, M >> 7);
    k_mgemm2<0,0,0,0><<<g, 256, 0, stream>>>(Ah, Al, Wh, Wl, bias, nullptr, nullptr,
        nullptr, nullptr, C, nullptr, nullptr, M, N, K, 0);
  };
  auto mgR = [&](const f16* Ah, const f16* Al, const f16* Wh, const f16* Wl,
                 const float* bias, const f16* Rh, const f16* Rl,
                 f16* Ch, f16* Cl, int M, int N, int K) {
    dim3 g(N >> 7, M >> 7);
    k_mgemm2<0,1,0,1><<<g, 256, 0, stream>>>(Ah, Al, Wh, Wl, bias, Rh, Rl,
        nullptr, nullptr, nullptr, Ch, Cl, M, N, K, 0);
  };
  auto mgG = [&](const f16* Ah, const f16* Al, const f16* Wh, const f16* Wl,
                 const float* bias, f16* Ch, f16* Cl, int M, int N, int K) {
    dim3 g(N >> 7, M >> 7);
    k_mgemm2<1,1,0,0><<<g, 256, 0, stream>>>(Ah, Al, Wh, Wl, bias, nullptr, nullptr,
        nullptr, nullptr, nullptr, Ch, Cl, M, N, K, 0);
  };
  auto Uof = [](int Lx) { int v = 5 * (int)ceil(log((double)Lx)); return v < Lx ? v : Lx; };

  auto attn = [&](f16* xqh, f16* xql, const f16* xkvh, const f16* xkvl,
                  int Lq, int Lk, const float* w, const float* bias,
                  bool masked, u32 fold, bool selfa) {
    int U = Uof(Lk), uu = Uof(Lq);
    u32 r0, r1, ka, kb2;
    tf_block(0u, 42u, 0u, fold, r0, r1);
    tf_block(r0, r1, 0u, 1u, ka, kb2);
    int n = Lq * U;
    k_idx<<<(n + 255) / 256, 256, 0, stream>>>(ka, kb2, n, Lk - 1, IDXi);

    f16 *Wqkvh = WSP,            *Wqkvl = WSP + 786432;
    f16 *WQh   = WSP,            *WQl   = WSP + 262144;
    f16 *WKVh  = WSP + 524288,   *WKVl  = WSP + 1048576;
    f16 *WOh   = WSP + 1572864,  *WOl   = WSP + 1835008;
    if (selfa) {
      wsplit(w, Wqkvh, Wqkvl, 512, 512, 3);
    } else {
      wsplit(w, WQh, WQl, 512, 512, 1);
      wsplit(w + 262144, WKVh, WKVl, 512, 512, 2);
    }
    wsplit(w + 786432, WOh, WOl, 512, 512, 1);

    int nsl = 16 / bs;
    for (int s = 0; s < nsl; ++s) {
      size_t qoff = (size_t)s * bs * Lq * 512;
      size_t koff = (size_t)s * bs * Lk * 512;
      const float *qp, *kp, *vp;
      int qstr, kstr, vstr;
      f16 *AOh, *AOl;
      if (selfa) {
        float* QKV = Y;
        AOh = (f16*)(Y + (size_t)bs * Lq * 1536);
        AOl = AOh + (size_t)bs * Lq * 512;
        mgQ(xqh + qoff, xql + qoff, Wqkvh, Wqkvl, bias, QKV, bs * Lq, 1536, 512);
        qp = QKV; qstr = 1536; kp = QKV + 512; kstr = 1536; vp = QKV + 1024; vstr = 1536;
      } else {
        float* Qb  = Y;
        float* KVb = Y + (size_t)bs * Lq * 512;
        AOh = (f16*)(KVb + (size_t)bs * Lk * 1024);
        AOl = AOh + (size_t)bs * Lq * 512;
        mgQ(xqh + qoff, xql + qoff, WQh, WQl, bias, Qb, bs * Lq, 512, 512);
        mgQ(xkvh + koff, xkvl + koff, WKVh, WKVl, bias + 512, KVb, bs * Lk, 1024, 512);
        qp = Qb; qstr = 512; kp = KVb; kstr = 1024; vp = KVb + 512; vstr = 1024;
      }
      int nch = Lk >> 8;
      dim3 gq(nch, bs * 8);
      k_qkM2<<<gq, 256, 0, stream>>>(qp, qstr, kp, kstr, IDXi, MPm, MPs, Lq, Lk, U);
      int tot = bs * 8 * Lq;
      k_qkMc<<<tot / 256, 256, 0, stream>>>(MPm, MPs, Mb, nch, tot, Lk);
      k_topk64<<<bs * 8, 64, 0, stream>>>(Mb, MTi, Lq, uu);
      if (masked) {
        k_cs1<<<bs * 8 * 8, 64, 0, stream>>>(vp, vstr, PS, Lq, Lq >> 3);
        k_cs3<<<bs * 8 * 8, 64, 0, stream>>>(vp, vstr, PS, AOh, AOl, Lq, Lq >> 3);
      } else {
        k_cm1<<<bs * 8 * 16, 64, 0, stream>>>(vp, vstr, PS, Lk, Lk >> 4);
        int tot2 = bs * Lq * 512;
        k_cm2<<<tot2 / 256, 256, 0, stream>>>(PS, AOh, AOl, 1.0f / (float)Lk, Lq, tot2);
      }
      int nbb = (uu + 3) >> 2;
      k_sattn4<<<bs * 8 * nbb, 256, 0, stream>>>(qp, qstr, kp, kstr, vp, vstr, MTi, AOh, AOl,
                                                 Lq, Lk, uu, masked ? 1 : 0);
      mgR(AOh, AOl, WOh, WOl, bias + 1536, xqh + qoff, xql + qoff,
          xqh + qoff, xql + qoff, bs * Lq, 512, 512);
    }
  };

  auto ffn = [&](f16* xh, f16* xl, const float* w1, const float* b1,
                 const float* w2, const float* b2, int Mtot) {
    f16 *W1h = WSP,           *W1l = WSP + 1048576,
        *W2h = WSP + 2097152, *W2l = WSP + 3145728;
    wsplit(w1, W1h, W1l, 512, 2048, 1);
    wsplit(w2, W2h, W2l, 2048, 512, 1);
    for (int c0 = 0; c0 < Mtot; c0 += 8192) {
      int rows = (Mtot - c0 < 8192) ? (Mtot - c0) : 8192;
      mgG(xh + (size_t)c0 * 512, xl + (size_t)c0 * 512, W1h, W1l, b1, Yh, Yl, rows, 2048, 512);
      mgR(Yh, Yl, W2h, W2l, b2, xh + (size_t)c0 * 512, xl + (size_t)c0 * 512,
          xh + (size_t)c0 * 512, xl + (size_t)c0 * 512, rows, 512, 2048);
    }
  };

  // ---------------- encoder ----------------
  k_pe<<<(2048 * 512) / 256, 256, 0, stream>>>(PE);
  k_embed<<<(16 * 2048 * 512) / 256, 256, 0, stream>>>(x_enc, x_mark_enc, enc_tok_w, enc_mark_w,
                                                       PE, Xh, Xl, 2048, 16 * 2048 * 512);
  int L = 2048;
  for (int l = 0; l < 3; ++l) {
    attn(Xh, Xl, Xh, Xl, L, L, enc_attn_w + (size_t)l * 4 * 262144,
         enc_attn_b + (size_t)l * 2048, false, (u32)l, true);
    ln(Xh, Xl, enc_ln_g + (size_t)(l * 2) * 512, enc_ln_b + (size_t)(l * 2) * 512, 16 * L,
       nullptr, Xh, Xl);
    ffn(Xh, Xl, enc_ffn1_w + (size_t)l * 512 * 2048, enc_ffn1_b + (size_t)l * 2048,
        enc_ffn2_w + (size_t)l * 2048 * 512, enc_ffn2_b + (size_t)l * 512, 16 * L);
    ln(Xh, Xl, enc_ln_g + (size_t)(l * 2 + 1) * 512, enc_ln_b + (size_t)(l * 2 + 1) * 512, 16 * L,
       nullptr, Xh, Xl);
    if (l < 2) {
      f16 *Dh = WSP, *Dl = WSP + 786432;
      k_wsplit_conv<<<(512 * 1536) / 256, 256, 0, stream>>>(distil_w + (size_t)l * 512 * 512 * 3, Dh, Dl);
      dim3 g(512 >> 7, (16 * L) >> 7);
      int lgL = (L == 2048) ? 11 : 10;
      k_mgemm2<2,0,1,0><<<g, 256, 0, stream>>>(Xh, Xl, Dh, Dl, distil_b + (size_t)l * 512,
          nullptr, nullptr, distil_bn_g + (size_t)l * 512, distil_bn_b + (size_t)l * 512,
          Y, nullptr, nullptr, 16 * L, 512, 1536, lgL);
      int Lo = L >> 1;
      k_maxpool<<<(16 * Lo * 512) / 256, 256, 0, stream>>>(Y, Xh, Xl, L);
      L = Lo;
    }
  }
  ln(Xh, Xl, enc_norm_g, enc_norm_b, 16 * 512, nullptr, ENCh, ENCl);

  // ---------------- decoder (in-place chain in Xh/Xl) ----------------
  k_embed<<<(16 * 1024 * 512) / 256, 256, 0, stream>>>(x_dec, x_mark_dec, dec_tok_w, dec_mark_w,
                                                       PE, Xh, Xl, 1024, 16 * 1024 * 512);
  for (int l = 0; l < 2; ++l) {
    attn(Xh, Xl, Xh, Xl, 1024, 1024, dec_self_w + (size_t)l * 4 * 262144,
         dec_self_b + (size_t)l * 2048, true, (u32)(100 + 2 * l), true);
    ln(Xh, Xl, dec_ln_g + (size_t)(l * 3) * 512, dec_ln_b + (size_t)(l * 3) * 512, 16384,
       nullptr, Xh, Xl);
    attn(Xh, Xl, ENCh, ENCl, 1024, 512, dec_cross_w + (size_t)l * 4 * 262144,
         dec_cross_b + (size_t)l * 2048, false, (u32)(101 + 2 * l), false);
    ln(Xh, Xl, dec_ln_g + (size_t)(l * 3 + 1) * 512, dec_ln_b + (size_t)(l * 3 + 1) * 512, 16384,
       nullptr, Xh, Xl);
    ffn(Xh, Xl, dec_ffn1_w + (size_t)l * 512 * 2048, dec_ffn1_b + (size_t)l * 2048,
        dec_ffn2_w + (size_t)l * 2048 * 512, dec_ffn2_b + (size_t)l * 512, 16384);
    ln(Xh, Xl, dec_ln_g + (size_t)(l * 3 + 2) * 512, dec_ln_b + (size_t)(l * 3 + 2) * 512, 16384,
       nullptr, Xh, Xl);
  }
  ln(Xh, Xl, dec_norm_g, dec_norm_b, 16384, Y, nullptr, nullptr);
  k_proj<<<(16 * 512 * 7 + 255) / 256, 256, 0, stream>>>(Y, proj_w, proj_b, (float*)d_out);
}

// Round 15
// 12838.676 us; speedup vs baseline: 1.5867x; 1.5867x over previous
//
#include <hip/hip_runtime.h>
#include <math.h>
#include <stdint.h>

typedef unsigned int u32;
typedef _Float16 f16;
typedef __attribute__((ext_vector_type(8))) _Float16 f16x8;
typedef __attribute__((ext_vector_type(4))) float f32x4;

// ---------------- Threefry-2x32 (20 rounds), matches JAX ----------------
__host__ __device__ __forceinline__ u32 rotl32(u32 x, int r) { return (x << r) | (x >> (32 - r)); }
__host__ __device__ __forceinline__ void tf_round(u32& x0, u32& x1, int r) {
  x0 += x1; x1 = rotl32(x1, r); x1 ^= x0;
}
__host__ __device__ __forceinline__ void tf_block(u32 k0, u32 k1, u32 x0, u32 x1, u32& o0, u32& o1) {
  u32 k2 = k0 ^ k1 ^ 0x1BD11BDAu;
  x0 += k0; x1 += k1;
  tf_round(x0,x1,13); tf_round(x0,x1,15); tf_round(x0,x1,26); tf_round(x0,x1,6);
  x0 += k1; x1 += k2 + 1u;
  tf_round(x0,x1,17); tf_round(x0,x1,29); tf_round(x0,x1,16); tf_round(x0,x1,24);
  x0 += k2; x1 += k0 + 2u;
  tf_round(x0,x1,13); tf_round(x0,x1,15); tf_round(x0,x1,26); tf_round(x0,x1,6);
  x0 += k0; x1 += k1 + 3u;
  tf_round(x0,x1,17); tf_round(x0,x1,29); tf_round(x0,x1,16); tf_round(x0,x1,24);
  x0 += k1; x1 += k2 + 4u;
  tf_round(x0,x1,13); tf_round(x0,x1,15); tf_round(x0,x1,26); tf_round(x0,x1,6);
  x0 += k2; x1 += k0 + 5u;
  o0 = x0; o1 = x1;
}

__global__ void k_idx(u32 ka, u32 kb, int n, int mask, int* __restrict__ idx) {
  int i = blockIdx.x * 256 + threadIdx.x;
  if (i >= n) return;
  u32 b1, b2; tf_block(ka, kb, 0u, (u32)i, b1, b2);
  idx[i] = (int)((b1 ^ b2) & (u32)mask);
}

__device__ __forceinline__ void emit_split(float v, f16* __restrict__ oh,
                                           f16* __restrict__ ol, size_t o) {
  f16 h = (f16)v;
  oh[o] = h;
  ol[o] = (f16)((v - (float)h) * 2048.0f);
}
__device__ __forceinline__ float rsplit(const f16* __restrict__ h,
                                        const f16* __restrict__ l, size_t o) {
  return (float)h[o] + (float)l[o] * (1.0f / 2048.0f);
}

// ---------------- positional embedding ----------------
__global__ void k_pe(float* __restrict__ pe) {
  int i = blockIdx.x * 256 + threadIdx.x;
  if (i >= 2048 * 512) return;
  int t = i >> 9, o = i & 511;
  float arg = (float)((o >> 1) * 2) * (float)(-(log(10000.0) / 512.0));
  float div = (float)exp((double)arg);
  float ang32 = (float)t * div;
  double ang = (double)ang32;
  pe[i] = (float)((o & 1) ? cos(ang) : sin(ang));
}

// ---------------- embedding (split-only output) ----------------
__global__ __launch_bounds__(256) void k_embed(
    const float* __restrict__ x, const float* __restrict__ mark,
    const float* __restrict__ tw, const float* __restrict__ mw,
    const float* __restrict__ pe, f16* __restrict__ oh, f16* __restrict__ ol,
    int L, int total) {
  int i = blockIdx.x * 256 + threadIdx.x;
  if (i >= total) return;
  int oo = i & 511;
  int bt = i >> 9;
  int t = bt % L;
  int b = bt / L;
  float acc = pe[(t << 9) + oo];
  #pragma unroll
  for (int k = 0; k < 3; ++k) {
    int st = t + k - 1; if (st < 0) st += L; else if (st >= L) st -= L;
    const float* xr = x + (size_t)(b * L + st) * 7;
    const float* wr = tw + oo * 21 + k;
    #pragma unroll
    for (int ii = 0; ii < 7; ++ii) acc += xr[ii] * wr[ii * 3];
  }
  const float* mr = mark + (size_t)bt * 4;
  #pragma unroll
  for (int m = 0; m < 4; ++m) acc += mr[m] * mw[(m << 9) + oo];
  emit_split(acc, oh, ol, ((size_t)bt << 9) + oo);
}

// ---------------- weight transpose + f16 split (z = matrix index) ----------------
__global__ __launch_bounds__(256) void k_wsplit(const float* __restrict__ W,
    f16* __restrict__ Wh, f16* __restrict__ Wl, int K, int N) {
  size_t zo = (size_t)blockIdx.z * K * N;
  W += zo; Wh += zo; Wl += zo;
  __shared__ float tile[32][33];
  int kb = blockIdx.x << 5, nb = blockIdx.y << 5;
  int t = threadIdx.x;
  int tr = t >> 5, tc = t & 31;
  #pragma unroll
  for (int p = 0; p < 4; ++p)
    tile[tr + p * 8][tc] = W[(size_t)(kb + tr + p * 8) * N + nb + tc];
  __syncthreads();
  #pragma unroll
  for (int p = 0; p < 4; ++p) {
    int n = tr + p * 8, k = tc;
    float v = tile[k][n];
    f16 h = (f16)v;
    size_t o = (size_t)(nb + n) * K + kb + k;
    Wh[o] = h;
    Wl[o] = (f16)((v - (float)h) * 2048.0f);
  }
}

__global__ void k_wsplit_conv(const float* __restrict__ w, f16* __restrict__ Wh, f16* __restrict__ Wl) {
  int i = blockIdx.x * 256 + threadIdx.x;
  if (i >= 512 * 1536) return;
  int o = i / 1536, k = i - o * 1536;
  float v = w[(size_t)o * 1536 + (k & 511) * 3 + (k >> 9)];
  f16 h = (f16)v;
  Wh[i] = h;
  Wl[i] = (f16)((v - (float)h) * 2048.0f);
}

__device__ __forceinline__ int swz_x(int r) { return ((((r >> 1) & 3) ^ ((r >> 3) & 3)) << 4); }

__device__ __forceinline__ void gload16(const void* g, void* l) {
  __builtin_amdgcn_global_load_lds(
      (const __attribute__((address_space(1))) void*)g,
      (__attribute__((address_space(3))) void*)l, 16, 0, 0);
}

// ---------------- MFMA GEMM v2: pre-split f16 A/B, async LDS, dbuf, 16x16x32 ----------------
// ACT: 0 none, 1 gelu, 2 bn+elu. OSPLIT: C as split pair. GATHER: circular distil rows.
// RESID: add residual reconstructed from split pair Rh/Rl.
// Block->tile mapping is XCD-swizzled (bijective when nwg%8==0) for L2 locality.
template<int ACT, int OSPLIT, int GATHER, int RESID>
__global__ __launch_bounds__(256, 2) void k_mgemm2(
    const f16* __restrict__ Ah, const f16* __restrict__ Al,
    const f16* __restrict__ Bh, const f16* __restrict__ Bl,
    const float* __restrict__ bias,
    const f16* __restrict__ Rh, const f16* __restrict__ Rl,
    const float* __restrict__ bns, const float* __restrict__ bnb,
    float* __restrict__ C, f16* __restrict__ Ch, f16* __restrict__ Cl,
    int M, int N, int K, int lgL) {
  __shared__ char lds[65536];
  const int t = threadIdx.x;
  int nwg = gridDim.x * gridDim.y;
  int bid = blockIdx.y * gridDim.x + blockIdx.x;
  if ((nwg & 7) == 0) {
    int cpx = nwg >> 3;
    bid = (bid & 7) * cpx + (bid >> 3);
  }
  const int bm = (bid / gridDim.x) << 7, bn = (bid % gridDim.x) << 7;
  const int w = t >> 6, l = t & 63;
  const int lr = l >> 2;
  const int qx = (l & 3) << 4;
  const int wr = (w >> 1) << 6, wc = (w & 1) << 6;
  const int fr = l & 15;
  const int fkB = (l >> 4) << 4;
  const f32x4 zero = {0.f, 0.f, 0.f, 0.f};
  f32x4 acc1[4][4], acc2[4][4];
  #pragma unroll
  for (int i = 0; i < 4; ++i)
    #pragma unroll
    for (int j = 0; j < 4; ++j) { acc1[i][j] = zero; acc2[i][j] = zero; }

  auto stage = [&](int k0, int bufo) {
    #pragma unroll
    for (int c = 0; c < 2; ++c) {
      int r = w * 32 + c * 16 + lr;
      int sx = qx ^ swz_x(r);
      const char *gAh, *gAl;
      if (GATHER) {
        int m = bm + r;
        int Lm = 1 << lgL;
        int ab = m >> lgL, at = m & (Lm - 1);
        int ke = k0 + (sx >> 1);
        int tap = ke >> 9, ii = ke & 511;
        int st = at + tap - 1; if (st < 0) st += Lm; else if (st >= Lm) st -= Lm;
        size_t aoff = (((size_t)((ab << lgL) + st)) << 9) + ii;
        gAh = (const char*)(Ah + aoff);
        gAl = (const char*)(Al + aoff);
      } else {
        gAh = (const char*)(Ah + (size_t)(bm + r) * K + k0) + sx;
        gAl = (const char*)(Al + (size_t)(bm + r) * K + k0) + sx;
      }
      const char* gBh = (const char*)(Bh + (size_t)(bn + r) * K + k0) + sx;
      const char* gBl = (const char*)(Bl + (size_t)(bn + r) * K + k0) + sx;
      char* base = lds + bufo + w * 2048 + c * 1024;
      gload16(gAh, base);
      gload16(gAl, base + 8192);
      gload16(gBh, base + 16384);
      gload16(gBl, base + 24576);
    }
  };

  int nt = K >> 5;
  stage(0, 0);
  __syncthreads();
  int bufo = 0;
  for (int tt = 0; tt < nt; ++tt) {
    int nb = bufo ^ 32768;
    if (tt + 1 < nt) stage((tt + 1) << 5, nb);
    char* pAh = lds + bufo;
    char* pAl = pAh + 8192;
    char* pBh = pAh + 16384;
    char* pBl = pAh + 24576;
    f16x8 ah4[4], al4[4];
    #pragma unroll
    for (int i = 0; i < 4; ++i) {
      int r = wr + i * 16 + fr;
      int ob = r * 64 + (fkB ^ swz_x(r));
      ah4[i] = *(f16x8*)(pAh + ob);
      al4[i] = *(f16x8*)(pAl + ob);
    }
    #pragma unroll
    for (int j = 0; j < 4; ++j) {
      int r = wc + j * 16 + fr;
      int ob = r * 64 + (fkB ^ swz_x(r));
      f16x8 bh_ = *(f16x8*)(pBh + ob);
      f16x8 bl_ = *(f16x8*)(pBl + ob);
      #pragma unroll
      for (int i = 0; i < 4; ++i) {
        acc1[i][j] = __builtin_amdgcn_mfma_f32_16x16x32_f16(ah4[i], bh_, acc1[i][j], 0, 0, 0);
        acc2[i][j] = __builtin_amdgcn_mfma_f32_16x16x32_f16(ah4[i], bl_, acc2[i][j], 0, 0, 0);
        acc2[i][j] = __builtin_amdgcn_mfma_f32_16x16x32_f16(al4[i], bh_, acc2[i][j], 0, 0, 0);
      }
    }
    __syncthreads();
    bufo = nb;
  }
  #pragma unroll
  for (int j = 0; j < 4; ++j) {
    int col = bn + wc + j * 16 + fr;
    float bsv = bias[col];
    float g2 = 0.f, b2 = 0.f;
    if (ACT == 2) { g2 = bns[col] * 0.9999950000375f; b2 = bnb[col]; }
    #pragma unroll
    for (int i = 0; i < 4; ++i) {
      #pragma unroll
      for (int r = 0; r < 4; ++r) {
        int row = bm + wr + i * 16 + ((l >> 4) << 2) + r;
        float v = acc1[i][j][r] + acc2[i][j][r] * (1.0f / 2048.0f) + bsv;
        if (ACT == 1) v = 0.5f * v * (1.0f + erff(v * 0.70710678118654752f));
        if (ACT == 2) { v = v * g2 + b2; v = v > 0.f ? v : expm1f(v); }
        size_t oi = (size_t)row * N + col;
        if (RESID) v += rsplit(Rh, Rl, oi);
        if (OSPLIT) emit_split(v, Ch, Cl, oi);
        else        C[oi] = v;
      }
    }
  }
}

// ---------------- LayerNorm on split input; optional split / f32 outputs ----------------
__global__ __launch_bounds__(256) void k_ln(const f16* __restrict__ xh, const f16* __restrict__ xl,
    const float* __restrict__ g, const float* __restrict__ b,
    float* __restrict__ of32, f16* __restrict__ oh, f16* __restrict__ ol) {
  int row = blockIdx.x, t = threadIdx.x;
  size_t base = (size_t)row << 9;
  float v0 = rsplit(xh, xl, base + t);
  float v1 = rsplit(xh, xl, base + t + 256);
  float s = v0 + v1;
  #pragma unroll
  for (int off = 32; off; off >>= 1) s += __shfl_down(s, off);
  __shared__ float ls[4];
  if ((t & 63) == 0) ls[t >> 6] = s;
  __syncthreads();
  float mean = (ls[0] + ls[1] + ls[2] + ls[3]) * (1.f / 512.f);
  __syncthreads();
  float d0 = v0 - mean, d1 = v1 - mean;
  float q = d0 * d0 + d1 * d1;
  #pragma unroll
  for (int off = 32; off; off >>= 1) q += __shfl_down(q, off);
  if ((t & 63) == 0) ls[t >> 6] = q;
  __syncthreads();
  float var = (ls[0] + ls[1] + ls[2] + ls[3]) * (1.f / 512.f);
  float rs = rsqrtf(var + 1e-5f);
  float r0 = d0 * rs * g[t] + b[t];
  float r1 = d1 * rs * g[t + 256] + b[t + 256];
  if (of32) { of32[base + t] = r0; of32[base + t + 256] = r1; }
  if (oh) {
    emit_split(r0, oh, ol, base + t);
    emit_split(r1, oh, ol, base + t + 256);
  }
}

// ---------------- M[bh,l] scoring (strided Q/K) ----------------
__global__ __launch_bounds__(256) void k_qkM(const float* __restrict__ Q, int qstr,
    const float* __restrict__ Kp, int kstr, const int* __restrict__ idx,
    float* __restrict__ M, int Lq, int Lk, int U) {
  int wid = (blockIdx.x * 256 + threadIdx.x) >> 6;
  int lane = threadIdx.x & 63;
  int l = wid & (Lq - 1); int bh = wid / Lq; int h = bh & 7; int b = bh >> 3;
  float dot = 0.f;
  if (lane < U) {
    int kr = idx[l * U + lane];
    const float4* q4 = (const float4*)(Q + (size_t)(b * Lq + l) * qstr + (h << 6));
    const float4* k4 = (const float4*)(Kp + (size_t)(b * Lk + kr) * kstr + (h << 6));
    #pragma unroll
    for (int i = 0; i < 16; ++i) {
      float4 a = q4[i], c = k4[i];
      dot += a.x * c.x + a.y * c.y + a.z * c.z + a.w * c.w;
    }
  }
  float mx = (lane < U) ? dot : -INFINITY;
  float sm = (lane < U) ? dot : 0.f;
  #pragma unroll
  for (int off = 32; off; off >>= 1) {
    mx = fmaxf(mx, __shfl_xor(mx, off));
    sm += __shfl_xor(sm, off);
  }
  if (lane == 0) M[(size_t)bh * Lq + l] = mx - sm / (float)Lk;
}

// ---------------- single-wave top-u per (b,h), ties -> lower index ----------------
__global__ void k_topk64(const float* __restrict__ M, int* __restrict__ mtop, int Lq, int u) {
  __shared__ float vals[2048];
  int bh = blockIdx.x, l = threadIdx.x;
  const float* Mr = M + (size_t)bh * Lq;
  for (int i = l; i < Lq; i += 64) vals[i] = Mr[i];
  __syncthreads();
  for (int it = 0; it < u; ++it) {
    float bv = -INFINITY; int bi = 0x7fffffff;
    for (int i = l; i < Lq; i += 64) {
      float v = vals[i];
      if (v > bv || (v == bv && i < bi)) { bv = v; bi = i; }
    }
    #pragma unroll
    for (int off = 32; off; off >>= 1) {
      float vv = __shfl_xor(bv, off); int ii = __shfl_xor(bi, off);
      if (vv > bv || (vv == bv && ii < bi)) { bv = vv; bi = ii; }
    }
    if (l == 0) { mtop[bh * u + it] = bi; vals[bi] = -INFINITY; }
    __syncthreads();
  }
}

// ---------------- ctx mean (AO split) ----------------
__global__ void k_cm1(const float* __restrict__ V, int vstr, float* __restrict__ PS,
                      int Lk, int rows) {
  int bid = blockIdx.x;
  int bh = bid >> 4, seg = bid & 15, d = threadIdx.x;
  int b = bh >> 3, h = bh & 7;
  const float* vp = V + (size_t)(b * Lk + seg * rows) * vstr + (h << 6) + d;
  float acc = 0.f;
  for (int r = 0; r < rows; ++r) acc += vp[(size_t)r * vstr];
  PS[(bid << 6) + d] = acc;
}
__global__ void k_cm2(const float* __restrict__ PS, f16* __restrict__ AOh,
                      f16* __restrict__ AOl, float invLk, int Lq, int total) {
  int i = blockIdx.x * 256 + threadIdx.x;
  if (i >= total) return;
  int c = i & 511; int h = c >> 6; int d = c & 63;
  int r = i >> 9; int b = r / Lq;
  float acc = 0.f;
  #pragma unroll
  for (int s = 0; s < 16; ++s) acc += PS[(((((b << 3) + h) << 4) + s) << 6) + d];
  emit_split(acc * invLk, AOh, AOl, (size_t)i);
}

// ---------------- cumsum (masked ctx; per-block prefix, AO split) ----------------
__global__ void k_cs1(const float* __restrict__ V, int vstr, float* __restrict__ PS,
                      int Lq, int rows) {
  int bid = blockIdx.x;
  int bh = bid >> 3, seg = bid & 7, d = threadIdx.x;
  int b = bh >> 3, h = bh & 7;
  const float* vp = V + (size_t)(b * Lq + seg * rows) * vstr + (h << 6) + d;
  float acc = 0.f;
  for (int r = 0; r < rows; ++r) acc += vp[(size_t)r * vstr];
  PS[(bid << 6) + d] = acc;
}
__global__ void k_cs3(const float* __restrict__ V, int vstr, const float* __restrict__ PS,
                      f16* __restrict__ AOh, f16* __restrict__ AOl, int Lq, int rows) {
  int bid = blockIdx.x;
  int bh = bid >> 3, seg = bid & 7, d = threadIdx.x;
  int b = bh >> 3, h = bh & 7;
  float acc = 0.f;
  for (int s2 = 0; s2 < seg; ++s2) acc += PS[(((bh << 3) + s2) << 6) + d];
  const float* vp = V + (size_t)(b * Lq + seg * rows) * vstr + (h << 6) + d;
  size_t ob = ((size_t)(b * Lq + seg * rows) << 9) + (h << 6) + d;
  for (int r = 0; r < rows; ++r) {
    acc += vp[(size_t)r * vstr];
    emit_split(acc, AOh, AOl, ob + ((size_t)r << 9));
  }
}

// ---------------- sparse attn: 4 selected rows per block (AO split) ----------------
__global__ __launch_bounds__(256) void k_sattn4(
    const float* __restrict__ Q, int qstr, const float* __restrict__ Kp, int kstr,
    const float* __restrict__ Vp, int vstr, const int* __restrict__ mtop,
    f16* __restrict__ AOh, f16* __restrict__ AOl, int Lq, int Lk, int u, int masked) {
  __shared__ float sc[4][2048];
  __shared__ float qs[4][64];
  __shared__ float red[4][256];
  __shared__ float pv[4][4][64];
  __shared__ int rowsh[4];
  __shared__ float mxs[4], sss[4];
  int nb = (u + 3) >> 2;
  int ub = blockIdx.x % nb, bh = blockIdx.x / nb;
  int b = bh >> 3, h = bh & 7;
  int t = threadIdx.x;
  if (t < 4) {
    int ui = ub * 4 + t;
    rowsh[t] = (ui < u) ? mtop[bh * u + ui] : -1;
  }
  __syncthreads();
  {
    int r = t >> 6, d = t & 63;
    int row = rowsh[r];
    qs[r][d] = (row >= 0) ? Q[(size_t)(b * Lq + row) * qstr + (h << 6) + d] : 0.f;
  }
  __syncthreads();
  float lm0 = -INFINITY, lm1 = -INFINITY, lm2 = -INFINITY, lm3 = -INFINITY;
  for (int c = t; c < Lk; c += 256) {
    const float4* kr = (const float4*)(Kp + (size_t)(b * Lk + c) * kstr + (h << 6));
    float d0 = 0.f, d1 = 0.f, d2 = 0.f, d3 = 0.f;
    #pragma unroll
    for (int e = 0; e < 16; ++e) {
      float4 kk = kr[e];
      d0 += qs[0][4*e]*kk.x + qs[0][4*e+1]*kk.y + qs[0][4*e+2]*kk.z + qs[0][4*e+3]*kk.w;
      d1 += qs[1][4*e]*kk.x + qs[1][4*e+1]*kk.y + qs[1][4*e+2]*kk.z + qs[1][4*e+3]*kk.w;
      d2 += qs[2][4*e]*kk.x + qs[2][4*e+1]*kk.y + qs[2][4*e+2]*kk.z + qs[2][4*e+3]*kk.w;
      d3 += qs[3][4*e]*kk.x + qs[3][4*e+1]*kk.y + qs[3][4*e+2]*kk.z + qs[3][4*e+3]*kk.w;
    }
    float dd[4] = {d0, d1, d2, d3};
    #pragma unroll
    for (int r = 0; r < 4; ++r) {
      float v = dd[r] * 0.125f;
      if (masked && c > rowsh[r]) v = -INFINITY;
      sc[r][c] = v;
    }
    lm0 = fmaxf(lm0, sc[0][c]); lm1 = fmaxf(lm1, sc[1][c]);
    lm2 = fmaxf(lm2, sc[2][c]); lm3 = fmaxf(lm3, sc[3][c]);
  }
  red[0][t] = lm0; red[1][t] = lm1; red[2][t] = lm2; red[3][t] = lm3;
  __syncthreads();
  {
    int w = t >> 6, lane = t & 63;
    float m = fmaxf(fmaxf(red[w][lane], red[w][lane + 64]),
                    fmaxf(red[w][lane + 128], red[w][lane + 192]));
    #pragma unroll
    for (int off = 32; off; off >>= 1) m = fmaxf(m, __shfl_xor(m, off));
    if (lane == 0) mxs[w] = m;
  }
  __syncthreads();
  float ls0 = 0.f, ls1 = 0.f, ls2 = 0.f, ls3 = 0.f;
  float m0 = mxs[0], m1 = mxs[1], m2 = mxs[2], m3 = mxs[3];
  for (int c = t; c < Lk; c += 256) {
    float e0 = expf(sc[0][c] - m0); sc[0][c] = e0; ls0 += e0;
    float e1 = expf(sc[1][c] - m1); sc[1][c] = e1; ls1 += e1;
    float e2 = expf(sc[2][c] - m2); sc[2][c] = e2; ls2 += e2;
    float e3 = expf(sc[3][c] - m3); sc[3][c] = e3; ls3 += e3;
  }
  red[0][t] = ls0; red[1][t] = ls1; red[2][t] = ls2; red[3][t] = ls3;
  __syncthreads();
  {
    int w = t >> 6, lane = t & 63;
    float s = red[w][lane] + red[w][lane + 64] + red[w][lane + 128] + red[w][lane + 192];
    #pragma unroll
    for (int off = 32; off; off >>= 1) s += __shfl_xor(s, off);
    if (lane == 0) sss[w] = s;
  }
  __syncthreads();
  {
    int g = t >> 6, d = t & 63;
    float a0 = 0.f, a1 = 0.f, a2 = 0.f, a3 = 0.f;
    for (int c = g; c < Lk; c += 4) {
      float v = Vp[(size_t)(b * Lk + c) * vstr + (h << 6) + d];
      a0 += sc[0][c] * v; a1 += sc[1][c] * v; a2 += sc[2][c] * v; a3 += sc[3][c] * v;
    }
    pv[g][0][d] = a0; pv[g][1][d] = a1; pv[g][2][d] = a2; pv[g][3][d] = a3;
  }
  __syncthreads();
  {
    int r = t >> 6, d = t & 63;
    int row = rowsh[r];
    if (row >= 0) {
      float s = (pv[0][r][d] + pv[1][r][d] + pv[2][r][d] + pv[3][r][d]) / sss[r];
      emit_split(s, AOh, AOl, ((size_t)(b * Lq + row) << 9) + (h << 6) + d);
    }
  }
}

// ---------------- maxpool w3 s2 p1 along L (split-only output) ----------------
__global__ void k_maxpool(const float* __restrict__ y, f16* __restrict__ oh,
                          f16* __restrict__ ol, int L) {
  int Lo = L >> 1;
  int i = blockIdx.x * 256 + threadIdx.x;
  int c = i & 511; int bj = i >> 9;
  int j = bj % Lo; int b = bj / Lo;
  float m = -INFINITY;
  int t0 = 2 * j - 1;
  #pragma unroll
  for (int k = 0; k < 3; ++k) {
    int tt = t0 + k;
    if (tt >= 0 && tt < L) m = fmaxf(m, y[((size_t)(b * L + tt) << 9) + c]);
  }
  emit_split(m, oh, ol, ((size_t)(b * Lo + j) << 9) + c);
}

// ---------------- final projection 512->7 (reads f32 from Y) ----------------
__global__ void k_proj(const float* __restrict__ Xn, const float* __restrict__ pw,
                       const float* __restrict__ pb, float* __restrict__ out) {
  int i = blockIdx.x * 256 + threadIdx.x;
  if (i >= 16 * 512 * 7) return;
  int c = i % 7; int r = i / 7;
  int b = r >> 9; int j = r & 511;
  const float* xr = Xn + ((size_t)(b * 1024 + 512 + j) << 9);
  float acc = pb[c];
  for (int d2 = 0; d2 < 512; ++d2) acc += xr[d2] * pw[d2 * 7 + c];
  out[i] = acc;
}

// =====================================================================
extern "C" void kernel_launch(void* const* d_in, const int* in_sizes, int n_in,
                              void* d_out, int out_size, void* d_ws, size_t ws_size,
                              hipStream_t stream) {
  const float* x_enc      = (const float*)d_in[0];
  const float* x_mark_enc = (const float*)d_in[1];
  const float* x_dec      = (const float*)d_in[2];
  const float* x_mark_dec = (const float*)d_in[3];
  const float* enc_tok_w  = (const float*)d_in[4];
  const float* enc_mark_w = (const float*)d_in[5];
  const float* dec_tok_w  = (const float*)d_in[6];
  const float* dec_mark_w = (const float*)d_in[7];
  const float* enc_attn_w = (const float*)d_in[8];
  const float* enc_attn_b = (const float*)d_in[9];
  const float* enc_ffn1_w = (const float*)d_in[10];
  const float* enc_ffn1_b = (const float*)d_in[11];
  const float* enc_ffn2_w = (const float*)d_in[12];
  const float* enc_ffn2_b = (const float*)d_in[13];
  const float* enc_ln_g   = (const float*)d_in[14];
  const float* enc_ln_b   = (const float*)d_in[15];
  const float* distil_w   = (const float*)d_in[16];
  const float* distil_b   = (const float*)d_in[17];
  const float* distil_bn_g= (const float*)d_in[18];
  const float* distil_bn_b= (const float*)d_in[19];
  const float* enc_norm_g = (const float*)d_in[20];
  const float* enc_norm_b = (const float*)d_in[21];
  const float* dec_self_w = (const float*)d_in[22];
  const float* dec_self_b = (const float*)d_in[23];
  const float* dec_cross_w= (const float*)d_in[24];
  const float* dec_cross_b= (const float*)d_in[25];
  const float* dec_ffn1_w = (const float*)d_in[26];
  const float* dec_ffn1_b = (const float*)d_in[27];
  const float* dec_ffn2_w = (const float*)d_in[28];
  const float* dec_ffn2_b = (const float*)d_in[29];
  const float* dec_ln_g   = (const float*)d_in[30];
  const float* dec_ln_b   = (const float*)d_in[31];
  const float* dec_norm_g = (const float*)d_in[32];
  const float* dec_norm_b = (const float*)d_in[33];
  const float* proj_w     = (const float*)d_in[34];
  const float* proj_b     = (const float*)d_in[35];

  // -------- workspace layout: split-only activations, ~164 MB --------
  float* ws = (float*)d_ws;
  size_t off = 0;
  f16* Xh   = (f16*)(ws + off); off += 16777216;
  f16* Xl   = Xh + 16777216;
  f16* ENCh = (f16*)(ws + off); off += 4194304;
  f16* ENCl = ENCh + 4194304;
  float* PE = ws + off; off += 1048576;
  float* Mb = ws + off; off += 65536;
  float* PS = ws + off; off += 32768;
  f16* WSP  = (f16*)(ws + off); off += 2097152;
  int* IDXi = (int*)(ws + off); off += 83200;
  float* Y  = ws + off; off += 16777216;
  int* MTi  = IDXi + 81920;
  if (ws_size < off * 4) return;
  f16* Yh = (f16*)Y;
  f16* Yl = Yh + 16777216;
  const int bs = 4;

  auto ln = [&](const f16* xh, const f16* xl, const float* g, const float* b, int rows,
                float* of32, f16* oh, f16* ol) {
    k_ln<<<rows, 256, 0, stream>>>(xh, xl, g, b, of32, oh, ol);
  };
  auto wsplit = [&](const float* W, f16* Wh, f16* Wl, int K, int N, int nmat) {
    dim3 g(K >> 5, N >> 5, nmat);
    k_wsplit<<<g, 256, 0, stream>>>(W, Wh, Wl, K, N);
  };
  auto mgQ = [&](const f16* Ah, const f16* Al, const f16* Wh, const f16* Wl,
                 const float* bias, float* C, int M, int N, int K) {
    dim3 g(N >> 7, M >> 7);
    k_mgemm2<0,0,0,0><<<g, 256, 0, stream>>>(Ah, Al, Wh, Wl, bias, nullptr, nullptr,
        nullptr, nullptr, C, nullptr, nullptr, M, N, K, 0);
  };
  auto mgR = [&](const f16* Ah, const f16* Al, const f16* Wh, const f16* Wl,
                 const float* bias, const f16* Rh, const f16* Rl,
                 f16* Ch, f16* Cl, int M, int N, int K) {
    dim3 g(N >> 7, M >> 7);
    k_mgemm2<0,1,0,1><<<g, 256, 0, stream>>>(Ah, Al, Wh, Wl, bias, Rh, Rl,
        nullptr, nullptr, nullptr, Ch, Cl, M, N, K, 0);
  };
  auto mgG = [&](const f16* Ah, const f16* Al, const f16* Wh, const f16* Wl,
                 const float* bias, f16* Ch, f16* Cl, int M, int N, int K) {
    dim3 g(N >> 7, M >> 7);
    k_mgemm2<1,1,0,0><<<g, 256, 0, stream>>>(Ah, Al, Wh, Wl, bias, nullptr, nullptr,
        nullptr, nullptr, nullptr, Ch, Cl, M, N, K, 0);
  };
  auto Uof = [](int Lx) { int v = 5 * (int)ceil(log((double)Lx)); return v < Lx ? v : Lx; };

  auto attn = [&](f16* xqh, f16* xql, const f16* xkvh, const f16* xkvl,
                  int Lq, int Lk, const float* w, const float* bias,
                  bool masked, u32 fold, bool selfa) {
    int U = Uof(Lk), uu = Uof(Lq);
    u32 r0, r1, ka, kb2;
    tf_block(0u, 42u, 0u, fold, r0, r1);
    tf_block(r0, r1, 0u, 1u, ka, kb2);
    int n = Lq * U;
    k_idx<<<(n + 255) / 256, 256, 0, stream>>>(ka, kb2, n, Lk - 1, IDXi);

    f16 *Wqkvh = WSP,            *Wqkvl = WSP + 786432;
    f16 *WQh   = WSP,            *WQl   = WSP + 262144;
    f16 *WKVh  = WSP + 524288,   *WKVl  = WSP + 1048576;
    f16 *WOh   = WSP + 1572864,  *WOl   = WSP + 1835008;
    if (selfa) {
      wsplit(w, Wqkvh, Wqkvl, 512, 512, 3);
    } else {
      wsplit(w, WQh, WQl, 512, 512, 1);
      wsplit(w + 262144, WKVh, WKVl, 512, 512, 2);
    }
    wsplit(w + 786432, WOh, WOl, 512, 512, 1);

    int nsl = 16 / bs;
    for (int s = 0; s < nsl; ++s) {
      size_t qoff = (size_t)s * bs * Lq * 512;
      size_t koff = (size_t)s * bs * Lk * 512;
      const float *qp, *kp, *vp;
      int qstr, kstr, vstr;
      f16 *AOh, *AOl;
      if (selfa) {
        float* QKV = Y;
        AOh = (f16*)(Y + (size_t)bs * Lq * 1536);
        AOl = AOh + (size_t)bs * Lq * 512;
        mgQ(xqh + qoff, xql + qoff, Wqkvh, Wqkvl, bias, QKV, bs * Lq, 1536, 512);
        qp = QKV; qstr = 1536; kp = QKV + 512; kstr = 1536; vp = QKV + 1024; vstr = 1536;
      } else {
        float* Qb  = Y;
        float* KVb = Y + (size_t)bs * Lq * 512;
        AOh = (f16*)(KVb + (size_t)bs * Lk * 1024);
        AOl = AOh + (size_t)bs * Lq * 512;
        mgQ(xqh + qoff, xql + qoff, WQh, WQl, bias, Qb, bs * Lq, 512, 512);
        mgQ(xkvh + koff, xkvl + koff, WKVh, WKVl, bias + 512, KVb, bs * Lk, 1024, 512);
        qp = Qb; qstr = 512; kp = KVb; kstr = 1024; vp = KVb + 512; vstr = 1024;
      }
      int wids = bs * 8 * Lq;
      k_qkM<<<wids / 4, 256, 0, stream>>>(qp, qstr, kp, kstr, IDXi, Mb, Lq, Lk, U);
      k_topk64<<<bs * 8, 64, 0, stream>>>(Mb, MTi, Lq, uu);
      if (masked) {
        k_cs1<<<bs * 8 * 8, 64, 0, stream>>>(vp, vstr, PS, Lq, Lq >> 3);
        k_cs3<<<bs * 8 * 8, 64, 0, stream>>>(vp, vstr, PS, AOh, AOl, Lq, Lq >> 3);
      } else {
        k_cm1<<<bs * 8 * 16, 64, 0, stream>>>(vp, vstr, PS, Lk, Lk >> 4);
        int tot = bs * Lq * 512;
        k_cm2<<<tot / 256, 256, 0, stream>>>(PS, AOh, AOl, 1.0f / (float)Lk, Lq, tot);
      }
      int nbb = (uu + 3) >> 2;
      k_sattn4<<<bs * 8 * nbb, 256, 0, stream>>>(qp, qstr, kp, kstr, vp, vstr, MTi, AOh, AOl,
                                                 Lq, Lk, uu, masked ? 1 : 0);
      mgR(AOh, AOl, WOh, WOl, bias + 1536, xqh + qoff, xql + qoff,
          xqh + qoff, xql + qoff, bs * Lq, 512, 512);
    }
  };

  auto ffn = [&](f16* xh, f16* xl, const float* w1, const float* b1,
                 const float* w2, const float* b2, int Mtot) {
    f16 *W1h = WSP,           *W1l = WSP + 1048576,
        *W2h = WSP + 2097152, *W2l = WSP + 3145728;
    wsplit(w1, W1h, W1l, 512, 2048, 1);
    wsplit(w2, W2h, W2l, 2048, 512, 1);
    for (int c0 = 0; c0 < Mtot; c0 += 8192) {
      int rows = (Mtot - c0 < 8192) ? (Mtot - c0) : 8192;
      mgG(xh + (size_t)c0 * 512, xl + (size_t)c0 * 512, W1h, W1l, b1, Yh, Yl, rows, 2048, 512);
      mgR(Yh, Yl, W2h, W2l, b2, xh + (size_t)c0 * 512, xl + (size_t)c0 * 512,
          xh + (size_t)c0 * 512, xl + (size_t)c0 * 512, rows, 512, 2048);
    }
  };

  // ---------------- encoder ----------------
  k_pe<<<(2048 * 512) / 256, 256, 0, stream>>>(PE);
  k_embed<<<(16 * 2048 * 512) / 256, 256, 0, stream>>>(x_enc, x_mark_enc, enc_tok_w, enc_mark_w,
                                                       PE, Xh, Xl, 2048, 16 * 2048 * 512);
  int L = 2048;
  for (int l = 0; l < 3; ++l) {
    attn(Xh, Xl, Xh, Xl, L, L, enc_attn_w + (size_t)l * 4 * 262144,
         enc_attn_b + (size_t)l * 2048, false, (u32)l, true);
    ln(Xh, Xl, enc_ln_g + (size_t)(l * 2) * 512, enc_ln_b + (size_t)(l * 2) * 512, 16 * L,
       nullptr, Xh, Xl);
    ffn(Xh, Xl, enc_ffn1_w + (size_t)l * 512 * 2048, enc_ffn1_b + (size_t)l * 2048,
        enc_ffn2_w + (size_t)l * 2048 * 512, enc_ffn2_b + (size_t)l * 512, 16 * L);
    ln(Xh, Xl, enc_ln_g + (size_t)(l * 2 + 1) * 512, enc_ln_b + (size_t)(l * 2 + 1) * 512, 16 * L,
       nullptr, Xh, Xl);
    if (l < 2) {
      f16 *Dh = WSP, *Dl = WSP + 786432;
      k_wsplit_conv<<<(512 * 1536) / 256, 256, 0, stream>>>(distil_w + (size_t)l * 512 * 512 * 3, Dh, Dl);
      dim3 g(512 >> 7, (16 * L) >> 7);
      int lgL = (L == 2048) ? 11 : 10;
      k_mgemm2<2,0,1,0><<<g, 256, 0, stream>>>(Xh, Xl, Dh, Dl, distil_b + (size_t)l * 512,
          nullptr, nullptr, distil_bn_g + (size_t)l * 512, distil_bn_b + (size_t)l * 512,
          Y, nullptr, nullptr, 16 * L, 512, 1536, lgL);
      int Lo = L >> 1;
      k_maxpool<<<(16 * Lo * 512) / 256, 256, 0, stream>>>(Y, Xh, Xl, L);
      L = Lo;
    }
  }
  ln(Xh, Xl, enc_norm_g, enc_norm_b, 16 * 512, nullptr, ENCh, ENCl);

  // ---------------- decoder (in-place chain in Xh/Xl) ----------------
  k_embed<<<(16 * 1024 * 512) / 256, 256, 0, stream>>>(x_dec, x_mark_dec, dec_tok_w, dec_mark_w,
                                                       PE, Xh, Xl, 1024, 16 * 1024 * 512);
  for (int l = 0; l < 2; ++l) {
    attn(Xh, Xl, Xh, Xl, 1024, 1024, dec_self_w + (size_t)l * 4 * 262144,
         dec_self_b + (size_t)l * 2048, true, (u32)(100 + 2 * l), true);
    ln(Xh, Xl, dec_ln_g + (size_t)(l * 3) * 512, dec_ln_b + (size_t)(l * 3) * 512, 16384,
       nullptr, Xh, Xl);
    attn(Xh, Xl, ENCh, ENCl, 1024, 512, dec_cross_w + (size_t)l * 4 * 262144,
         dec_cross_b + (size_t)l * 2048, false, (u32)(101 + 2 * l), false);
    ln(Xh, Xl, dec_ln_g + (size_t)(l * 3 + 1) * 512, dec_ln_b + (size_t)(l * 3 + 1) * 512, 16384,
       nullptr, Xh, Xl);
    ffn(Xh, Xl, dec_ffn1_w + (size_t)l * 512 * 2048, dec_ffn1_b + (size_t)l * 2048,
        dec_ffn2_w + (size_t)l * 2048 * 512, dec_ffn2_b + (size_t)l * 512, 16384);
    ln(Xh, Xl, dec_ln_g + (size_t)(l * 3 + 2) * 512, dec_ln_b + (size_t)(l * 3 + 2) * 512, 16384,
       nullptr, Xh, Xl);
  }
  ln(Xh, Xl, dec_norm_g, dec_norm_b, 16384, Y, nullptr, nullptr);
  k_proj<<<(16 * 512 * 7 + 255) / 256, 256, 0, stream>>>(Y, proj_w, proj_b, (float*)d_out);
}

// Round 16
// 9998.239 us; speedup vs baseline: 2.0375x; 1.2841x over previous
//
#include <hip/hip_runtime.h>
#include <math.h>
#include <stdint.h>

typedef unsigned int u32;
typedef _Float16 f16;
typedef __attribute__((ext_vector_type(8))) _Float16 f16x8;
typedef __attribute__((ext_vector_type(4))) float f32x4;

// ---------------- Threefry-2x32 (20 rounds), matches JAX ----------------
__host__ __device__ __forceinline__ u32 rotl32(u32 x, int r) { return (x << r) | (x >> (32 - r)); }
__host__ __device__ __forceinline__ void tf_round(u32& x0, u32& x1, int r) {
  x0 += x1; x1 = rotl32(x1, r); x1 ^= x0;
}
__host__ __device__ __forceinline__ void tf_block(u32 k0, u32 k1, u32 x0, u32 x1, u32& o0, u32& o1) {
  u32 k2 = k0 ^ k1 ^ 0x1BD11BDAu;
  x0 += k0; x1 += k1;
  tf_round(x0,x1,13); tf_round(x0,x1,15); tf_round(x0,x1,26); tf_round(x0,x1,6);
  x0 += k1; x1 += k2 + 1u;
  tf_round(x0,x1,17); tf_round(x0,x1,29); tf_round(x0,x1,16); tf_round(x0,x1,24);
  x0 += k2; x1 += k0 + 2u;
  tf_round(x0,x1,13); tf_round(x0,x1,15); tf_round(x0,x1,26); tf_round(x0,x1,6);
  x0 += k0; x1 += k1 + 3u;
  tf_round(x0,x1,17); tf_round(x0,x1,29); tf_round(x0,x1,16); tf_round(x0,x1,24);
  x0 += k1; x1 += k2 + 4u;
  tf_round(x0,x1,13); tf_round(x0,x1,15); tf_round(x0,x1,26); tf_round(x0,x1,6);
  x0 += k2; x1 += k0 + 5u;
  o0 = x0; o1 = x1;
}

__global__ void k_idx(u32 ka, u32 kb, int n, int mask, int* __restrict__ idx) {
  int i = blockIdx.x * 256 + threadIdx.x;
  if (i >= n) return;
  u32 b1, b2; tf_block(ka, kb, 0u, (u32)i, b1, b2);
  idx[i] = (int)((b1 ^ b2) & (u32)mask);
}

__device__ __forceinline__ void emit_split(float v, f16* __restrict__ oh,
                                           f16* __restrict__ ol, size_t o) {
  f16 h = (f16)v;
  oh[o] = h;
  ol[o] = (f16)((v - (float)h) * 2048.0f);
}
__device__ __forceinline__ float rsplit(const f16* __restrict__ h,
                                        const f16* __restrict__ l, size_t o) {
  return (float)h[o] + (float)l[o] * (1.0f / 2048.0f);
}

// ---------------- positional embedding ----------------
__global__ void k_pe(float* __restrict__ pe) {
  int i = blockIdx.x * 256 + threadIdx.x;
  if (i >= 2048 * 512) return;
  int t = i >> 9, o = i & 511;
  float arg = (float)((o >> 1) * 2) * (float)(-(log(10000.0) / 512.0));
  float div = (float)exp((double)arg);
  float ang32 = (float)t * div;
  double ang = (double)ang32;
  pe[i] = (float)((o & 1) ? cos(ang) : sin(ang));
}

// ---------------- embedding (split-only output) ----------------
__global__ __launch_bounds__(256) void k_embed(
    const float* __restrict__ x, const float* __restrict__ mark,
    const float* __restrict__ tw, const float* __restrict__ mw,
    const float* __restrict__ pe, f16* __restrict__ oh, f16* __restrict__ ol,
    int L, int total) {
  int i = blockIdx.x * 256 + threadIdx.x;
  if (i >= total) return;
  int oo = i & 511;
  int bt = i >> 9;
  int t = bt % L;
  int b = bt / L;
  float acc = pe[(t << 9) + oo];
  #pragma unroll
  for (int k = 0; k < 3; ++k) {
    int st = t + k - 1; if (st < 0) st += L; else if (st >= L) st -= L;
    const float* xr = x + (size_t)(b * L + st) * 7;
    const float* wr = tw + oo * 21 + k;
    #pragma unroll
    for (int ii = 0; ii < 7; ++ii) acc += xr[ii] * wr[ii * 3];
  }
  const float* mr = mark + (size_t)bt * 4;
  #pragma unroll
  for (int m = 0; m < 4; ++m) acc += mr[m] * mw[(m << 9) + oo];
  emit_split(acc, oh, ol, ((size_t)bt << 9) + oo);
}

// ---------------- weight transpose + f16 split (z = matrix index) ----------------
__global__ __launch_bounds__(256) void k_wsplit(const float* __restrict__ W,
    f16* __restrict__ Wh, f16* __restrict__ Wl, int K, int N) {
  size_t zo = (size_t)blockIdx.z * K * N;
  W += zo; Wh += zo; Wl += zo;
  __shared__ float tile[32][33];
  int kb = blockIdx.x << 5, nb = blockIdx.y << 5;
  int t = threadIdx.x;
  int tr = t >> 5, tc = t & 31;
  #pragma unroll
  for (int p = 0; p < 4; ++p)
    tile[tr + p * 8][tc] = W[(size_t)(kb + tr + p * 8) * N + nb + tc];
  __syncthreads();
  #pragma unroll
  for (int p = 0; p < 4; ++p) {
    int n = tr + p * 8, k = tc;
    float v = tile[k][n];
    f16 h = (f16)v;
    size_t o = (size_t)(nb + n) * K + kb + k;
    Wh[o] = h;
    Wl[o] = (f16)((v - (float)h) * 2048.0f);
  }
}

__global__ void k_wsplit_conv(const float* __restrict__ w, f16* __restrict__ Wh, f16* __restrict__ Wl) {
  int i = blockIdx.x * 256 + threadIdx.x;
  if (i >= 512 * 1536) return;
  int o = i / 1536, k = i - o * 1536;
  float v = w[(size_t)o * 1536 + (k & 511) * 3 + (k >> 9)];
  f16 h = (f16)v;
  Wh[i] = h;
  Wl[i] = (f16)((v - (float)h) * 2048.0f);
}

__device__ __forceinline__ int swz_x(int r) { return ((((r >> 1) & 3) ^ ((r >> 3) & 3)) << 4); }

__device__ __forceinline__ void gload16(const void* g, void* l) {
  __builtin_amdgcn_global_load_lds(
      (const __attribute__((address_space(1))) void*)g,
      (__attribute__((address_space(3))) void*)l, 16, 0, 0);
}

// ---------------- MFMA GEMM v2: pre-split f16 A/B, async LDS, dbuf, 16x16x32 ----------------
template<int ACT, int OSPLIT, int GATHER, int RESID>
__global__ __launch_bounds__(256, 2) void k_mgemm2(
    const f16* __restrict__ Ah, const f16* __restrict__ Al,
    const f16* __restrict__ Bh, const f16* __restrict__ Bl,
    const float* __restrict__ bias,
    const f16* __restrict__ Rh, const f16* __restrict__ Rl,
    const float* __restrict__ bns, const float* __restrict__ bnb,
    float* __restrict__ C, f16* __restrict__ Ch, f16* __restrict__ Cl,
    int M, int N, int K, int lgL) {
  __shared__ char lds[65536];
  const int t = threadIdx.x;
  int nwg = gridDim.x * gridDim.y;
  int bid = blockIdx.y * gridDim.x + blockIdx.x;
  if ((nwg & 7) == 0) {
    int cpx = nwg >> 3;
    bid = (bid & 7) * cpx + (bid >> 3);
  }
  const int bm = (bid / gridDim.x) << 7, bn = (bid % gridDim.x) << 7;
  const int w = t >> 6, l = t & 63;
  const int lr = l >> 2;
  const int qx = (l & 3) << 4;
  const int wr = (w >> 1) << 6, wc = (w & 1) << 6;
  const int fr = l & 15;
  const int fkB = (l >> 4) << 4;
  const f32x4 zero = {0.f, 0.f, 0.f, 0.f};
  f32x4 acc1[4][4], acc2[4][4];
  #pragma unroll
  for (int i = 0; i < 4; ++i)
    #pragma unroll
    for (int j = 0; j < 4; ++j) { acc1[i][j] = zero; acc2[i][j] = zero; }

  auto stage = [&](int k0, int bufo) {
    #pragma unroll
    for (int c = 0; c < 2; ++c) {
      int r = w * 32 + c * 16 + lr;
      int sx = qx ^ swz_x(r);
      const char *gAh, *gAl;
      if (GATHER) {
        int m = bm + r;
        int Lm = 1 << lgL;
        int ab = m >> lgL, at = m & (Lm - 1);
        int ke = k0 + (sx >> 1);
        int tap = ke >> 9, ii = ke & 511;
        int st = at + tap - 1; if (st < 0) st += Lm; else if (st >= Lm) st -= Lm;
        size_t aoff = (((size_t)((ab << lgL) + st)) << 9) + ii;
        gAh = (const char*)(Ah + aoff);
        gAl = (const char*)(Al + aoff);
      } else {
        gAh = (const char*)(Ah + (size_t)(bm + r) * K + k0) + sx;
        gAl = (const char*)(Al + (size_t)(bm + r) * K + k0) + sx;
      }
      const char* gBh = (const char*)(Bh + (size_t)(bn + r) * K + k0) + sx;
      const char* gBl = (const char*)(Bl + (size_t)(bn + r) * K + k0) + sx;
      char* base = lds + bufo + w * 2048 + c * 1024;
      gload16(gAh, base);
      gload16(gAl, base + 8192);
      gload16(gBh, base + 16384);
      gload16(gBl, base + 24576);
    }
  };

  int nt = K >> 5;
  stage(0, 0);
  __syncthreads();
  int bufo = 0;
  for (int tt = 0; tt < nt; ++tt) {
    int nb = bufo ^ 32768;
    if (tt + 1 < nt) stage((tt + 1) << 5, nb);
    char* pAh = lds + bufo;
    char* pAl = pAh + 8192;
    char* pBh = pAh + 16384;
    char* pBl = pAh + 24576;
    f16x8 ah4[4], al4[4];
    #pragma unroll
    for (int i = 0; i < 4; ++i) {
      int r = wr + i * 16 + fr;
      int ob = r * 64 + (fkB ^ swz_x(r));
      ah4[i] = *(f16x8*)(pAh + ob);
      al4[i] = *(f16x8*)(pAl + ob);
    }
    #pragma unroll
    for (int j = 0; j < 4; ++j) {
      int r = wc + j * 16 + fr;
      int ob = r * 64 + (fkB ^ swz_x(r));
      f16x8 bh_ = *(f16x8*)(pBh + ob);
      f16x8 bl_ = *(f16x8*)(pBl + ob);
      #pragma unroll
      for (int i = 0; i < 4; ++i) {
        acc1[i][j] = __builtin_amdgcn_mfma_f32_16x16x32_f16(ah4[i], bh_, acc1[i][j], 0, 0, 0);
        acc2[i][j] = __builtin_amdgcn_mfma_f32_16x16x32_f16(ah4[i], bl_, acc2[i][j], 0, 0, 0);
        acc2[i][j] = __builtin_amdgcn_mfma_f32_16x16x32_f16(al4[i], bh_, acc2[i][j], 0, 0, 0);
      }
    }
    __syncthreads();
    bufo = nb;
  }
  #pragma unroll
  for (int j = 0; j < 4; ++j) {
    int col = bn + wc + j * 16 + fr;
    float bsv = bias[col];
    float g2 = 0.f, b2 = 0.f;
    if (ACT == 2) { g2 = bns[col] * 0.9999950000375f; b2 = bnb[col]; }
    #pragma unroll
    for (int i = 0; i < 4; ++i) {
      #pragma unroll
      for (int r = 0; r < 4; ++r) {
        int row = bm + wr + i * 16 + ((l >> 4) << 2) + r;
        float v = acc1[i][j][r] + acc2[i][j][r] * (1.0f / 2048.0f) + bsv;
        if (ACT == 1) v = 0.5f * v * (1.0f + erff(v * 0.70710678118654752f));
        if (ACT == 2) { v = v * g2 + b2; v = v > 0.f ? v : expm1f(v); }
        size_t oi = (size_t)row * N + col;
        if (RESID) v += rsplit(Rh, Rl, oi);
        if (OSPLIT) emit_split(v, Ch, Cl, oi);
        else        C[oi] = v;
      }
    }
  }
}

// ---------------- LayerNorm on split input; optional split / f32 outputs ----------------
__global__ __launch_bounds__(256) void k_ln(const f16* __restrict__ xh, const f16* __restrict__ xl,
    const float* __restrict__ g, const float* __restrict__ b,
    float* __restrict__ of32, f16* __restrict__ oh, f16* __restrict__ ol) {
  int row = blockIdx.x, t = threadIdx.x;
  size_t base = (size_t)row << 9;
  float v0 = rsplit(xh, xl, base + t);
  float v1 = rsplit(xh, xl, base + t + 256);
  float s = v0 + v1;
  #pragma unroll
  for (int off = 32; off; off >>= 1) s += __shfl_down(s, off);
  __shared__ float ls[4];
  if ((t & 63) == 0) ls[t >> 6] = s;
  __syncthreads();
  float mean = (ls[0] + ls[1] + ls[2] + ls[3]) * (1.f / 512.f);
  __syncthreads();
  float d0 = v0 - mean, d1 = v1 - mean;
  float q = d0 * d0 + d1 * d1;
  #pragma unroll
  for (int off = 32; off; off >>= 1) q += __shfl_down(q, off);
  if ((t & 63) == 0) ls[t >> 6] = q;
  __syncthreads();
  float var = (ls[0] + ls[1] + ls[2] + ls[3]) * (1.f / 512.f);
  float rs = rsqrtf(var + 1e-5f);
  float r0 = d0 * rs * g[t] + b[t];
  float r1 = d1 * rs * g[t + 256] + b[t + 256];
  if (of32) { of32[base + t] = r0; of32[base + t + 256] = r1; }
  if (oh) {
    emit_split(r0, oh, ol, base + t);
    emit_split(r1, oh, ol, base + t + 256);
  }
}

// ---------------- M[bh,l] scoring (strided Q/K) ----------------
__global__ __launch_bounds__(256) void k_qkM(const float* __restrict__ Q, int qstr,
    const float* __restrict__ Kp, int kstr, const int* __restrict__ idx,
    float* __restrict__ M, int Lq, int Lk, int U) {
  int wid = (blockIdx.x * 256 + threadIdx.x) >> 6;
  int lane = threadIdx.x & 63;
  int l = wid & (Lq - 1); int bh = wid / Lq; int h = bh & 7; int b = bh >> 3;
  float dot = 0.f;
  if (lane < U) {
    int kr = idx[l * U + lane];
    const float4* q4 = (const float4*)(Q + (size_t)(b * Lq + l) * qstr + (h << 6));
    const float4* k4 = (const float4*)(Kp + (size_t)(b * Lk + kr) * kstr + (h << 6));
    #pragma unroll
    for (int i = 0; i < 16; ++i) {
      float4 a = q4[i], c = k4[i];
      dot += a.x * c.x + a.y * c.y + a.z * c.z + a.w * c.w;
    }
  }
  float mx = (lane < U) ? dot : -INFINITY;
  float sm = (lane < U) ? dot : 0.f;
  #pragma unroll
  for (int off = 32; off; off >>= 1) {
    mx = fmaxf(mx, __shfl_xor(mx, off));
    sm += __shfl_xor(sm, off);
  }
  if (lane == 0) M[(size_t)bh * Lq + l] = mx - sm / (float)Lk;
}

// ---------------- single-wave top-u per (b,h), ties -> lower index ----------------
__global__ void k_topk64(const float* __restrict__ M, int* __restrict__ mtop, int Lq, int u) {
  __shared__ float vals[2048];
  int bh = blockIdx.x, l = threadIdx.x;
  const float* Mr = M + (size_t)bh * Lq;
  for (int i = l; i < Lq; i += 64) vals[i] = Mr[i];
  __syncthreads();
  for (int it = 0; it < u; ++it) {
    float bv = -INFINITY; int bi = 0x7fffffff;
    for (int i = l; i < Lq; i += 64) {
      float v = vals[i];
      if (v > bv || (v == bv && i < bi)) { bv = v; bi = i; }
    }
    #pragma unroll
    for (int off = 32; off; off >>= 1) {
      float vv = __shfl_xor(bv, off); int ii = __shfl_xor(bi, off);
      if (vv > bv || (vv == bv && ii < bi)) { bv = vv; bi = ii; }
    }
    if (l == 0) { mtop[bh * u + it] = bi; vals[bi] = -INFINITY; }
    __syncthreads();
  }
}

// ---------------- ctx mean (AO split) ----------------
__global__ void k_cm1(const float* __restrict__ V, int vstr, float* __restrict__ PS,
                      int Lk, int rows) {
  int bid = blockIdx.x;
  int bh = bid >> 4, seg = bid & 15, d = threadIdx.x;
  int b = bh >> 3, h = bh & 7;
  const float* vp = V + (size_t)(b * Lk + seg * rows) * vstr + (h << 6) + d;
  float acc = 0.f;
  for (int r = 0; r < rows; ++r) acc += vp[(size_t)r * vstr];
  PS[(bid << 6) + d] = acc;
}
__global__ void k_cm2(const float* __restrict__ PS, f16* __restrict__ AOh,
                      f16* __restrict__ AOl, float invLk, int Lq, int total) {
  int i = blockIdx.x * 256 + threadIdx.x;
  if (i >= total) return;
  int c = i & 511; int h = c >> 6; int d = c & 63;
  int r = i >> 9; int b = r / Lq;
  float acc = 0.f;
  #pragma unroll
  for (int s = 0; s < 16; ++s) acc += PS[(((((b << 3) + h) << 4) + s) << 6) + d];
  emit_split(acc * invLk, AOh, AOl, (size_t)i);
}

// ---------------- cumsum (masked ctx; per-block prefix, AO split) ----------------
__global__ void k_cs1(const float* __restrict__ V, int vstr, float* __restrict__ PS,
                      int Lq, int rows) {
  int bid = blockIdx.x;
  int bh = bid >> 3, seg = bid & 7, d = threadIdx.x;
  int b = bh >> 3, h = bh & 7;
  const float* vp = V + (size_t)(b * Lq + seg * rows) * vstr + (h << 6) + d;
  float acc = 0.f;
  for (int r = 0; r < rows; ++r) acc += vp[(size_t)r * vstr];
  PS[(bid << 6) + d] = acc;
}
__global__ void k_cs3(const float* __restrict__ V, int vstr, const float* __restrict__ PS,
                      f16* __restrict__ AOh, f16* __restrict__ AOl, int Lq, int rows) {
  int bid = blockIdx.x;
  int bh = bid >> 3, seg = bid & 7, d = threadIdx.x;
  int b = bh >> 3, h = bh & 7;
  float acc = 0.f;
  for (int s2 = 0; s2 < seg; ++s2) acc += PS[(((bh << 3) + s2) << 6) + d];
  const float* vp = V + (size_t)(b * Lq + seg * rows) * vstr + (h << 6) + d;
  size_t ob = ((size_t)(b * Lq + seg * rows) << 9) + (h << 6) + d;
  for (int r = 0; r < rows; ++r) {
    acc += vp[(size_t)r * vstr];
    emit_split(acc, AOh, AOl, ob + ((size_t)r << 9));
  }
}

// ---------------- sparse attn: 4 selected rows per block (AO split) ----------------
__global__ __launch_bounds__(256) void k_sattn4(
    const float* __restrict__ Q, int qstr, const float* __restrict__ Kp, int kstr,
    const float* __restrict__ Vp, int vstr, const int* __restrict__ mtop,
    f16* __restrict__ AOh, f16* __restrict__ AOl, int Lq, int Lk, int u, int masked) {
  __shared__ float sc[4][2048];
  __shared__ float qs[4][64];
  __shared__ float red[4][256];
  __shared__ float pv[4][4][64];
  __shared__ int rowsh[4];
  __shared__ float mxs[4], sss[4];
  int nb = (u + 3) >> 2;
  int ub = blockIdx.x % nb, bh = blockIdx.x / nb;
  int b = bh >> 3, h = bh & 7;
  int t = threadIdx.x;
  if (t < 4) {
    int ui = ub * 4 + t;
    rowsh[t] = (ui < u) ? mtop[bh * u + ui] : -1;
  }
  __syncthreads();
  {
    int r = t >> 6, d = t & 63;
    int row = rowsh[r];
    qs[r][d] = (row >= 0) ? Q[(size_t)(b * Lq + row) * qstr + (h << 6) + d] : 0.f;
  }
  __syncthreads();
  float lm0 = -INFINITY, lm1 = -INFINITY, lm2 = -INFINITY, lm3 = -INFINITY;
  for (int c = t; c < Lk; c += 256) {
    const float4* kr = (const float4*)(Kp + (size_t)(b * Lk + c) * kstr + (h << 6));
    float d0 = 0.f, d1 = 0.f, d2 = 0.f, d3 = 0.f;
    #pragma unroll
    for (int e = 0; e < 16; ++e) {
      float4 kk = kr[e];
      d0 += qs[0][4*e]*kk.x + qs[0][4*e+1]*kk.y + qs[0][4*e+2]*kk.z + qs[0][4*e+3]*kk.w;
      d1 += qs[1][4*e]*kk.x + qs[1][4*e+1]*kk.y + qs[1][4*e+2]*kk.z + qs[1][4*e+3]*kk.w;
      d2 += qs[2][4*e]*kk.x + qs[2][4*e+1]*kk.y + qs[2][4*e+2]*kk.z + qs[2][4*e+3]*kk.w;
      d3 += qs[3][4*e]*kk.x + qs[3][4*e+1]*kk.y + qs[3][4*e+2]*kk.z + qs[3][4*e+3]*kk.w;
    }
    float dd[4] = {d0, d1, d2, d3};
    #pragma unroll
    for (int r = 0; r < 4; ++r) {
      float v = dd[r] * 0.125f;
      if (masked && c > rowsh[r]) v = -INFINITY;
      sc[r][c] = v;
    }
    lm0 = fmaxf(lm0, sc[0][c]); lm1 = fmaxf(lm1, sc[1][c]);
    lm2 = fmaxf(lm2, sc[2][c]); lm3 = fmaxf(lm3, sc[3][c]);
  }
  red[0][t] = lm0; red[1][t] = lm1; red[2][t] = lm2; red[3][t] = lm3;
  __syncthreads();
  {
    int w = t >> 6, lane = t & 63;
    float m = fmaxf(fmaxf(red[w][lane], red[w][lane + 64]),
                    fmaxf(red[w][lane + 128], red[w][lane + 192]));
    #pragma unroll
    for (int off = 32; off; off >>= 1) m = fmaxf(m, __shfl_xor(m, off));
    if (lane == 0) mxs[w] = m;
  }
  __syncthreads();
  float ls0 = 0.f, ls1 = 0.f, ls2 = 0.f, ls3 = 0.f;
  float m0 = mxs[0], m1 = mxs[1], m2 = mxs[2], m3 = mxs[3];
  for (int c = t; c < Lk; c += 256) {
    float e0 = expf(sc[0][c] - m0); sc[0][c] = e0; ls0 += e0;
    float e1 = expf(sc[1][c] - m1); sc[1][c] = e1; ls1 += e1;
    float e2 = expf(sc[2][c] - m2); sc[2][c] = e2; ls2 += e2;
    float e3 = expf(sc[3][c] - m3); sc[3][c] = e3; ls3 += e3;
  }
  red[0][t] = ls0; red[1][t] = ls1; red[2][t] = ls2; red[3][t] = ls3;
  __syncthreads();
  {
    int w = t >> 6, lane = t & 63;
    float s = red[w][lane] + red[w][lane + 64] + red[w][lane + 128] + red[w][lane + 192];
    #pragma unroll
    for (int off = 32; off; off >>= 1) s += __shfl_xor(s, off);
    if (lane == 0) sss[w] = s;
  }
  __syncthreads();
  {
    int g = t >> 6, d = t & 63;
    float a0 = 0.f, a1 = 0.f, a2 = 0.f, a3 = 0.f;
    for (int c = g; c < Lk; c += 4) {
      float v = Vp[(size_t)(b * Lk + c) * vstr + (h << 6) + d];
      a0 += sc[0][c] * v; a1 += sc[1][c] * v; a2 += sc[2][c] * v; a3 += sc[3][c] * v;
    }
    pv[g][0][d] = a0; pv[g][1][d] = a1; pv[g][2][d] = a2; pv[g][3][d] = a3;
  }
  __syncthreads();
  {
    int r = t >> 6, d = t & 63;
    int row = rowsh[r];
    if (row >= 0) {
      float s = (pv[0][r][d] + pv[1][r][d] + pv[2][r][d] + pv[3][r][d]) / sss[r];
      emit_split(s, AOh, AOl, ((size_t)(b * Lq + row) << 9) + (h << 6) + d);
    }
  }
}

// ---------------- maxpool w3 s2 p1 along L (split-only output) ----------------
__global__ void k_maxpool(const float* __restrict__ y, f16* __restrict__ oh,
                          f16* __restrict__ ol, int L) {
  int Lo = L >> 1;
  int i = blockIdx.x * 256 + threadIdx.x;
  int c = i & 511; int bj = i >> 9;
  int j = bj % Lo; int b = bj / Lo;
  float m = -INFINITY;
  int t0 = 2 * j - 1;
  #pragma unroll
  for (int k = 0; k < 3; ++k) {
    int tt = t0 + k;
    if (tt >= 0 && tt < L) m = fmaxf(m, y[((size_t)(b * L + tt) << 9) + c]);
  }
  emit_split(m, oh, ol, ((size_t)(b * Lo + j) << 9) + c);
}

// ---------------- final projection 512->7 (reads f32 from Y) ----------------
__global__ void k_proj(const float* __restrict__ Xn, const float* __restrict__ pw,
                       const float* __restrict__ pb, float* __restrict__ out) {
  int i = blockIdx.x * 256 + threadIdx.x;
  if (i >= 16 * 512 * 7) return;
  int c = i % 7; int r = i / 7;
  int b = r >> 9; int j = r & 511;
  const float* xr = Xn + ((size_t)(b * 1024 + 512 + j) << 9);
  float acc = pb[c];
  for (int d2 = 0; d2 < 512; ++d2) acc += xr[d2] * pw[d2 * 7 + c];
  out[i] = acc;
}

// =====================================================================
extern "C" void kernel_launch(void* const* d_in, const int* in_sizes, int n_in,
                              void* d_out, int out_size, void* d_ws, size_t ws_size,
                              hipStream_t stream) {
  const float* x_enc      = (const float*)d_in[0];
  const float* x_mark_enc = (const float*)d_in[1];
  const float* x_dec      = (const float*)d_in[2];
  const float* x_mark_dec = (const float*)d_in[3];
  const float* enc_tok_w  = (const float*)d_in[4];
  const float* enc_mark_w = (const float*)d_in[5];
  const float* dec_tok_w  = (const float*)d_in[6];
  const float* dec_mark_w = (const float*)d_in[7];
  const float* enc_attn_w = (const float*)d_in[8];
  const float* enc_attn_b = (const float*)d_in[9];
  const float* enc_ffn1_w = (const float*)d_in[10];
  const float* enc_ffn1_b = (const float*)d_in[11];
  const float* enc_ffn2_w = (const float*)d_in[12];
  const float* enc_ffn2_b = (const float*)d_in[13];
  const float* enc_ln_g   = (const float*)d_in[14];
  const float* enc_ln_b   = (const float*)d_in[15];
  const float* distil_w   = (const float*)d_in[16];
  const float* distil_b   = (const float*)d_in[17];
  const float* distil_bn_g= (const float*)d_in[18];
  const float* distil_bn_b= (const float*)d_in[19];
  const float* enc_norm_g = (const float*)d_in[20];
  const float* enc_norm_b = (const float*)d_in[21];
  const float* dec_self_w = (const float*)d_in[22];
  const float* dec_self_b = (const float*)d_in[23];
  const float* dec_cross_w= (const float*)d_in[24];
  const float* dec_cross_b= (const float*)d_in[25];
  const float* dec_ffn1_w = (const float*)d_in[26];
  const float* dec_ffn1_b = (const float*)d_in[27];
  const float* dec_ffn2_w = (const float*)d_in[28];
  const float* dec_ffn2_b = (const float*)d_in[29];
  const float* dec_ln_g   = (const float*)d_in[30];
  const float* dec_ln_b   = (const float*)d_in[31];
  const float* dec_norm_g = (const float*)d_in[32];
  const float* dec_norm_b = (const float*)d_in[33];
  const float* proj_w     = (const float*)d_in[34];
  const float* proj_b     = (const float*)d_in[35];

  // -------- workspace layout: split-only activations; Y sized by tier --------
  float* ws = (float*)d_ws;
  size_t off = 0;
  f16* Xh   = (f16*)(ws + off); off += 16777216;
  f16* Xl   = Xh + 16777216;
  f16* ENCh = (f16*)(ws + off); off += 4194304;
  f16* ENCl = ENCh + 4194304;
  float* PE = ws + off; off += 1048576;
  float* Mb = ws + off; off += 131072;     // up to 64 bh x 2048
  float* PS = ws + off; off += 65536;      // up to 1024 blocks x 64
  f16* WSP  = (f16*)(ws + off); off += 2097152;
  int* IDXi = (int*)(ws + off); off += 84480;  // 81920 idx + 2560 mtop
  float* Y  = ws + off;
  int* MTi  = IDXi + 81920;
  size_t need4 = (off + 16777216ull) * 4;      // bs=4: Y = 16.78M f32
  size_t need8 = (off + 33554432ull) * 4;      // bs=8: Y = 33.55M f32
  int bs;
  if      (ws_size >= need8) bs = 8;
  else if (ws_size >= need4) bs = 4;
  else return;
  f16* Yh = (f16*)Y;
  f16* Yl = Yh + 16777216;                     // FFN fixed at 8192-row chunks

  auto ln = [&](const f16* xh, const f16* xl, const float* g, const float* b, int rows,
                float* of32, f16* oh, f16* ol) {
    k_ln<<<rows, 256, 0, stream>>>(xh, xl, g, b, of32, oh, ol);
  };
  auto wsplit = [&](const float* W, f16* Wh, f16* Wl, int K, int N, int nmat) {
    dim3 g(K >> 5, N >> 5, nmat);
    k_wsplit<<<g, 256, 0, stream>>>(W, Wh, Wl, K, N);
  };
  auto mgQ = [&](const f16* Ah, const f16* Al, const f16* Wh, const f16* Wl,
                 const float* bias, float* C, int M, int N, int K) {
    dim3 g(N >> 7, M >> 7);
    k_mgemm2<0,0,0,0><<<g, 256, 0, stream>>>(Ah, Al, Wh, Wl, bias, nullptr, nullptr,
        nullptr, nullptr, C, nullptr, nullptr, M, N, K, 0);
  };
  auto mgR = [&](const f16* Ah, const f16* Al, const f16* Wh, const f16* Wl,
                 const float* bias, const f16* Rh, const f16* Rl,
                 f16* Ch, f16* Cl, int M, int N, int K) {
    dim3 g(N >> 7, M >> 7);
    k_mgemm2<0,1,0,1><<<g, 256, 0, stream>>>(Ah, Al, Wh, Wl, bias, Rh, Rl,
        nullptr, nullptr, nullptr, Ch, Cl, M, N, K, 0);
  };
  auto mgG = [&](const f16* Ah, const f16* Al, const f16* Wh, const f16* Wl,
                 const float* bias, f16* Ch, f16* Cl, int M, int N, int K) {
    dim3 g(N >> 7, M >> 7);
    k_mgemm2<1,1,0,0><<<g, 256, 0, stream>>>(Ah, Al, Wh, Wl, bias, nullptr, nullptr,
        nullptr, nullptr, nullptr, Ch, Cl, M, N, K, 0);
  };
  auto Uof = [](int Lx) { int v = 5 * (int)ceil(log((double)Lx)); return v < Lx ? v : Lx; };

  auto attn = [&](f16* xqh, f16* xql, const f16* xkvh, const f16* xkvl,
                  int Lq, int Lk, const float* w, const float* bias,
                  bool masked, u32 fold, bool selfa) {
    int U = Uof(Lk), uu = Uof(Lq);
    u32 r0, r1, ka, kb2;
    tf_block(0u, 42u, 0u, fold, r0, r1);
    tf_block(r0, r1, 0u, 1u, ka, kb2);
    int n = Lq * U;
    k_idx<<<(n + 255) / 256, 256, 0, stream>>>(ka, kb2, n, Lk - 1, IDXi);

    f16 *Wqkvh = WSP,            *Wqkvl = WSP + 786432;
    f16 *WQh   = WSP,            *WQl   = WSP + 262144;
    f16 *WKVh  = WSP + 524288,   *WKVl  = WSP + 1048576;
    f16 *WOh   = WSP + 1572864,  *WOl   = WSP + 1835008;
    if (selfa) {
      wsplit(w, Wqkvh, Wqkvl, 512, 512, 3);
    } else {
      wsplit(w, WQh, WQl, 512, 512, 1);
      wsplit(w + 262144, WKVh, WKVl, 512, 512, 2);
    }
    wsplit(w + 786432, WOh, WOl, 512, 512, 1);

    int nsl = 16 / bs;
    for (int s = 0; s < nsl; ++s) {
      size_t qoff = (size_t)s * bs * Lq * 512;
      size_t koff = (size_t)s * bs * Lk * 512;
      const float *qp, *kp, *vp;
      int qstr, kstr, vstr;
      f16 *AOh, *AOl;
      if (selfa) {
        float* QKV = Y;
        AOh = (f16*)(Y + (size_t)bs * Lq * 1536);
        AOl = AOh + (size_t)bs * Lq * 512;
        mgQ(xqh + qoff, xql + qoff, Wqkvh, Wqkvl, bias, QKV, bs * Lq, 1536, 512);
        qp = QKV; qstr = 1536; kp = QKV + 512; kstr = 1536; vp = QKV + 1024; vstr = 1536;
      } else {
        float* Qb  = Y;
        float* KVb = Y + (size_t)bs * Lq * 512;
        AOh = (f16*)(KVb + (size_t)bs * Lk * 1024);
        AOl = AOh + (size_t)bs * Lq * 512;
        mgQ(xqh + qoff, xql + qoff, WQh, WQl, bias, Qb, bs * Lq, 512, 512);
        mgQ(xkvh + koff, xkvl + koff, WKVh, WKVl, bias + 512, KVb, bs * Lk, 1024, 512);
        qp = Qb; qstr = 512; kp = KVb; kstr = 1024; vp = KVb + 512; vstr = 1024;
      }
      int wids = bs * 8 * Lq;
      k_qkM<<<wids / 4, 256, 0, stream>>>(qp, qstr, kp, kstr, IDXi, Mb, Lq, Lk, U);
      k_topk64<<<bs * 8, 64, 0, stream>>>(Mb, MTi, Lq, uu);
      if (masked) {
        k_cs1<<<bs * 8 * 8, 64, 0, stream>>>(vp, vstr, PS, Lq, Lq >> 3);
        k_cs3<<<bs * 8 * 8, 64, 0, stream>>>(vp, vstr, PS, AOh, AOl, Lq, Lq >> 3);
      } else {
        k_cm1<<<bs * 8 * 16, 64, 0, stream>>>(vp, vstr, PS, Lk, Lk >> 4);
        int tot = bs * Lq * 512;
        k_cm2<<<tot / 256, 256, 0, stream>>>(PS, AOh, AOl, 1.0f / (float)Lk, Lq, tot);
      }
      int nbb = (uu + 3) >> 2;
      k_sattn4<<<bs * 8 * nbb, 256, 0, stream>>>(qp, qstr, kp, kstr, vp, vstr, MTi, AOh, AOl,
                                                 Lq, Lk, uu, masked ? 1 : 0);
      mgR(AOh, AOl, WOh, WOl, bias + 1536, xqh + qoff, xql + qoff,
          xqh + qoff, xql + qoff, bs * Lq, 512, 512);
    }
  };

  auto ffn = [&](f16* xh, f16* xl, const float* w1, const float* b1,
                 const float* w2, const float* b2, int Mtot) {
    f16 *W1h = WSP,           *W1l = WSP + 1048576,
        *W2h = WSP + 2097152, *W2l = WSP + 3145728;
    wsplit(w1, W1h, W1l, 512, 2048, 1);
    wsplit(w2, W2h, W2l, 2048, 512, 1);
    for (int c0 = 0; c0 < Mtot; c0 += 8192) {
      int rows = (Mtot - c0 < 8192) ? (Mtot - c0) : 8192;
      mgG(xh + (size_t)c0 * 512, xl + (size_t)c0 * 512, W1h, W1l, b1, Yh, Yl, rows, 2048, 512);
      mgR(Yh, Yl, W2h, W2l, b2, xh + (size_t)c0 * 512, xl + (size_t)c0 * 512,
          xh + (size_t)c0 * 512, xl + (size_t)c0 * 512, rows, 512, 2048);
    }
  };

  // ---------------- encoder ----------------
  k_pe<<<(2048 * 512) / 256, 256, 0, stream>>>(PE);
  k_embed<<<(16 * 2048 * 512) / 256, 256, 0, stream>>>(x_enc, x_mark_enc, enc_tok_w, enc_mark_w,
                                                       PE, Xh, Xl, 2048, 16 * 2048 * 512);
  int L = 2048;
  for (int l = 0; l < 3; ++l) {
    attn(Xh, Xl, Xh, Xl, L, L, enc_attn_w + (size_t)l * 4 * 262144,
         enc_attn_b + (size_t)l * 2048, false, (u32)l, true);
    ln(Xh, Xl, enc_ln_g + (size_t)(l * 2) * 512, enc_ln_b + (size_t)(l * 2) * 512, 16 * L,
       nullptr, Xh, Xl);
    ffn(Xh, Xl, enc_ffn1_w + (size_t)l * 512 * 2048, enc_ffn1_b + (size_t)l * 2048,
        enc_ffn2_w + (size_t)l * 2048 * 512, enc_ffn2_b + (size_t)l * 512, 16 * L);
    ln(Xh, Xl, enc_ln_g + (size_t)(l * 2 + 1) * 512, enc_ln_b + (size_t)(l * 2 + 1) * 512, 16 * L,
       nullptr, Xh, Xl);
    if (l < 2) {
      f16 *Dh = WSP, *Dl = WSP + 786432;
      k_wsplit_conv<<<(512 * 1536) / 256, 256, 0, stream>>>(distil_w + (size_t)l * 512 * 512 * 3, Dh, Dl);
      dim3 g(512 >> 7, (16 * L) >> 7);
      int lgL = (L == 2048) ? 11 : 10;
      k_mgemm2<2,0,1,0><<<g, 256, 0, stream>>>(Xh, Xl, Dh, Dl, distil_b + (size_t)l * 512,
          nullptr, nullptr, distil_bn_g + (size_t)l * 512, distil_bn_b + (size_t)l * 512,
          Y, nullptr, nullptr, 16 * L, 512, 1536, lgL);
      int Lo = L >> 1;
      k_maxpool<<<(16 * Lo * 512) / 256, 256, 0, stream>>>(Y, Xh, Xl, L);
      L = Lo;
    }
  }
  ln(Xh, Xl, enc_norm_g, enc_norm_b, 16 * 512, nullptr, ENCh, ENCl);

  // ---------------- decoder (in-place chain in Xh/Xl) ----------------
  k_embed<<<(16 * 1024 * 512) / 256, 256, 0, stream>>>(x_dec, x_mark_dec, dec_tok_w, dec_mark_w,
                                                       PE, Xh, Xl, 1024, 16 * 1024 * 512);
  for (int l = 0; l < 2; ++l) {
    attn(Xh, Xl, Xh, Xl, 1024, 1024, dec_self_w + (size_t)l * 4 * 262144,
         dec_self_b + (size_t)l * 2048, true, (u32)(100 + 2 * l), true);
    ln(Xh, Xl, dec_ln_g + (size_t)(l * 3) * 512, dec_ln_b + (size_t)(l * 3) * 512, 16384,
       nullptr, Xh, Xl);
    attn(Xh, Xl, ENCh, ENCl, 1024, 512, dec_cross_w + (size_t)l * 4 * 262144,
         dec_cross_b + (size_t)l * 2048, false, (u32)(101 + 2 * l), false);
    ln(Xh, Xl, dec_ln_g + (size_t)(l * 3 + 1) * 512, dec_ln_b + (size_t)(l * 3 + 1) * 512, 16384,
       nullptr, Xh, Xl);
    ffn(Xh, Xl, dec_ffn1_w + (size_t)l * 512 * 2048, dec_ffn1_b + (size_t)l * 2048,
        dec_ffn2_w + (size_t)l * 2048 * 512, dec_ffn2_b + (size_t)l * 512, 16384);
    ln(Xh, Xl, dec_ln_g + (size_t)(l * 3 + 2) * 512, dec_ln_b + (size_t)(l * 3 + 2) * 512, 16384,
       nullptr, Xh, Xl);
  }
  ln(Xh, Xl, dec_norm_g, dec_norm_b, 16384, Y, nullptr, nullptr);
  k_proj<<<(16 * 512 * 7 + 255) / 256, 256, 0, stream>>>(Y, proj_w, proj_b, (float*)d_out);
}

// Round 17
// 9854.630 us; speedup vs baseline: 2.0672x; 1.0146x over previous
//
#include <hip/hip_runtime.h>
#include <math.h>
#include <stdint.h>

typedef unsigned int u32;
typedef _Float16 f16;
typedef __attribute__((ext_vector_type(8))) _Float16 f16x8;
typedef __attribute__((ext_vector_type(4))) float f32x4;

// ---------------- Threefry-2x32 (20 rounds), matches JAX ----------------
__host__ __device__ __forceinline__ u32 rotl32(u32 x, int r) { return (x << r) | (x >> (32 - r)); }
__host__ __device__ __forceinline__ void tf_round(u32& x0, u32& x1, int r) {
  x0 += x1; x1 = rotl32(x1, r); x1 ^= x0;
}
__host__ __device__ __forceinline__ void tf_block(u32 k0, u32 k1, u32 x0, u32 x1, u32& o0, u32& o1) {
  u32 k2 = k0 ^ k1 ^ 0x1BD11BDAu;
  x0 += k0; x1 += k1;
  tf_round(x0,x1,13); tf_round(x0,x1,15); tf_round(x0,x1,26); tf_round(x0,x1,6);
  x0 += k1; x1 += k2 + 1u;
  tf_round(x0,x1,17); tf_round(x0,x1,29); tf_round(x0,x1,16); tf_round(x0,x1,24);
  x0 += k2; x1 += k0 + 2u;
  tf_round(x0,x1,13); tf_round(x0,x1,15); tf_round(x0,x1,26); tf_round(x0,x1,6);
  x0 += k0; x1 += k1 + 3u;
  tf_round(x0,x1,17); tf_round(x0,x1,29); tf_round(x0,x1,16); tf_round(x0,x1,24);
  x0 += k1; x1 += k2 + 4u;
  tf_round(x0,x1,13); tf_round(x0,x1,15); tf_round(x0,x1,26); tf_round(x0,x1,6);
  x0 += k2; x1 += k0 + 5u;
  o0 = x0; o1 = x1;
}

__global__ void k_idx(u32 ka, u32 kb, int n, int mask, int* __restrict__ idx) {
  int i = blockIdx.x * 256 + threadIdx.x;
  if (i >= n) return;
  u32 b1, b2; tf_block(ka, kb, 0u, (u32)i, b1, b2);
  idx[i] = (int)((b1 ^ b2) & (u32)mask);
}

__device__ __forceinline__ void emit_split(float v, f16* __restrict__ oh,
                                           f16* __restrict__ ol, size_t o) {
  f16 h = (f16)v;
  oh[o] = h;
  ol[o] = (f16)((v - (float)h) * 2048.0f);
}
__device__ __forceinline__ float rsplit(const f16* __restrict__ h,
                                        const f16* __restrict__ l, size_t o) {
  return (float)h[o] + (float)l[o] * (1.0f / 2048.0f);
}

// ---------------- positional embedding ----------------
__global__ void k_pe(float* __restrict__ pe) {
  int i = blockIdx.x * 256 + threadIdx.x;
  if (i >= 2048 * 512) return;
  int t = i >> 9, o = i & 511;
  float arg = (float)((o >> 1) * 2) * (float)(-(log(10000.0) / 512.0));
  float div = (float)exp((double)arg);
  float ang32 = (float)t * div;
  double ang = (double)ang32;
  pe[i] = (float)((o & 1) ? cos(ang) : sin(ang));
}

// ---------------- embedding (split-only output) ----------------
__global__ __launch_bounds__(256) void k_embed(
    const float* __restrict__ x, const float* __restrict__ mark,
    const float* __restrict__ tw, const float* __restrict__ mw,
    const float* __restrict__ pe, f16* __restrict__ oh, f16* __restrict__ ol,
    int L, int total) {
  int i = blockIdx.x * 256 + threadIdx.x;
  if (i >= total) return;
  int oo = i & 511;
  int bt = i >> 9;
  int t = bt % L;
  int b = bt / L;
  float acc = pe[(t << 9) + oo];
  #pragma unroll
  for (int k = 0; k < 3; ++k) {
    int st = t + k - 1; if (st < 0) st += L; else if (st >= L) st -= L;
    const float* xr = x + (size_t)(b * L + st) * 7;
    const float* wr = tw + oo * 21 + k;
    #pragma unroll
    for (int ii = 0; ii < 7; ++ii) acc += xr[ii] * wr[ii * 3];
  }
  const float* mr = mark + (size_t)bt * 4;
  #pragma unroll
  for (int m = 0; m < 4; ++m) acc += mr[m] * mw[(m << 9) + oo];
  emit_split(acc, oh, ol, ((size_t)bt << 9) + oo);
}

// ---------------- weight transpose + f16 split (z = matrix index) ----------------
__global__ __launch_bounds__(256) void k_wsplit(const float* __restrict__ W,
    f16* __restrict__ Wh, f16* __restrict__ Wl, int K, int N) {
  size_t zo = (size_t)blockIdx.z * K * N;
  W += zo; Wh += zo; Wl += zo;
  __shared__ float tile[32][33];
  int kb = blockIdx.x << 5, nb = blockIdx.y << 5;
  int t = threadIdx.x;
  int tr = t >> 5, tc = t & 31;
  #pragma unroll
  for (int p = 0; p < 4; ++p)
    tile[tr + p * 8][tc] = W[(size_t)(kb + tr + p * 8) * N + nb + tc];
  __syncthreads();
  #pragma unroll
  for (int p = 0; p < 4; ++p) {
    int n = tr + p * 8, k = tc;
    float v = tile[k][n];
    f16 h = (f16)v;
    size_t o = (size_t)(nb + n) * K + kb + k;
    Wh[o] = h;
    Wl[o] = (f16)((v - (float)h) * 2048.0f);
  }
}

__global__ void k_wsplit_conv(const float* __restrict__ w, f16* __restrict__ Wh, f16* __restrict__ Wl) {
  int i = blockIdx.x * 256 + threadIdx.x;
  if (i >= 512 * 1536) return;
  int o = i / 1536, k = i - o * 1536;
  float v = w[(size_t)o * 1536 + (k & 511) * 3 + (k >> 9)];
  f16 h = (f16)v;
  Wh[i] = h;
  Wl[i] = (f16)((v - (float)h) * 2048.0f);
}

__device__ __forceinline__ int swz_x(int r) { return ((((r >> 1) & 3) ^ ((r >> 3) & 3)) << 4); }

__device__ __forceinline__ void gload16(const void* g, void* l) {
  __builtin_amdgcn_global_load_lds(
      (const __attribute__((address_space(1))) void*)g,
      (__attribute__((address_space(3))) void*)l, 16, 0, 0);
}

// ---------------- MFMA GEMM v2: pre-split f16 A/B, async LDS, dbuf, 16x16x32 ----------------
template<int ACT, int OSPLIT, int GATHER, int RESID>
__global__ __launch_bounds__(256, 2) void k_mgemm2(
    const f16* __restrict__ Ah, const f16* __restrict__ Al,
    const f16* __restrict__ Bh, const f16* __restrict__ Bl,
    const float* __restrict__ bias,
    const f16* __restrict__ Rh, const f16* __restrict__ Rl,
    const float* __restrict__ bns, const float* __restrict__ bnb,
    float* __restrict__ C, f16* __restrict__ Ch, f16* __restrict__ Cl,
    int M, int N, int K, int lgL) {
  __shared__ char lds[65536];
  const int t = threadIdx.x;
  int nwg = gridDim.x * gridDim.y;
  int bid = blockIdx.y * gridDim.x + blockIdx.x;
  if ((nwg & 7) == 0) {
    int cpx = nwg >> 3;
    bid = (bid & 7) * cpx + (bid >> 3);
  }
  const int bm = (bid / gridDim.x) << 7, bn = (bid % gridDim.x) << 7;
  const int w = t >> 6, l = t & 63;
  const int lr = l >> 2;
  const int qx = (l & 3) << 4;
  const int wr = (w >> 1) << 6, wc = (w & 1) << 6;
  const int fr = l & 15;
  const int fkB = (l >> 4) << 4;
  const f32x4 zero = {0.f, 0.f, 0.f, 0.f};
  f32x4 acc1[4][4], acc2[4][4];
  #pragma unroll
  for (int i = 0; i < 4; ++i)
    #pragma unroll
    for (int j = 0; j < 4; ++j) { acc1[i][j] = zero; acc2[i][j] = zero; }

  auto stage = [&](int k0, int bufo) {
    #pragma unroll
    for (int c = 0; c < 2; ++c) {
      int r = w * 32 + c * 16 + lr;
      int sx = qx ^ swz_x(r);
      const char *gAh, *gAl;
      if (GATHER) {
        int m = bm + r;
        int Lm = 1 << lgL;
        int ab = m >> lgL, at = m & (Lm - 1);
        int ke = k0 + (sx >> 1);
        int tap = ke >> 9, ii = ke & 511;
        int st = at + tap - 1; if (st < 0) st += Lm; else if (st >= Lm) st -= Lm;
        size_t aoff = (((size_t)((ab << lgL) + st)) << 9) + ii;
        gAh = (const char*)(Ah + aoff);
        gAl = (const char*)(Al + aoff);
      } else {
        gAh = (const char*)(Ah + (size_t)(bm + r) * K + k0) + sx;
        gAl = (const char*)(Al + (size_t)(bm + r) * K + k0) + sx;
      }
      const char* gBh = (const char*)(Bh + (size_t)(bn + r) * K + k0) + sx;
      const char* gBl = (const char*)(Bl + (size_t)(bn + r) * K + k0) + sx;
      char* base = lds + bufo + w * 2048 + c * 1024;
      gload16(gAh, base);
      gload16(gAl, base + 8192);
      gload16(gBh, base + 16384);
      gload16(gBl, base + 24576);
    }
  };

  int nt = K >> 5;
  stage(0, 0);
  __syncthreads();
  int bufo = 0;
  for (int tt = 0; tt < nt; ++tt) {
    int nb = bufo ^ 32768;
    if (tt + 1 < nt) stage((tt + 1) << 5, nb);
    char* pAh = lds + bufo;
    char* pAl = pAh + 8192;
    char* pBh = pAh + 16384;
    char* pBl = pAh + 24576;
    f16x8 ah4[4], al4[4];
    #pragma unroll
    for (int i = 0; i < 4; ++i) {
      int r = wr + i * 16 + fr;
      int ob = r * 64 + (fkB ^ swz_x(r));
      ah4[i] = *(f16x8*)(pAh + ob);
      al4[i] = *(f16x8*)(pAl + ob);
    }
    #pragma unroll
    for (int j = 0; j < 4; ++j) {
      int r = wc + j * 16 + fr;
      int ob = r * 64 + (fkB ^ swz_x(r));
      f16x8 bh_ = *(f16x8*)(pBh + ob);
      f16x8 bl_ = *(f16x8*)(pBl + ob);
      #pragma unroll
      for (int i = 0; i < 4; ++i) {
        acc1[i][j] = __builtin_amdgcn_mfma_f32_16x16x32_f16(ah4[i], bh_, acc1[i][j], 0, 0, 0);
        acc2[i][j] = __builtin_amdgcn_mfma_f32_16x16x32_f16(ah4[i], bl_, acc2[i][j], 0, 0, 0);
        acc2[i][j] = __builtin_amdgcn_mfma_f32_16x16x32_f16(al4[i], bh_, acc2[i][j], 0, 0, 0);
      }
    }
    __syncthreads();
    bufo = nb;
  }
  #pragma unroll
  for (int j = 0; j < 4; ++j) {
    int col = bn + wc + j * 16 + fr;
    float bsv = bias[col];
    float g2 = 0.f, b2 = 0.f;
    if (ACT == 2) { g2 = bns[col] * 0.9999950000375f; b2 = bnb[col]; }
    #pragma unroll
    for (int i = 0; i < 4; ++i) {
      #pragma unroll
      for (int r = 0; r < 4; ++r) {
        int row = bm + wr + i * 16 + ((l >> 4) << 2) + r;
        float v = acc1[i][j][r] + acc2[i][j][r] * (1.0f / 2048.0f) + bsv;
        if (ACT == 1) v = 0.5f * v * (1.0f + erff(v * 0.70710678118654752f));
        if (ACT == 2) { v = v * g2 + b2; v = v > 0.f ? v : expm1f(v); }
        size_t oi = (size_t)row * N + col;
        if (RESID) v += rsplit(Rh, Rl, oi);
        if (OSPLIT) emit_split(v, Ch, Cl, oi);
        else        C[oi] = v;
      }
    }
  }
}

// ---------------- LayerNorm on split input; optional split / f32 outputs ----------------
__global__ __launch_bounds__(256) void k_ln(const f16* __restrict__ xh, const f16* __restrict__ xl,
    const float* __restrict__ g, const float* __restrict__ b,
    float* __restrict__ of32, f16* __restrict__ oh, f16* __restrict__ ol) {
  int row = blockIdx.x, t = threadIdx.x;
  size_t base = (size_t)row << 9;
  float v0 = rsplit(xh, xl, base + t);
  float v1 = rsplit(xh, xl, base + t + 256);
  float s = v0 + v1;
  #pragma unroll
  for (int off = 32; off; off >>= 1) s += __shfl_down(s, off);
  __shared__ float ls[4];
  if ((t & 63) == 0) ls[t >> 6] = s;
  __syncthreads();
  float mean = (ls[0] + ls[1] + ls[2] + ls[3]) * (1.f / 512.f);
  __syncthreads();
  float d0 = v0 - mean, d1 = v1 - mean;
  float q = d0 * d0 + d1 * d1;
  #pragma unroll
  for (int off = 32; off; off >>= 1) q += __shfl_down(q, off);
  if ((t & 63) == 0) ls[t >> 6] = q;
  __syncthreads();
  float var = (ls[0] + ls[1] + ls[2] + ls[3]) * (1.f / 512.f);
  float rs = rsqrtf(var + 1e-5f);
  float r0 = d0 * rs * g[t] + b[t];
  float r1 = d1 * rs * g[t + 256] + b[t + 256];
  if (of32) { of32[base + t] = r0; of32[base + t + 256] = r1; }
  if (oh) {
    emit_split(r0, oh, ol, base + t);
    emit_split(r1, oh, ol, base + t + 256);
  }
}

// ---------------- M[bh,l] scoring (strided Q/K) ----------------
__global__ __launch_bounds__(256) void k_qkM(const float* __restrict__ Q, int qstr,
    const float* __restrict__ Kp, int kstr, const int* __restrict__ idx,
    float* __restrict__ M, int Lq, int Lk, int U) {
  int wid = (blockIdx.x * 256 + threadIdx.x) >> 6;
  int lane = threadIdx.x & 63;
  int l = wid & (Lq - 1); int bh = wid / Lq; int h = bh & 7; int b = bh >> 3;
  float dot = 0.f;
  if (lane < U) {
    int kr = idx[l * U + lane];
    const float4* q4 = (const float4*)(Q + (size_t)(b * Lq + l) * qstr + (h << 6));
    const float4* k4 = (const float4*)(Kp + (size_t)(b * Lk + kr) * kstr + (h << 6));
    #pragma unroll
    for (int i = 0; i < 16; ++i) {
      float4 a = q4[i], c = k4[i];
      dot += a.x * c.x + a.y * c.y + a.z * c.z + a.w * c.w;
    }
  }
  float mx = (lane < U) ? dot : -INFINITY;
  float sm = (lane < U) ? dot : 0.f;
  #pragma unroll
  for (int off = 32; off; off >>= 1) {
    mx = fmaxf(mx, __shfl_xor(mx, off));
    sm += __shfl_xor(sm, off);
  }
  if (lane == 0) M[(size_t)bh * Lq + l] = mx - sm / (float)Lk;
}

// ---------------- single-wave top-u per (b,h), ties -> lower index ----------------
__global__ void k_topk64(const float* __restrict__ M, int* __restrict__ mtop, int Lq, int u) {
  __shared__ float vals[2048];
  int bh = blockIdx.x, l = threadIdx.x;
  const float* Mr = M + (size_t)bh * Lq;
  for (int i = l; i < Lq; i += 64) vals[i] = Mr[i];
  __syncthreads();
  for (int it = 0; it < u; ++it) {
    float bv = -INFINITY; int bi = 0x7fffffff;
    for (int i = l; i < Lq; i += 64) {
      float v = vals[i];
      if (v > bv || (v == bv && i < bi)) { bv = v; bi = i; }
    }
    #pragma unroll
    for (int off = 32; off; off >>= 1) {
      float vv = __shfl_xor(bv, off); int ii = __shfl_xor(bi, off);
      if (vv > bv || (vv == bv && ii < bi)) { bv = vv; bi = ii; }
    }
    if (l == 0) { mtop[bh * u + it] = bi; vals[bi] = -INFINITY; }
    __syncthreads();
  }
}

// ---------------- ctx mean (AO split) ----------------
__global__ void k_cm1(const float* __restrict__ V, int vstr, float* __restrict__ PS,
                      int Lk, int rows) {
  int bid = blockIdx.x;
  int bh = bid >> 4, seg = bid & 15, d = threadIdx.x;
  int b = bh >> 3, h = bh & 7;
  const float* vp = V + (size_t)(b * Lk + seg * rows) * vstr + (h << 6) + d;
  float acc = 0.f;
  for (int r = 0; r < rows; ++r) acc += vp[(size_t)r * vstr];
  PS[(bid << 6) + d] = acc;
}
__global__ void k_cm2(const float* __restrict__ PS, f16* __restrict__ AOh,
                      f16* __restrict__ AOl, float invLk, int Lq, int total) {
  int i = blockIdx.x * 256 + threadIdx.x;
  if (i >= total) return;
  int c = i & 511; int h = c >> 6; int d = c & 63;
  int r = i >> 9; int b = r / Lq;
  float acc = 0.f;
  #pragma unroll
  for (int s = 0; s < 16; ++s) acc += PS[(((((b << 3) + h) << 4) + s) << 6) + d];
  emit_split(acc * invLk, AOh, AOl, (size_t)i);
}

// ---------------- cumsum (masked ctx; per-block prefix, AO split) ----------------
__global__ void k_cs1(const float* __restrict__ V, int vstr, float* __restrict__ PS,
                      int Lq, int rows) {
  int bid = blockIdx.x;
  int bh = bid >> 3, seg = bid & 7, d = threadIdx.x;
  int b = bh >> 3, h = bh & 7;
  const float* vp = V + (size_t)(b * Lq + seg * rows) * vstr + (h << 6) + d;
  float acc = 0.f;
  for (int r = 0; r < rows; ++r) acc += vp[(size_t)r * vstr];
  PS[(bid << 6) + d] = acc;
}
__global__ void k_cs3(const float* __restrict__ V, int vstr, const float* __restrict__ PS,
                      f16* __restrict__ AOh, f16* __restrict__ AOl, int Lq, int rows) {
  int bid = blockIdx.x;
  int bh = bid >> 3, seg = bid & 7, d = threadIdx.x;
  int b = bh >> 3, h = bh & 7;
  float acc = 0.f;
  for (int s2 = 0; s2 < seg; ++s2) acc += PS[(((bh << 3) + s2) << 6) + d];
  const float* vp = V + (size_t)(b * Lq + seg * rows) * vstr + (h << 6) + d;
  size_t ob = ((size_t)(b * Lq + seg * rows) << 9) + (h << 6) + d;
  for (int r = 0; r < rows; ++r) {
    acc += vp[(size_t)r * vstr];
    emit_split(acc, AOh, AOl, ob + ((size_t)r << 9));
  }
}

// ---------------- sparse attn partials: 4 rows x 512-col chunk per block ----------------
// grid (nbb, nch, bhn). Emits per (chunk,row): max, expsum, pv[64].
__global__ __launch_bounds__(256) void k_sattn4p(
    const float* __restrict__ Q, int qstr, const float* __restrict__ Kp, int kstr,
    const float* __restrict__ Vp, int vstr, const int* __restrict__ mtop,
    float* __restrict__ PPm, float* __restrict__ PPs, float* __restrict__ PPv,
    int Lq, int Lk, int u, int masked, int bhn) {
  __shared__ float sc[4][512];
  __shared__ float qs[4][64];
  __shared__ float red[4][256];
  __shared__ float pv[4][4][64];
  __shared__ int rowsh[4];
  __shared__ float mxs[4];
  int ub = blockIdx.x, ch = blockIdx.y, bh = blockIdx.z;
  int b = bh >> 3, h = bh & 7;
  int c0 = ch << 9;
  int t = threadIdx.x;
  if (t < 4) {
    int ui = ub * 4 + t;
    rowsh[t] = (ui < u) ? mtop[bh * u + ui] : -1;
  }
  __syncthreads();
  {
    int r = t >> 6, d = t & 63;
    int row = rowsh[r];
    qs[r][d] = (row >= 0) ? Q[(size_t)(b * Lq + row) * qstr + (h << 6) + d] : 0.f;
  }
  __syncthreads();
  float lm0 = -INFINITY, lm1 = -INFINITY, lm2 = -INFINITY, lm3 = -INFINITY;
  for (int c = c0 + t; c < c0 + 512; c += 256) {
    const float4* kr = (const float4*)(Kp + (size_t)(b * Lk + c) * kstr + (h << 6));
    float d0 = 0.f, d1 = 0.f, d2 = 0.f, d3 = 0.f;
    #pragma unroll
    for (int e = 0; e < 16; ++e) {
      float4 kk = kr[e];
      d0 += qs[0][4*e]*kk.x + qs[0][4*e+1]*kk.y + qs[0][4*e+2]*kk.z + qs[0][4*e+3]*kk.w;
      d1 += qs[1][4*e]*kk.x + qs[1][4*e+1]*kk.y + qs[1][4*e+2]*kk.z + qs[1][4*e+3]*kk.w;
      d2 += qs[2][4*e]*kk.x + qs[2][4*e+1]*kk.y + qs[2][4*e+2]*kk.z + qs[2][4*e+3]*kk.w;
      d3 += qs[3][4*e]*kk.x + qs[3][4*e+1]*kk.y + qs[3][4*e+2]*kk.z + qs[3][4*e+3]*kk.w;
    }
    float dd[4] = {d0, d1, d2, d3};
    #pragma unroll
    for (int r = 0; r < 4; ++r) {
      float v = dd[r] * 0.125f;
      if (masked && c > rowsh[r]) v = -INFINITY;
      sc[r][c - c0] = v;
    }
    lm0 = fmaxf(lm0, sc[0][c - c0]); lm1 = fmaxf(lm1, sc[1][c - c0]);
    lm2 = fmaxf(lm2, sc[2][c - c0]); lm3 = fmaxf(lm3, sc[3][c - c0]);
  }
  red[0][t] = lm0; red[1][t] = lm1; red[2][t] = lm2; red[3][t] = lm3;
  __syncthreads();
  {
    int w = t >> 6, lane = t & 63;
    float m = fmaxf(fmaxf(red[w][lane], red[w][lane + 64]),
                    fmaxf(red[w][lane + 128], red[w][lane + 192]));
    #pragma unroll
    for (int off = 32; off; off >>= 1) m = fmaxf(m, __shfl_xor(m, off));
    if (lane == 0) mxs[w] = m;
  }
  __syncthreads();
  float ls0 = 0.f, ls1 = 0.f, ls2 = 0.f, ls3 = 0.f;
  float m0 = mxs[0], m1 = mxs[1], m2 = mxs[2], m3 = mxs[3];
  bool f0 = m0 > -3e38f, f1 = m1 > -3e38f, f2 = m2 > -3e38f, f3 = m3 > -3e38f;
  for (int c = t; c < 512; c += 256) {
    float e0 = f0 ? expf(sc[0][c] - m0) : 0.f; sc[0][c] = e0; ls0 += e0;
    float e1 = f1 ? expf(sc[1][c] - m1) : 0.f; sc[1][c] = e1; ls1 += e1;
    float e2 = f2 ? expf(sc[2][c] - m2) : 0.f; sc[2][c] = e2; ls2 += e2;
    float e3 = f3 ? expf(sc[3][c] - m3) : 0.f; sc[3][c] = e3; ls3 += e3;
  }
  red[0][t] = ls0; red[1][t] = ls1; red[2][t] = ls2; red[3][t] = ls3;
  __syncthreads();
  {
    int w = t >> 6, lane = t & 63;
    float s = red[w][lane] + red[w][lane + 64] + red[w][lane + 128] + red[w][lane + 192];
    #pragma unroll
    for (int off = 32; off; off >>= 1) s += __shfl_xor(s, off);
    if (lane == 0) {
      int ui = ub * 4 + w;
      if (ui < u) {
        size_t pidx = (size_t)(ch * bhn + bh) * u + ui;
        PPm[pidx] = mxs[w];
        PPs[pidx] = s;
      }
    }
  }
  __syncthreads();
  {
    int g = t >> 6, d = t & 63;
    float a0 = 0.f, a1 = 0.f, a2 = 0.f, a3 = 0.f;
    for (int c = g; c < 512; c += 4) {
      float v = Vp[(size_t)(b * Lk + c0 + c) * vstr + (h << 6) + d];
      a0 += sc[0][c] * v; a1 += sc[1][c] * v; a2 += sc[2][c] * v; a3 += sc[3][c] * v;
    }
    pv[g][0][d] = a0; pv[g][1][d] = a1; pv[g][2][d] = a2; pv[g][3][d] = a3;
  }
  __syncthreads();
  {
    int r = t >> 6, d = t & 63;
    int ui = ub * 4 + r;
    if (ui < u) {
      float s = pv[0][r][d] + pv[1][r][d] + pv[2][r][d] + pv[3][r][d];
      PPv[((size_t)(ch * bhn + bh) * u + ui) * 64 + d] = s;
    }
  }
}

// ---------------- combine chunk partials -> AO (online softmax rescale) ----------------
__global__ void k_sattnc(const float* __restrict__ PPm, const float* __restrict__ PPs,
                         const float* __restrict__ PPv, const int* __restrict__ mtop,
                         f16* __restrict__ AOh, f16* __restrict__ AOl,
                         int Lq, int u, int nch, int bhn) {
  int rowid = blockIdx.x;
  int bh = rowid / u, ui = rowid % u;
  int d = threadIdx.x;
  int b = bh >> 3, h = bh & 7;
  int row = mtop[bh * u + ui];
  float M = -INFINITY;
  for (int c = 0; c < nch; ++c)
    M = fmaxf(M, PPm[(size_t)(c * bhn + bh) * u + ui]);
  float S = 0.f, o = 0.f;
  for (int c = 0; c < nch; ++c) {
    size_t pidx = (size_t)(c * bhn + bh) * u + ui;
    float pm = PPm[pidx];
    float sc = (pm > -3e38f) ? expf(pm - M) : 0.f;
    S += sc * PPs[pidx];
    o += sc * PPv[pidx * 64 + d];
  }
  emit_split(o / S, AOh, AOl, ((size_t)(b * Lq + row) << 9) + (h << 6) + d);
}

// ---------------- maxpool w3 s2 p1 along L (split-only output) ----------------
__global__ void k_maxpool(const float* __restrict__ y, f16* __restrict__ oh,
                          f16* __restrict__ ol, int L) {
  int Lo = L >> 1;
  int i = blockIdx.x * 256 + threadIdx.x;
  int c = i & 511; int bj = i >> 9;
  int j = bj % Lo; int b = bj / Lo;
  float m = -INFINITY;
  int t0 = 2 * j - 1;
  #pragma unroll
  for (int k = 0; k < 3; ++k) {
    int tt = t0 + k;
    if (tt >= 0 && tt < L) m = fmaxf(m, y[((size_t)(b * L + tt) << 9) + c]);
  }
  emit_split(m, oh, ol, ((size_t)(b * Lo + j) << 9) + c);
}

// ---------------- final projection 512->7 (reads f32 from Y) ----------------
__global__ void k_proj(const float* __restrict__ Xn, const float* __restrict__ pw,
                       const float* __restrict__ pb, float* __restrict__ out) {
  int i = blockIdx.x * 256 + threadIdx.x;
  if (i >= 16 * 512 * 7) return;
  int c = i % 7; int r = i / 7;
  int b = r >> 9; int j = r & 511;
  const float* xr = Xn + ((size_t)(b * 1024 + 512 + j) << 9);
  float acc = pb[c];
  for (int d2 = 0; d2 < 512; ++d2) acc += xr[d2] * pw[d2 * 7 + c];
  out[i] = acc;
}

// =====================================================================
extern "C" void kernel_launch(void* const* d_in, const int* in_sizes, int n_in,
                              void* d_out, int out_size, void* d_ws, size_t ws_size,
                              hipStream_t stream) {
  const float* x_enc      = (const float*)d_in[0];
  const float* x_mark_enc = (const float*)d_in[1];
  const float* x_dec      = (const float*)d_in[2];
  const float* x_mark_dec = (const float*)d_in[3];
  const float* enc_tok_w  = (const float*)d_in[4];
  const float* enc_mark_w = (const float*)d_in[5];
  const float* dec_tok_w  = (const float*)d_in[6];
  const float* dec_mark_w = (const float*)d_in[7];
  const float* enc_attn_w = (const float*)d_in[8];
  const float* enc_attn_b = (const float*)d_in[9];
  const float* enc_ffn1_w = (const float*)d_in[10];
  const float* enc_ffn1_b = (const float*)d_in[11];
  const float* enc_ffn2_w = (const float*)d_in[12];
  const float* enc_ffn2_b = (const float*)d_in[13];
  const float* enc_ln_g   = (const float*)d_in[14];
  const float* enc_ln_b   = (const float*)d_in[15];
  const float* distil_w   = (const float*)d_in[16];
  const float* distil_b   = (const float*)d_in[17];
  const float* distil_bn_g= (const float*)d_in[18];
  const float* distil_bn_b= (const float*)d_in[19];
  const float* enc_norm_g = (const float*)d_in[20];
  const float* enc_norm_b = (const float*)d_in[21];
  const float* dec_self_w = (const float*)d_in[22];
  const float* dec_self_b = (const float*)d_in[23];
  const float* dec_cross_w= (const float*)d_in[24];
  const float* dec_cross_b= (const float*)d_in[25];
  const float* dec_ffn1_w = (const float*)d_in[26];
  const float* dec_ffn1_b = (const float*)d_in[27];
  const float* dec_ffn2_w = (const float*)d_in[28];
  const float* dec_ffn2_b = (const float*)d_in[29];
  const float* dec_ln_g   = (const float*)d_in[30];
  const float* dec_ln_b   = (const float*)d_in[31];
  const float* dec_norm_g = (const float*)d_in[32];
  const float* dec_norm_b = (const float*)d_in[33];
  const float* proj_w     = (const float*)d_in[34];
  const float* proj_b     = (const float*)d_in[35];

  // -------- workspace layout: split-only activations; Y sized by tier --------
  float* ws = (float*)d_ws;
  size_t off = 0;
  f16* Xh   = (f16*)(ws + off); off += 16777216;
  f16* Xl   = Xh + 16777216;
  f16* ENCh = (f16*)(ws + off); off += 4194304;
  f16* ENCl = ENCh + 4194304;
  float* PE = ws + off; off += 1048576;
  float* Mb = ws + off; off += 131072;
  float* PS = ws + off; off += 65536;
  f16* WSP  = (f16*)(ws + off); off += 2097152;
  int* IDXi = (int*)(ws + off); off += 84480;
  float* Y  = ws + off;
  int* MTi  = IDXi + 81920;
  size_t need4 = (off + 16777216ull) * 4;
  size_t need8 = (off + 33554432ull) * 4;
  int bs;
  if      (ws_size >= need8) bs = 8;
  else if (ws_size >= need4) bs = 4;
  else return;
  f16* Yh = (f16*)Y;
  f16* Yl = Yh + 16777216;
  // attention chunk partials live in the free upper half of WSP (weights use lower half)
  float* WF  = (float*)WSP + 1048576;
  float* PPm = WF;              // <= 16384
  float* PPs = WF + 16384;      // <= 16384
  float* PPv = WF + 32768;      // <= 655360

  auto ln = [&](const f16* xh, const f16* xl, const float* g, const float* b, int rows,
                float* of32, f16* oh, f16* ol) {
    k_ln<<<rows, 256, 0, stream>>>(xh, xl, g, b, of32, oh, ol);
  };
  auto wsplit = [&](const float* W, f16* Wh, f16* Wl, int K, int N, int nmat) {
    dim3 g(K >> 5, N >> 5, nmat);
    k_wsplit<<<g, 256, 0, stream>>>(W, Wh, Wl, K, N);
  };
  auto mgQ = [&](const f16* Ah, const f16* Al, const f16* Wh, const f16* Wl,
                 const float* bias, float* C, int M, int N, int K) {
    dim3 g(N >> 7, M >> 7);
    k_mgemm2<0,0,0,0><<<g, 256, 0, stream>>>(Ah, Al, Wh, Wl, bias, nullptr, nullptr,
        nullptr, nullptr, C, nullptr, nullptr, M, N, K, 0);
  };
  auto mgR = [&](const f16* Ah, const f16* Al, const f16* Wh, const f16* Wl,
                 const float* bias, const f16* Rh, const f16* Rl,
                 f16* Ch, f16* Cl, int M, int N, int K) {
    dim3 g(N >> 7, M >> 7);
    k_mgemm2<0,1,0,1><<<g, 256, 0, stream>>>(Ah, Al, Wh, Wl, bias, Rh, Rl,
        nullptr, nullptr, nullptr, Ch, Cl, M, N, K, 0);
  };
  auto mgG = [&](const f16* Ah, const f16* Al, const f16* Wh, const f16* Wl,
                 const float* bias, f16* Ch, f16* Cl, int M, int N, int K) {
    dim3 g(N >> 7, M >> 7);
    k_mgemm2<1,1,0,0><<<g, 256, 0, stream>>>(Ah, Al, Wh, Wl, bias, nullptr, nullptr,
        nullptr, nullptr, nullptr, Ch, Cl, M, N, K, 0);
  };
  auto Uof = [](int Lx) { int v = 5 * (int)ceil(log((double)Lx)); return v < Lx ? v : Lx; };

  auto attn = [&](f16* xqh, f16* xql, const f16* xkvh, const f16* xkvl,
                  int Lq, int Lk, const float* w, const float* bias,
                  bool masked, u32 fold, bool selfa) {
    int U = Uof(Lk), uu = Uof(Lq);
    u32 r0, r1, ka, kb2;
    tf_block(0u, 42u, 0u, fold, r0, r1);
    tf_block(r0, r1, 0u, 1u, ka, kb2);
    int n = Lq * U;
    k_idx<<<(n + 255) / 256, 256, 0, stream>>>(ka, kb2, n, Lk - 1, IDXi);

    f16 *Wqkvh = WSP,            *Wqkvl = WSP + 786432;
    f16 *WQh   = WSP,            *WQl   = WSP + 262144;
    f16 *WKVh  = WSP + 524288,   *WKVl  = WSP + 1048576;
    f16 *WOh   = WSP + 1572864,  *WOl   = WSP + 1835008;
    if (selfa) {
      wsplit(w, Wqkvh, Wqkvl, 512, 512, 3);
    } else {
      wsplit(w, WQh, WQl, 512, 512, 1);
      wsplit(w + 262144, WKVh, WKVl, 512, 512, 2);
    }
    wsplit(w + 786432, WOh, WOl, 512, 512, 1);

    int nsl = 16 / bs;
    int bhn = bs * 8;
    for (int s = 0; s < nsl; ++s) {
      size_t qoff = (size_t)s * bs * Lq * 512;
      size_t koff = (size_t)s * bs * Lk * 512;
      const float *qp, *kp, *vp;
      int qstr, kstr, vstr;
      f16 *AOh, *AOl;
      if (selfa) {
        float* QKV = Y;
        AOh = (f16*)(Y + (size_t)bs * Lq * 1536);
        AOl = AOh + (size_t)bs * Lq * 512;
        mgQ(xqh + qoff, xql + qoff, Wqkvh, Wqkvl, bias, QKV, bs * Lq, 1536, 512);
        qp = QKV; qstr = 1536; kp = QKV + 512; kstr = 1536; vp = QKV + 1024; vstr = 1536;
      } else {
        float* Qb  = Y;
        float* KVb = Y + (size_t)bs * Lq * 512;
        AOh = (f16*)(KVb + (size_t)bs * Lk * 1024);
        AOl = AOh + (size_t)bs * Lq * 512;
        mgQ(xqh + qoff, xql + qoff, WQh, WQl, bias, Qb, bs * Lq, 512, 512);
        mgQ(xkvh + koff, xkvl + koff, WKVh, WKVl, bias + 512, KVb, bs * Lk, 1024, 512);
        qp = Qb; qstr = 512; kp = KVb; kstr = 1024; vp = KVb + 512; vstr = 1024;
      }
      int wids = bhn * Lq;
      k_qkM<<<wids / 4, 256, 0, stream>>>(qp, qstr, kp, kstr, IDXi, Mb, Lq, Lk, U);
      k_topk64<<<bhn, 64, 0, stream>>>(Mb, MTi, Lq, uu);
      if (masked) {
        k_cs1<<<bhn * 8, 64, 0, stream>>>(vp, vstr, PS, Lq, Lq >> 3);
        k_cs3<<<bhn * 8, 64, 0, stream>>>(vp, vstr, PS, AOh, AOl, Lq, Lq >> 3);
      } else {
        k_cm1<<<bhn * 16, 64, 0, stream>>>(vp, vstr, PS, Lk, Lk >> 4);
        int tot = bs * Lq * 512;
        k_cm2<<<tot / 256, 256, 0, stream>>>(PS, AOh, AOl, 1.0f / (float)Lk, Lq, tot);
      }
      int nbb = (uu + 3) >> 2;
      int nch = Lk >> 9;
      dim3 gs(nbb, nch, bhn);
      k_sattn4p<<<gs, 256, 0, stream>>>(qp, qstr, kp, kstr, vp, vstr, MTi,
                                        PPm, PPs, PPv, Lq, Lk, uu, masked ? 1 : 0, bhn);
      k_sattnc<<<bhn * uu, 64, 0, stream>>>(PPm, PPs, PPv, MTi, AOh, AOl, Lq, uu, nch, bhn);
      mgR(AOh, AOl, WOh, WOl, bias + 1536, xqh + qoff, xql + qoff,
          xqh + qoff, xql + qoff, bs * Lq, 512, 512);
    }
  };

  auto ffn = [&](f16* xh, f16* xl, const float* w1, const float* b1,
                 const float* w2, const float* b2, int Mtot) {
    f16 *W1h = WSP,           *W1l = WSP + 1048576,
        *W2h = WSP + 2097152, *W2l = WSP + 3145728;
    wsplit(w1, W1h, W1l, 512, 2048, 1);
    wsplit(w2, W2h, W2l, 2048, 512, 1);
    for (int c0 = 0; c0 < Mtot; c0 += 8192) {
      int rows = (Mtot - c0 < 8192) ? (Mtot - c0) : 8192;
      mgG(xh + (size_t)c0 * 512, xl + (size_t)c0 * 512, W1h, W1l, b1, Yh, Yl, rows, 2048, 512);
      mgR(Yh, Yl, W2h, W2l, b2, xh + (size_t)c0 * 512, xl + (size_t)c0 * 512,
          xh + (size_t)c0 * 512, xl + (size_t)c0 * 512, rows, 512, 2048);
    }
  };

  // ---------------- encoder ----------------
  k_pe<<<(2048 * 512) / 256, 256, 0, stream>>>(PE);
  k_embed<<<(16 * 2048 * 512) / 256, 256, 0, stream>>>(x_enc, x_mark_enc, enc_tok_w, enc_mark_w,
                                                       PE, Xh, Xl, 2048, 16 * 2048 * 512);
  int L = 2048;
  for (int l = 0; l < 3; ++l) {
    attn(Xh, Xl, Xh, Xl, L, L, enc_attn_w + (size_t)l * 4 * 262144,
         enc_attn_b + (size_t)l * 2048, false, (u32)l, true);
    ln(Xh, Xl, enc_ln_g + (size_t)(l * 2) * 512, enc_ln_b + (size_t)(l * 2) * 512, 16 * L,
       nullptr, Xh, Xl);
    ffn(Xh, Xl, enc_ffn1_w + (size_t)l * 512 * 2048, enc_ffn1_b + (size_t)l * 2048,
        enc_ffn2_w + (size_t)l * 2048 * 512, enc_ffn2_b + (size_t)l * 512, 16 * L);
    ln(Xh, Xl, enc_ln_g + (size_t)(l * 2 + 1) * 512, enc_ln_b + (size_t)(l * 2 + 1) * 512, 16 * L,
       nullptr, Xh, Xl);
    if (l < 2) {
      f16 *Dh = WSP, *Dl = WSP + 786432;
      k_wsplit_conv<<<(512 * 1536) / 256, 256, 0, stream>>>(distil_w + (size_t)l * 512 * 512 * 3, Dh, Dl);
      dim3 g(512 >> 7, (16 * L) >> 7);
      int lgL = (L == 2048) ? 11 : 10;
      k_mgemm2<2,0,1,0><<<g, 256, 0, stream>>>(Xh, Xl, Dh, Dl, distil_b + (size_t)l * 512,
          nullptr, nullptr, distil_bn_g + (size_t)l * 512, distil_bn_b + (size_t)l * 512,
          Y, nullptr, nullptr, 16 * L, 512, 1536, lgL);
      int Lo = L >> 1;
      k_maxpool<<<(16 * Lo * 512) / 256, 256, 0, stream>>>(Y, Xh, Xl, L);
      L = Lo;
    }
  }
  ln(Xh, Xl, enc_norm_g, enc_norm_b, 16 * 512, nullptr, ENCh, ENCl);

  // ---------------- decoder (in-place chain in Xh/Xl) ----------------
  k_embed<<<(16 * 1024 * 512) / 256, 256, 0, stream>>>(x_dec, x_mark_dec, dec_tok_w, dec_mark_w,
                                                       PE, Xh, Xl, 1024, 16 * 1024 * 512);
  for (int l = 0; l < 2; ++l) {
    attn(Xh, Xl, Xh, Xl, 1024, 1024, dec_self_w + (size_t)l * 4 * 262144,
         dec_self_b + (size_t)l * 2048, true, (u32)(100 + 2 * l), true);
    ln(Xh, Xl, dec_ln_g + (size_t)(l * 3) * 512, dec_ln_b + (size_t)(l * 3) * 512, 16384,
       nullptr, Xh, Xl);
    attn(Xh, Xl, ENCh, ENCl, 1024, 512, dec_cross_w + (size_t)l * 4 * 262144,
         dec_cross_b + (size_t)l * 2048, false, (u32)(101 + 2 * l), false);
    ln(Xh, Xl, dec_ln_g + (size_t)(l * 3 + 1) * 512, dec_ln_b + (size_t)(l * 3 + 1) * 512, 16384,
       nullptr, Xh, Xl);
    ffn(Xh, Xl, dec_ffn1_w + (size_t)l * 512 * 2048, dec_ffn1_b + (size_t)l * 2048,
        dec_ffn2_w + (size_t)l * 2048 * 512, dec_ffn2_b + (size_t)l * 512, 16384);
    ln(Xh, Xl, dec_ln_g + (size_t)(l * 3 + 2) * 512, dec_ln_b + (size_t)(l * 3 + 2) * 512, 16384,
       nullptr, Xh, Xl);
  }
  ln(Xh, Xl, dec_norm_g, dec_norm_b, 16384, Y, nullptr, nullptr);
  k_proj<<<(16 * 512 * 7 + 255) / 256, 256, 0, stream>>>(Y, proj_w, proj_b, (float*)d_out);
}

// Round 18
// 8268.510 us; speedup vs baseline: 2.4637x; 1.1918x over previous
//
#include <hip/hip_runtime.h>
#include <math.h>
#include <stdint.h>

typedef unsigned int u32;
typedef _Float16 f16;
typedef __attribute__((ext_vector_type(8))) _Float16 f16x8;
typedef __attribute__((ext_vector_type(4))) float f32x4;

// ---------------- Threefry-2x32 (20 rounds), matches JAX ----------------
__host__ __device__ __forceinline__ u32 rotl32(u32 x, int r) { return (x << r) | (x >> (32 - r)); }
__host__ __device__ __forceinline__ void tf_round(u32& x0, u32& x1, int r) {
  x0 += x1; x1 = rotl32(x1, r); x1 ^= x0;
}
__host__ __device__ __forceinline__ void tf_block(u32 k0, u32 k1, u32 x0, u32 x1, u32& o0, u32& o1) {
  u32 k2 = k0 ^ k1 ^ 0x1BD11BDAu;
  x0 += k0; x1 += k1;
  tf_round(x0,x1,13); tf_round(x0,x1,15); tf_round(x0,x1,26); tf_round(x0,x1,6);
  x0 += k1; x1 += k2 + 1u;
  tf_round(x0,x1,17); tf_round(x0,x1,29); tf_round(x0,x1,16); tf_round(x0,x1,24);
  x0 += k2; x1 += k0 + 2u;
  tf_round(x0,x1,13); tf_round(x0,x1,15); tf_round(x0,x1,26); tf_round(x0,x1,6);
  x0 += k0; x1 += k1 + 3u;
  tf_round(x0,x1,17); tf_round(x0,x1,29); tf_round(x0,x1,16); tf_round(x0,x1,24);
  x0 += k1; x1 += k2 + 4u;
  tf_round(x0,x1,13); tf_round(x0,x1,15); tf_round(x0,x1,26); tf_round(x0,x1,6);
  x0 += k2; x1 += k0 + 5u;
  o0 = x0; o1 = x1;
}

__global__ void k_idx(u32 ka, u32 kb, int n, int mask, int* __restrict__ idx) {
  int i = blockIdx.x * 256 + threadIdx.x;
  if (i >= n) return;
  u32 b1, b2; tf_block(ka, kb, 0u, (u32)i, b1, b2);
  idx[i] = (int)((b1 ^ b2) & (u32)mask);
}

__device__ __forceinline__ void emit_split(float v, f16* __restrict__ oh,
                                           f16* __restrict__ ol, size_t o) {
  f16 h = (f16)v;
  oh[o] = h;
  ol[o] = (f16)((v - (float)h) * 2048.0f);
}
__device__ __forceinline__ float rsplit(const f16* __restrict__ h,
                                        const f16* __restrict__ l, size_t o) {
  return (float)h[o] + (float)l[o] * (1.0f / 2048.0f);
}

// ---------------- positional embedding ----------------
__global__ void k_pe(float* __restrict__ pe) {
  int i = blockIdx.x * 256 + threadIdx.x;
  if (i >= 2048 * 512) return;
  int t = i >> 9, o = i & 511;
  float arg = (float)((o >> 1) * 2) * (float)(-(log(10000.0) / 512.0));
  float div = (float)exp((double)arg);
  float ang32 = (float)t * div;
  double ang = (double)ang32;
  pe[i] = (float)((o & 1) ? cos(ang) : sin(ang));
}

// ---------------- embedding (split-only output) ----------------
__global__ __launch_bounds__(256) void k_embed(
    const float* __restrict__ x, const float* __restrict__ mark,
    const float* __restrict__ tw, const float* __restrict__ mw,
    const float* __restrict__ pe, f16* __restrict__ oh, f16* __restrict__ ol,
    int L, int total) {
  int i = blockIdx.x * 256 + threadIdx.x;
  if (i >= total) return;
  int oo = i & 511;
  int bt = i >> 9;
  int t = bt % L;
  int b = bt / L;
  float acc = pe[(t << 9) + oo];
  #pragma unroll
  for (int k = 0; k < 3; ++k) {
    int st = t + k - 1; if (st < 0) st += L; else if (st >= L) st -= L;
    const float* xr = x + (size_t)(b * L + st) * 7;
    const float* wr = tw + oo * 21 + k;
    #pragma unroll
    for (int ii = 0; ii < 7; ++ii) acc += xr[ii] * wr[ii * 3];
  }
  const float* mr = mark + (size_t)bt * 4;
  #pragma unroll
  for (int m = 0; m < 4; ++m) acc += mr[m] * mw[(m << 9) + oo];
  emit_split(acc, oh, ol, ((size_t)bt << 9) + oo);
}

// ---------------- weight transpose + f16 split (z = matrix index) ----------------
__global__ __launch_bounds__(256) void k_wsplit(const float* __restrict__ W,
    f16* __restrict__ Wh, f16* __restrict__ Wl, int K, int N) {
  size_t zo = (size_t)blockIdx.z * K * N;
  W += zo; Wh += zo; Wl += zo;
  __shared__ float tile[32][33];
  int kb = blockIdx.x << 5, nb = blockIdx.y << 5;
  int t = threadIdx.x;
  int tr = t >> 5, tc = t & 31;
  #pragma unroll
  for (int p = 0; p < 4; ++p)
    tile[tr + p * 8][tc] = W[(size_t)(kb + tr + p * 8) * N + nb + tc];
  __syncthreads();
  #pragma unroll
  for (int p = 0; p < 4; ++p) {
    int n = tr + p * 8, k = tc;
    float v = tile[k][n];
    f16 h = (f16)v;
    size_t o = (size_t)(nb + n) * K + kb + k;
    Wh[o] = h;
    Wl[o] = (f16)((v - (float)h) * 2048.0f);
  }
}

__global__ void k_wsplit_conv(const float* __restrict__ w, f16* __restrict__ Wh, f16* __restrict__ Wl) {
  int i = blockIdx.x * 256 + threadIdx.x;
  if (i >= 512 * 1536) return;
  int o = i / 1536, k = i - o * 1536;
  float v = w[(size_t)o * 1536 + (k & 511) * 3 + (k >> 9)];
  f16 h = (f16)v;
  Wh[i] = h;
  Wl[i] = (f16)((v - (float)h) * 2048.0f);
}

__device__ __forceinline__ int swz_x(int r) { return ((((r >> 1) & 3) ^ ((r >> 3) & 3)) << 4); }

__device__ __forceinline__ void gload16(const void* g, void* l) {
  __builtin_amdgcn_global_load_lds(
      (const __attribute__((address_space(1))) void*)g,
      (__attribute__((address_space(3))) void*)l, 16, 0, 0);
}

// ---------------- MFMA GEMM v2: pre-split f16 A/B, async LDS, dbuf, 16x16x32 ----------------
template<int ACT, int OSPLIT, int GATHER, int RESID>
__global__ __launch_bounds__(256, 2) void k_mgemm2(
    const f16* __restrict__ Ah, const f16* __restrict__ Al,
    const f16* __restrict__ Bh, const f16* __restrict__ Bl,
    const float* __restrict__ bias,
    const f16* __restrict__ Rh, const f16* __restrict__ Rl,
    const float* __restrict__ bns, const float* __restrict__ bnb,
    float* __restrict__ C, f16* __restrict__ Ch, f16* __restrict__ Cl,
    int M, int N, int K, int lgL) {
  __shared__ char lds[65536];
  const int t = threadIdx.x;
  int nwg = gridDim.x * gridDim.y;
  int bid = blockIdx.y * gridDim.x + blockIdx.x;
  if ((nwg & 7) == 0) {
    int cpx = nwg >> 3;
    bid = (bid & 7) * cpx + (bid >> 3);
  }
  const int bm = (bid / gridDim.x) << 7, bn = (bid % gridDim.x) << 7;
  const int w = t >> 6, l = t & 63;
  const int lr = l >> 2;
  const int qx = (l & 3) << 4;
  const int wr = (w >> 1) << 6, wc = (w & 1) << 6;
  const int fr = l & 15;
  const int fkB = (l >> 4) << 4;
  const f32x4 zero = {0.f, 0.f, 0.f, 0.f};
  f32x4 acc1[4][4], acc2[4][4];
  #pragma unroll
  for (int i = 0; i < 4; ++i)
    #pragma unroll
    for (int j = 0; j < 4; ++j) { acc1[i][j] = zero; acc2[i][j] = zero; }

  auto stage = [&](int k0, int bufo) {
    #pragma unroll
    for (int c = 0; c < 2; ++c) {
      int r = w * 32 + c * 16 + lr;
      int sx = qx ^ swz_x(r);
      const char *gAh, *gAl;
      if (GATHER) {
        int m = bm + r;
        int Lm = 1 << lgL;
        int ab = m >> lgL, at = m & (Lm - 1);
        int ke = k0 + (sx >> 1);
        int tap = ke >> 9, ii = ke & 511;
        int st = at + tap - 1; if (st < 0) st += Lm; else if (st >= Lm) st -= Lm;
        size_t aoff = (((size_t)((ab << lgL) + st)) << 9) + ii;
        gAh = (const char*)(Ah + aoff);
        gAl = (const char*)(Al + aoff);
      } else {
        gAh = (const char*)(Ah + (size_t)(bm + r) * K + k0) + sx;
        gAl = (const char*)(Al + (size_t)(bm + r) * K + k0) + sx;
      }
      const char* gBh = (const char*)(Bh + (size_t)(bn + r) * K + k0) + sx;
      const char* gBl = (const char*)(Bl + (size_t)(bn + r) * K + k0) + sx;
      char* base = lds + bufo + w * 2048 + c * 1024;
      gload16(gAh, base);
      gload16(gAl, base + 8192);
      gload16(gBh, base + 16384);
      gload16(gBl, base + 24576);
    }
  };

  int nt = K >> 5;
  stage(0, 0);
  __syncthreads();
  int bufo = 0;
  for (int tt = 0; tt < nt; ++tt) {
    int nb = bufo ^ 32768;
    if (tt + 1 < nt) stage((tt + 1) << 5, nb);
    char* pAh = lds + bufo;
    char* pAl = pAh + 8192;
    char* pBh = pAh + 16384;
    char* pBl = pAh + 24576;
    f16x8 ah4[4], al4[4];
    #pragma unroll
    for (int i = 0; i < 4; ++i) {
      int r = wr + i * 16 + fr;
      int ob = r * 64 + (fkB ^ swz_x(r));
      ah4[i] = *(f16x8*)(pAh + ob);
      al4[i] = *(f16x8*)(pAl + ob);
    }
    #pragma unroll
    for (int j = 0; j < 4; ++j) {
      int r = wc + j * 16 + fr;
      int ob = r * 64 + (fkB ^ swz_x(r));
      f16x8 bh_ = *(f16x8*)(pBh + ob);
      f16x8 bl_ = *(f16x8*)(pBl + ob);
      #pragma unroll
      for (int i = 0; i < 4; ++i) {
        acc1[i][j] = __builtin_amdgcn_mfma_f32_16x16x32_f16(ah4[i], bh_, acc1[i][j], 0, 0, 0);
        acc2[i][j] = __builtin_amdgcn_mfma_f32_16x16x32_f16(ah4[i], bl_, acc2[i][j], 0, 0, 0);
        acc2[i][j] = __builtin_amdgcn_mfma_f32_16x16x32_f16(al4[i], bh_, acc2[i][j], 0, 0, 0);
      }
    }
    __syncthreads();
    bufo = nb;
  }
  #pragma unroll
  for (int j = 0; j < 4; ++j) {
    int col = bn + wc + j * 16 + fr;
    float bsv = bias[col];
    float g2 = 0.f, b2 = 0.f;
    if (ACT == 2) { g2 = bns[col] * 0.9999950000375f; b2 = bnb[col]; }
    #pragma unroll
    for (int i = 0; i < 4; ++i) {
      #pragma unroll
      for (int r = 0; r < 4; ++r) {
        int row = bm + wr + i * 16 + ((l >> 4) << 2) + r;
        float v = acc1[i][j][r] + acc2[i][j][r] * (1.0f / 2048.0f) + bsv;
        if (ACT == 1) v = 0.5f * v * (1.0f + erff(v * 0.70710678118654752f));
        if (ACT == 2) { v = v * g2 + b2; v = v > 0.f ? v : expm1f(v); }
        size_t oi = (size_t)row * N + col;
        if (RESID) v += rsplit(Rh, Rl, oi);
        if (OSPLIT) emit_split(v, Ch, Cl, oi);
        else        C[oi] = v;
      }
    }
  }
}

// ---------------- LayerNorm on split input; optional split / f32 outputs ----------------
__global__ __launch_bounds__(256) void k_ln(const f16* __restrict__ xh, const f16* __restrict__ xl,
    const float* __restrict__ g, const float* __restrict__ b,
    float* __restrict__ of32, f16* __restrict__ oh, f16* __restrict__ ol) {
  int row = blockIdx.x, t = threadIdx.x;
  size_t base = (size_t)row << 9;
  float v0 = rsplit(xh, xl, base + t);
  float v1 = rsplit(xh, xl, base + t + 256);
  float s = v0 + v1;
  #pragma unroll
  for (int off = 32; off; off >>= 1) s += __shfl_down(s, off);
  __shared__ float ls[4];
  if ((t & 63) == 0) ls[t >> 6] = s;
  __syncthreads();
  float mean = (ls[0] + ls[1] + ls[2] + ls[3]) * (1.f / 512.f);
  __syncthreads();
  float d0 = v0 - mean, d1 = v1 - mean;
  float q = d0 * d0 + d1 * d1;
  #pragma unroll
  for (int off = 32; off; off >>= 1) q += __shfl_down(q, off);
  if ((t & 63) == 0) ls[t >> 6] = q;
  __syncthreads();
  float var = (ls[0] + ls[1] + ls[2] + ls[3]) * (1.f / 512.f);
  float rs = rsqrtf(var + 1e-5f);
  float r0 = d0 * rs * g[t] + b[t];
  float r1 = d1 * rs * g[t + 256] + b[t + 256];
  if (of32) { of32[base + t] = r0; of32[base + t + 256] = r1; }
  if (oh) {
    emit_split(r0, oh, ol, base + t);
    emit_split(r1, oh, ol, base + t + 256);
  }
}

// ---------------- M[bh,l] scoring (strided Q/K) ----------------
__global__ __launch_bounds__(256) void k_qkM(const float* __restrict__ Q, int qstr,
    const float* __restrict__ Kp, int kstr, const int* __restrict__ idx,
    float* __restrict__ M, int Lq, int Lk, int U) {
  int wid = (blockIdx.x * 256 + threadIdx.x) >> 6;
  int lane = threadIdx.x & 63;
  int l = wid & (Lq - 1); int bh = wid / Lq; int h = bh & 7; int b = bh >> 3;
  float dot = 0.f;
  if (lane < U) {
    int kr = idx[l * U + lane];
    const float4* q4 = (const float4*)(Q + (size_t)(b * Lq + l) * qstr + (h << 6));
    const float4* k4 = (const float4*)(Kp + (size_t)(b * Lk + kr) * kstr + (h << 6));
    #pragma unroll
    for (int i = 0; i < 16; ++i) {
      float4 a = q4[i], c = k4[i];
      dot += a.x * c.x + a.y * c.y + a.z * c.z + a.w * c.w;
    }
  }
  float mx = (lane < U) ? dot : -INFINITY;
  float sm = (lane < U) ? dot : 0.f;
  #pragma unroll
  for (int off = 32; off; off >>= 1) {
    mx = fmaxf(mx, __shfl_xor(mx, off));
    sm += __shfl_xor(sm, off);
  }
  if (lane == 0) M[(size_t)bh * Lq + l] = mx - sm / (float)Lk;
}

// ---------------- single-wave top-u per (b,h), ties -> lower index ----------------
__global__ void k_topk64(const float* __restrict__ M, int* __restrict__ mtop, int Lq, int u) {
  __shared__ float vals[2048];
  int bh = blockIdx.x, l = threadIdx.x;
  const float* Mr = M + (size_t)bh * Lq;
  for (int i = l; i < Lq; i += 64) vals[i] = Mr[i];
  __syncthreads();
  for (int it = 0; it < u; ++it) {
    float bv = -INFINITY; int bi = 0x7fffffff;
    for (int i = l; i < Lq; i += 64) {
      float v = vals[i];
      if (v > bv || (v == bv && i < bi)) { bv = v; bi = i; }
    }
    #pragma unroll
    for (int off = 32; off; off >>= 1) {
      float vv = __shfl_xor(bv, off); int ii = __shfl_xor(bi, off);
      if (vv > bv || (vv == bv && ii < bi)) { bv = vv; bi = ii; }
    }
    if (l == 0) { mtop[bh * u + it] = bi; vals[bi] = -INFINITY; }
    __syncthreads();
  }
}

// ---------------- ctx mean (AO split) ----------------
__global__ void k_cm1(const float* __restrict__ V, int vstr, float* __restrict__ PS,
                      int Lk, int rows) {
  int bid = blockIdx.x;
  int bh = bid >> 4, seg = bid & 15, d = threadIdx.x;
  int b = bh >> 3, h = bh & 7;
  const float* vp = V + (size_t)(b * Lk + seg * rows) * vstr + (h << 6) + d;
  float acc = 0.f;
  for (int r = 0; r < rows; ++r) acc += vp[(size_t)r * vstr];
  PS[(bid << 6) + d] = acc;
}
__global__ void k_cm2(const float* __restrict__ PS, f16* __restrict__ AOh,
                      f16* __restrict__ AOl, float invLk, int Lq, int total) {
  int i = blockIdx.x * 256 + threadIdx.x;
  if (i >= total) return;
  int c = i & 511; int h = c >> 6; int d = c & 63;
  int r = i >> 9; int b = r / Lq;
  float acc = 0.f;
  #pragma unroll
  for (int s = 0; s < 16; ++s) acc += PS[(((((b << 3) + h) << 4) + s) << 6) + d];
  emit_split(acc * invLk, AOh, AOl, (size_t)i);
}

// ---------------- cumsum (masked ctx; per-block prefix, AO split) ----------------
__global__ void k_cs1(const float* __restrict__ V, int vstr, float* __restrict__ PS,
                      int Lq, int rows) {
  int bid = blockIdx.x;
  int bh = bid >> 3, seg = bid & 7, d = threadIdx.x;
  int b = bh >> 3, h = bh & 7;
  const float* vp = V + (size_t)(b * Lq + seg * rows) * vstr + (h << 6) + d;
  float acc = 0.f;
  for (int r = 0; r < rows; ++r) acc += vp[(size_t)r * vstr];
  PS[(bid << 6) + d] = acc;
}
__global__ void k_cs3(const float* __restrict__ V, int vstr, const float* __restrict__ PS,
                      f16* __restrict__ AOh, f16* __restrict__ AOl, int Lq, int rows) {
  int bid = blockIdx.x;
  int bh = bid >> 3, seg = bid & 7, d = threadIdx.x;
  int b = bh >> 3, h = bh & 7;
  float acc = 0.f;
  for (int s2 = 0; s2 < seg; ++s2) acc += PS[(((bh << 3) + s2) << 6) + d];
  const float* vp = V + (size_t)(b * Lq + seg * rows) * vstr + (h << 6) + d;
  size_t ob = ((size_t)(b * Lq + seg * rows) << 9) + (h << 6) + d;
  for (int r = 0; r < rows; ++r) {
    acc += vp[(size_t)r * vstr];
    emit_split(acc, AOh, AOl, ob + ((size_t)r << 9));
  }
}

// ---------------- flash sparse attn: ALL u rows per (512-key chunk, bh) block ----------------
// K read once per chunk (coalesced LDS staging), online softmax per row, partials out.
__global__ __launch_bounds__(256) void k_sattnF(
    const float* __restrict__ Q, int qstr, const float* __restrict__ Kp, int kstr,
    const float* __restrict__ Vp, int vstr, const int* __restrict__ mtop,
    float* __restrict__ PPm, float* __restrict__ PPs, float* __restrict__ PPv,
    int Lq, int Lk, int u, int masked, int bhn) {
  __shared__ float Qs[40 * 64];        // 10.2 KB
  __shared__ float Kt[64 * 65];        // 16.6 KB  Kt[e*65+k]
  __shared__ float Vs[64 * 65];        // 16.6 KB  Vs[k*65+e]
  __shared__ float els[40 * 64];       // 10.2 KB
  __shared__ int rowsh[40];
  int ch = blockIdx.x, bh = blockIdx.y;
  int b = bh >> 3, h = bh & 7;
  int c0 = ch << 9;
  int t = threadIdx.x;
  int g = t >> 6, d = t & 63;
  if (t < 40) rowsh[t] = (t < u) ? mtop[bh * u + t] : -1;
  __syncthreads();
  // stage Q rows (gathered)
  for (int i = t; i < 40 * 16; i += 256) {
    int r = i >> 4, e4 = i & 15;
    int row = rowsh[r];
    float4 v;
    if (row >= 0) v = *(const float4*)(Q + (size_t)(b * Lq + row) * qstr + (h << 6) + e4 * 4);
    else          v = make_float4(0.f, 0.f, 0.f, 0.f);
    *(float4*)(Qs + r * 64 + e4 * 4) = v;
  }
  int rows_[10];
  #pragma unroll
  for (int i = 0; i < 10; ++i) rows_[i] = (t < 0) ? 0 : 0;  // init below after barrier
  __syncthreads();
  #pragma unroll
  for (int i = 0; i < 10; ++i) rows_[i] = rowsh[g + i * 4];
  float pv[10], m[10], sum[10];
  #pragma unroll
  for (int i = 0; i < 10; ++i) { pv[i] = 0.f; m[i] = -INFINITY; sum[i] = 0.f; }
  const int srow = t >> 2, seg = t & 3;   // staging: row 0..63, 16-float segment
  for (int kt = 0; kt < 8; ++kt) {
    __syncthreads();   // protect Kt/Vs (prev tile PV done)
    {
      int crow = c0 + (kt << 6) + srow;
      const float* kp2 = Kp + (size_t)(b * Lk + crow) * kstr + (h << 6) + seg * 16;
      const float* vp2 = Vp + (size_t)(b * Lk + crow) * vstr + (h << 6) + seg * 16;
      #pragma unroll
      for (int q4 = 0; q4 < 4; ++q4) {
        float4 kv = *(const float4*)(kp2 + q4 * 4);
        float4 vv = *(const float4*)(vp2 + q4 * 4);
        int e0 = seg * 16 + q4 * 4;
        Kt[(e0 + 0) * 65 + srow] = kv.x;
        Kt[(e0 + 1) * 65 + srow] = kv.y;
        Kt[(e0 + 2) * 65 + srow] = kv.z;
        Kt[(e0 + 3) * 65 + srow] = kv.w;
        Vs[srow * 65 + e0 + 0] = vv.x;
        Vs[srow * 65 + e0 + 1] = vv.y;
        Vs[srow * 65 + e0 + 2] = vv.z;
        Vs[srow * 65 + e0 + 3] = vv.w;
      }
    }
    __syncthreads();
    // scores: dot[i] for rows g+4i, key = d  (e ascending, same order as before)
    float dot[10];
    #pragma unroll
    for (int i = 0; i < 10; ++i) dot[i] = 0.f;
    for (int e = 0; e < 64; ++e) {
      float kv = Kt[e * 65 + d];
      #pragma unroll
      for (int i = 0; i < 10; ++i)
        dot[i] += Qs[(g + i * 4) * 64 + e] * kv;
    }
    int key = c0 + (kt << 6) + d;
    float scale_[10];
    #pragma unroll
    for (int i = 0; i < 10; ++i) {
      float s = dot[i] * 0.125f;
      if (masked && key > rows_[i]) s = -INFINITY;
      float tm = s;
      #pragma unroll
      for (int off = 32; off; off >>= 1) tm = fmaxf(tm, __shfl_xor(tm, off));
      float nm = fmaxf(m[i], tm);
      if (nm > -3e38f) {
        float scl = expf(m[i] - nm);      // m=-inf -> 0
        float e_ = expf(s - nm);          // s=-inf -> 0
        float ts = e_;
        #pragma unroll
        for (int off = 32; off; off >>= 1) ts += __shfl_xor(ts, off);
        sum[i] = sum[i] * scl + ts;
        m[i] = nm;
        scale_[i] = scl;
        els[(g + i * 4) * 64 + d] = e_;
      } else {
        scale_[i] = 1.f;
        els[(g + i * 4) * 64 + d] = 0.f;
      }
    }
    __syncthreads();
    // PV: pv[i][d] = pv*scale + sum_k els[r][k] * Vs[k][d]
    float acc[10];
    #pragma unroll
    for (int i = 0; i < 10; ++i) acc[i] = 0.f;
    for (int k = 0; k < 64; ++k) {
      float vv = Vs[k * 65 + d];
      #pragma unroll
      for (int i = 0; i < 10; ++i)
        acc[i] += els[(g + i * 4) * 64 + k] * vv;
    }
    #pragma unroll
    for (int i = 0; i < 10; ++i) pv[i] = pv[i] * scale_[i] + acc[i];
  }
  // write partials
  #pragma unroll
  for (int i = 0; i < 10; ++i) {
    int r = g + i * 4;
    if (r < u) {
      size_t pidx = (size_t)(ch * bhn + bh) * u + r;
      if (d == 0) { PPm[pidx] = m[i]; PPs[pidx] = sum[i]; }
      PPv[pidx * 64 + d] = pv[i];
    }
  }
}

// ---------------- combine chunk partials -> AO (online softmax rescale) ----------------
__global__ void k_sattnc(const float* __restrict__ PPm, const float* __restrict__ PPs,
                         const float* __restrict__ PPv, const int* __restrict__ mtop,
                         f16* __restrict__ AOh, f16* __restrict__ AOl,
                         int Lq, int u, int nch, int bhn) {
  int rowid = blockIdx.x;
  int bh = rowid / u, ui = rowid % u;
  int d = threadIdx.x;
  int b = bh >> 3, h = bh & 7;
  int row = mtop[bh * u + ui];
  float M = -INFINITY;
  for (int c = 0; c < nch; ++c)
    M = fmaxf(M, PPm[(size_t)(c * bhn + bh) * u + ui]);
  float S = 0.f, o = 0.f;
  for (int c = 0; c < nch; ++c) {
    size_t pidx = (size_t)(c * bhn + bh) * u + ui;
    float pm = PPm[pidx];
    float sc = (pm > -3e38f) ? expf(pm - M) : 0.f;
    S += sc * PPs[pidx];
    o += sc * PPv[pidx * 64 + d];
  }
  emit_split(o / S, AOh, AOl, ((size_t)(b * Lq + row) << 9) + (h << 6) + d);
}

// ---------------- maxpool w3 s2 p1 along L (split-only output) ----------------
__global__ void k_maxpool(const float* __restrict__ y, f16* __restrict__ oh,
                          f16* __restrict__ ol, int L) {
  int Lo = L >> 1;
  int i = blockIdx.x * 256 + threadIdx.x;
  int c = i & 511; int bj = i >> 9;
  int j = bj % Lo; int b = bj / Lo;
  float m = -INFINITY;
  int t0 = 2 * j - 1;
  #pragma unroll
  for (int k = 0; k < 3; ++k) {
    int tt = t0 + k;
    if (tt >= 0 && tt < L) m = fmaxf(m, y[((size_t)(b * L + tt) << 9) + c]);
  }
  emit_split(m, oh, ol, ((size_t)(b * Lo + j) << 9) + c);
}

// ---------------- final projection 512->7 (reads f32 from Y) ----------------
__global__ void k_proj(const float* __restrict__ Xn, const float* __restrict__ pw,
                       const float* __restrict__ pb, float* __restrict__ out) {
  int i = blockIdx.x * 256 + threadIdx.x;
  if (i >= 16 * 512 * 7) return;
  int c = i % 7; int r = i / 7;
  int b = r >> 9; int j = r & 511;
  const float* xr = Xn + ((size_t)(b * 1024 + 512 + j) << 9);
  float acc = pb[c];
  for (int d2 = 0; d2 < 512; ++d2) acc += xr[d2] * pw[d2 * 7 + c];
  out[i] = acc;
}

// =====================================================================
extern "C" void kernel_launch(void* const* d_in, const int* in_sizes, int n_in,
                              void* d_out, int out_size, void* d_ws, size_t ws_size,
                              hipStream_t stream) {
  const float* x_enc      = (const float*)d_in[0];
  const float* x_mark_enc = (const float*)d_in[1];
  const float* x_dec      = (const float*)d_in[2];
  const float* x_mark_dec = (const float*)d_in[3];
  const float* enc_tok_w  = (const float*)d_in[4];
  const float* enc_mark_w = (const float*)d_in[5];
  const float* dec_tok_w  = (const float*)d_in[6];
  const float* dec_mark_w = (const float*)d_in[7];
  const float* enc_attn_w = (const float*)d_in[8];
  const float* enc_attn_b = (const float*)d_in[9];
  const float* enc_ffn1_w = (const float*)d_in[10];
  const float* enc_ffn1_b = (const float*)d_in[11];
  const float* enc_ffn2_w = (const float*)d_in[12];
  const float* enc_ffn2_b = (const float*)d_in[13];
  const float* enc_ln_g   = (const float*)d_in[14];
  const float* enc_ln_b   = (const float*)d_in[15];
  const float* distil_w   = (const float*)d_in[16];
  const float* distil_b   = (const float*)d_in[17];
  const float* distil_bn_g= (const float*)d_in[18];
  const float* distil_bn_b= (const float*)d_in[19];
  const float* enc_norm_g = (const float*)d_in[20];
  const float* enc_norm_b = (const float*)d_in[21];
  const float* dec_self_w = (const float*)d_in[22];
  const float* dec_self_b = (const float*)d_in[23];
  const float* dec_cross_w= (const float*)d_in[24];
  const float* dec_cross_b= (const float*)d_in[25];
  const float* dec_ffn1_w = (const float*)d_in[26];
  const float* dec_ffn1_b = (const float*)d_in[27];
  const float* dec_ffn2_w = (const float*)d_in[28];
  const float* dec_ffn2_b = (const float*)d_in[29];
  const float* dec_ln_g   = (const float*)d_in[30];
  const float* dec_ln_b   = (const float*)d_in[31];
  const float* dec_norm_g = (const float*)d_in[32];
  const float* dec_norm_b = (const float*)d_in[33];
  const float* proj_w     = (const float*)d_in[34];
  const float* proj_b     = (const float*)d_in[35];

  // -------- workspace layout: split-only activations; Y sized by tier --------
  float* ws = (float*)d_ws;
  size_t off = 0;
  f16* Xh   = (f16*)(ws + off); off += 16777216;
  f16* Xl   = Xh + 16777216;
  f16* ENCh = (f16*)(ws + off); off += 4194304;
  f16* ENCl = ENCh + 4194304;
  float* PE = ws + off; off += 1048576;
  float* Mb = ws + off; off += 131072;
  float* PS = ws + off; off += 65536;
  f16* WSP  = (f16*)(ws + off); off += 2097152;
  int* IDXi = (int*)(ws + off); off += 84480;
  float* Y  = ws + off;
  int* MTi  = IDXi + 81920;
  size_t need4 = (off + 16777216ull) * 4;
  size_t need8 = (off + 33554432ull) * 4;
  int bs;
  if      (ws_size >= need8) bs = 8;
  else if (ws_size >= need4) bs = 4;
  else return;
  f16* Yh = (f16*)Y;
  f16* Yl = Yh + 16777216;
  // attention chunk partials in the free upper half of WSP
  float* WF  = (float*)WSP + 1048576;
  float* PPm = WF;              // <= 16384
  float* PPs = WF + 16384;      // <= 16384
  float* PPv = WF + 32768;      // <= 655360

  auto ln = [&](const f16* xh, const f16* xl, const float* g, const float* b, int rows,
                float* of32, f16* oh, f16* ol) {
    k_ln<<<rows, 256, 0, stream>>>(xh, xl, g, b, of32, oh, ol);
  };
  auto wsplit = [&](const float* W, f16* Wh, f16* Wl, int K, int N, int nmat) {
    dim3 g(K >> 5, N >> 5, nmat);
    k_wsplit<<<g, 256, 0, stream>>>(W, Wh, Wl, K, N);
  };
  auto mgQ = [&](const f16* Ah, const f16* Al, const f16* Wh, const f16* Wl,
                 const float* bias, float* C, int M, int N, int K) {
    dim3 g(N >> 7, M >> 7);
    k_mgemm2<0,0,0,0><<<g, 256, 0, stream>>>(Ah, Al, Wh, Wl, bias, nullptr, nullptr,
        nullptr, nullptr, C, nullptr, nullptr, M, N, K, 0);
  };
  auto mgR = [&](const f16* Ah, const f16* Al, const f16* Wh, const f16* Wl,
                 const float* bias, const f16* Rh, const f16* Rl,
                 f16* Ch, f16* Cl, int M, int N, int K) {
    dim3 g(N >> 7, M >> 7);
    k_mgemm2<0,1,0,1><<<g, 256, 0, stream>>>(Ah, Al, Wh, Wl, bias, Rh, Rl,
        nullptr, nullptr, nullptr, Ch, Cl, M, N, K, 0);
  };
  auto mgG = [&](const f16* Ah, const f16* Al, const f16* Wh, const f16* Wl,
                 const float* bias, f16* Ch, f16* Cl, int M, int N, int K) {
    dim3 g(N >> 7, M >> 7);
    k_mgemm2<1,1,0,0><<<g, 256, 0, stream>>>(Ah, Al, Wh, Wl, bias, nullptr, nullptr,
        nullptr, nullptr, nullptr, Ch, Cl, M, N, K, 0);
  };
  auto Uof = [](int Lx) { int v = 5 * (int)ceil(log((double)Lx)); return v < Lx ? v : Lx; };

  auto attn = [&](f16* xqh, f16* xql, const f16* xkvh, const f16* xkvl,
                  int Lq, int Lk, const float* w, const float* bias,
                  bool masked, u32 fold, bool selfa) {
    int U = Uof(Lk), uu = Uof(Lq);
    u32 r0, r1, ka, kb2;
    tf_block(0u, 42u, 0u, fold, r0, r1);
    tf_block(r0, r1, 0u, 1u, ka, kb2);
    int n = Lq * U;
    k_idx<<<(n + 255) / 256, 256, 0, stream>>>(ka, kb2, n, Lk - 1, IDXi);

    f16 *Wqkvh = WSP,            *Wqkvl = WSP + 786432;
    f16 *WQh   = WSP,            *WQl   = WSP + 262144;
    f16 *WKVh  = WSP + 524288,   *WKVl  = WSP + 1048576;
    f16 *WOh   = WSP + 1572864,  *WOl   = WSP + 1835008;
    if (selfa) {
      wsplit(w, Wqkvh, Wqkvl, 512, 512, 3);
    } else {
      wsplit(w, WQh, WQl, 512, 512, 1);
      wsplit(w + 262144, WKVh, WKVl, 512, 512, 2);
    }
    wsplit(w + 786432, WOh, WOl, 512, 512, 1);

    int nsl = 16 / bs;
    int bhn = bs * 8;
    for (int s = 0; s < nsl; ++s) {
      size_t qoff = (size_t)s * bs * Lq * 512;
      size_t koff = (size_t)s * bs * Lk * 512;
      const float *qp, *kp, *vp;
      int qstr, kstr, vstr;
      f16 *AOh, *AOl;
      if (selfa) {
        float* QKV = Y;
        AOh = (f16*)(Y + (size_t)bs * Lq * 1536);
        AOl = AOh + (size_t)bs * Lq * 512;
        mgQ(xqh + qoff, xql + qoff, Wqkvh, Wqkvl, bias, QKV, bs * Lq, 1536, 512);
        qp = QKV; qstr = 1536; kp = QKV + 512; kstr = 1536; vp = QKV + 1024; vstr = 1536;
      } else {
        float* Qb  = Y;
        float* KVb = Y + (size_t)bs * Lq * 512;
        AOh = (f16*)(KVb + (size_t)bs * Lk * 1024);
        AOl = AOh + (size_t)bs * Lq * 512;
        mgQ(xqh + qoff, xql + qoff, WQh, WQl, bias, Qb, bs * Lq, 512, 512);
        mgQ(xkvh + koff, xkvl + koff, WKVh, WKVl, bias + 512, KVb, bs * Lk, 1024, 512);
        qp = Qb; qstr = 512; kp = KVb; kstr = 1024; vp = KVb + 512; vstr = 1024;
      }
      int wids = bhn * Lq;
      k_qkM<<<wids / 4, 256, 0, stream>>>(qp, qstr, kp, kstr, IDXi, Mb, Lq, Lk, U);
      k_topk64<<<bhn, 64, 0, stream>>>(Mb, MTi, Lq, uu);
      if (masked) {
        k_cs1<<<bhn * 8, 64, 0, stream>>>(vp, vstr, PS, Lq, Lq >> 3);
        k_cs3<<<bhn * 8, 64, 0, stream>>>(vp, vstr, PS, AOh, AOl, Lq, Lq >> 3);
      } else {
        k_cm1<<<bhn * 16, 64, 0, stream>>>(vp, vstr, PS, Lk, Lk >> 4);
        int tot = bs * Lq * 512;
        k_cm2<<<tot / 256, 256, 0, stream>>>(PS, AOh, AOl, 1.0f / (float)Lk, Lq, tot);
      }
      int nch = Lk >> 9;
      dim3 gs(nch, bhn);
      k_sattnF<<<gs, 256, 0, stream>>>(qp, qstr, kp, kstr, vp, vstr, MTi,
                                       PPm, PPs, PPv, Lq, Lk, uu, masked ? 1 : 0, bhn);
      k_sattnc<<<bhn * uu, 64, 0, stream>>>(PPm, PPs, PPv, MTi, AOh, AOl, Lq, uu, nch, bhn);
      mgR(AOh, AOl, WOh, WOl, bias + 1536, xqh + qoff, xql + qoff,
          xqh + qoff, xql + qoff, bs * Lq, 512, 512);
    }
  };

  auto ffn = [&](f16* xh, f16* xl, const float* w1, const float* b1,
                 const float* w2, const float* b2, int Mtot) {
    f16 *W1h = WSP,           *W1l = WSP + 1048576,
        *W2h = WSP + 2097152, *W2l = WSP + 3145728;
    wsplit(w1, W1h, W1l, 512, 2048, 1);
    wsplit(w2, W2h, W2l, 2048, 512, 1);
    for (int c0 = 0; c0 < Mtot; c0 += 8192) {
      int rows = (Mtot - c0 < 8192) ? (Mtot - c0) : 8192;
      mgG(xh + (size_t)c0 * 512, xl + (size_t)c0 * 512, W1h, W1l, b1, Yh, Yl, rows, 2048, 512);
      mgR(Yh, Yl, W2h, W2l, b2, xh + (size_t)c0 * 512, xl + (size_t)c0 * 512,
          xh + (size_t)c0 * 512, xl + (size_t)c0 * 512, rows, 512, 2048);
    }
  };

  // ---------------- encoder ----------------
  k_pe<<<(2048 * 512) / 256, 256, 0, stream>>>(PE);
  k_embed<<<(16 * 2048 * 512) / 256, 256, 0, stream>>>(x_enc, x_mark_enc, enc_tok_w, enc_mark_w,
                                                       PE, Xh, Xl, 2048, 16 * 2048 * 512);
  int L = 2048;
  for (int l = 0; l < 3; ++l) {
    attn(Xh, Xl, Xh, Xl, L, L, enc_attn_w + (size_t)l * 4 * 262144,
         enc_attn_b + (size_t)l * 2048, false, (u32)l, true);
    ln(Xh, Xl, enc_ln_g + (size_t)(l * 2) * 512, enc_ln_b + (size_t)(l * 2) * 512, 16 * L,
       nullptr, Xh, Xl);
    ffn(Xh, Xl, enc_ffn1_w + (size_t)l * 512 * 2048, enc_ffn1_b + (size_t)l * 2048,
        enc_ffn2_w + (size_t)l * 2048 * 512, enc_ffn2_b + (size_t)l * 512, 16 * L);
    ln(Xh, Xl, enc_ln_g + (size_t)(l * 2 + 1) * 512, enc_ln_b + (size_t)(l * 2 + 1) * 512, 16 * L,
       nullptr, Xh, Xl);
    if (l < 2) {
      f16 *Dh = WSP, *Dl = WSP + 786432;
      k_wsplit_conv<<<(512 * 1536) / 256, 256, 0, stream>>>(distil_w + (size_t)l * 512 * 512 * 3, Dh, Dl);
      dim3 g(512 >> 7, (16 * L) >> 7);
      int lgL = (L == 2048) ? 11 : 10;
      k_mgemm2<2,0,1,0><<<g, 256, 0, stream>>>(Xh, Xl, Dh, Dl, distil_b + (size_t)l * 512,
          nullptr, nullptr, distil_bn_g + (size_t)l * 512, distil_bn_b + (size_t)l * 512,
          Y, nullptr, nullptr, 16 * L, 512, 1536, lgL);
      int Lo = L >> 1;
      k_maxpool<<<(16 * Lo * 512) / 256, 256, 0, stream>>>(Y, Xh, Xl, L);
      L = Lo;
    }
  }
  ln(Xh, Xl, enc_norm_g, enc_norm_b, 16 * 512, nullptr, ENCh, ENCl);

  // ---------------- decoder (in-place chain in Xh/Xl) ----------------
  k_embed<<<(16 * 1024 * 512) / 256, 256, 0, stream>>>(x_dec, x_mark_dec, dec_tok_w, dec_mark_w,
                                                       PE, Xh, Xl, 1024, 16 * 1024 * 512);
  for (int l = 0; l < 2; ++l) {
    attn(Xh, Xl, Xh, Xl, 1024, 1024, dec_self_w + (size_t)l * 4 * 262144,
         dec_self_b + (size_t)l * 2048, true, (u32)(100 + 2 * l), true);
    ln(Xh, Xl, dec_ln_g + (size_t)(l * 3) * 512, dec_ln_b + (size_t)(l * 3) * 512, 16384,
       nullptr, Xh, Xl);
    attn(Xh, Xl, ENCh, ENCl, 1024, 512, dec_cross_w + (size_t)l * 4 * 262144,
         dec_cross_b + (size_t)l * 2048, false, (u32)(101 + 2 * l), false);
    ln(Xh, Xl, dec_ln_g + (size_t)(l * 3 + 1) * 512, dec_ln_b + (size_t)(l * 3 + 1) * 512, 16384,
       nullptr, Xh, Xl);
    ffn(Xh, Xl, dec_ffn1_w + (size_t)l * 512 * 2048, dec_ffn1_b + (size_t)l * 2048,
        dec_ffn2_w + (size_t)l * 2048 * 512, dec_ffn2_b + (size_t)l * 512, 16384);
    ln(Xh, Xl, dec_ln_g + (size_t)(l * 3 + 2) * 512, dec_ln_b + (size_t)(l * 3 + 2) * 512, 16384,
       nullptr, Xh, Xl);
  }
  ln(Xh, Xl, dec_norm_g, dec_norm_b, 16384, Y, nullptr, nullptr);
  k_proj<<<(16 * 512 * 7 + 255) / 256, 256, 0, stream>>>(Y, proj_w, proj_b, (float*)d_out);
}

// Round 19
// 7629.388 us; speedup vs baseline: 2.6701x; 1.0838x over previous
//
#include <hip/hip_runtime.h>
#include <math.h>
#include <stdint.h>

typedef unsigned int u32;
typedef _Float16 f16;
typedef __attribute__((ext_vector_type(8))) _Float16 f16x8;
typedef __attribute__((ext_vector_type(4))) float f32x4;

// ---------------- Threefry-2x32 (20 rounds), matches JAX ----------------
__host__ __device__ __forceinline__ u32 rotl32(u32 x, int r) { return (x << r) | (x >> (32 - r)); }
__host__ __device__ __forceinline__ void tf_round(u32& x0, u32& x1, int r) {
  x0 += x1; x1 = rotl32(x1, r); x1 ^= x0;
}
__host__ __device__ __forceinline__ void tf_block(u32 k0, u32 k1, u32 x0, u32 x1, u32& o0, u32& o1) {
  u32 k2 = k0 ^ k1 ^ 0x1BD11BDAu;
  x0 += k0; x1 += k1;
  tf_round(x0,x1,13); tf_round(x0,x1,15); tf_round(x0,x1,26); tf_round(x0,x1,6);
  x0 += k1; x1 += k2 + 1u;
  tf_round(x0,x1,17); tf_round(x0,x1,29); tf_round(x0,x1,16); tf_round(x0,x1,24);
  x0 += k2; x1 += k0 + 2u;
  tf_round(x0,x1,13); tf_round(x0,x1,15); tf_round(x0,x1,26); tf_round(x0,x1,6);
  x0 += k0; x1 += k1 + 3u;
  tf_round(x0,x1,17); tf_round(x0,x1,29); tf_round(x0,x1,16); tf_round(x0,x1,24);
  x0 += k1; x1 += k2 + 4u;
  tf_round(x0,x1,13); tf_round(x0,x1,15); tf_round(x0,x1,26); tf_round(x0,x1,6);
  x0 += k2; x1 += k0 + 5u;
  o0 = x0; o1 = x1;
}

__global__ void k_idx(u32 ka, u32 kb, int n, int mask, int* __restrict__ idx) {
  int i = blockIdx.x * 256 + threadIdx.x;
  if (i >= n) return;
  u32 b1, b2; tf_block(ka, kb, 0u, (u32)i, b1, b2);
  idx[i] = (int)((b1 ^ b2) & (u32)mask);
}

__device__ __forceinline__ void emit_split(float v, f16* __restrict__ oh,
                                           f16* __restrict__ ol, size_t o) {
  f16 h = (f16)v;
  oh[o] = h;
  ol[o] = (f16)((v - (float)h) * 2048.0f);
}
__device__ __forceinline__ float rsplit(const f16* __restrict__ h,
                                        const f16* __restrict__ l, size_t o) {
  return (float)h[o] + (float)l[o] * (1.0f / 2048.0f);
}

// ---------------- positional embedding ----------------
__global__ void k_pe(float* __restrict__ pe) {
  int i = blockIdx.x * 256 + threadIdx.x;
  if (i >= 2048 * 512) return;
  int t = i >> 9, o = i & 511;
  float arg = (float)((o >> 1) * 2) * (float)(-(log(10000.0) / 512.0));
  float div = (float)exp((double)arg);
  float ang32 = (float)t * div;
  double ang = (double)ang32;
  pe[i] = (float)((o & 1) ? cos(ang) : sin(ang));
}

// ---------------- embedding (split-only output) ----------------
__global__ __launch_bounds__(256) void k_embed(
    const float* __restrict__ x, const float* __restrict__ mark,
    const float* __restrict__ tw, const float* __restrict__ mw,
    const float* __restrict__ pe, f16* __restrict__ oh, f16* __restrict__ ol,
    int L, int total) {
  int i = blockIdx.x * 256 + threadIdx.x;
  if (i >= total) return;
  int oo = i & 511;
  int bt = i >> 9;
  int t = bt % L;
  int b = bt / L;
  float acc = pe[(t << 9) + oo];
  #pragma unroll
  for (int k = 0; k < 3; ++k) {
    int st = t + k - 1; if (st < 0) st += L; else if (st >= L) st -= L;
    const float* xr = x + (size_t)(b * L + st) * 7;
    const float* wr = tw + oo * 21 + k;
    #pragma unroll
    for (int ii = 0; ii < 7; ++ii) acc += xr[ii] * wr[ii * 3];
  }
  const float* mr = mark + (size_t)bt * 4;
  #pragma unroll
  for (int m = 0; m < 4; ++m) acc += mr[m] * mw[(m << 9) + oo];
  emit_split(acc, oh, ol, ((size_t)bt << 9) + oo);
}

// ---------------- weight transpose + f16 split (z = matrix index) ----------------
__global__ __launch_bounds__(256) void k_wsplit(const float* __restrict__ W,
    f16* __restrict__ Wh, f16* __restrict__ Wl, int K, int N) {
  size_t zo = (size_t)blockIdx.z * K * N;
  W += zo; Wh += zo; Wl += zo;
  __shared__ float tile[32][33];
  int kb = blockIdx.x << 5, nb = blockIdx.y << 5;
  int t = threadIdx.x;
  int tr = t >> 5, tc = t & 31;
  #pragma unroll
  for (int p = 0; p < 4; ++p)
    tile[tr + p * 8][tc] = W[(size_t)(kb + tr + p * 8) * N + nb + tc];
  __syncthreads();
  #pragma unroll
  for (int p = 0; p < 4; ++p) {
    int n = tr + p * 8, k = tc;
    float v = tile[k][n];
    f16 h = (f16)v;
    size_t o = (size_t)(nb + n) * K + kb + k;
    Wh[o] = h;
    Wl[o] = (f16)((v - (float)h) * 2048.0f);
  }
}

__global__ void k_wsplit_conv(const float* __restrict__ w, f16* __restrict__ Wh, f16* __restrict__ Wl) {
  int i = blockIdx.x * 256 + threadIdx.x;
  if (i >= 512 * 1536) return;
  int o = i / 1536, k = i - o * 1536;
  float v = w[(size_t)o * 1536 + (k & 511) * 3 + (k >> 9)];
  f16 h = (f16)v;
  Wh[i] = h;
  Wl[i] = (f16)((v - (float)h) * 2048.0f);
}

__device__ __forceinline__ int swz_x(int r) { return ((((r >> 1) & 3) ^ ((r >> 3) & 3)) << 4); }

__device__ __forceinline__ void gload16(const void* g, void* l) {
  __builtin_amdgcn_global_load_lds(
      (const __attribute__((address_space(1))) void*)g,
      (__attribute__((address_space(3))) void*)l, 16, 0, 0);
}

// ---------------- MFMA GEMM v2: pre-split f16 A/B, async LDS, dbuf, 16x16x32 ----------------
template<int ACT, int OSPLIT, int GATHER, int RESID>
__global__ __launch_bounds__(256, 2) void k_mgemm2(
    const f16* __restrict__ Ah, const f16* __restrict__ Al,
    const f16* __restrict__ Bh, const f16* __restrict__ Bl,
    const float* __restrict__ bias,
    const f16* __restrict__ Rh, const f16* __restrict__ Rl,
    const float* __restrict__ bns, const float* __restrict__ bnb,
    float* __restrict__ C, f16* __restrict__ Ch, f16* __restrict__ Cl,
    int M, int N, int K, int lgL) {
  __shared__ char lds[65536];
  const int t = threadIdx.x;
  int nwg = gridDim.x * gridDim.y;
  int bid = blockIdx.y * gridDim.x + blockIdx.x;
  if ((nwg & 7) == 0) {
    int cpx = nwg >> 3;
    bid = (bid & 7) * cpx + (bid >> 3);
  }
  const int bm = (bid / gridDim.x) << 7, bn = (bid % gridDim.x) << 7;
  const int w = t >> 6, l = t & 63;
  const int lr = l >> 2;
  const int qx = (l & 3) << 4;
  const int wr = (w >> 1) << 6, wc = (w & 1) << 6;
  const int fr = l & 15;
  const int fkB = (l >> 4) << 4;
  const f32x4 zero = {0.f, 0.f, 0.f, 0.f};
  f32x4 acc1[4][4], acc2[4][4];
  #pragma unroll
  for (int i = 0; i < 4; ++i)
    #pragma unroll
    for (int j = 0; j < 4; ++j) { acc1[i][j] = zero; acc2[i][j] = zero; }

  auto stage = [&](int k0, int bufo) {
    #pragma unroll
    for (int c = 0; c < 2; ++c) {
      int r = w * 32 + c * 16 + lr;
      int sx = qx ^ swz_x(r);
      const char *gAh, *gAl;
      if (GATHER) {
        int m = bm + r;
        int Lm = 1 << lgL;
        int ab = m >> lgL, at = m & (Lm - 1);
        int ke = k0 + (sx >> 1);
        int tap = ke >> 9, ii = ke & 511;
        int st = at + tap - 1; if (st < 0) st += Lm; else if (st >= Lm) st -= Lm;
        size_t aoff = (((size_t)((ab << lgL) + st)) << 9) + ii;
        gAh = (const char*)(Ah + aoff);
        gAl = (const char*)(Al + aoff);
      } else {
        gAh = (const char*)(Ah + (size_t)(bm + r) * K + k0) + sx;
        gAl = (const char*)(Al + (size_t)(bm + r) * K + k0) + sx;
      }
      const char* gBh = (const char*)(Bh + (size_t)(bn + r) * K + k0) + sx;
      const char* gBl = (const char*)(Bl + (size_t)(bn + r) * K + k0) + sx;
      char* base = lds + bufo + w * 2048 + c * 1024;
      gload16(gAh, base);
      gload16(gAl, base + 8192);
      gload16(gBh, base + 16384);
      gload16(gBl, base + 24576);
    }
  };

  int nt = K >> 5;
  stage(0, 0);
  __syncthreads();
  int bufo = 0;
  for (int tt = 0; tt < nt; ++tt) {
    int nb = bufo ^ 32768;
    if (tt + 1 < nt) stage((tt + 1) << 5, nb);
    char* pAh = lds + bufo;
    char* pAl = pAh + 8192;
    char* pBh = pAh + 16384;
    char* pBl = pAh + 24576;
    f16x8 ah4[4], al4[4];
    #pragma unroll
    for (int i = 0; i < 4; ++i) {
      int r = wr + i * 16 + fr;
      int ob = r * 64 + (fkB ^ swz_x(r));
      ah4[i] = *(f16x8*)(pAh + ob);
      al4[i] = *(f16x8*)(pAl + ob);
    }
    #pragma unroll
    for (int j = 0; j < 4; ++j) {
      int r = wc + j * 16 + fr;
      int ob = r * 64 + (fkB ^ swz_x(r));
      f16x8 bh_ = *(f16x8*)(pBh + ob);
      f16x8 bl_ = *(f16x8*)(pBl + ob);
      #pragma unroll
      for (int i = 0; i < 4; ++i) {
        acc1[i][j] = __builtin_amdgcn_mfma_f32_16x16x32_f16(ah4[i], bh_, acc1[i][j], 0, 0, 0);
        acc2[i][j] = __builtin_amdgcn_mfma_f32_16x16x32_f16(ah4[i], bl_, acc2[i][j], 0, 0, 0);
        acc2[i][j] = __builtin_amdgcn_mfma_f32_16x16x32_f16(al4[i], bh_, acc2[i][j], 0, 0, 0);
      }
    }
    __syncthreads();
    bufo = nb;
  }
  #pragma unroll
  for (int j = 0; j < 4; ++j) {
    int col = bn + wc + j * 16 + fr;
    float bsv = bias[col];
    float g2 = 0.f, b2 = 0.f;
    if (ACT == 2) { g2 = bns[col] * 0.9999950000375f; b2 = bnb[col]; }
    #pragma unroll
    for (int i = 0; i < 4; ++i) {
      #pragma unroll
      for (int r = 0; r < 4; ++r) {
        int row = bm + wr + i * 16 + ((l >> 4) << 2) + r;
        float v = acc1[i][j][r] + acc2[i][j][r] * (1.0f / 2048.0f) + bsv;
        if (ACT == 1) v = 0.5f * v * (1.0f + erff(v * 0.70710678118654752f));
        if (ACT == 2) { v = v * g2 + b2; v = v > 0.f ? v : expm1f(v); }
        size_t oi = (size_t)row * N + col;
        if (RESID) v += rsplit(Rh, Rl, oi);
        if (OSPLIT) emit_split(v, Ch, Cl, oi);
        else        C[oi] = v;
      }
    }
  }
}

// ---------------- LayerNorm on split input; optional split / f32 outputs ----------------
__global__ __launch_bounds__(256) void k_ln(const f16* __restrict__ xh, const f16* __restrict__ xl,
    const float* __restrict__ g, const float* __restrict__ b,
    float* __restrict__ of32, f16* __restrict__ oh, f16* __restrict__ ol) {
  int row = blockIdx.x, t = threadIdx.x;
  size_t base = (size_t)row << 9;
  float v0 = rsplit(xh, xl, base + t);
  float v1 = rsplit(xh, xl, base + t + 256);
  float s = v0 + v1;
  #pragma unroll
  for (int off = 32; off; off >>= 1) s += __shfl_down(s, off);
  __shared__ float ls[4];
  if ((t & 63) == 0) ls[t >> 6] = s;
  __syncthreads();
  float mean = (ls[0] + ls[1] + ls[2] + ls[3]) * (1.f / 512.f);
  __syncthreads();
  float d0 = v0 - mean, d1 = v1 - mean;
  float q = d0 * d0 + d1 * d1;
  #pragma unroll
  for (int off = 32; off; off >>= 1) q += __shfl_down(q, off);
  if ((t & 63) == 0) ls[t >> 6] = q;
  __syncthreads();
  float var = (ls[0] + ls[1] + ls[2] + ls[3]) * (1.f / 512.f);
  float rs = rsqrtf(var + 1e-5f);
  float r0 = d0 * rs * g[t] + b[t];
  float r1 = d1 * rs * g[t + 256] + b[t + 256];
  if (of32) { of32[base + t] = r0; of32[base + t + 256] = r1; }
  if (oh) {
    emit_split(r0, oh, ol, base + t);
    emit_split(r1, oh, ol, base + t + 256);
  }
}

// ---------------- M[bh,l] scoring (strided Q/K), register-batched K loads ----------------
__global__ __launch_bounds__(256) void k_qkM(const float* __restrict__ Q, int qstr,
    const float* __restrict__ Kp, int kstr, const int* __restrict__ idx,
    float* __restrict__ M, int Lq, int Lk, int U) {
  __shared__ float qsh[4][64];
  int wib = threadIdx.x >> 6;
  int wid = (blockIdx.x * 256 + threadIdx.x) >> 6;
  int lane = threadIdx.x & 63;
  int l = wid & (Lq - 1); int bh = wid / Lq; int h = bh & 7; int b = bh >> 3;
  // stage this wave's Q row into LDS
  if (lane < 16) {
    const float4* qr = (const float4*)(Q + (size_t)(b * Lq + l) * qstr + (h << 6));
    *(float4*)(&qsh[wib][lane * 4]) = qr[lane];
  }
  __syncthreads();
  // load sampled K row as one burst of 16 float4s (idle lanes: sample 0's row, hot line)
  int kr = idx[l * U + (lane < U ? lane : 0)];
  const float4* k4 = (const float4*)(Kp + (size_t)(b * Lk + kr) * kstr + (h << 6));
  float4 c[16];
  #pragma unroll
  for (int i = 0; i < 16; ++i) c[i] = k4[i];
  const float* qs = qsh[wib];
  float dot = 0.f;
  #pragma unroll
  for (int i = 0; i < 16; ++i)
    dot += qs[4*i] * c[i].x + qs[4*i+1] * c[i].y + qs[4*i+2] * c[i].z + qs[4*i+3] * c[i].w;
  float mx = (lane < U) ? dot : -INFINITY;
  float sm = (lane < U) ? dot : 0.f;
  #pragma unroll
  for (int off = 32; off; off >>= 1) {
    mx = fmaxf(mx, __shfl_xor(mx, off));
    sm += __shfl_xor(sm, off);
  }
  if (lane == 0) M[(size_t)bh * Lq + l] = mx - sm / (float)Lk;
}

// ---------------- single-wave top-u per (b,h), ties -> lower index ----------------
__global__ void k_topk64(const float* __restrict__ M, int* __restrict__ mtop, int Lq, int u) {
  __shared__ float vals[2048];
  int bh = blockIdx.x, l = threadIdx.x;
  const float* Mr = M + (size_t)bh * Lq;
  for (int i = l; i < Lq; i += 64) vals[i] = Mr[i];
  __syncthreads();
  for (int it = 0; it < u; ++it) {
    float bv = -INFINITY; int bi = 0x7fffffff;
    for (int i = l; i < Lq; i += 64) {
      float v = vals[i];
      if (v > bv || (v == bv && i < bi)) { bv = v; bi = i; }
    }
    #pragma unroll
    for (int off = 32; off; off >>= 1) {
      float vv = __shfl_xor(bv, off); int ii = __shfl_xor(bi, off);
      if (vv > bv || (vv == bv && ii < bi)) { bv = vv; bi = ii; }
    }
    if (l == 0) { mtop[bh * u + it] = bi; vals[bi] = -INFINITY; }
    __syncthreads();
  }
}

// ---------------- ctx mean (AO split) ----------------
__global__ void k_cm1(const float* __restrict__ V, int vstr, float* __restrict__ PS,
                      int Lk, int rows) {
  int bid = blockIdx.x;
  int bh = bid >> 4, seg = bid & 15, d = threadIdx.x;
  int b = bh >> 3, h = bh & 7;
  const float* vp = V + (size_t)(b * Lk + seg * rows) * vstr + (h << 6) + d;
  float acc = 0.f;
  for (int r = 0; r < rows; ++r) acc += vp[(size_t)r * vstr];
  PS[(bid << 6) + d] = acc;
}
__global__ void k_cm2(const float* __restrict__ PS, f16* __restrict__ AOh,
                      f16* __restrict__ AOl, float invLk, int Lq, int total) {
  int i = blockIdx.x * 256 + threadIdx.x;
  if (i >= total) return;
  int c = i & 511; int h = c >> 6; int d = c & 63;
  int r = i >> 9; int b = r / Lq;
  float acc = 0.f;
  #pragma unroll
  for (int s = 0; s < 16; ++s) acc += PS[(((((b << 3) + h) << 4) + s) << 6) + d];
  emit_split(acc * invLk, AOh, AOl, (size_t)i);
}

// ---------------- cumsum (masked ctx; per-block prefix, AO split) ----------------
__global__ void k_cs1(const float* __restrict__ V, int vstr, float* __restrict__ PS,
                      int Lq, int rows) {
  int bid = blockIdx.x;
  int bh = bid >> 3, seg = bid & 7, d = threadIdx.x;
  int b = bh >> 3, h = bh & 7;
  const float* vp = V + (size_t)(b * Lq + seg * rows) * vstr + (h << 6) + d;
  float acc = 0.f;
  for (int r = 0; r < rows; ++r) acc += vp[(size_t)r * vstr];
  PS[(bid << 6) + d] = acc;
}
__global__ void k_cs3(const float* __restrict__ V, int vstr, const float* __restrict__ PS,
                      f16* __restrict__ AOh, f16* __restrict__ AOl, int Lq, int rows) {
  int bid = blockIdx.x;
  int bh = bid >> 3, seg = bid & 7, d = threadIdx.x;
  int b = bh >> 3, h = bh & 7;
  float acc = 0.f;
  for (int s2 = 0; s2 < seg; ++s2) acc += PS[(((bh << 3) + s2) << 6) + d];
  const float* vp = V + (size_t)(b * Lq + seg * rows) * vstr + (h << 6) + d;
  size_t ob = ((size_t)(b * Lq + seg * rows) << 9) + (h << 6) + d;
  for (int r = 0; r < rows; ++r) {
    acc += vp[(size_t)r * vstr];
    emit_split(acc, AOh, AOl, ob + ((size_t)r << 9));
  }
}

// ---------------- flash sparse attn: ALL u rows per (512-key chunk, bh) block ----------------
__global__ __launch_bounds__(256) void k_sattnF(
    const float* __restrict__ Q, int qstr, const float* __restrict__ Kp, int kstr,
    const float* __restrict__ Vp, int vstr, const int* __restrict__ mtop,
    float* __restrict__ PPm, float* __restrict__ PPs, float* __restrict__ PPv,
    int Lq, int Lk, int u, int masked, int bhn) {
  __shared__ float Qs[40 * 64];
  __shared__ float Kt[64 * 65];
  __shared__ float Vs[64 * 65];
  __shared__ float els[40 * 64];
  __shared__ int rowsh[40];
  int ch = blockIdx.x, bh = blockIdx.y;
  int b = bh >> 3, h = bh & 7;
  int c0 = ch << 9;
  int t = threadIdx.x;
  int g = t >> 6, d = t & 63;
  if (t < 40) rowsh[t] = (t < u) ? mtop[bh * u + t] : -1;
  __syncthreads();
  for (int i = t; i < 40 * 16; i += 256) {
    int r = i >> 4, e4 = i & 15;
    int row = rowsh[r];
    float4 v;
    if (row >= 0) v = *(const float4*)(Q + (size_t)(b * Lq + row) * qstr + (h << 6) + e4 * 4);
    else          v = make_float4(0.f, 0.f, 0.f, 0.f);
    *(float4*)(Qs + r * 64 + e4 * 4) = v;
  }
  int rows_[10];
  __syncthreads();
  #pragma unroll
  for (int i = 0; i < 10; ++i) rows_[i] = rowsh[g + i * 4];
  float pv[10], m[10], sum[10];
  #pragma unroll
  for (int i = 0; i < 10; ++i) { pv[i] = 0.f; m[i] = -INFINITY; sum[i] = 0.f; }
  const int srow = t >> 2, seg = t & 3;
  for (int kt = 0; kt < 8; ++kt) {
    __syncthreads();
    {
      int crow = c0 + (kt << 6) + srow;
      const float* kp2 = Kp + (size_t)(b * Lk + crow) * kstr + (h << 6) + seg * 16;
      const float* vp2 = Vp + (size_t)(b * Lk + crow) * vstr + (h << 6) + seg * 16;
      #pragma unroll
      for (int q4 = 0; q4 < 4; ++q4) {
        float4 kv = *(const float4*)(kp2 + q4 * 4);
        float4 vv = *(const float4*)(vp2 + q4 * 4);
        int e0 = seg * 16 + q4 * 4;
        Kt[(e0 + 0) * 65 + srow] = kv.x;
        Kt[(e0 + 1) * 65 + srow] = kv.y;
        Kt[(e0 + 2) * 65 + srow] = kv.z;
        Kt[(e0 + 3) * 65 + srow] = kv.w;
        Vs[srow * 65 + e0 + 0] = vv.x;
        Vs[srow * 65 + e0 + 1] = vv.y;
        Vs[srow * 65 + e0 + 2] = vv.z;
        Vs[srow * 65 + e0 + 3] = vv.w;
      }
    }
    __syncthreads();
    float dot[10];
    #pragma unroll
    for (int i = 0; i < 10; ++i) dot[i] = 0.f;
    for (int e = 0; e < 64; ++e) {
      float kv = Kt[e * 65 + d];
      #pragma unroll
      for (int i = 0; i < 10; ++i)
        dot[i] += Qs[(g + i * 4) * 64 + e] * kv;
    }
    int key = c0 + (kt << 6) + d;
    float scale_[10];
    #pragma unroll
    for (int i = 0; i < 10; ++i) {
      float s = dot[i] * 0.125f;
      if (masked && key > rows_[i]) s = -INFINITY;
      float tm = s;
      #pragma unroll
      for (int off = 32; off; off >>= 1) tm = fmaxf(tm, __shfl_xor(tm, off));
      float nm = fmaxf(m[i], tm);
      if (nm > -3e38f) {
        float scl = expf(m[i] - nm);
        float e_ = expf(s - nm);
        float ts = e_;
        #pragma unroll
        for (int off = 32; off; off >>= 1) ts += __shfl_xor(ts, off);
        sum[i] = sum[i] * scl + ts;
        m[i] = nm;
        scale_[i] = scl;
        els[(g + i * 4) * 64 + d] = e_;
      } else {
        scale_[i] = 1.f;
        els[(g + i * 4) * 64 + d] = 0.f;
      }
    }
    __syncthreads();
    float acc[10];
    #pragma unroll
    for (int i = 0; i < 10; ++i) acc[i] = 0.f;
    for (int k = 0; k < 64; ++k) {
      float vv = Vs[k * 65 + d];
      #pragma unroll
      for (int i = 0; i < 10; ++i)
        acc[i] += els[(g + i * 4) * 64 + k] * vv;
    }
    #pragma unroll
    for (int i = 0; i < 10; ++i) pv[i] = pv[i] * scale_[i] + acc[i];
  }
  #pragma unroll
  for (int i = 0; i < 10; ++i) {
    int r = g + i * 4;
    if (r < u) {
      size_t pidx = (size_t)(ch * bhn + bh) * u + r;
      if (d == 0) { PPm[pidx] = m[i]; PPs[pidx] = sum[i]; }
      PPv[pidx * 64 + d] = pv[i];
    }
  }
}

// ---------------- combine chunk partials -> AO (online softmax rescale) ----------------
__global__ void k_sattnc(const float* __restrict__ PPm, const float* __restrict__ PPs,
                         const float* __restrict__ PPv, const int* __restrict__ mtop,
                         f16* __restrict__ AOh, f16* __restrict__ AOl,
                         int Lq, int u, int nch, int bhn) {
  int rowid = blockIdx.x;
  int bh = rowid / u, ui = rowid % u;
  int d = threadIdx.x;
  int b = bh >> 3, h = bh & 7;
  int row = mtop[bh * u + ui];
  float M = -INFINITY;
  for (int c = 0; c < nch; ++c)
    M = fmaxf(M, PPm[(size_t)(c * bhn + bh) * u + ui]);
  float S = 0.f, o = 0.f;
  for (int c = 0; c < nch; ++c) {
    size_t pidx = (size_t)(c * bhn + bh) * u + ui;
    float pm = PPm[pidx];
    float sc = (pm > -3e38f) ? expf(pm - M) : 0.f;
    S += sc * PPs[pidx];
    o += sc * PPv[pidx * 64 + d];
  }
  emit_split(o / S, AOh, AOl, ((size_t)(b * Lq + row) << 9) + (h << 6) + d);
}

// ---------------- maxpool w3 s2 p1 along L (split-only output) ----------------
__global__ void k_maxpool(const float* __restrict__ y, f16* __restrict__ oh,
                          f16* __restrict__ ol, int L) {
  int Lo = L >> 1;
  int i = blockIdx.x * 256 + threadIdx.x;
  int c = i & 511; int bj = i >> 9;
  int j = bj % Lo; int b = bj / Lo;
  float m = -INFINITY;
  int t0 = 2 * j - 1;
  #pragma unroll
  for (int k = 0; k < 3; ++k) {
    int tt = t0 + k;
    if (tt >= 0 && tt < L) m = fmaxf(m, y[((size_t)(b * L + tt) << 9) + c]);
  }
  emit_split(m, oh, ol, ((size_t)(b * Lo + j) << 9) + c);
}

// ---------------- final projection 512->7 (reads f32 from Y) ----------------
__global__ void k_proj(const float* __restrict__ Xn, const float* __restrict__ pw,
                       const float* __restrict__ pb, float* __restrict__ out) {
  int i = blockIdx.x * 256 + threadIdx.x;
  if (i >= 16 * 512 * 7) return;
  int c = i % 7; int r = i / 7;
  int b = r >> 9; int j = r & 511;
  const float* xr = Xn + ((size_t)(b * 1024 + 512 + j) << 9);
  float acc = pb[c];
  for (int d2 = 0; d2 < 512; ++d2) acc += xr[d2] * pw[d2 * 7 + c];
  out[i] = acc;
}

// =====================================================================
extern "C" void kernel_launch(void* const* d_in, const int* in_sizes, int n_in,
                              void* d_out, int out_size, void* d_ws, size_t ws_size,
                              hipStream_t stream) {
  const float* x_enc      = (const float*)d_in[0];
  const float* x_mark_enc = (const float*)d_in[1];
  const float* x_dec      = (const float*)d_in[2];
  const float* x_mark_dec = (const float*)d_in[3];
  const float* enc_tok_w  = (const float*)d_in[4];
  const float* enc_mark_w = (const float*)d_in[5];
  const float* dec_tok_w  = (const float*)d_in[6];
  const float* dec_mark_w = (const float*)d_in[7];
  const float* enc_attn_w = (const float*)d_in[8];
  const float* enc_attn_b = (const float*)d_in[9];
  const float* enc_ffn1_w = (const float*)d_in[10];
  const float* enc_ffn1_b = (const float*)d_in[11];
  const float* enc_ffn2_w = (const float*)d_in[12];
  const float* enc_ffn2_b = (const float*)d_in[13];
  const float* enc_ln_g   = (const float*)d_in[14];
  const float* enc_ln_b   = (const float*)d_in[15];
  const float* distil_w   = (const float*)d_in[16];
  const float* distil_b   = (const float*)d_in[17];
  const float* distil_bn_g= (const float*)d_in[18];
  const float* distil_bn_b= (const float*)d_in[19];
  const float* enc_norm_g = (const float*)d_in[20];
  const float* enc_norm_b = (const float*)d_in[21];
  const float* dec_self_w = (const float*)d_in[22];
  const float* dec_self_b = (const float*)d_in[23];
  const float* dec_cross_w= (const float*)d_in[24];
  const float* dec_cross_b= (const float*)d_in[25];
  const float* dec_ffn1_w = (const float*)d_in[26];
  const float* dec_ffn1_b = (const float*)d_in[27];
  const float* dec_ffn2_w = (const float*)d_in[28];
  const float* dec_ffn2_b = (const float*)d_in[29];
  const float* dec_ln_g   = (const float*)d_in[30];
  const float* dec_ln_b   = (const float*)d_in[31];
  const float* dec_norm_g = (const float*)d_in[32];
  const float* dec_norm_b = (const float*)d_in[33];
  const float* proj_w     = (const float*)d_in[34];
  const float* proj_b     = (const float*)d_in[35];

  // -------- workspace layout: split-only activations; Y sized by tier --------
  float* ws = (float*)d_ws;
  size_t off = 0;
  f16* Xh   = (f16*)(ws + off); off += 16777216;
  f16* Xl   = Xh + 16777216;
  f16* ENCh = (f16*)(ws + off); off += 4194304;
  f16* ENCl = ENCh + 4194304;
  float* PE = ws + off; off += 1048576;
  float* Mb = ws + off; off += 131072;
  float* PS = ws + off; off += 65536;
  f16* WSP  = (f16*)(ws + off); off += 2097152;
  int* IDXi = (int*)(ws + off); off += 84480;
  float* Y  = ws + off;
  int* MTi  = IDXi + 81920;
  size_t need4 = (off + 16777216ull) * 4;
  size_t need8 = (off + 33554432ull) * 4;
  int bs;
  if      (ws_size >= need8) bs = 8;
  else if (ws_size >= need4) bs = 4;
  else return;
  f16* Yh = (f16*)Y;
  f16* Yl = Yh + 16777216;
  float* WF  = (float*)WSP + 1048576;
  float* PPm = WF;
  float* PPs = WF + 16384;
  float* PPv = WF + 32768;

  auto ln = [&](const f16* xh, const f16* xl, const float* g, const float* b, int rows,
                float* of32, f16* oh, f16* ol) {
    k_ln<<<rows, 256, 0, stream>>>(xh, xl, g, b, of32, oh, ol);
  };
  auto wsplit = [&](const float* W, f16* Wh, f16* Wl, int K, int N, int nmat) {
    dim3 g(K >> 5, N >> 5, nmat);
    k_wsplit<<<g, 256, 0, stream>>>(W, Wh, Wl, K, N);
  };
  auto mgQ = [&](const f16* Ah, const f16* Al, const f16* Wh, const f16* Wl,
                 const float* bias, float* C, int M, int N, int K) {
    dim3 g(N >> 7, M >> 7);
    k_mgemm2<0,0,0,0><<<g, 256, 0, stream>>>(Ah, Al, Wh, Wl, bias, nullptr, nullptr,
        nullptr, nullptr, C, nullptr, nullptr, M, N, K, 0);
  };
  auto mgR = [&](const f16* Ah, const f16* Al, const f16* Wh, const f16* Wl,
                 const float* bias, const f16* Rh, const f16* Rl,
                 f16* Ch, f16* Cl, int M, int N, int K) {
    dim3 g(N >> 7, M >> 7);
    k_mgemm2<0,1,0,1><<<g, 256, 0, stream>>>(Ah, Al, Wh, Wl, bias, Rh, Rl,
        nullptr, nullptr, nullptr, Ch, Cl, M, N, K, 0);
  };
  auto mgG = [&](const f16* Ah, const f16* Al, const f16* Wh, const f16* Wl,
                 const float* bias, f16* Ch, f16* Cl, int M, int N, int K) {
    dim3 g(N >> 7, M >> 7);
    k_mgemm2<1,1,0,0><<<g, 256, 0, stream>>>(Ah, Al, Wh, Wl, bias, nullptr, nullptr,
        nullptr, nullptr, nullptr, Ch, Cl, M, N, K, 0);
  };
  auto Uof = [](int Lx) { int v = 5 * (int)ceil(log((double)Lx)); return v < Lx ? v : Lx; };

  auto attn = [&](f16* xqh, f16* xql, const f16* xkvh, const f16* xkvl,
                  int Lq, int Lk, const float* w, const float* bias,
                  bool masked, u32 fold, bool selfa) {
    int U = Uof(Lk), uu = Uof(Lq);
    u32 r0, r1, ka, kb2;
    tf_block(0u, 42u, 0u, fold, r0, r1);
    tf_block(r0, r1, 0u, 1u, ka, kb2);
    int n = Lq * U;
    k_idx<<<(n + 255) / 256, 256, 0, stream>>>(ka, kb2, n, Lk - 1, IDXi);

    f16 *Wqkvh = WSP,            *Wqkvl = WSP + 786432;
    f16 *WQh   = WSP,            *WQl   = WSP + 262144;
    f16 *WKVh  = WSP + 524288,   *WKVl  = WSP + 1048576;
    f16 *WOh   = WSP + 1572864,  *WOl   = WSP + 1835008;
    if (selfa) {
      wsplit(w, Wqkvh, Wqkvl, 512, 512, 3);
    } else {
      wsplit(w, WQh, WQl, 512, 512, 1);
      wsplit(w + 262144, WKVh, WKVl, 512, 512, 2);
    }
    wsplit(w + 786432, WOh, WOl, 512, 512, 1);

    int nsl = 16 / bs;
    int bhn = bs * 8;
    for (int s = 0; s < nsl; ++s) {
      size_t qoff = (size_t)s * bs * Lq * 512;
      size_t koff = (size_t)s * bs * Lk * 512;
      const float *qp, *kp, *vp;
      int qstr, kstr, vstr;
      f16 *AOh, *AOl;
      if (selfa) {
        float* QKV = Y;
        AOh = (f16*)(Y + (size_t)bs * Lq * 1536);
        AOl = AOh + (size_t)bs * Lq * 512;
        mgQ(xqh + qoff, xql + qoff, Wqkvh, Wqkvl, bias, QKV, bs * Lq, 1536, 512);
        qp = QKV; qstr = 1536; kp = QKV + 512; kstr = 1536; vp = QKV + 1024; vstr = 1536;
      } else {
        float* Qb  = Y;
        float* KVb = Y + (size_t)bs * Lq * 512;
        AOh = (f16*)(KVb + (size_t)bs * Lk * 1024);
        AOl = AOh + (size_t)bs * Lq * 512;
        mgQ(xqh + qoff, xql + qoff, WQh, WQl, bias, Qb, bs * Lq, 512, 512);
        mgQ(xkvh + koff, xkvl + koff, WKVh, WKVl, bias + 512, KVb, bs * Lk, 1024, 512);
        qp = Qb; qstr = 512; kp = KVb; kstr = 1024; vp = KVb + 512; vstr = 1024;
      }
      int wids = bhn * Lq;
      k_qkM<<<wids / 4, 256, 0, stream>>>(qp, qstr, kp, kstr, IDXi, Mb, Lq, Lk, U);
      k_topk64<<<bhn, 64, 0, stream>>>(Mb, MTi, Lq, uu);
      if (masked) {
        k_cs1<<<bhn * 8, 64, 0, stream>>>(vp, vstr, PS, Lq, Lq >> 3);
        k_cs3<<<bhn * 8, 64, 0, stream>>>(vp, vstr, PS, AOh, AOl, Lq, Lq >> 3);
      } else {
        k_cm1<<<bhn * 16, 64, 0, stream>>>(vp, vstr, PS, Lk, Lk >> 4);
        int tot = bs * Lq * 512;
        k_cm2<<<tot / 256, 256, 0, stream>>>(PS, AOh, AOl, 1.0f / (float)Lk, Lq, tot);
      }
      int nch = Lk >> 9;
      dim3 gs(nch, bhn);
      k_sattnF<<<gs, 256, 0, stream>>>(qp, qstr, kp, kstr, vp, vstr, MTi,
                                       PPm, PPs, PPv, Lq, Lk, uu, masked ? 1 : 0, bhn);
      k_sattnc<<<bhn * uu, 64, 0, stream>>>(PPm, PPs, PPv, MTi, AOh, AOl, Lq, uu, nch, bhn);
      mgR(AOh, AOl, WOh, WOl, bias + 1536, xqh + qoff, xql + qoff,
          xqh + qoff, xql + qoff, bs * Lq, 512, 512);
    }
  };

  auto ffn = [&](f16* xh, f16* xl, const float* w1, const float* b1,
                 const float* w2, const float* b2, int Mtot) {
    f16 *W1h = WSP,           *W1l = WSP + 1048576,
        *W2h = WSP + 2097152, *W2l = WSP + 3145728;
    wsplit(w1, W1h, W1l, 512, 2048, 1);
    wsplit(w2, W2h, W2l, 2048, 512, 1);
    for (int c0 = 0; c0 < Mtot; c0 += 8192) {
      int rows = (Mtot - c0 < 8192) ? (Mtot - c0) : 8192;
      mgG(xh + (size_t)c0 * 512, xl + (size_t)c0 * 512, W1h, W1l, b1, Yh, Yl, rows, 2048, 512);
      mgR(Yh, Yl, W2h, W2l, b2, xh + (size_t)c0 * 512, xl + (size_t)c0 * 512,
          xh + (size_t)c0 * 512, xl + (size_t)c0 * 512, rows, 512, 2048);
    }
  };

  // ---------------- encoder ----------------
  k_pe<<<(2048 * 512) / 256, 256, 0, stream>>>(PE);
  k_embed<<<(16 * 2048 * 512) / 256, 256, 0, stream>>>(x_enc, x_mark_enc, enc_tok_w, enc_mark_w,
                                                       PE, Xh, Xl, 2048, 16 * 2048 * 512);
  int L = 2048;
  for (int l = 0; l < 3; ++l) {
    attn(Xh, Xl, Xh, Xl, L, L, enc_attn_w + (size_t)l * 4 * 262144,
         enc_attn_b + (size_t)l * 2048, false, (u32)l, true);
    ln(Xh, Xl, enc_ln_g + (size_t)(l * 2) * 512, enc_ln_b + (size_t)(l * 2) * 512, 16 * L,
       nullptr, Xh, Xl);
    ffn(Xh, Xl, enc_ffn1_w + (size_t)l * 512 * 2048, enc_ffn1_b + (size_t)l * 2048,
        enc_ffn2_w + (size_t)l * 2048 * 512, enc_ffn2_b + (size_t)l * 512, 16 * L);
    ln(Xh, Xl, enc_ln_g + (size_t)(l * 2 + 1) * 512, enc_ln_b + (size_t)(l * 2 + 1) * 512, 16 * L,
       nullptr, Xh, Xl);
    if (l < 2) {
      f16 *Dh = WSP, *Dl = WSP + 786432;
      k_wsplit_conv<<<(512 * 1536) / 256, 256, 0, stream>>>(distil_w + (size_t)l * 512 * 512 * 3, Dh, Dl);
      dim3 g(512 >> 7, (16 * L) >> 7);
      int lgL = (L == 2048) ? 11 : 10;
      k_mgemm2<2,0,1,0><<<g, 256, 0, stream>>>(Xh, Xl, Dh, Dl, distil_b + (size_t)l * 512,
          nullptr, nullptr, distil_bn_g + (size_t)l * 512, distil_bn_b + (size_t)l * 512,
          Y, nullptr, nullptr, 16 * L, 512, 1536, lgL);
      int Lo = L >> 1;
      k_maxpool<<<(16 * Lo * 512) / 256, 256, 0, stream>>>(Y, Xh, Xl, L);
      L = Lo;
    }
  }
  ln(Xh, Xl, enc_norm_g, enc_norm_b, 16 * 512, nullptr, ENCh, ENCl);

  // ---------------- decoder (in-place chain in Xh/Xl) ----------------
  k_embed<<<(16 * 1024 * 512) / 256, 256, 0, stream>>>(x_dec, x_mark_dec, dec_tok_w, dec_mark_w,
                                                       PE, Xh, Xl, 1024, 16 * 1024 * 512);
  for (int l = 0; l < 2; ++l) {
    attn(Xh, Xl, Xh, Xl, 1024, 1024, dec_self_w + (size_t)l * 4 * 262144,
         dec_self_b + (size_t)l * 2048, true, (u32)(100 + 2 * l), true);
    ln(Xh, Xl, dec_ln_g + (size_t)(l * 3) * 512, dec_ln_b + (size_t)(l * 3) * 512, 16384,
       nullptr, Xh, Xl);
    attn(Xh, Xl, ENCh, ENCl, 1024, 512, dec_cross_w + (size_t)l * 4 * 262144,
         dec_cross_b + (size_t)l * 2048, false, (u32)(101 + 2 * l), false);
    ln(Xh, Xl, dec_ln_g + (size_t)(l * 3 + 1) * 512, dec_ln_b + (size_t)(l * 3 + 1) * 512, 16384,
       nullptr, Xh, Xl);
    ffn(Xh, Xl, dec_ffn1_w + (size_t)l * 512 * 2048, dec_ffn1_b + (size_t)l * 2048,
        dec_ffn2_w + (size_t)l * 2048 * 512, dec_ffn2_b + (size_t)l * 512, 16384);
    ln(Xh, Xl, dec_ln_g + (size_t)(l * 3 + 2) * 512, dec_ln_b + (size_t)(l * 3 + 2) * 512, 16384,
       nullptr, Xh, Xl);
  }
  ln(Xh, Xl, dec_norm_g, dec_norm_b, 16384, Y, nullptr, nullptr);
  k_proj<<<(16 * 512 * 7 + 255) / 256, 256, 0, stream>>>(Y, proj_w, proj_b, (float*)d_out);
}

// Round 20
// 7568.356 us; speedup vs baseline: 2.6916x; 1.0081x over previous
//
#include <hip/hip_runtime.h>
#include <math.h>
#include <stdint.h>

typedef unsigned int u32;
typedef _Float16 f16;
typedef __attribute__((ext_vector_type(8))) _Float16 f16x8;
typedef __attribute__((ext_vector_type(4))) float f32x4;

// ---------------- Threefry-2x32 (20 rounds), matches JAX ----------------
__host__ __device__ __forceinline__ u32 rotl32(u32 x, int r) { return (x << r) | (x >> (32 - r)); }
__host__ __device__ __forceinline__ void tf_round(u32& x0, u32& x1, int r) {
  x0 += x1; x1 = rotl32(x1, r); x1 ^= x0;
}
__host__ __device__ __forceinline__ void tf_block(u32 k0, u32 k1, u32 x0, u32 x1, u32& o0, u32& o1) {
  u32 k2 = k0 ^ k1 ^ 0x1BD11BDAu;
  x0 += k0; x1 += k1;
  tf_round(x0,x1,13); tf_round(x0,x1,15); tf_round(x0,x1,26); tf_round(x0,x1,6);
  x0 += k1; x1 += k2 + 1u;
  tf_round(x0,x1,17); tf_round(x0,x1,29); tf_round(x0,x1,16); tf_round(x0,x1,24);
  x0 += k2; x1 += k0 + 2u;
  tf_round(x0,x1,13); tf_round(x0,x1,15); tf_round(x0,x1,26); tf_round(x0,x1,6);
  x0 += k0; x1 += k1 + 3u;
  tf_round(x0,x1,17); tf_round(x0,x1,29); tf_round(x0,x1,16); tf_round(x0,x1,24);
  x0 += k1; x1 += k2 + 4u;
  tf_round(x0,x1,13); tf_round(x0,x1,15); tf_round(x0,x1,26); tf_round(x0,x1,6);
  x0 += k2; x1 += k0 + 5u;
  o0 = x0; o1 = x1;
}

__global__ void k_idx(u32 ka, u32 kb, int n, int mask, int* __restrict__ idx) {
  int i = blockIdx.x * 256 + threadIdx.x;
  if (i >= n) return;
  u32 b1, b2; tf_block(ka, kb, 0u, (u32)i, b1, b2);
  idx[i] = (int)((b1 ^ b2) & (u32)mask);
}

__device__ __forceinline__ void emit_split(float v, f16* __restrict__ oh,
                                           f16* __restrict__ ol, size_t o) {
  f16 h = (f16)v;
  oh[o] = h;
  ol[o] = (f16)((v - (float)h) * 2048.0f);
}
__device__ __forceinline__ float rsplit(const f16* __restrict__ h,
                                        const f16* __restrict__ l, size_t o) {
  return (float)h[o] + (float)l[o] * (1.0f / 2048.0f);
}

// ---------------- positional embedding ----------------
__global__ void k_pe(float* __restrict__ pe) {
  int i = blockIdx.x * 256 + threadIdx.x;
  if (i >= 2048 * 512) return;
  int t = i >> 9, o = i & 511;
  float arg = (float)((o >> 1) * 2) * (float)(-(log(10000.0) / 512.0));
  float div = (float)exp((double)arg);
  float ang32 = (float)t * div;
  double ang = (double)ang32;
  pe[i] = (float)((o & 1) ? cos(ang) : sin(ang));
}

// ---------------- embedding (split-only output) ----------------
__global__ __launch_bounds__(256) void k_embed(
    const float* __restrict__ x, const float* __restrict__ mark,
    const float* __restrict__ tw, const float* __restrict__ mw,
    const float* __restrict__ pe, f16* __restrict__ oh, f16* __restrict__ ol,
    int L, int total) {
  int i = blockIdx.x * 256 + threadIdx.x;
  if (i >= total) return;
  int oo = i & 511;
  int bt = i >> 9;
  int t = bt % L;
  int b = bt / L;
  float acc = pe[(t << 9) + oo];
  #pragma unroll
  for (int k = 0; k < 3; ++k) {
    int st = t + k - 1; if (st < 0) st += L; else if (st >= L) st -= L;
    const float* xr = x + (size_t)(b * L + st) * 7;
    const float* wr = tw + oo * 21 + k;
    #pragma unroll
    for (int ii = 0; ii < 7; ++ii) acc += xr[ii] * wr[ii * 3];
  }
  const float* mr = mark + (size_t)bt * 4;
  #pragma unroll
  for (int m = 0; m < 4; ++m) acc += mr[m] * mw[(m << 9) + oo];
  emit_split(acc, oh, ol, ((size_t)bt << 9) + oo);
}

// ---------------- weight transpose + f16 split (z = matrix index) ----------------
__global__ __launch_bounds__(256) void k_wsplit(const float* __restrict__ W,
    f16* __restrict__ Wh, f16* __restrict__ Wl, int K, int N) {
  size_t zo = (size_t)blockIdx.z * K * N;
  W += zo; Wh += zo; Wl += zo;
  __shared__ float tile[32][33];
  int kb = blockIdx.x << 5, nb = blockIdx.y << 5;
  int t = threadIdx.x;
  int tr = t >> 5, tc = t & 31;
  #pragma unroll
  for (int p = 0; p < 4; ++p)
    tile[tr + p * 8][tc] = W[(size_t)(kb + tr + p * 8) * N + nb + tc];
  __syncthreads();
  #pragma unroll
  for (int p = 0; p < 4; ++p) {
    int n = tr + p * 8, k = tc;
    float v = tile[k][n];
    f16 h = (f16)v;
    size_t o = (size_t)(nb + n) * K + kb + k;
    Wh[o] = h;
    Wl[o] = (f16)((v - (float)h) * 2048.0f);
  }
}

__global__ void k_wsplit_conv(const float* __restrict__ w, f16* __restrict__ Wh, f16* __restrict__ Wl) {
  int i = blockIdx.x * 256 + threadIdx.x;
  if (i >= 512 * 1536) return;
  int o = i / 1536, k = i - o * 1536;
  float v = w[(size_t)o * 1536 + (k & 511) * 3 + (k >> 9)];
  f16 h = (f16)v;
  Wh[i] = h;
  Wl[i] = (f16)((v - (float)h) * 2048.0f);
}

__device__ __forceinline__ int swz_x(int r) { return ((((r >> 1) & 3) ^ ((r >> 3) & 3)) << 4); }

__device__ __forceinline__ void gload16(const void* g, void* l) {
  __builtin_amdgcn_global_load_lds(
      (const __attribute__((address_space(1))) void*)g,
      (__attribute__((address_space(3))) void*)l, 16, 0, 0);
}

// ---------------- MFMA GEMM v2: pre-split f16 A/B, async LDS, dbuf, 16x16x32 ----------------
template<int ACT, int OSPLIT, int GATHER, int RESID>
__global__ __launch_bounds__(256, 2) void k_mgemm2(
    const f16* __restrict__ Ah, const f16* __restrict__ Al,
    const f16* __restrict__ Bh, const f16* __restrict__ Bl,
    const float* __restrict__ bias,
    const f16* __restrict__ Rh, const f16* __restrict__ Rl,
    const float* __restrict__ bns, const float* __restrict__ bnb,
    float* __restrict__ C, f16* __restrict__ Ch, f16* __restrict__ Cl,
    int M, int N, int K, int lgL) {
  __shared__ char lds[65536];
  const int t = threadIdx.x;
  int nwg = gridDim.x * gridDim.y;
  int bid = blockIdx.y * gridDim.x + blockIdx.x;
  if ((nwg & 7) == 0) {
    int cpx = nwg >> 3;
    bid = (bid & 7) * cpx + (bid >> 3);
  }
  const int bm = (bid / gridDim.x) << 7, bn = (bid % gridDim.x) << 7;
  const int w = t >> 6, l = t & 63;
  const int lr = l >> 2;
  const int qx = (l & 3) << 4;
  const int wr = (w >> 1) << 6, wc = (w & 1) << 6;
  const int fr = l & 15;
  const int fkB = (l >> 4) << 4;
  const f32x4 zero = {0.f, 0.f, 0.f, 0.f};
  f32x4 acc1[4][4], acc2[4][4];
  #pragma unroll
  for (int i = 0; i < 4; ++i)
    #pragma unroll
    for (int j = 0; j < 4; ++j) { acc1[i][j] = zero; acc2[i][j] = zero; }

  auto stage = [&](int k0, int bufo) {
    #pragma unroll
    for (int c = 0; c < 2; ++c) {
      int r = w * 32 + c * 16 + lr;
      int sx = qx ^ swz_x(r);
      const char *gAh, *gAl;
      if (GATHER) {
        int m = bm + r;
        int Lm = 1 << lgL;
        int ab = m >> lgL, at = m & (Lm - 1);
        int ke = k0 + (sx >> 1);
        int tap = ke >> 9, ii = ke & 511;
        int st = at + tap - 1; if (st < 0) st += Lm; else if (st >= Lm) st -= Lm;
        size_t aoff = (((size_t)((ab << lgL) + st)) << 9) + ii;
        gAh = (const char*)(Ah + aoff);
        gAl = (const char*)(Al + aoff);
      } else {
        gAh = (const char*)(Ah + (size_t)(bm + r) * K + k0) + sx;
        gAl = (const char*)(Al + (size_t)(bm + r) * K + k0) + sx;
      }
      const char* gBh = (const char*)(Bh + (size_t)(bn + r) * K + k0) + sx;
      const char* gBl = (const char*)(Bl + (size_t)(bn + r) * K + k0) + sx;
      char* base = lds + bufo + w * 2048 + c * 1024;
      gload16(gAh, base);
      gload16(gAl, base + 8192);
      gload16(gBh, base + 16384);
      gload16(gBl, base + 24576);
    }
  };

  int nt = K >> 5;
  stage(0, 0);
  __syncthreads();
  int bufo = 0;
  for (int tt = 0; tt < nt; ++tt) {
    int nb = bufo ^ 32768;
    if (tt + 1 < nt) stage((tt + 1) << 5, nb);
    char* pAh = lds + bufo;
    char* pAl = pAh + 8192;
    char* pBh = pAh + 16384;
    char* pBl = pAh + 24576;
    f16x8 ah4[4], al4[4];
    #pragma unroll
    for (int i = 0; i < 4; ++i) {
      int r = wr + i * 16 + fr;
      int ob = r * 64 + (fkB ^ swz_x(r));
      ah4[i] = *(f16x8*)(pAh + ob);
      al4[i] = *(f16x8*)(pAl + ob);
    }
    #pragma unroll
    for (int j = 0; j < 4; ++j) {
      int r = wc + j * 16 + fr;
      int ob = r * 64 + (fkB ^ swz_x(r));
      f16x8 bh_ = *(f16x8*)(pBh + ob);
      f16x8 bl_ = *(f16x8*)(pBl + ob);
      #pragma unroll
      for (int i = 0; i < 4; ++i) {
        acc1[i][j] = __builtin_amdgcn_mfma_f32_16x16x32_f16(ah4[i], bh_, acc1[i][j], 0, 0, 0);
        acc2[i][j] = __builtin_amdgcn_mfma_f32_16x16x32_f16(ah4[i], bl_, acc2[i][j], 0, 0, 0);
        acc2[i][j] = __builtin_amdgcn_mfma_f32_16x16x32_f16(al4[i], bh_, acc2[i][j], 0, 0, 0);
      }
    }
    __syncthreads();
    bufo = nb;
  }
  #pragma unroll
  for (int j = 0; j < 4; ++j) {
    int col = bn + wc + j * 16 + fr;
    float bsv = bias[col];
    float g2 = 0.f, b2 = 0.f;
    if (ACT == 2) { g2 = bns[col] * 0.9999950000375f; b2 = bnb[col]; }
    #pragma unroll
    for (int i = 0; i < 4; ++i) {
      #pragma unroll
      for (int r = 0; r < 4; ++r) {
        int row = bm + wr + i * 16 + ((l >> 4) << 2) + r;
        float v = acc1[i][j][r] + acc2[i][j][r] * (1.0f / 2048.0f) + bsv;
        if (ACT == 1) v = 0.5f * v * (1.0f + erff(v * 0.70710678118654752f));
        if (ACT == 2) { v = v * g2 + b2; v = v > 0.f ? v : expm1f(v); }
        size_t oi = (size_t)row * N + col;
        if (RESID) v += rsplit(Rh, Rl, oi);
        if (OSPLIT) emit_split(v, Ch, Cl, oi);
        else        C[oi] = v;
      }
    }
  }
}

// ---------------- LayerNorm on split input; optional split / f32 outputs ----------------
__global__ __launch_bounds__(256) void k_ln(const f16* __restrict__ xh, const f16* __restrict__ xl,
    const float* __restrict__ g, const float* __restrict__ b,
    float* __restrict__ of32, f16* __restrict__ oh, f16* __restrict__ ol) {
  int row = blockIdx.x, t = threadIdx.x;
  size_t base = (size_t)row << 9;
  float v0 = rsplit(xh, xl, base + t);
  float v1 = rsplit(xh, xl, base + t + 256);
  float s = v0 + v1;
  #pragma unroll
  for (int off = 32; off; off >>= 1) s += __shfl_down(s, off);
  __shared__ float ls[4];
  if ((t & 63) == 0) ls[t >> 6] = s;
  __syncthreads();
  float mean = (ls[0] + ls[1] + ls[2] + ls[3]) * (1.f / 512.f);
  __syncthreads();
  float d0 = v0 - mean, d1 = v1 - mean;
  float q = d0 * d0 + d1 * d1;
  #pragma unroll
  for (int off = 32; off; off >>= 1) q += __shfl_down(q, off);
  if ((t & 63) == 0) ls[t >> 6] = q;
  __syncthreads();
  float var = (ls[0] + ls[1] + ls[2] + ls[3]) * (1.f / 512.f);
  float rs = rsqrtf(var + 1e-5f);
  float r0 = d0 * rs * g[t] + b[t];
  float r1 = d1 * rs * g[t + 256] + b[t + 256];
  if (of32) { of32[base + t] = r0; of32[base + t + 256] = r1; }
  if (oh) {
    emit_split(r0, oh, ol, base + t);
    emit_split(r1, oh, ol, base + t + 256);
  }
}

// ---------------- M[bh,l] scoring, register-batched K loads, XCD-swizzled blocks ----------------
__global__ __launch_bounds__(256) void k_qkM(const float* __restrict__ Q, int qstr,
    const float* __restrict__ Kp, int kstr, const int* __restrict__ idx,
    float* __restrict__ M, int Lq, int Lk, int U) {
  __shared__ float qsh[4][64];
  int nwg = gridDim.x;
  int bid = blockIdx.x;
  if ((nwg & 7) == 0) {
    int cpx = nwg >> 3;
    bid = (bid & 7) * cpx + (bid >> 3);   // same-bh blocks land on one XCD -> K panel L2-resident
  }
  int wib = threadIdx.x >> 6;
  int wid = (bid << 2) + wib;
  int lane = threadIdx.x & 63;
  int l = wid & (Lq - 1); int bh = wid / Lq; int h = bh & 7; int b = bh >> 3;
  // stage this wave's Q row into LDS
  if (lane < 16) {
    const float4* qr = (const float4*)(Q + (size_t)(b * Lq + l) * qstr + (h << 6));
    *(float4*)(&qsh[wib][lane * 4]) = qr[lane];
  }
  __syncthreads();
  // load sampled K row as one burst of 16 float4s (idle lanes: sample 0's row, hot line)
  int kr = idx[l * U + (lane < U ? lane : 0)];
  const float4* k4 = (const float4*)(Kp + (size_t)(b * Lk + kr) * kstr + (h << 6));
  float4 c[16];
  #pragma unroll
  for (int i = 0; i < 16; ++i) c[i] = k4[i];
  const float* qs = qsh[wib];
  float dot = 0.f;
  #pragma unroll
  for (int i = 0; i < 16; ++i)
    dot += qs[4*i] * c[i].x + qs[4*i+1] * c[i].y + qs[4*i+2] * c[i].z + qs[4*i+3] * c[i].w;
  float mx = (lane < U) ? dot : -INFINITY;
  float sm = (lane < U) ? dot : 0.f;
  #pragma unroll
  for (int off = 32; off; off >>= 1) {
    mx = fmaxf(mx, __shfl_xor(mx, off));
    sm += __shfl_xor(sm, off);
  }
  if (lane == 0) M[(size_t)bh * Lq + l] = mx - sm / (float)Lk;
}

// ---------------- single-wave top-u per (b,h), ties -> lower index ----------------
__global__ void k_topk64(const float* __restrict__ M, int* __restrict__ mtop, int Lq, int u) {
  __shared__ float vals[2048];
  int bh = blockIdx.x, l = threadIdx.x;
  const float* Mr = M + (size_t)bh * Lq;
  for (int i = l; i < Lq; i += 64) vals[i] = Mr[i];
  __syncthreads();
  for (int it = 0; it < u; ++it) {
    float bv = -INFINITY; int bi = 0x7fffffff;
    for (int i = l; i < Lq; i += 64) {
      float v = vals[i];
      if (v > bv || (v == bv && i < bi)) { bv = v; bi = i; }
    }
    #pragma unroll
    for (int off = 32; off; off >>= 1) {
      float vv = __shfl_xor(bv, off); int ii = __shfl_xor(bi, off);
      if (vv > bv || (vv == bv && ii < bi)) { bv = vv; bi = ii; }
    }
    if (l == 0) { mtop[bh * u + it] = bi; vals[bi] = -INFINITY; }
    __syncthreads();
  }
}

// ---------------- ctx mean (AO split) ----------------
__global__ void k_cm1(const float* __restrict__ V, int vstr, float* __restrict__ PS,
                      int Lk, int rows) {
  int bid = blockIdx.x;
  int bh = bid >> 4, seg = bid & 15, d = threadIdx.x;
  int b = bh >> 3, h = bh & 7;
  const float* vp = V + (size_t)(b * Lk + seg * rows) * vstr + (h << 6) + d;
  float acc = 0.f;
  for (int r = 0; r < rows; ++r) acc += vp[(size_t)r * vstr];
  PS[(bid << 6) + d] = acc;
}
__global__ void k_cm2(const float* __restrict__ PS, f16* __restrict__ AOh,
                      f16* __restrict__ AOl, float invLk, int Lq, int total) {
  int i = blockIdx.x * 256 + threadIdx.x;
  if (i >= total) return;
  int c = i & 511; int h = c >> 6; int d = c & 63;
  int r = i >> 9; int b = r / Lq;
  float acc = 0.f;
  #pragma unroll
  for (int s = 0; s < 16; ++s) acc += PS[(((((b << 3) + h) << 4) + s) << 6) + d];
  emit_split(acc * invLk, AOh, AOl, (size_t)i);
}

// ---------------- cumsum (masked ctx; per-block prefix, AO split) ----------------
__global__ void k_cs1(const float* __restrict__ V, int vstr, float* __restrict__ PS,
                      int Lq, int rows) {
  int bid = blockIdx.x;
  int bh = bid >> 3, seg = bid & 7, d = threadIdx.x;
  int b = bh >> 3, h = bh & 7;
  const float* vp = V + (size_t)(b * Lq + seg * rows) * vstr + (h << 6) + d;
  float acc = 0.f;
  for (int r = 0; r < rows; ++r) acc += vp[(size_t)r * vstr];
  PS[(bid << 6) + d] = acc;
}
__global__ void k_cs3(const float* __restrict__ V, int vstr, const float* __restrict__ PS,
                      f16* __restrict__ AOh, f16* __restrict__ AOl, int Lq, int rows) {
  int bid = blockIdx.x;
  int bh = bid >> 3, seg = bid & 7, d = threadIdx.x;
  int b = bh >> 3, h = bh & 7;
  float acc = 0.f;
  for (int s2 = 0; s2 < seg; ++s2) acc += PS[(((bh << 3) + s2) << 6) + d];
  const float* vp = V + (size_t)(b * Lq + seg * rows) * vstr + (h << 6) + d;
  size_t ob = ((size_t)(b * Lq + seg * rows) << 9) + (h << 6) + d;
  for (int r = 0; r < rows; ++r) {
    acc += vp[(size_t)r * vstr];
    emit_split(acc, AOh, AOl, ob + ((size_t)r << 9));
  }
}

// ---------------- flash sparse attn: ALL u rows per (512-key chunk, bh) block ----------------
__global__ __launch_bounds__(256) void k_sattnF(
    const float* __restrict__ Q, int qstr, const float* __restrict__ Kp, int kstr,
    const float* __restrict__ Vp, int vstr, const int* __restrict__ mtop,
    float* __restrict__ PPm, float* __restrict__ PPs, float* __restrict__ PPv,
    int Lq, int Lk, int u, int masked, int bhn) {
  __shared__ float Qs[40 * 64];
  __shared__ float Kt[64 * 65];
  __shared__ float Vs[64 * 65];
  __shared__ float els[40 * 64];
  __shared__ int rowsh[40];
  int ch = blockIdx.x, bh = blockIdx.y;
  int b = bh >> 3, h = bh & 7;
  int c0 = ch << 9;
  int t = threadIdx.x;
  int g = t >> 6, d = t & 63;
  if (t < 40) rowsh[t] = (t < u) ? mtop[bh * u + t] : -1;
  __syncthreads();
  for (int i = t; i < 40 * 16; i += 256) {
    int r = i >> 4, e4 = i & 15;
    int row = rowsh[r];
    float4 v;
    if (row >= 0) v = *(const float4*)(Q + (size_t)(b * Lq + row) * qstr + (h << 6) + e4 * 4);
    else          v = make_float4(0.f, 0.f, 0.f, 0.f);
    *(float4*)(Qs + r * 64 + e4 * 4) = v;
  }
  int rows_[10];
  __syncthreads();
  #pragma unroll
  for (int i = 0; i < 10; ++i) rows_[i] = rowsh[g + i * 4];
  float pv[10], m[10], sum[10];
  #pragma unroll
  for (int i = 0; i < 10; ++i) { pv[i] = 0.f; m[i] = -INFINITY; sum[i] = 0.f; }
  const int srow = t >> 2, seg = t & 3;
  for (int kt = 0; kt < 8; ++kt) {
    __syncthreads();
    {
      int crow = c0 + (kt << 6) + srow;
      const float* kp2 = Kp + (size_t)(b * Lk + crow) * kstr + (h << 6) + seg * 16;
      const float* vp2 = Vp + (size_t)(b * Lk + crow) * vstr + (h << 6) + seg * 16;
      #pragma unroll
      for (int q4 = 0; q4 < 4; ++q4) {
        float4 kv = *(const float4*)(kp2 + q4 * 4);
        float4 vv = *(const float4*)(vp2 + q4 * 4);
        int e0 = seg * 16 + q4 * 4;
        Kt[(e0 + 0) * 65 + srow] = kv.x;
        Kt[(e0 + 1) * 65 + srow] = kv.y;
        Kt[(e0 + 2) * 65 + srow] = kv.z;
        Kt[(e0 + 3) * 65 + srow] = kv.w;
        Vs[srow * 65 + e0 + 0] = vv.x;
        Vs[srow * 65 + e0 + 1] = vv.y;
        Vs[srow * 65 + e0 + 2] = vv.z;
        Vs[srow * 65 + e0 + 3] = vv.w;
      }
    }
    __syncthreads();
    float dot[10];
    #pragma unroll
    for (int i = 0; i < 10; ++i) dot[i] = 0.f;
    for (int e = 0; e < 64; ++e) {
      float kv = Kt[e * 65 + d];
      #pragma unroll
      for (int i = 0; i < 10; ++i)
        dot[i] += Qs[(g + i * 4) * 64 + e] * kv;
    }
    int key = c0 + (kt << 6) + d;
    float scale_[10];
    #pragma unroll
    for (int i = 0; i < 10; ++i) {
      float s = dot[i] * 0.125f;
      if (masked && key > rows_[i]) s = -INFINITY;
      float tm = s;
      #pragma unroll
      for (int off = 32; off; off >>= 1) tm = fmaxf(tm, __shfl_xor(tm, off));
      float nm = fmaxf(m[i], tm);
      if (nm > -3e38f) {
        float scl = expf(m[i] - nm);
        float e_ = expf(s - nm);
        float ts = e_;
        #pragma unroll
        for (int off = 32; off; off >>= 1) ts += __shfl_xor(ts, off);
        sum[i] = sum[i] * scl + ts;
        m[i] = nm;
        scale_[i] = scl;
        els[(g + i * 4) * 64 + d] = e_;
      } else {
        scale_[i] = 1.f;
        els[(g + i * 4) * 64 + d] = 0.f;
      }
    }
    __syncthreads();
    float acc[10];
    #pragma unroll
    for (int i = 0; i < 10; ++i) acc[i] = 0.f;
    for (int k = 0; k < 64; ++k) {
      float vv = Vs[k * 65 + d];
      #pragma unroll
      for (int i = 0; i < 10; ++i)
        acc[i] += els[(g + i * 4) * 64 + k] * vv;
    }
    #pragma unroll
    for (int i = 0; i < 10; ++i) pv[i] = pv[i] * scale_[i] + acc[i];
  }
  #pragma unroll
  for (int i = 0; i < 10; ++i) {
    int r = g + i * 4;
    if (r < u) {
      size_t pidx = (size_t)(ch * bhn + bh) * u + r;
      if (d == 0) { PPm[pidx] = m[i]; PPs[pidx] = sum[i]; }
      PPv[pidx * 64 + d] = pv[i];
    }
  }
}

// ---------------- combine chunk partials -> AO (online softmax rescale) ----------------
__global__ void k_sattnc(const float* __restrict__ PPm, const float* __restrict__ PPs,
                         const float* __restrict__ PPv, const int* __restrict__ mtop,
                         f16* __restrict__ AOh, f16* __restrict__ AOl,
                         int Lq, int u, int nch, int bhn) {
  int rowid = blockIdx.x;
  int bh = rowid / u, ui = rowid % u;
  int d = threadIdx.x;
  int b = bh >> 3, h = bh & 7;
  int row = mtop[bh * u + ui];
  float M = -INFINITY;
  for (int c = 0; c < nch; ++c)
    M = fmaxf(M, PPm[(size_t)(c * bhn + bh) * u + ui]);
  float S = 0.f, o = 0.f;
  for (int c = 0; c < nch; ++c) {
    size_t pidx = (size_t)(c * bhn + bh) * u + ui;
    float pm = PPm[pidx];
    float sc = (pm > -3e38f) ? expf(pm - M) : 0.f;
    S += sc * PPs[pidx];
    o += sc * PPv[pidx * 64 + d];
  }
  emit_split(o / S, AOh, AOl, ((size_t)(b * Lq + row) << 9) + (h << 6) + d);
}

// ---------------- maxpool w3 s2 p1 along L (split-only output) ----------------
__global__ void k_maxpool(const float* __restrict__ y, f16* __restrict__ oh,
                          f16* __restrict__ ol, int L) {
  int Lo = L >> 1;
  int i = blockIdx.x * 256 + threadIdx.x;
  int c = i & 511; int bj = i >> 9;
  int j = bj % Lo; int b = bj / Lo;
  float m = -INFINITY;
  int t0 = 2 * j - 1;
  #pragma unroll
  for (int k = 0; k < 3; ++k) {
    int tt = t0 + k;
    if (tt >= 0 && tt < L) m = fmaxf(m, y[((size_t)(b * L + tt) << 9) + c]);
  }
  emit_split(m, oh, ol, ((size_t)(b * Lo + j) << 9) + c);
}

// ---------------- final projection 512->7 (reads f32 from Y) ----------------
__global__ void k_proj(const float* __restrict__ Xn, const float* __restrict__ pw,
                       const float* __restrict__ pb, float* __restrict__ out) {
  int i = blockIdx.x * 256 + threadIdx.x;
  if (i >= 16 * 512 * 7) return;
  int c = i % 7; int r = i / 7;
  int b = r >> 9; int j = r & 511;
  const float* xr = Xn + ((size_t)(b * 1024 + 512 + j) << 9);
  float acc = pb[c];
  for (int d2 = 0; d2 < 512; ++d2) acc += xr[d2] * pw[d2 * 7 + c];
  out[i] = acc;
}

// =====================================================================
extern "C" void kernel_launch(void* const* d_in, const int* in_sizes, int n_in,
                              void* d_out, int out_size, void* d_ws, size_t ws_size,
                              hipStream_t stream) {
  const float* x_enc      = (const float*)d_in[0];
  const float* x_mark_enc = (const float*)d_in[1];
  const float* x_dec      = (const float*)d_in[2];
  const float* x_mark_dec = (const float*)d_in[3];
  const float* enc_tok_w  = (const float*)d_in[4];
  const float* enc_mark_w = (const float*)d_in[5];
  const float* dec_tok_w  = (const float*)d_in[6];
  const float* dec_mark_w = (const float*)d_in[7];
  const float* enc_attn_w = (const float*)d_in[8];
  const float* enc_attn_b = (const float*)d_in[9];
  const float* enc_ffn1_w = (const float*)d_in[10];
  const float* enc_ffn1_b = (const float*)d_in[11];
  const float* enc_ffn2_w = (const float*)d_in[12];
  const float* enc_ffn2_b = (const float*)d_in[13];
  const float* enc_ln_g   = (const float*)d_in[14];
  const float* enc_ln_b   = (const float*)d_in[15];
  const float* distil_w   = (const float*)d_in[16];
  const float* distil_b   = (const float*)d_in[17];
  const float* distil_bn_g= (const float*)d_in[18];
  const float* distil_bn_b= (const float*)d_in[19];
  const float* enc_norm_g = (const float*)d_in[20];
  const float* enc_norm_b = (const float*)d_in[21];
  const float* dec_self_w = (const float*)d_in[22];
  const float* dec_self_b = (const float*)d_in[23];
  const float* dec_cross_w= (const float*)d_in[24];
  const float* dec_cross_b= (const float*)d_in[25];
  const float* dec_ffn1_w = (const float*)d_in[26];
  const float* dec_ffn1_b = (const float*)d_in[27];
  const float* dec_ffn2_w = (const float*)d_in[28];
  const float* dec_ffn2_b = (const float*)d_in[29];
  const float* dec_ln_g   = (const float*)d_in[30];
  const float* dec_ln_b   = (const float*)d_in[31];
  const float* dec_norm_g = (const float*)d_in[32];
  const float* dec_norm_b = (const float*)d_in[33];
  const float* proj_w     = (const float*)d_in[34];
  const float* proj_b     = (const float*)d_in[35];

  // -------- workspace layout: split-only activations; Y sized by tier --------
  float* ws = (float*)d_ws;
  size_t off = 0;
  f16* Xh   = (f16*)(ws + off); off += 16777216;
  f16* Xl   = Xh + 16777216;
  f16* ENCh = (f16*)(ws + off); off += 4194304;
  f16* ENCl = ENCh + 4194304;
  float* PE = ws + off; off += 1048576;
  float* Mb = ws + off; off += 131072;
  float* PS = ws + off; off += 65536;
  f16* WSP  = (f16*)(ws + off); off += 2097152;
  int* IDXi = (int*)(ws + off); off += 84480;
  float* Y  = ws + off;
  int* MTi  = IDXi + 81920;
  size_t need4 = (off + 16777216ull) * 4;
  size_t need8 = (off + 33554432ull) * 4;
  int bs;
  if      (ws_size >= need8) bs = 8;
  else if (ws_size >= need4) bs = 4;
  else return;
  f16* Yh = (f16*)Y;
  f16* Yl = Yh + 16777216;
  float* WF  = (float*)WSP + 1048576;
  float* PPm = WF;
  float* PPs = WF + 16384;
  float* PPv = WF + 32768;

  auto ln = [&](const f16* xh, const f16* xl, const float* g, const float* b, int rows,
                float* of32, f16* oh, f16* ol) {
    k_ln<<<rows, 256, 0, stream>>>(xh, xl, g, b, of32, oh, ol);
  };
  auto wsplit = [&](const float* W, f16* Wh, f16* Wl, int K, int N, int nmat) {
    dim3 g(K >> 5, N >> 5, nmat);
    k_wsplit<<<g, 256, 0, stream>>>(W, Wh, Wl, K, N);
  };
  auto mgQ = [&](const f16* Ah, const f16* Al, const f16* Wh, const f16* Wl,
                 const float* bias, float* C, int M, int N, int K) {
    dim3 g(N >> 7, M >> 7);
    k_mgemm2<0,0,0,0><<<g, 256, 0, stream>>>(Ah, Al, Wh, Wl, bias, nullptr, nullptr,
        nullptr, nullptr, C, nullptr, nullptr, M, N, K, 0);
  };
  auto mgR = [&](const f16* Ah, const f16* Al, const f16* Wh, const f16* Wl,
                 const float* bias, const f16* Rh, const f16* Rl,
                 f16* Ch, f16* Cl, int M, int N, int K) {
    dim3 g(N >> 7, M >> 7);
    k_mgemm2<0,1,0,1><<<g, 256, 0, stream>>>(Ah, Al, Wh, Wl, bias, Rh, Rl,
        nullptr, nullptr, nullptr, Ch, Cl, M, N, K, 0);
  };
  auto mgG = [&](const f16* Ah, const f16* Al, const f16* Wh, const f16* Wl,
                 const float* bias, f16* Ch, f16* Cl, int M, int N, int K) {
    dim3 g(N >> 7, M >> 7);
    k_mgemm2<1,1,0,0><<<g, 256, 0, stream>>>(Ah, Al, Wh, Wl, bias, nullptr, nullptr,
        nullptr, nullptr, nullptr, Ch, Cl, M, N, K, 0);
  };
  auto Uof = [](int Lx) { int v = 5 * (int)ceil(log((double)Lx)); return v < Lx ? v : Lx; };

  auto attn = [&](f16* xqh, f16* xql, const f16* xkvh, const f16* xkvl,
                  int Lq, int Lk, const float* w, const float* bias,
                  bool masked, u32 fold, bool selfa) {
    int U = Uof(Lk), uu = Uof(Lq);
    u32 r0, r1, ka, kb2;
    tf_block(0u, 42u, 0u, fold, r0, r1);
    tf_block(r0, r1, 0u, 1u, ka, kb2);
    int n = Lq * U;
    k_idx<<<(n + 255) / 256, 256, 0, stream>>>(ka, kb2, n, Lk - 1, IDXi);

    f16 *Wqkvh = WSP,            *Wqkvl = WSP + 786432;
    f16 *WQh   = WSP,            *WQl   = WSP + 262144;
    f16 *WKVh  = WSP + 524288,   *WKVl  = WSP + 1048576;
    f16 *WOh   = WSP + 1572864,  *WOl   = WSP + 1835008;
    if (selfa) {
      wsplit(w, Wqkvh, Wqkvl, 512, 512, 3);
    } else {
      wsplit(w, WQh, WQl, 512, 512, 1);
      wsplit(w + 262144, WKVh, WKVl, 512, 512, 2);
    }
    wsplit(w + 786432, WOh, WOl, 512, 512, 1);

    int nsl = 16 / bs;
    int bhn = bs * 8;
    for (int s = 0; s < nsl; ++s) {
      size_t qoff = (size_t)s * bs * Lq * 512;
      size_t koff = (size_t)s * bs * Lk * 512;
      const float *qp, *kp, *vp;
      int qstr, kstr, vstr;
      f16 *AOh, *AOl;
      if (selfa) {
        float* QKV = Y;
        AOh = (f16*)(Y + (size_t)bs * Lq * 1536);
        AOl = AOh + (size_t)bs * Lq * 512;
        mgQ(xqh + qoff, xql + qoff, Wqkvh, Wqkvl, bias, QKV, bs * Lq, 1536, 512);
        qp = QKV; qstr = 1536; kp = QKV + 512; kstr = 1536; vp = QKV + 1024; vstr = 1536;
      } else {
        float* Qb  = Y;
        float* KVb = Y + (size_t)bs * Lq * 512;
        AOh = (f16*)(KVb + (size_t)bs * Lk * 1024);
        AOl = AOh + (size_t)bs * Lq * 512;
        mgQ(xqh + qoff, xql + qoff, WQh, WQl, bias, Qb, bs * Lq, 512, 512);
        mgQ(xkvh + koff, xkvl + koff, WKVh, WKVl, bias + 512, KVb, bs * Lk, 1024, 512);
        qp = Qb; qstr = 512; kp = KVb; kstr = 1024; vp = KVb + 512; vstr = 1024;
      }
      int wids = bhn * Lq;
      k_qkM<<<wids / 4, 256, 0, stream>>>(qp, qstr, kp, kstr, IDXi, Mb, Lq, Lk, U);
      k_topk64<<<bhn, 64, 0, stream>>>(Mb, MTi, Lq, uu);
      if (masked) {
        k_cs1<<<bhn * 8, 64, 0, stream>>>(vp, vstr, PS, Lq, Lq >> 3);
        k_cs3<<<bhn * 8, 64, 0, stream>>>(vp, vstr, PS, AOh, AOl, Lq, Lq >> 3);
      } else {
        k_cm1<<<bhn * 16, 64, 0, stream>>>(vp, vstr, PS, Lk, Lk >> 4);
        int tot = bs * Lq * 512;
        k_cm2<<<tot / 256, 256, 0, stream>>>(PS, AOh, AOl, 1.0f / (float)Lk, Lq, tot);
      }
      int nch = Lk >> 9;
      dim3 gs(nch, bhn);
      k_sattnF<<<gs, 256, 0, stream>>>(qp, qstr, kp, kstr, vp, vstr, MTi,
                                       PPm, PPs, PPv, Lq, Lk, uu, masked ? 1 : 0, bhn);
      k_sattnc<<<bhn * uu, 64, 0, stream>>>(PPm, PPs, PPv, MTi, AOh, AOl, Lq, uu, nch, bhn);
      mgR(AOh, AOl, WOh, WOl, bias + 1536, xqh + qoff, xql + qoff,
          xqh + qoff, xql + qoff, bs * Lq, 512, 512);
    }
  };

  auto ffn = [&](f16* xh, f16* xl, const float* w1, const float* b1,
                 const float* w2, const float* b2, int Mtot) {
    f16 *W1h = WSP,           *W1l = WSP + 1048576,
        *W2h = WSP + 2097152, *W2l = WSP + 3145728;
    wsplit(w1, W1h, W1l, 512, 2048, 1);
    wsplit(w2, W2h, W2l, 2048, 512, 1);
    for (int c0 = 0; c0 < Mtot; c0 += 8192) {
      int rows = (Mtot - c0 < 8192) ? (Mtot - c0) : 8192;
      mgG(xh + (size_t)c0 * 512, xl + (size_t)c0 * 512, W1h, W1l, b1, Yh, Yl, rows, 2048, 512);
      mgR(Yh, Yl, W2h, W2l, b2, xh + (size_t)c0 * 512, xl + (size_t)c0 * 512,
          xh + (size_t)c0 * 512, xl + (size_t)c0 * 512, rows, 512, 2048);
    }
  };

  // ---------------- encoder ----------------
  k_pe<<<(2048 * 512) / 256, 256, 0, stream>>>(PE);
  k_embed<<<(16 * 2048 * 512) / 256, 256, 0, stream>>>(x_enc, x_mark_enc, enc_tok_w, enc_mark_w,
                                                       PE, Xh, Xl, 2048, 16 * 2048 * 512);
  int L = 2048;
  for (int l = 0; l < 3; ++l) {
    attn(Xh, Xl, Xh, Xl, L, L, enc_attn_w + (size_t)l * 4 * 262144,
         enc_attn_b + (size_t)l * 2048, false, (u32)l, true);
    ln(Xh, Xl, enc_ln_g + (size_t)(l * 2) * 512, enc_ln_b + (size_t)(l * 2) * 512, 16 * L,
       nullptr, Xh, Xl);
    ffn(Xh, Xl, enc_ffn1_w + (size_t)l * 512 * 2048, enc_ffn1_b + (size_t)l * 2048,
        enc_ffn2_w + (size_t)l * 2048 * 512, enc_ffn2_b + (size_t)l * 512, 16 * L);
    ln(Xh, Xl, enc_ln_g + (size_t)(l * 2 + 1) * 512, enc_ln_b + (size_t)(l * 2 + 1) * 512, 16 * L,
       nullptr, Xh, Xl);
    if (l < 2) {
      f16 *Dh = WSP, *Dl = WSP + 786432;
      k_wsplit_conv<<<(512 * 1536) / 256, 256, 0, stream>>>(distil_w + (size_t)l * 512 * 512 * 3, Dh, Dl);
      dim3 g(512 >> 7, (16 * L) >> 7);
      int lgL = (L == 2048) ? 11 : 10;
      k_mgemm2<2,0,1,0><<<g, 256, 0, stream>>>(Xh, Xl, Dh, Dl, distil_b + (size_t)l * 512,
          nullptr, nullptr, distil_bn_g + (size_t)l * 512, distil_bn_b + (size_t)l * 512,
          Y, nullptr, nullptr, 16 * L, 512, 1536, lgL);
      int Lo = L >> 1;
      k_maxpool<<<(16 * Lo * 512) / 256, 256, 0, stream>>>(Y, Xh, Xl, L);
      L = Lo;
    }
  }
  ln(Xh, Xl, enc_norm_g, enc_norm_b, 16 * 512, nullptr, ENCh, ENCl);

  // ---------------- decoder (in-place chain in Xh/Xl) ----------------
  k_embed<<<(16 * 1024 * 512) / 256, 256, 0, stream>>>(x_dec, x_mark_dec, dec_tok_w, dec_mark_w,
                                                       PE, Xh, Xl, 1024, 16 * 1024 * 512);
  for (int l = 0; l < 2; ++l) {
    attn(Xh, Xl, Xh, Xl, 1024, 1024, dec_self_w + (size_t)l * 4 * 262144,
         dec_self_b + (size_t)l * 2048, true, (u32)(100 + 2 * l), true);
    ln(Xh, Xl, dec_ln_g + (size_t)(l * 3) * 512, dec_ln_b + (size_t)(l * 3) * 512, 16384,
       nullptr, Xh, Xl);
    attn(Xh, Xl, ENCh, ENCl, 1024, 512, dec_cross_w + (size_t)l * 4 * 262144,
         dec_cross_b + (size_t)l * 2048, false, (u32)(101 + 2 * l), false);
    ln(Xh, Xl, dec_ln_g + (size_t)(l * 3 + 1) * 512, dec_ln_b + (size_t)(l * 3 + 1) * 512, 16384,
       nullptr, Xh, Xl);
    ffn(Xh, Xl, dec_ffn1_w + (size_t)l * 512 * 2048, dec_ffn1_b + (size_t)l * 2048,
        dec_ffn2_w + (size_t)l * 2048 * 512, dec_ffn2_b + (size_t)l * 512, 16384);
    ln(Xh, Xl, dec_ln_g + (size_t)(l * 3 + 2) * 512, dec_ln_b + (size_t)(l * 3 + 2) * 512, 16384,
       nullptr, Xh, Xl);
  }
  ln(Xh, Xl, dec_norm_g, dec_norm_b, 16384, Y, nullptr, nullptr);
  k_proj<<<(16 * 512 * 7 + 255) / 256, 256, 0, stream>>>(Y, proj_w, proj_b, (float*)d_out);
}

// Round 21
// 6842.277 us; speedup vs baseline: 2.9772x; 1.1061x over previous
//
#include <hip/hip_runtime.h>
#include <math.h>
#include <stdint.h>

typedef unsigned int u32;
typedef _Float16 f16;
typedef __attribute__((ext_vector_type(8))) _Float16 f16x8;
typedef __attribute__((ext_vector_type(4))) float f32x4;

// ---------------- Threefry-2x32 (20 rounds), matches JAX ----------------
__host__ __device__ __forceinline__ u32 rotl32(u32 x, int r) { return (x << r) | (x >> (32 - r)); }
__host__ __device__ __forceinline__ void tf_round(u32& x0, u32& x1, int r) {
  x0 += x1; x1 = rotl32(x1, r); x1 ^= x0;
}
__host__ __device__ __forceinline__ void tf_block(u32 k0, u32 k1, u32 x0, u32 x1, u32& o0, u32& o1) {
  u32 k2 = k0 ^ k1 ^ 0x1BD11BDAu;
  x0 += k0; x1 += k1;
  tf_round(x0,x1,13); tf_round(x0,x1,15); tf_round(x0,x1,26); tf_round(x0,x1,6);
  x0 += k1; x1 += k2 + 1u;
  tf_round(x0,x1,17); tf_round(x0,x1,29); tf_round(x0,x1,16); tf_round(x0,x1,24);
  x0 += k2; x1 += k0 + 2u;
  tf_round(x0,x1,13); tf_round(x0,x1,15); tf_round(x0,x1,26); tf_round(x0,x1,6);
  x0 += k0; x1 += k1 + 3u;
  tf_round(x0,x1,17); tf_round(x0,x1,29); tf_round(x0,x1,16); tf_round(x0,x1,24);
  x0 += k1; x1 += k2 + 4u;
  tf_round(x0,x1,13); tf_round(x0,x1,15); tf_round(x0,x1,26); tf_round(x0,x1,6);
  x0 += k2; x1 += k0 + 5u;
  o0 = x0; o1 = x1;
}

__global__ void k_idx(u32 ka, u32 kb, int n, int mask, int* __restrict__ idx) {
  int i = blockIdx.x * 256 + threadIdx.x;
  if (i >= n) return;
  u32 b1, b2; tf_block(ka, kb, 0u, (u32)i, b1, b2);
  idx[i] = (int)((b1 ^ b2) & (u32)mask);
}

__device__ __forceinline__ void emit_split(float v, f16* __restrict__ oh,
                                           f16* __restrict__ ol, size_t o) {
  f16 h = (f16)v;
  oh[o] = h;
  ol[o] = (f16)((v - (float)h) * 2048.0f);
}
__device__ __forceinline__ float rsplit(const f16* __restrict__ h,
                                        const f16* __restrict__ l, size_t o) {
  return (float)h[o] + (float)l[o] * (1.0f / 2048.0f);
}

// ---------------- positional embedding ----------------
__global__ void k_pe(float* __restrict__ pe) {
  int i = blockIdx.x * 256 + threadIdx.x;
  if (i >= 2048 * 512) return;
  int t = i >> 9, o = i & 511;
  float arg = (float)((o >> 1) * 2) * (float)(-(log(10000.0) / 512.0));
  float div = (float)exp((double)arg);
  float ang32 = (float)t * div;
  double ang = (double)ang32;
  pe[i] = (float)((o & 1) ? cos(ang) : sin(ang));
}

// ---------------- embedding (split-only output) ----------------
__global__ __launch_bounds__(256) void k_embed(
    const float* __restrict__ x, const float* __restrict__ mark,
    const float* __restrict__ tw, const float* __restrict__ mw,
    const float* __restrict__ pe, f16* __restrict__ oh, f16* __restrict__ ol,
    int L, int total) {
  int i = blockIdx.x * 256 + threadIdx.x;
  if (i >= total) return;
  int oo = i & 511;
  int bt = i >> 9;
  int t = bt % L;
  int b = bt / L;
  float acc = pe[(t << 9) + oo];
  #pragma unroll
  for (int k = 0; k < 3; ++k) {
    int st = t + k - 1; if (st < 0) st += L; else if (st >= L) st -= L;
    const float* xr = x + (size_t)(b * L + st) * 7;
    const float* wr = tw + oo * 21 + k;
    #pragma unroll
    for (int ii = 0; ii < 7; ++ii) acc += xr[ii] * wr[ii * 3];
  }
  const float* mr = mark + (size_t)bt * 4;
  #pragma unroll
  for (int m = 0; m < 4; ++m) acc += mr[m] * mw[(m << 9) + oo];
  emit_split(acc, oh, ol, ((size_t)bt << 9) + oo);
}

// ---------------- weight transpose + f16 split (z = matrix index) ----------------
__global__ __launch_bounds__(256) void k_wsplit(const float* __restrict__ W,
    f16* __restrict__ Wh, f16* __restrict__ Wl, int K, int N) {
  size_t zo = (size_t)blockIdx.z * K * N;
  W += zo; Wh += zo; Wl += zo;
  __shared__ float tile[32][33];
  int kb = blockIdx.x << 5, nb = blockIdx.y << 5;
  int t = threadIdx.x;
  int tr = t >> 5, tc = t & 31;
  #pragma unroll
  for (int p = 0; p < 4; ++p)
    tile[tr + p * 8][tc] = W[(size_t)(kb + tr + p * 8) * N + nb + tc];
  __syncthreads();
  #pragma unroll
  for (int p = 0; p < 4; ++p) {
    int n = tr + p * 8, k = tc;
    float v = tile[k][n];
    f16 h = (f16)v;
    size_t o = (size_t)(nb + n) * K + kb + k;
    Wh[o] = h;
    Wl[o] = (f16)((v - (float)h) * 2048.0f);
  }
}

__global__ void k_wsplit_conv(const float* __restrict__ w, f16* __restrict__ Wh, f16* __restrict__ Wl) {
  int i = blockIdx.x * 256 + threadIdx.x;
  if (i >= 512 * 1536) return;
  int o = i / 1536, k = i - o * 1536;
  float v = w[(size_t)o * 1536 + (k & 511) * 3 + (k >> 9)];
  f16 h = (f16)v;
  Wh[i] = h;
  Wl[i] = (f16)((v - (float)h) * 2048.0f);
}

__device__ __forceinline__ int swz_x(int r) { return ((((r >> 1) & 3) ^ ((r >> 3) & 3)) << 4); }

__device__ __forceinline__ void gload16(const void* g, void* l) {
  __builtin_amdgcn_global_load_lds(
      (const __attribute__((address_space(1))) void*)g,
      (__attribute__((address_space(3))) void*)l, 16, 0, 0);
}

// ---------------- MFMA GEMM v2: pre-split f16 A/B, async LDS, dbuf, 16x16x32 ----------------
template<int ACT, int OSPLIT, int GATHER, int RESID>
__global__ __launch_bounds__(256, 2) void k_mgemm2(
    const f16* __restrict__ Ah, const f16* __restrict__ Al,
    const f16* __restrict__ Bh, const f16* __restrict__ Bl,
    const float* __restrict__ bias,
    const f16* __restrict__ Rh, const f16* __restrict__ Rl,
    const float* __restrict__ bns, const float* __restrict__ bnb,
    float* __restrict__ C, f16* __restrict__ Ch, f16* __restrict__ Cl,
    int M, int N, int K, int lgL) {
  __shared__ char lds[65536];
  const int t = threadIdx.x;
  int nwg = gridDim.x * gridDim.y;
  int bid = blockIdx.y * gridDim.x + blockIdx.x;
  if ((nwg & 7) == 0) {
    int cpx = nwg >> 3;
    bid = (bid & 7) * cpx + (bid >> 3);
  }
  const int bm = (bid / gridDim.x) << 7, bn = (bid % gridDim.x) << 7;
  const int w = t >> 6, l = t & 63;
  const int lr = l >> 2;
  const int qx = (l & 3) << 4;
  const int wr = (w >> 1) << 6, wc = (w & 1) << 6;
  const int fr = l & 15;
  const int fkB = (l >> 4) << 4;
  const f32x4 zero = {0.f, 0.f, 0.f, 0.f};
  f32x4 acc1[4][4], acc2[4][4];
  #pragma unroll
  for (int i = 0; i < 4; ++i)
    #pragma unroll
    for (int j = 0; j < 4; ++j) { acc1[i][j] = zero; acc2[i][j] = zero; }

  auto stage = [&](int k0, int bufo) {
    #pragma unroll
    for (int c = 0; c < 2; ++c) {
      int r = w * 32 + c * 16 + lr;
      int sx = qx ^ swz_x(r);
      const char *gAh, *gAl;
      if (GATHER) {
        int m = bm + r;
        int Lm = 1 << lgL;
        int ab = m >> lgL, at = m & (Lm - 1);
        int ke = k0 + (sx >> 1);
        int tap = ke >> 9, ii = ke & 511;
        int st = at + tap - 1; if (st < 0) st += Lm; else if (st >= Lm) st -= Lm;
        size_t aoff = (((size_t)((ab << lgL) + st)) << 9) + ii;
        gAh = (const char*)(Ah + aoff);
        gAl = (const char*)(Al + aoff);
      } else {
        gAh = (const char*)(Ah + (size_t)(bm + r) * K + k0) + sx;
        gAl = (const char*)(Al + (size_t)(bm + r) * K + k0) + sx;
      }
      const char* gBh = (const char*)(Bh + (size_t)(bn + r) * K + k0) + sx;
      const char* gBl = (const char*)(Bl + (size_t)(bn + r) * K + k0) + sx;
      char* base = lds + bufo + w * 2048 + c * 1024;
      gload16(gAh, base);
      gload16(gAl, base + 8192);
      gload16(gBh, base + 16384);
      gload16(gBl, base + 24576);
    }
  };

  int nt = K >> 5;
  stage(0, 0);
  __syncthreads();
  int bufo = 0;
  for (int tt = 0; tt < nt; ++tt) {
    int nb = bufo ^ 32768;
    if (tt + 1 < nt) stage((tt + 1) << 5, nb);
    char* pAh = lds + bufo;
    char* pAl = pAh + 8192;
    char* pBh = pAh + 16384;
    char* pBl = pAh + 24576;
    f16x8 ah4[4], al4[4];
    #pragma unroll
    for (int i = 0; i < 4; ++i) {
      int r = wr + i * 16 + fr;
      int ob = r * 64 + (fkB ^ swz_x(r));
      ah4[i] = *(f16x8*)(pAh + ob);
      al4[i] = *(f16x8*)(pAl + ob);
    }
    #pragma unroll
    for (int j = 0; j < 4; ++j) {
      int r = wc + j * 16 + fr;
      int ob = r * 64 + (fkB ^ swz_x(r));
      f16x8 bh_ = *(f16x8*)(pBh + ob);
      f16x8 bl_ = *(f16x8*)(pBl + ob);
      #pragma unroll
      for (int i = 0; i < 4; ++i) {
        acc1[i][j] = __builtin_amdgcn_mfma_f32_16x16x32_f16(ah4[i], bh_, acc1[i][j], 0, 0, 0);
        acc2[i][j] = __builtin_amdgcn_mfma_f32_16x16x32_f16(ah4[i], bl_, acc2[i][j], 0, 0, 0);
        acc2[i][j] = __builtin_amdgcn_mfma_f32_16x16x32_f16(al4[i], bh_, acc2[i][j], 0, 0, 0);
      }
    }
    __syncthreads();
    bufo = nb;
  }
  #pragma unroll
  for (int j = 0; j < 4; ++j) {
    int col = bn + wc + j * 16 + fr;
    float bsv = bias[col];
    float g2 = 0.f, b2 = 0.f;
    if (ACT == 2) { g2 = bns[col] * 0.9999950000375f; b2 = bnb[col]; }
    #pragma unroll
    for (int i = 0; i < 4; ++i) {
      #pragma unroll
      for (int r = 0; r < 4; ++r) {
        int row = bm + wr + i * 16 + ((l >> 4) << 2) + r;
        float v = acc1[i][j][r] + acc2[i][j][r] * (1.0f / 2048.0f) + bsv;
        if (ACT == 1) v = 0.5f * v * (1.0f + erff(v * 0.70710678118654752f));
        if (ACT == 2) { v = v * g2 + b2; v = v > 0.f ? v : expm1f(v); }
        size_t oi = (size_t)row * N + col;
        if (RESID) v += rsplit(Rh, Rl, oi);
        if (OSPLIT) emit_split(v, Ch, Cl, oi);
        else        C[oi] = v;
      }
    }
  }
}

// ---------------- LayerNorm on split input; optional split / f32 outputs ----------------
__global__ __launch_bounds__(256) void k_ln(const f16* __restrict__ xh, const f16* __restrict__ xl,
    const float* __restrict__ g, const float* __restrict__ b,
    float* __restrict__ of32, f16* __restrict__ oh, f16* __restrict__ ol) {
  int row = blockIdx.x, t = threadIdx.x;
  size_t base = (size_t)row << 9;
  float v0 = rsplit(xh, xl, base + t);
  float v1 = rsplit(xh, xl, base + t + 256);
  float s = v0 + v1;
  #pragma unroll
  for (int off = 32; off; off >>= 1) s += __shfl_down(s, off);
  __shared__ float ls[4];
  if ((t & 63) == 0) ls[t >> 6] = s;
  __syncthreads();
  float mean = (ls[0] + ls[1] + ls[2] + ls[3]) * (1.f / 512.f);
  __syncthreads();
  float d0 = v0 - mean, d1 = v1 - mean;
  float q = d0 * d0 + d1 * d1;
  #pragma unroll
  for (int off = 32; off; off >>= 1) q += __shfl_down(q, off);
  if ((t & 63) == 0) ls[t >> 6] = q;
  __syncthreads();
  float var = (ls[0] + ls[1] + ls[2] + ls[3]) * (1.f / 512.f);
  float rs = rsqrtf(var + 1e-5f);
  float r0 = d0 * rs * g[t] + b[t];
  float r1 = d1 * rs * g[t + 256] + b[t + 256];
  if (of32) { of32[base + t] = r0; of32[base + t + 256] = r1; }
  if (oh) {
    emit_split(r0, oh, ol, base + t);
    emit_split(r1, oh, ol, base + t + 256);
  }
}

// ---------------- M[bh,l] scoring: 4-lane cooperative row gather, XCD-swizzled ----------------
// Each group of 4 lanes shares one sampled K row; per load instruction the group's
// 4 lanes read consecutive 16B of one 64B line -> 1 transaction/line (4x fewer).
// Per-sample dot reassociated (lane-partial + 2 shfl combine) — 1-ulp class.
__global__ __launch_bounds__(256) void k_qkM(const float* __restrict__ Q, int qstr,
    const float* __restrict__ Kp, int kstr, const int* __restrict__ idx,
    float* __restrict__ M, int Lq, int Lk, int U) {
  __shared__ float qsh[4][64];
  __shared__ int idxs[4][40];
  int nwg = gridDim.x;
  int bid = blockIdx.x;
  if ((nwg & 7) == 0) {
    int cpx = nwg >> 3;
    bid = (bid & 7) * cpx + (bid >> 3);   // same-bh blocks on one XCD -> K panel L2-resident
  }
  int wib = threadIdx.x >> 6;
  int wid = (bid << 2) + wib;
  int lane = threadIdx.x & 63;
  int l = wid & (Lq - 1); int bh = wid / Lq; int h = bh & 7; int b = bh >> 3;
  if (lane < 16) {
    const float4* qr = (const float4*)(Q + (size_t)(b * Lq + l) * qstr + (h << 6));
    *(float4*)(&qsh[wib][lane * 4]) = qr[lane];
  }
  if (lane < U) idxs[wib][lane] = idx[l * U + lane];
  __syncthreads();
  int g = lane >> 2, j = lane & 3;
  const float* qs = qsh[wib];
  float mx = -INFINITY, sm = 0.f;
  #pragma unroll
  for (int p = 0; p < 3; ++p) {
    int s = p * 16 + g;
    bool act = s < U;
    int kr = idxs[wib][act ? s : 0];
    const float* kb_ = Kp + (size_t)((size_t)b * Lk + kr) * kstr + (h << 6);
    // instruction i: lane j reads floats [16i+4j, 16i+4j+4) -> group covers line i
    float4 c0 = *(const float4*)(kb_ +  0 + 4 * j);
    float4 c1 = *(const float4*)(kb_ + 16 + 4 * j);
    float4 c2 = *(const float4*)(kb_ + 32 + 4 * j);
    float4 c3 = *(const float4*)(kb_ + 48 + 4 * j);
    float pd = 0.f;
    pd += qs[ 0 + 4*j] * c0.x + qs[ 1 + 4*j] * c0.y + qs[ 2 + 4*j] * c0.z + qs[ 3 + 4*j] * c0.w;
    pd += qs[16 + 4*j] * c1.x + qs[17 + 4*j] * c1.y + qs[18 + 4*j] * c1.z + qs[19 + 4*j] * c1.w;
    pd += qs[32 + 4*j] * c2.x + qs[33 + 4*j] * c2.y + qs[34 + 4*j] * c2.z + qs[35 + 4*j] * c2.w;
    pd += qs[48 + 4*j] * c3.x + qs[49 + 4*j] * c3.y + qs[50 + 4*j] * c3.z + qs[51 + 4*j] * c3.w;
    pd += __shfl_xor(pd, 1);
    pd += __shfl_xor(pd, 2);    // all 4 lanes of group hold the full dot
    if (act) { mx = fmaxf(mx, pd); sm += pd; }
  }
  // reduce across the 16 groups (j-slices are duplicates; strides >=4 keep them separate)
  #pragma unroll
  for (int off = 32; off >= 4; off >>= 1) {
    mx = fmaxf(mx, __shfl_xor(mx, off));
    sm += __shfl_xor(sm, off);
  }
  if (lane == 0) M[(size_t)bh * Lq + l] = mx - sm / (float)Lk;
}

// ---------------- single-wave top-u per (b,h), ties -> lower index ----------------
__global__ void k_topk64(const float* __restrict__ M, int* __restrict__ mtop, int Lq, int u) {
  __shared__ float vals[2048];
  int bh = blockIdx.x, l = threadIdx.x;
  const float* Mr = M + (size_t)bh * Lq;
  for (int i = l; i < Lq; i += 64) vals[i] = Mr[i];
  __syncthreads();
  for (int it = 0; it < u; ++it) {
    float bv = -INFINITY; int bi = 0x7fffffff;
    for (int i = l; i < Lq; i += 64) {
      float v = vals[i];
      if (v > bv || (v == bv && i < bi)) { bv = v; bi = i; }
    }
    #pragma unroll
    for (int off = 32; off; off >>= 1) {
      float vv = __shfl_xor(bv, off); int ii = __shfl_xor(bi, off);
      if (vv > bv || (vv == bv && ii < bi)) { bv = vv; bi = ii; }
    }
    if (l == 0) { mtop[bh * u + it] = bi; vals[bi] = -INFINITY; }
    __syncthreads();
  }
}

// ---------------- ctx mean (AO split) ----------------
__global__ void k_cm1(const float* __restrict__ V, int vstr, float* __restrict__ PS,
                      int Lk, int rows) {
  int bid = blockIdx.x;
  int bh = bid >> 4, seg = bid & 15, d = threadIdx.x;
  int b = bh >> 3, h = bh & 7;
  const float* vp = V + (size_t)(b * Lk + seg * rows) * vstr + (h << 6) + d;
  float acc = 0.f;
  for (int r = 0; r < rows; ++r) acc += vp[(size_t)r * vstr];
  PS[(bid << 6) + d] = acc;
}
__global__ void k_cm2(const float* __restrict__ PS, f16* __restrict__ AOh,
                      f16* __restrict__ AOl, float invLk, int Lq, int total) {
  int i = blockIdx.x * 256 + threadIdx.x;
  if (i >= total) return;
  int c = i & 511; int h = c >> 6; int d = c & 63;
  int r = i >> 9; int b = r / Lq;
  float acc = 0.f;
  #pragma unroll
  for (int s = 0; s < 16; ++s) acc += PS[(((((b << 3) + h) << 4) + s) << 6) + d];
  emit_split(acc * invLk, AOh, AOl, (size_t)i);
}

// ---------------- cumsum (masked ctx; per-block prefix, AO split) ----------------
__global__ void k_cs1(const float* __restrict__ V, int vstr, float* __restrict__ PS,
                      int Lq, int rows) {
  int bid = blockIdx.x;
  int bh = bid >> 3, seg = bid & 7, d = threadIdx.x;
  int b = bh >> 3, h = bh & 7;
  const float* vp = V + (size_t)(b * Lq + seg * rows) * vstr + (h << 6) + d;
  float acc = 0.f;
  for (int r = 0; r < rows; ++r) acc += vp[(size_t)r * vstr];
  PS[(bid << 6) + d] = acc;
}
__global__ void k_cs3(const float* __restrict__ V, int vstr, const float* __restrict__ PS,
                      f16* __restrict__ AOh, f16* __restrict__ AOl, int Lq, int rows) {
  int bid = blockIdx.x;
  int bh = bid >> 3, seg = bid & 7, d = threadIdx.x;
  int b = bh >> 3, h = bh & 7;
  float acc = 0.f;
  for (int s2 = 0; s2 < seg; ++s2) acc += PS[(((bh << 3) + s2) << 6) + d];
  const float* vp = V + (size_t)(b * Lq + seg * rows) * vstr + (h << 6) + d;
  size_t ob = ((size_t)(b * Lq + seg * rows) << 9) + (h << 6) + d;
  for (int r = 0; r < rows; ++r) {
    acc += vp[(size_t)r * vstr];
    emit_split(acc, AOh, AOl, ob + ((size_t)r << 9));
  }
}

// ---------------- flash sparse attn: ALL u rows per (512-key chunk, bh) block ----------------
__global__ __launch_bounds__(256) void k_sattnF(
    const float* __restrict__ Q, int qstr, const float* __restrict__ Kp, int kstr,
    const float* __restrict__ Vp, int vstr, const int* __restrict__ mtop,
    float* __restrict__ PPm, float* __restrict__ PPs, float* __restrict__ PPv,
    int Lq, int Lk, int u, int masked, int bhn) {
  __shared__ float Qs[40 * 64];
  __shared__ float Kt[64 * 65];
  __shared__ float Vs[64 * 65];
  __shared__ float els[40 * 64];
  __shared__ int rowsh[40];
  int ch = blockIdx.x, bh = blockIdx.y;
  int b = bh >> 3, h = bh & 7;
  int c0 = ch << 9;
  int t = threadIdx.x;
  int g = t >> 6, d = t & 63;
  if (t < 40) rowsh[t] = (t < u) ? mtop[bh * u + t] : -1;
  __syncthreads();
  for (int i = t; i < 40 * 16; i += 256) {
    int r = i >> 4, e4 = i & 15;
    int row = rowsh[r];
    float4 v;
    if (row >= 0) v = *(const float4*)(Q + (size_t)(b * Lq + row) * qstr + (h << 6) + e4 * 4);
    else          v = make_float4(0.f, 0.f, 0.f, 0.f);
    *(float4*)(Qs + r * 64 + e4 * 4) = v;
  }
  int rows_[10];
  __syncthreads();
  #pragma unroll
  for (int i = 0; i < 10; ++i) rows_[i] = rowsh[g + i * 4];
  float pv[10], m[10], sum[10];
  #pragma unroll
  for (int i = 0; i < 10; ++i) { pv[i] = 0.f; m[i] = -INFINITY; sum[i] = 0.f; }
  const int srow = t >> 2, seg = t & 3;
  for (int kt = 0; kt < 8; ++kt) {
    __syncthreads();
    {
      int crow = c0 + (kt << 6) + srow;
      const float* kp2 = Kp + (size_t)(b * Lk + crow) * kstr + (h << 6) + seg * 16;
      const float* vp2 = Vp + (size_t)(b * Lk + crow) * vstr + (h << 6) + seg * 16;
      #pragma unroll
      for (int q4 = 0; q4 < 4; ++q4) {
        float4 kv = *(const float4*)(kp2 + q4 * 4);
        float4 vv = *(const float4*)(vp2 + q4 * 4);
        int e0 = seg * 16 + q4 * 4;
        Kt[(e0 + 0) * 65 + srow] = kv.x;
        Kt[(e0 + 1) * 65 + srow] = kv.y;
        Kt[(e0 + 2) * 65 + srow] = kv.z;
        Kt[(e0 + 3) * 65 + srow] = kv.w;
        Vs[srow * 65 + e0 + 0] = vv.x;
        Vs[srow * 65 + e0 + 1] = vv.y;
        Vs[srow * 65 + e0 + 2] = vv.z;
        Vs[srow * 65 + e0 + 3] = vv.w;
      }
    }
    __syncthreads();
    float dot[10];
    #pragma unroll
    for (int i = 0; i < 10; ++i) dot[i] = 0.f;
    for (int e = 0; e < 64; ++e) {
      float kv = Kt[e * 65 + d];
      #pragma unroll
      for (int i = 0; i < 10; ++i)
        dot[i] += Qs[(g + i * 4) * 64 + e] * kv;
    }
    int key = c0 + (kt << 6) + d;
    float scale_[10];
    #pragma unroll
    for (int i = 0; i < 10; ++i) {
      float s = dot[i] * 0.125f;
      if (masked && key > rows_[i]) s = -INFINITY;
      float tm = s;
      #pragma unroll
      for (int off = 32; off; off >>= 1) tm = fmaxf(tm, __shfl_xor(tm, off));
      float nm = fmaxf(m[i], tm);
      if (nm > -3e38f) {
        float scl = expf(m[i] - nm);
        float e_ = expf(s - nm);
        float ts = e_;
        #pragma unroll
        for (int off = 32; off; off >>= 1) ts += __shfl_xor(ts, off);
        sum[i] = sum[i] * scl + ts;
        m[i] = nm;
        scale_[i] = scl;
        els[(g + i * 4) * 64 + d] = e_;
      } else {
        scale_[i] = 1.f;
        els[(g + i * 4) * 64 + d] = 0.f;
      }
    }
    __syncthreads();
    float acc[10];
    #pragma unroll
    for (int i = 0; i < 10; ++i) acc[i] = 0.f;
    for (int k = 0; k < 64; ++k) {
      float vv = Vs[k * 65 + d];
      #pragma unroll
      for (int i = 0; i < 10; ++i)
        acc[i] += els[(g + i * 4) * 64 + k] * vv;
    }
    #pragma unroll
    for (int i = 0; i < 10; ++i) pv[i] = pv[i] * scale_[i] + acc[i];
  }
  #pragma unroll
  for (int i = 0; i < 10; ++i) {
    int r = g + i * 4;
    if (r < u) {
      size_t pidx = (size_t)(ch * bhn + bh) * u + r;
      if (d == 0) { PPm[pidx] = m[i]; PPs[pidx] = sum[i]; }
      PPv[pidx * 64 + d] = pv[i];
    }
  }
}

// ---------------- combine chunk partials -> AO (online softmax rescale) ----------------
__global__ void k_sattnc(const float* __restrict__ PPm, const float* __restrict__ PPs,
                         const float* __restrict__ PPv, const int* __restrict__ mtop,
                         f16* __restrict__ AOh, f16* __restrict__ AOl,
                         int Lq, int u, int nch, int bhn) {
  int rowid = blockIdx.x;
  int bh = rowid / u, ui = rowid % u;
  int d = threadIdx.x;
  int b = bh >> 3, h = bh & 7;
  int row = mtop[bh * u + ui];
  float M = -INFINITY;
  for (int c = 0; c < nch; ++c)
    M = fmaxf(M, PPm[(size_t)(c * bhn + bh) * u + ui]);
  float S = 0.f, o = 0.f;
  for (int c = 0; c < nch; ++c) {
    size_t pidx = (size_t)(c * bhn + bh) * u + ui;
    float pm = PPm[pidx];
    float sc = (pm > -3e38f) ? expf(pm - M) : 0.f;
    S += sc * PPs[pidx];
    o += sc * PPv[pidx * 64 + d];
  }
  emit_split(o / S, AOh, AOl, ((size_t)(b * Lq + row) << 9) + (h << 6) + d);
}

// ---------------- maxpool w3 s2 p1 along L (split-only output) ----------------
__global__ void k_maxpool(const float* __restrict__ y, f16* __restrict__ oh,
                          f16* __restrict__ ol, int L) {
  int Lo = L >> 1;
  int i = blockIdx.x * 256 + threadIdx.x;
  int c = i & 511; int bj = i >> 9;
  int j = bj % Lo; int b = bj / Lo;
  float m = -INFINITY;
  int t0 = 2 * j - 1;
  #pragma unroll
  for (int k = 0; k < 3; ++k) {
    int tt = t0 + k;
    if (tt >= 0 && tt < L) m = fmaxf(m, y[((size_t)(b * L + tt) << 9) + c]);
  }
  emit_split(m, oh, ol, ((size_t)(b * Lo + j) << 9) + c);
}

// ---------------- final projection 512->7 (reads f32 from Y) ----------------
__global__ void k_proj(const float* __restrict__ Xn, const float* __restrict__ pw,
                       const float* __restrict__ pb, float* __restrict__ out) {
  int i = blockIdx.x * 256 + threadIdx.x;
  if (i >= 16 * 512 * 7) return;
  int c = i % 7; int r = i / 7;
  int b = r >> 9; int j = r & 511;
  const float* xr = Xn + ((size_t)(b * 1024 + 512 + j) << 9);
  float acc = pb[c];
  for (int d2 = 0; d2 < 512; ++d2) acc += xr[d2] * pw[d2 * 7 + c];
  out[i] = acc;
}

// =====================================================================
extern "C" void kernel_launch(void* const* d_in, const int* in_sizes, int n_in,
                              void* d_out, int out_size, void* d_ws, size_t ws_size,
                              hipStream_t stream) {
  const float* x_enc      = (const float*)d_in[0];
  const float* x_mark_enc = (const float*)d_in[1];
  const float* x_dec      = (const float*)d_in[2];
  const float* x_mark_dec = (const float*)d_in[3];
  const float* enc_tok_w  = (const float*)d_in[4];
  const float* enc_mark_w = (const float*)d_in[5];
  const float* dec_tok_w  = (const float*)d_in[6];
  const float* dec_mark_w = (const float*)d_in[7];
  const float* enc_attn_w = (const float*)d_in[8];
  const float* enc_attn_b = (const float*)d_in[9];
  const float* enc_ffn1_w = (const float*)d_in[10];
  const float* enc_ffn1_b = (const float*)d_in[11];
  const float* enc_ffn2_w = (const float*)d_in[12];
  const float* enc_ffn2_b = (const float*)d_in[13];
  const float* enc_ln_g   = (const float*)d_in[14];
  const float* enc_ln_b   = (const float*)d_in[15];
  const float* distil_w   = (const float*)d_in[16];
  const float* distil_b   = (const float*)d_in[17];
  const float* distil_bn_g= (const float*)d_in[18];
  const float* distil_bn_b= (const float*)d_in[19];
  const float* enc_norm_g = (const float*)d_in[20];
  const float* enc_norm_b = (const float*)d_in[21];
  const float* dec_self_w = (const float*)d_in[22];
  const float* dec_self_b = (const float*)d_in[23];
  const float* dec_cross_w= (const float*)d_in[24];
  const float* dec_cross_b= (const float*)d_in[25];
  const float* dec_ffn1_w = (const float*)d_in[26];
  const float* dec_ffn1_b = (const float*)d_in[27];
  const float* dec_ffn2_w = (const float*)d_in[28];
  const float* dec_ffn2_b = (const float*)d_in[29];
  const float* dec_ln_g   = (const float*)d_in[30];
  const float* dec_ln_b   = (const float*)d_in[31];
  const float* dec_norm_g = (const float*)d_in[32];
  const float* dec_norm_b = (const float*)d_in[33];
  const float* proj_w     = (const float*)d_in[34];
  const float* proj_b     = (const float*)d_in[35];

  // -------- workspace layout: split-only activations; Y sized by tier --------
  float* ws = (float*)d_ws;
  size_t off = 0;
  f16* Xh   = (f16*)(ws + off); off += 16777216;
  f16* Xl   = Xh + 16777216;
  f16* ENCh = (f16*)(ws + off); off += 4194304;
  f16* ENCl = ENCh + 4194304;
  float* PE = ws + off; off += 1048576;
  float* Mb = ws + off; off += 131072;
  float* PS = ws + off; off += 65536;
  f16* WSP  = (f16*)(ws + off); off += 2097152;
  int* IDXi = (int*)(ws + off); off += 84480;
  float* Y  = ws + off;
  int* MTi  = IDXi + 81920;
  size_t need4 = (off + 16777216ull) * 4;
  size_t need8 = (off + 33554432ull) * 4;
  int bs;
  if      (ws_size >= need8) bs = 8;
  else if (ws_size >= need4) bs = 4;
  else return;
  f16* Yh = (f16*)Y;
  f16* Yl = Yh + 16777216;
  float* WF  = (float*)WSP + 1048576;
  float* PPm = WF;
  float* PPs = WF + 16384;
  float* PPv = WF + 32768;

  auto ln = [&](const f16* xh, const f16* xl, const float* g, const float* b, int rows,
                float* of32, f16* oh, f16* ol) {
    k_ln<<<rows, 256, 0, stream>>>(xh, xl, g, b, of32, oh, ol);
  };
  auto wsplit = [&](const float* W, f16* Wh, f16* Wl, int K, int N, int nmat) {
    dim3 g(K >> 5, N >> 5, nmat);
    k_wsplit<<<g, 256, 0, stream>>>(W, Wh, Wl, K, N);
  };
  auto mgQ = [&](const f16* Ah, const f16* Al, const f16* Wh, const f16* Wl,
                 const float* bias, float* C, int M, int N, int K) {
    dim3 g(N >> 7, M >> 7);
    k_mgemm2<0,0,0,0><<<g, 256, 0, stream>>>(Ah, Al, Wh, Wl, bias, nullptr, nullptr,
        nullptr, nullptr, C, nullptr, nullptr, M, N, K, 0);
  };
  auto mgR = [&](const f16* Ah, const f16* Al, const f16* Wh, const f16* Wl,
                 const float* bias, const f16* Rh, const f16* Rl,
                 f16* Ch, f16* Cl, int M, int N, int K) {
    dim3 g(N >> 7, M >> 7);
    k_mgemm2<0,1,0,1><<<g, 256, 0, stream>>>(Ah, Al, Wh, Wl, bias, Rh, Rl,
        nullptr, nullptr, nullptr, Ch, Cl, M, N, K, 0);
  };
  auto mgG = [&](const f16* Ah, const f16* Al, const f16* Wh, const f16* Wl,
                 const float* bias, f16* Ch, f16* Cl, int M, int N, int K) {
    dim3 g(N >> 7, M >> 7);
    k_mgemm2<1,1,0,0><<<g, 256, 0, stream>>>(Ah, Al, Wh, Wl, bias, nullptr, nullptr,
        nullptr, nullptr, nullptr, Ch, Cl, M, N, K, 0);
  };
  auto Uof = [](int Lx) { int v = 5 * (int)ceil(log((double)Lx)); return v < Lx ? v : Lx; };

  auto attn = [&](f16* xqh, f16* xql, const f16* xkvh, const f16* xkvl,
                  int Lq, int Lk, const float* w, const float* bias,
                  bool masked, u32 fold, bool selfa) {
    int U = Uof(Lk), uu = Uof(Lq);
    u32 r0, r1, ka, kb2;
    tf_block(0u, 42u, 0u, fold, r0, r1);
    tf_block(r0, r1, 0u, 1u, ka, kb2);
    int n = Lq * U;
    k_idx<<<(n + 255) / 256, 256, 0, stream>>>(ka, kb2, n, Lk - 1, IDXi);

    f16 *Wqkvh = WSP,            *Wqkvl = WSP + 786432;
    f16 *WQh   = WSP,            *WQl   = WSP + 262144;
    f16 *WKVh  = WSP + 524288,   *WKVl  = WSP + 1048576;
    f16 *WOh   = WSP + 1572864,  *WOl   = WSP + 1835008;
    if (selfa) {
      wsplit(w, Wqkvh, Wqkvl, 512, 512, 3);
    } else {
      wsplit(w, WQh, WQl, 512, 512, 1);
      wsplit(w + 262144, WKVh, WKVl, 512, 512, 2);
    }
    wsplit(w + 786432, WOh, WOl, 512, 512, 1);

    int nsl = 16 / bs;
    int bhn = bs * 8;
    for (int s = 0; s < nsl; ++s) {
      size_t qoff = (size_t)s * bs * Lq * 512;
      size_t koff = (size_t)s * bs * Lk * 512;
      const float *qp, *kp, *vp;
      int qstr, kstr, vstr;
      f16 *AOh, *AOl;
      if (selfa) {
        float* QKV = Y;
        AOh = (f16*)(Y + (size_t)bs * Lq * 1536);
        AOl = AOh + (size_t)bs * Lq * 512;
        mgQ(xqh + qoff, xql + qoff, Wqkvh, Wqkvl, bias, QKV, bs * Lq, 1536, 512);
        qp = QKV; qstr = 1536; kp = QKV + 512; kstr = 1536; vp = QKV + 1024; vstr = 1536;
      } else {
        float* Qb  = Y;
        float* KVb = Y + (size_t)bs * Lq * 512;
        AOh = (f16*)(KVb + (size_t)bs * Lk * 1024);
        AOl = AOh + (size_t)bs * Lq * 512;
        mgQ(xqh + qoff, xql + qoff, WQh, WQl, bias, Qb, bs * Lq, 512, 512);
        mgQ(xkvh + koff, xkvl + koff, WKVh, WKVl, bias + 512, KVb, bs * Lk, 1024, 512);
        qp = Qb; qstr = 512; kp = KVb; kstr = 1024; vp = KVb + 512; vstr = 1024;
      }
      int wids = bhn * Lq;
      k_qkM<<<wids / 4, 256, 0, stream>>>(qp, qstr, kp, kstr, IDXi, Mb, Lq, Lk, U);
      k_topk64<<<bhn, 64, 0, stream>>>(Mb, MTi, Lq, uu);
      if (masked) {
        k_cs1<<<bhn * 8, 64, 0, stream>>>(vp, vstr, PS, Lq, Lq >> 3);
        k_cs3<<<bhn * 8, 64, 0, stream>>>(vp, vstr, PS, AOh, AOl, Lq, Lq >> 3);
      } else {
        k_cm1<<<bhn * 16, 64, 0, stream>>>(vp, vstr, PS, Lk, Lk >> 4);
        int tot = bs * Lq * 512;
        k_cm2<<<tot / 256, 256, 0, stream>>>(PS, AOh, AOl, 1.0f / (float)Lk, Lq, tot);
      }
      int nch = Lk >> 9;
      dim3 gs(nch, bhn);
      k_sattnF<<<gs, 256, 0, stream>>>(qp, qstr, kp, kstr, vp, vstr, MTi,
                                       PPm, PPs, PPv, Lq, Lk, uu, masked ? 1 : 0, bhn);
      k_sattnc<<<bhn * uu, 64, 0, stream>>>(PPm, PPs, PPv, MTi, AOh, AOl, Lq, uu, nch, bhn);
      mgR(AOh, AOl, WOh, WOl, bias + 1536, xqh + qoff, xql + qoff,
          xqh + qoff, xql + qoff, bs * Lq, 512, 512);
    }
  };

  auto ffn = [&](f16* xh, f16* xl, const float* w1, const float* b1,
                 const float* w2, const float* b2, int Mtot) {
    f16 *W1h = WSP,           *W1l = WSP + 1048576,
        *W2h = WSP + 2097152, *W2l = WSP + 3145728;
    wsplit(w1, W1h, W1l, 512, 2048, 1);
    wsplit(w2, W2h, W2l, 2048, 512, 1);
    for (int c0 = 0; c0 < Mtot; c0 += 8192) {
      int rows = (Mtot - c0 < 8192) ? (Mtot - c0) : 8192;
      mgG(xh + (size_t)c0 * 512, xl + (size_t)c0 * 512, W1h, W1l, b1, Yh, Yl, rows, 2048, 512);
      mgR(Yh, Yl, W2h, W2l, b2, xh + (size_t)c0 * 512, xl + (size_t)c0 * 512,
          xh + (size_t)c0 * 512, xl + (size_t)c0 * 512, rows, 512, 2048);
    }
  };

  // ---------------- encoder ----------------
  k_pe<<<(2048 * 512) / 256, 256, 0, stream>>>(PE);
  k_embed<<<(16 * 2048 * 512) / 256, 256, 0, stream>>>(x_enc, x_mark_enc, enc_tok_w, enc_mark_w,
                                                       PE, Xh, Xl, 2048, 16 * 2048 * 512);
  int L = 2048;
  for (int l = 0; l < 3; ++l) {
    attn(Xh, Xl, Xh, Xl, L, L, enc_attn_w + (size_t)l * 4 * 262144,
         enc_attn_b + (size_t)l * 2048, false, (u32)l, true);
    ln(Xh, Xl, enc_ln_g + (size_t)(l * 2) * 512, enc_ln_b + (size_t)(l * 2) * 512, 16 * L,
       nullptr, Xh, Xl);
    ffn(Xh, Xl, enc_ffn1_w + (size_t)l * 512 * 2048, enc_ffn1_b + (size_t)l * 2048,
        enc_ffn2_w + (size_t)l * 2048 * 512, enc_ffn2_b + (size_t)l * 512, 16 * L);
    ln(Xh, Xl, enc_ln_g + (size_t)(l * 2 + 1) * 512, enc_ln_b + (size_t)(l * 2 + 1) * 512, 16 * L,
       nullptr, Xh, Xl);
    if (l < 2) {
      f16 *Dh = WSP, *Dl = WSP + 786432;
      k_wsplit_conv<<<(512 * 1536) / 256, 256, 0, stream>>>(distil_w + (size_t)l * 512 * 512 * 3, Dh, Dl);
      dim3 g(512 >> 7, (16 * L) >> 7);
      int lgL = (L == 2048) ? 11 : 10;
      k_mgemm2<2,0,1,0><<<g, 256, 0, stream>>>(Xh, Xl, Dh, Dl, distil_b + (size_t)l * 512,
          nullptr, nullptr, distil_bn_g + (size_t)l * 512, distil_bn_b + (size_t)l * 512,
          Y, nullptr, nullptr, 16 * L, 512, 1536, lgL);
      int Lo = L >> 1;
      k_maxpool<<<(16 * Lo * 512) / 256, 256, 0, stream>>>(Y, Xh, Xl, L);
      L = Lo;
    }
  }
  ln(Xh, Xl, enc_norm_g, enc_norm_b, 16 * 512, nullptr, ENCh, ENCl);

  // ---------------- decoder (in-place chain in Xh/Xl) ----------------
  k_embed<<<(16 * 1024 * 512) / 256, 256, 0, stream>>>(x_dec, x_mark_dec, dec_tok_w, dec_mark_w,
                                                       PE, Xh, Xl, 1024, 16 * 1024 * 512);
  for (int l = 0; l < 2; ++l) {
    attn(Xh, Xl, Xh, Xl, 1024, 1024, dec_self_w + (size_t)l * 4 * 262144,
         dec_self_b + (size_t)l * 2048, true, (u32)(100 + 2 * l), true);
    ln(Xh, Xl, dec_ln_g + (size_t)(l * 3) * 512, dec_ln_b + (size_t)(l * 3) * 512, 16384,
       nullptr, Xh, Xl);
    attn(Xh, Xl, ENCh, ENCl, 1024, 512, dec_cross_w + (size_t)l * 4 * 262144,
         dec_cross_b + (size_t)l * 2048, false, (u32)(101 + 2 * l), false);
    ln(Xh, Xl, dec_ln_g + (size_t)(l * 3 + 1) * 512, dec_ln_b + (size_t)(l * 3 + 1) * 512, 16384,
       nullptr, Xh, Xl);
    ffn(Xh, Xl, dec_ffn1_w + (size_t)l * 512 * 2048, dec_ffn1_b + (size_t)l * 2048,
        dec_ffn2_w + (size_t)l * 2048 * 512, dec_ffn2_b + (size_t)l * 512, 16384);
    ln(Xh, Xl, dec_ln_g + (size_t)(l * 3 + 2) * 512, dec_ln_b + (size_t)(l * 3 + 2) * 512, 16384,
       nullptr, Xh, Xl);
  }
  ln(Xh, Xl, dec_norm_g, dec_norm_b, 16384, Y, nullptr, nullptr);
  k_proj<<<(16 * 512 * 7 + 255) / 256, 256, 0, stream>>>(Y, proj_w, proj_b, (float*)d_out);
}

// Round 22
// 6162.573 us; speedup vs baseline: 3.3056x; 1.1103x over previous
//
#include <hip/hip_runtime.h>
#include <math.h>
#include <stdint.h>

typedef unsigned int u32;
typedef _Float16 f16;
typedef __attribute__((ext_vector_type(8))) _Float16 f16x8;
typedef __attribute__((ext_vector_type(4))) float f32x4;

// ---------------- Threefry-2x32 (20 rounds), matches JAX ----------------
__host__ __device__ __forceinline__ u32 rotl32(u32 x, int r) { return (x << r) | (x >> (32 - r)); }
__host__ __device__ __forceinline__ void tf_round(u32& x0, u32& x1, int r) {
  x0 += x1; x1 = rotl32(x1, r); x1 ^= x0;
}
__host__ __device__ __forceinline__ void tf_block(u32 k0, u32 k1, u32 x0, u32 x1, u32& o0, u32& o1) {
  u32 k2 = k0 ^ k1 ^ 0x1BD11BDAu;
  x0 += k0; x1 += k1;
  tf_round(x0,x1,13); tf_round(x0,x1,15); tf_round(x0,x1,26); tf_round(x0,x1,6);
  x0 += k1; x1 += k2 + 1u;
  tf_round(x0,x1,17); tf_round(x0,x1,29); tf_round(x0,x1,16); tf_round(x0,x1,24);
  x0 += k2; x1 += k0 + 2u;
  tf_round(x0,x1,13); tf_round(x0,x1,15); tf_round(x0,x1,26); tf_round(x0,x1,6);
  x0 += k0; x1 += k1 + 3u;
  tf_round(x0,x1,17); tf_round(x0,x1,29); tf_round(x0,x1,16); tf_round(x0,x1,24);
  x0 += k1; x1 += k2 + 4u;
  tf_round(x0,x1,13); tf_round(x0,x1,15); tf_round(x0,x1,26); tf_round(x0,x1,6);
  x0 += k2; x1 += k0 + 5u;
  o0 = x0; o1 = x1;
}

__global__ void k_idx(u32 ka, u32 kb, int n, int mask, int* __restrict__ idx) {
  int i = blockIdx.x * 256 + threadIdx.x;
  if (i >= n) return;
  u32 b1, b2; tf_block(ka, kb, 0u, (u32)i, b1, b2);
  idx[i] = (int)((b1 ^ b2) & (u32)mask);
}

__device__ __forceinline__ void emit_split(float v, f16* __restrict__ oh,
                                           f16* __restrict__ ol, size_t o) {
  f16 h = (f16)v;
  oh[o] = h;
  ol[o] = (f16)((v - (float)h) * 2048.0f);
}
__device__ __forceinline__ float rsplit(const f16* __restrict__ h,
                                        const f16* __restrict__ l, size_t o) {
  return (float)h[o] + (float)l[o] * (1.0f / 2048.0f);
}

// ---------------- positional embedding ----------------
__global__ void k_pe(float* __restrict__ pe) {
  int i = blockIdx.x * 256 + threadIdx.x;
  if (i >= 2048 * 512) return;
  int t = i >> 9, o = i & 511;
  float arg = (float)((o >> 1) * 2) * (float)(-(log(10000.0) / 512.0));
  float div = (float)exp((double)arg);
  float ang32 = (float)t * div;
  double ang = (double)ang32;
  pe[i] = (float)((o & 1) ? cos(ang) : sin(ang));
}

// ---------------- embedding (split-only output) ----------------
__global__ __launch_bounds__(256) void k_embed(
    const float* __restrict__ x, const float* __restrict__ mark,
    const float* __restrict__ tw, const float* __restrict__ mw,
    const float* __restrict__ pe, f16* __restrict__ oh, f16* __restrict__ ol,
    int L, int total) {
  int i = blockIdx.x * 256 + threadIdx.x;
  if (i >= total) return;
  int oo = i & 511;
  int bt = i >> 9;
  int t = bt % L;
  int b = bt / L;
  float acc = pe[(t << 9) + oo];
  #pragma unroll
  for (int k = 0; k < 3; ++k) {
    int st = t + k - 1; if (st < 0) st += L; else if (st >= L) st -= L;
    const float* xr = x + (size_t)(b * L + st) * 7;
    const float* wr = tw + oo * 21 + k;
    #pragma unroll
    for (int ii = 0; ii < 7; ++ii) acc += xr[ii] * wr[ii * 3];
  }
  const float* mr = mark + (size_t)bt * 4;
  #pragma unroll
  for (int m = 0; m < 4; ++m) acc += mr[m] * mw[(m << 9) + oo];
  emit_split(acc, oh, ol, ((size_t)bt << 9) + oo);
}

// ---------------- weight transpose + f16 split (z = matrix index) ----------------
__global__ __launch_bounds__(256) void k_wsplit(const float* __restrict__ W,
    f16* __restrict__ Wh, f16* __restrict__ Wl, int K, int N) {
  size_t zo = (size_t)blockIdx.z * K * N;
  W += zo; Wh += zo; Wl += zo;
  __shared__ float tile[32][33];
  int kb = blockIdx.x << 5, nb = blockIdx.y << 5;
  int t = threadIdx.x;
  int tr = t >> 5, tc = t & 31;
  #pragma unroll
  for (int p = 0; p < 4; ++p)
    tile[tr + p * 8][tc] = W[(size_t)(kb + tr + p * 8) * N + nb + tc];
  __syncthreads();
  #pragma unroll
  for (int p = 0; p < 4; ++p) {
    int n = tr + p * 8, k = tc;
    float v = tile[k][n];
    f16 h = (f16)v;
    size_t o = (size_t)(nb + n) * K + kb + k;
    Wh[o] = h;
    Wl[o] = (f16)((v - (float)h) * 2048.0f);
  }
}

__global__ void k_wsplit_conv(const float* __restrict__ w, f16* __restrict__ Wh, f16* __restrict__ Wl) {
  int i = blockIdx.x * 256 + threadIdx.x;
  if (i >= 512 * 1536) return;
  int o = i / 1536, k = i - o * 1536;
  float v = w[(size_t)o * 1536 + (k & 511) * 3 + (k >> 9)];
  f16 h = (f16)v;
  Wh[i] = h;
  Wl[i] = (f16)((v - (float)h) * 2048.0f);
}

__device__ __forceinline__ int swz_x(int r) { return ((((r >> 1) & 3) ^ ((r >> 3) & 3)) << 4); }

__device__ __forceinline__ void gload16(const void* g, void* l) {
  __builtin_amdgcn_global_load_lds(
      (const __attribute__((address_space(1))) void*)g,
      (__attribute__((address_space(3))) void*)l, 16, 0, 0);
}

// ---------------- MFMA GEMM v2: pre-split f16 A/B, async LDS, dbuf, 16x16x32 ----------------
template<int ACT, int OSPLIT, int GATHER, int RESID>
__global__ __launch_bounds__(256, 2) void k_mgemm2(
    const f16* __restrict__ Ah, const f16* __restrict__ Al,
    const f16* __restrict__ Bh, const f16* __restrict__ Bl,
    const float* __restrict__ bias,
    const f16* __restrict__ Rh, const f16* __restrict__ Rl,
    const float* __restrict__ bns, const float* __restrict__ bnb,
    float* __restrict__ C, f16* __restrict__ Ch, f16* __restrict__ Cl,
    int M, int N, int K, int lgL) {
  __shared__ char lds[65536];
  const int t = threadIdx.x;
  int nwg = gridDim.x * gridDim.y;
  int bid = blockIdx.y * gridDim.x + blockIdx.x;
  if ((nwg & 7) == 0) {
    int cpx = nwg >> 3;
    bid = (bid & 7) * cpx + (bid >> 3);
  }
  const int bm = (bid / gridDim.x) << 7, bn = (bid % gridDim.x) << 7;
  const int w = t >> 6, l = t & 63;
  const int lr = l >> 2;
  const int qx = (l & 3) << 4;
  const int wr = (w >> 1) << 6, wc = (w & 1) << 6;
  const int fr = l & 15;
  const int fkB = (l >> 4) << 4;
  const f32x4 zero = {0.f, 0.f, 0.f, 0.f};
  f32x4 acc1[4][4], acc2[4][4];
  #pragma unroll
  for (int i = 0; i < 4; ++i)
    #pragma unroll
    for (int j = 0; j < 4; ++j) { acc1[i][j] = zero; acc2[i][j] = zero; }

  auto stage = [&](int k0, int bufo) {
    #pragma unroll
    for (int c = 0; c < 2; ++c) {
      int r = w * 32 + c * 16 + lr;
      int sx = qx ^ swz_x(r);
      const char *gAh, *gAl;
      if (GATHER) {
        int m = bm + r;
        int Lm = 1 << lgL;
        int ab = m >> lgL, at = m & (Lm - 1);
        int ke = k0 + (sx >> 1);
        int tap = ke >> 9, ii = ke & 511;
        int st = at + tap - 1; if (st < 0) st += Lm; else if (st >= Lm) st -= Lm;
        size_t aoff = (((size_t)((ab << lgL) + st)) << 9) + ii;
        gAh = (const char*)(Ah + aoff);
        gAl = (const char*)(Al + aoff);
      } else {
        gAh = (const char*)(Ah + (size_t)(bm + r) * K + k0) + sx;
        gAl = (const char*)(Al + (size_t)(bm + r) * K + k0) + sx;
      }
      const char* gBh = (const char*)(Bh + (size_t)(bn + r) * K + k0) + sx;
      const char* gBl = (const char*)(Bl + (size_t)(bn + r) * K + k0) + sx;
      char* base = lds + bufo + w * 2048 + c * 1024;
      gload16(gAh, base);
      gload16(gAl, base + 8192);
      gload16(gBh, base + 16384);
      gload16(gBl, base + 24576);
    }
  };

  int nt = K >> 5;
  stage(0, 0);
  __syncthreads();
  int bufo = 0;
  for (int tt = 0; tt < nt; ++tt) {
    int nb = bufo ^ 32768;
    if (tt + 1 < nt) stage((tt + 1) << 5, nb);
    char* pAh = lds + bufo;
    char* pAl = pAh + 8192;
    char* pBh = pAh + 16384;
    char* pBl = pAh + 24576;
    f16x8 ah4[4], al4[4];
    #pragma unroll
    for (int i = 0; i < 4; ++i) {
      int r = wr + i * 16 + fr;
      int ob = r * 64 + (fkB ^ swz_x(r));
      ah4[i] = *(f16x8*)(pAh + ob);
      al4[i] = *(f16x8*)(pAl + ob);
    }
    #pragma unroll
    for (int j = 0; j < 4; ++j) {
      int r = wc + j * 16 + fr;
      int ob = r * 64 + (fkB ^ swz_x(r));
      f16x8 bh_ = *(f16x8*)(pBh + ob);
      f16x8 bl_ = *(f16x8*)(pBl + ob);
      #pragma unroll
      for (int i = 0; i < 4; ++i) {
        acc1[i][j] = __builtin_amdgcn_mfma_f32_16x16x32_f16(ah4[i], bh_, acc1[i][j], 0, 0, 0);
        acc2[i][j] = __builtin_amdgcn_mfma_f32_16x16x32_f16(ah4[i], bl_, acc2[i][j], 0, 0, 0);
        acc2[i][j] = __builtin_amdgcn_mfma_f32_16x16x32_f16(al4[i], bh_, acc2[i][j], 0, 0, 0);
      }
    }
    __syncthreads();
    bufo = nb;
  }
  #pragma unroll
  for (int j = 0; j < 4; ++j) {
    int col = bn + wc + j * 16 + fr;
    float bsv = bias[col];
    float g2 = 0.f, b2 = 0.f;
    if (ACT == 2) { g2 = bns[col] * 0.9999950000375f; b2 = bnb[col]; }
    #pragma unroll
    for (int i = 0; i < 4; ++i) {
      #pragma unroll
      for (int r = 0; r < 4; ++r) {
        int row = bm + wr + i * 16 + ((l >> 4) << 2) + r;
        float v = acc1[i][j][r] + acc2[i][j][r] * (1.0f / 2048.0f) + bsv;
        if (ACT == 1) v = 0.5f * v * (1.0f + erff(v * 0.70710678118654752f));
        if (ACT == 2) { v = v * g2 + b2; v = v > 0.f ? v : expm1f(v); }
        size_t oi = (size_t)row * N + col;
        if (RESID) v += rsplit(Rh, Rl, oi);
        if (OSPLIT) emit_split(v, Ch, Cl, oi);
        else        C[oi] = v;
      }
    }
  }
}

// ---------------- LayerNorm on split input; optional split / f32 outputs ----------------
__global__ __launch_bounds__(256) void k_ln(const f16* __restrict__ xh, const f16* __restrict__ xl,
    const float* __restrict__ g, const float* __restrict__ b,
    float* __restrict__ of32, f16* __restrict__ oh, f16* __restrict__ ol) {
  int row = blockIdx.x, t = threadIdx.x;
  size_t base = (size_t)row << 9;
  float v0 = rsplit(xh, xl, base + t);
  float v1 = rsplit(xh, xl, base + t + 256);
  float s = v0 + v1;
  #pragma unroll
  for (int off = 32; off; off >>= 1) s += __shfl_down(s, off);
  __shared__ float ls[4];
  if ((t & 63) == 0) ls[t >> 6] = s;
  __syncthreads();
  float mean = (ls[0] + ls[1] + ls[2] + ls[3]) * (1.f / 512.f);
  __syncthreads();
  float d0 = v0 - mean, d1 = v1 - mean;
  float q = d0 * d0 + d1 * d1;
  #pragma unroll
  for (int off = 32; off; off >>= 1) q += __shfl_down(q, off);
  if ((t & 63) == 0) ls[t >> 6] = q;
  __syncthreads();
  float var = (ls[0] + ls[1] + ls[2] + ls[3]) * (1.f / 512.f);
  float rs = rsqrtf(var + 1e-5f);
  float r0 = d0 * rs * g[t] + b[t];
  float r1 = d1 * rs * g[t + 256] + b[t + 256];
  if (of32) { of32[base + t] = r0; of32[base + t + 256] = r1; }
  if (oh) {
    emit_split(r0, oh, ol, base + t);
    emit_split(r1, oh, ol, base + t + 256);
  }
}

// ---------------- M[bh,l] scoring: 2 queries/wave, 4-lane cooperative gather ----------------
// 2 queries x U samples packed into 5 passes of 16 groups (U=40: exact, zero idle).
// Even-query partials bit-identical to the 1-query version (same per-lane sample
// order + same butterfly); odd-query sm reassociates (ulp-class).
__global__ __launch_bounds__(256) void k_qkM(const float* __restrict__ Q, int qstr,
    const float* __restrict__ Kp, int kstr, const int* __restrict__ idx,
    float* __restrict__ M, int Lq, int Lk, int U) {
  __shared__ float qsh[4][2][64];
  __shared__ int idxs[4][2][40];
  int nwg = gridDim.x;
  int bid = blockIdx.x;
  if ((nwg & 7) == 0) {
    int cpx = nwg >> 3;
    bid = (bid & 7) * cpx + (bid >> 3);   // same-bh blocks on one XCD -> K panel L2-resident
  }
  int wib = threadIdx.x >> 6;
  int wid = (bid << 2) + wib;
  int lane = threadIdx.x & 63;
  int Lh = Lq >> 1;
  int lp = wid & (Lh - 1);
  int bh = wid / Lh;
  int l0 = lp * 2;
  int h = bh & 7; int b = bh >> 3;
  if (lane < 32) {
    int q = lane >> 4, e = lane & 15;
    const float4* qr = (const float4*)(Q + (size_t)(b * Lq + l0 + q) * qstr + (h << 6));
    *(float4*)(&qsh[wib][q][e * 4]) = qr[e];
  }
  if (lane < U) {
    idxs[wib][0][lane] = idx[l0 * U + lane];
    idxs[wib][1][lane] = idx[(l0 + 1) * U + lane];
  }
  __syncthreads();
  int g = lane >> 2, j = lane & 3;
  float mx0 = -INFINITY, sm0 = 0.f, mx1 = -INFINITY, sm1 = 0.f;
  #pragma unroll
  for (int p = 0; p < 5; ++p) {
    int sp = p * 16 + g;
    int q = (sp >= U) ? 1 : 0;
    int s = sp - U * q;
    bool act = sp < 2 * U;
    int kr = idxs[wib][act ? q : 0][act ? s : 0];
    const float* kb_ = Kp + (size_t)((size_t)b * Lk + kr) * kstr + (h << 6);
    // instruction i: lane j reads floats [16i+4j, 16i+4j+4) -> group covers line i
    float4 c0 = *(const float4*)(kb_ +  0 + 4 * j);
    float4 c1 = *(const float4*)(kb_ + 16 + 4 * j);
    float4 c2 = *(const float4*)(kb_ + 32 + 4 * j);
    float4 c3 = *(const float4*)(kb_ + 48 + 4 * j);
    const float* qs = qsh[wib][act ? q : 0];
    float pd = 0.f;
    pd += qs[ 0 + 4*j] * c0.x + qs[ 1 + 4*j] * c0.y + qs[ 2 + 4*j] * c0.z + qs[ 3 + 4*j] * c0.w;
    pd += qs[16 + 4*j] * c1.x + qs[17 + 4*j] * c1.y + qs[18 + 4*j] * c1.z + qs[19 + 4*j] * c1.w;
    pd += qs[32 + 4*j] * c2.x + qs[33 + 4*j] * c2.y + qs[34 + 4*j] * c2.z + qs[35 + 4*j] * c2.w;
    pd += qs[48 + 4*j] * c3.x + qs[49 + 4*j] * c3.y + qs[50 + 4*j] * c3.z + qs[51 + 4*j] * c3.w;
    pd += __shfl_xor(pd, 1);
    pd += __shfl_xor(pd, 2);    // all 4 lanes of group hold the full dot
    if (act) {
      if (q == 0) { mx0 = fmaxf(mx0, pd); sm0 += pd; }
      else        { mx1 = fmaxf(mx1, pd); sm1 += pd; }
    }
  }
  // reduce across the 16 groups (j-slices are duplicates; strides >=4 keep them separate)
  #pragma unroll
  for (int off = 32; off >= 4; off >>= 1) {
    mx0 = fmaxf(mx0, __shfl_xor(mx0, off)); sm0 += __shfl_xor(sm0, off);
    mx1 = fmaxf(mx1, __shfl_xor(mx1, off)); sm1 += __shfl_xor(sm1, off);
  }
  if (lane == 0) {
    M[(size_t)bh * Lq + l0]     = mx0 - sm0 / (float)Lk;
    M[(size_t)bh * Lq + l0 + 1] = mx1 - sm1 / (float)Lk;
  }
}

// ---------------- single-wave top-u per (b,h), ties -> lower index ----------------
__global__ void k_topk64(const float* __restrict__ M, int* __restrict__ mtop, int Lq, int u) {
  __shared__ float vals[2048];
  int bh = blockIdx.x, l = threadIdx.x;
  const float* Mr = M + (size_t)bh * Lq;
  for (int i = l; i < Lq; i += 64) vals[i] = Mr[i];
  __syncthreads();
  for (int it = 0; it < u; ++it) {
    float bv = -INFINITY; int bi = 0x7fffffff;
    for (int i = l; i < Lq; i += 64) {
      float v = vals[i];
      if (v > bv || (v == bv && i < bi)) { bv = v; bi = i; }
    }
    #pragma unroll
    for (int off = 32; off; off >>= 1) {
      float vv = __shfl_xor(bv, off); int ii = __shfl_xor(bi, off);
      if (vv > bv || (vv == bv && ii < bi)) { bv = vv; bi = ii; }
    }
    if (l == 0) { mtop[bh * u + it] = bi; vals[bi] = -INFINITY; }
    __syncthreads();
  }
}

// ---------------- ctx mean (AO split) ----------------
__global__ void k_cm1(const float* __restrict__ V, int vstr, float* __restrict__ PS,
                      int Lk, int rows) {
  int bid = blockIdx.x;
  int bh = bid >> 4, seg = bid & 15, d = threadIdx.x;
  int b = bh >> 3, h = bh & 7;
  const float* vp = V + (size_t)(b * Lk + seg * rows) * vstr + (h << 6) + d;
  float acc = 0.f;
  for (int r = 0; r < rows; ++r) acc += vp[(size_t)r * vstr];
  PS[(bid << 6) + d] = acc;
}
__global__ void k_cm2(const float* __restrict__ PS, f16* __restrict__ AOh,
                      f16* __restrict__ AOl, float invLk, int Lq, int total) {
  int i = blockIdx.x * 256 + threadIdx.x;
  if (i >= total) return;
  int c = i & 511; int h = c >> 6; int d = c & 63;
  int r = i >> 9; int b = r / Lq;
  float acc = 0.f;
  #pragma unroll
  for (int s = 0; s < 16; ++s) acc += PS[(((((b << 3) + h) << 4) + s) << 6) + d];
  emit_split(acc * invLk, AOh, AOl, (size_t)i);
}

// ---------------- cumsum (masked ctx; per-block prefix, AO split) ----------------
__global__ void k_cs1(const float* __restrict__ V, int vstr, float* __restrict__ PS,
                      int Lq, int rows) {
  int bid = blockIdx.x;
  int bh = bid >> 3, seg = bid & 7, d = threadIdx.x;
  int b = bh >> 3, h = bh & 7;
  const float* vp = V + (size_t)(b * Lq + seg * rows) * vstr + (h << 6) + d;
  float acc = 0.f;
  for (int r = 0; r < rows; ++r) acc += vp[(size_t)r * vstr];
  PS[(bid << 6) + d] = acc;
}
__global__ void k_cs3(const float* __restrict__ V, int vstr, const float* __restrict__ PS,
                      f16* __restrict__ AOh, f16* __restrict__ AOl, int Lq, int rows) {
  int bid = blockIdx.x;
  int bh = bid >> 3, seg = bid & 7, d = threadIdx.x;
  int b = bh >> 3, h = bh & 7;
  float acc = 0.f;
  for (int s2 = 0; s2 < seg; ++s2) acc += PS[(((bh << 3) + s2) << 6) + d];
  const float* vp = V + (size_t)(b * Lq + seg * rows) * vstr + (h << 6) + d;
  size_t ob = ((size_t)(b * Lq + seg * rows) << 9) + (h << 6) + d;
  for (int r = 0; r < rows; ++r) {
    acc += vp[(size_t)r * vstr];
    emit_split(acc, AOh, AOl, ob + ((size_t)r << 9));
  }
}

// ---------------- flash sparse attn: ALL u rows per (chunk, bh) block ----------------
// chunk sized so nch=4 (256 blocks) for every Lk -> full-CU utilization.
__global__ __launch_bounds__(256) void k_sattnF(
    const float* __restrict__ Q, int qstr, const float* __restrict__ Kp, int kstr,
    const float* __restrict__ Vp, int vstr, const int* __restrict__ mtop,
    float* __restrict__ PPm, float* __restrict__ PPs, float* __restrict__ PPv,
    int Lq, int Lk, int u, int masked, int bhn, int chunk) {
  __shared__ float Qs[40 * 64];
  __shared__ float Kt[64 * 65];
  __shared__ float Vs[64 * 65];
  __shared__ float els[40 * 64];
  __shared__ int rowsh[40];
  int ch = blockIdx.x, bh = blockIdx.y;
  int b = bh >> 3, h = bh & 7;
  int c0 = ch * chunk;
  int nkt = chunk >> 6;
  int t = threadIdx.x;
  int g = t >> 6, d = t & 63;
  if (t < 40) rowsh[t] = (t < u) ? mtop[bh * u + t] : -1;
  __syncthreads();
  for (int i = t; i < 40 * 16; i += 256) {
    int r = i >> 4, e4 = i & 15;
    int row = rowsh[r];
    float4 v;
    if (row >= 0) v = *(const float4*)(Q + (size_t)(b * Lq + row) * qstr + (h << 6) + e4 * 4);
    else          v = make_float4(0.f, 0.f, 0.f, 0.f);
    *(float4*)(Qs + r * 64 + e4 * 4) = v;
  }
  int rows_[10];
  __syncthreads();
  #pragma unroll
  for (int i = 0; i < 10; ++i) rows_[i] = rowsh[g + i * 4];
  float pv[10], m[10], sum[10];
  #pragma unroll
  for (int i = 0; i < 10; ++i) { pv[i] = 0.f; m[i] = -INFINITY; sum[i] = 0.f; }
  const int srow = t >> 2, seg = t & 3;
  for (int kt = 0; kt < nkt; ++kt) {
    __syncthreads();
    {
      int crow = c0 + (kt << 6) + srow;
      const float* kp2 = Kp + (size_t)(b * Lk + crow) * kstr + (h << 6) + seg * 16;
      const float* vp2 = Vp + (size_t)(b * Lk + crow) * vstr + (h << 6) + seg * 16;
      #pragma unroll
      for (int q4 = 0; q4 < 4; ++q4) {
        float4 kv = *(const float4*)(kp2 + q4 * 4);
        float4 vv = *(const float4*)(vp2 + q4 * 4);
        int e0 = seg * 16 + q4 * 4;
        Kt[(e0 + 0) * 65 + srow] = kv.x;
        Kt[(e0 + 1) * 65 + srow] = kv.y;
        Kt[(e0 + 2) * 65 + srow] = kv.z;
        Kt[(e0 + 3) * 65 + srow] = kv.w;
        Vs[srow * 65 + e0 + 0] = vv.x;
        Vs[srow * 65 + e0 + 1] = vv.y;
        Vs[srow * 65 + e0 + 2] = vv.z;
        Vs[srow * 65 + e0 + 3] = vv.w;
      }
    }
    __syncthreads();
    float dot[10];
    #pragma unroll
    for (int i = 0; i < 10; ++i) dot[i] = 0.f;
    for (int e = 0; e < 64; ++e) {
      float kv = Kt[e * 65 + d];
      #pragma unroll
      for (int i = 0; i < 10; ++i)
        dot[i] += Qs[(g + i * 4) * 64 + e] * kv;
    }
    int key = c0 + (kt << 6) + d;
    float scale_[10];
    #pragma unroll
    for (int i = 0; i < 10; ++i) {
      float s = dot[i] * 0.125f;
      if (masked && key > rows_[i]) s = -INFINITY;
      float tm = s;
      #pragma unroll
      for (int off = 32; off; off >>= 1) tm = fmaxf(tm, __shfl_xor(tm, off));
      float nm = fmaxf(m[i], tm);
      if (nm > -3e38f) {
        float scl = expf(m[i] - nm);
        float e_ = expf(s - nm);
        float ts = e_;
        #pragma unroll
        for (int off = 32; off; off >>= 1) ts += __shfl_xor(ts, off);
        sum[i] = sum[i] * scl + ts;
        m[i] = nm;
        scale_[i] = scl;
        els[(g + i * 4) * 64 + d] = e_;
      } else {
        scale_[i] = 1.f;
        els[(g + i * 4) * 64 + d] = 0.f;
      }
    }
    __syncthreads();
    float acc[10];
    #pragma unroll
    for (int i = 0; i < 10; ++i) acc[i] = 0.f;
    for (int k = 0; k < 64; ++k) {
      float vv = Vs[k * 65 + d];
      #pragma unroll
      for (int i = 0; i < 10; ++i)
        acc[i] += els[(g + i * 4) * 64 + k] * vv;
    }
    #pragma unroll
    for (int i = 0; i < 10; ++i) pv[i] = pv[i] * scale_[i] + acc[i];
  }
  #pragma unroll
  for (int i = 0; i < 10; ++i) {
    int r = g + i * 4;
    if (r < u) {
      size_t pidx = (size_t)(ch * bhn + bh) * u + r;
      if (d == 0) { PPm[pidx] = m[i]; PPs[pidx] = sum[i]; }
      PPv[pidx * 64 + d] = pv[i];
    }
  }
}

// ---------------- combine chunk partials -> AO (online softmax rescale) ----------------
__global__ void k_sattnc(const float* __restrict__ PPm, const float* __restrict__ PPs,
                         const float* __restrict__ PPv, const int* __restrict__ mtop,
                         f16* __restrict__ AOh, f16* __restrict__ AOl,
                         int Lq, int u, int nch, int bhn) {
  int rowid = blockIdx.x;
  int bh = rowid / u, ui = rowid % u;
  int d = threadIdx.x;
  int b = bh >> 3, h = bh & 7;
  int row = mtop[bh * u + ui];
  float M = -INFINITY;
  for (int c = 0; c < nch; ++c)
    M = fmaxf(M, PPm[(size_t)(c * bhn + bh) * u + ui]);
  float S = 0.f, o = 0.f;
  for (int c = 0; c < nch; ++c) {
    size_t pidx = (size_t)(c * bhn + bh) * u + ui;
    float pm = PPm[pidx];
    float sc = (pm > -3e38f) ? expf(pm - M) : 0.f;
    S += sc * PPs[pidx];
    o += sc * PPv[pidx * 64 + d];
  }
  emit_split(o / S, AOh, AOl, ((size_t)(b * Lq + row) << 9) + (h << 6) + d);
}

// ---------------- maxpool w3 s2 p1 along L (split-only output) ----------------
__global__ void k_maxpool(const float* __restrict__ y, f16* __restrict__ oh,
                          f16* __restrict__ ol, int L) {
  int Lo = L >> 1;
  int i = blockIdx.x * 256 + threadIdx.x;
  int c = i & 511; int bj = i >> 9;
  int j = bj % Lo; int b = bj / Lo;
  float m = -INFINITY;
  int t0 = 2 * j - 1;
  #pragma unroll
  for (int k = 0; k < 3; ++k) {
    int tt = t0 + k;
    if (tt >= 0 && tt < L) m = fmaxf(m, y[((size_t)(b * L + tt) << 9) + c]);
  }
  emit_split(m, oh, ol, ((size_t)(b * Lo + j) << 9) + c);
}

// ---------------- final projection 512->7 (reads f32 from Y) ----------------
__global__ void k_proj(const float* __restrict__ Xn, const float* __restrict__ pw,
                       const float* __restrict__ pb, float* __restrict__ out) {
  int i = blockIdx.x * 256 + threadIdx.x;
  if (i >= 16 * 512 * 7) return;
  int c = i % 7; int r = i / 7;
  int b = r >> 9; int j = r & 511;
  const float* xr = Xn + ((size_t)(b * 1024 + 512 + j) << 9);
  float acc = pb[c];
  for (int d2 = 0; d2 < 512; ++d2) acc += xr[d2] * pw[d2 * 7 + c];
  out[i] = acc;
}

// =====================================================================
extern "C" void kernel_launch(void* const* d_in, const int* in_sizes, int n_in,
                              void* d_out, int out_size, void* d_ws, size_t ws_size,
                              hipStream_t stream) {
  const float* x_enc      = (const float*)d_in[0];
  const float* x_mark_enc = (const float*)d_in[1];
  const float* x_dec      = (const float*)d_in[2];
  const float* x_mark_dec = (const float*)d_in[3];
  const float* enc_tok_w  = (const float*)d_in[4];
  const float* enc_mark_w = (const float*)d_in[5];
  const float* dec_tok_w  = (const float*)d_in[6];
  const float* dec_mark_w = (const float*)d_in[7];
  const float* enc_attn_w = (const float*)d_in[8];
  const float* enc_attn_b = (const float*)d_in[9];
  const float* enc_ffn1_w = (const float*)d_in[10];
  const float* enc_ffn1_b = (const float*)d_in[11];
  const float* enc_ffn2_w = (const float*)d_in[12];
  const float* enc_ffn2_b = (const float*)d_in[13];
  const float* enc_ln_g   = (const float*)d_in[14];
  const float* enc_ln_b   = (const float*)d_in[15];
  const float* distil_w   = (const float*)d_in[16];
  const float* distil_b   = (const float*)d_in[17];
  const float* distil_bn_g= (const float*)d_in[18];
  const float* distil_bn_b= (const float*)d_in[19];
  const float* enc_norm_g = (const float*)d_in[20];
  const float* enc_norm_b = (const float*)d_in[21];
  const float* dec_self_w = (const float*)d_in[22];
  const float* dec_self_b = (const float*)d_in[23];
  const float* dec_cross_w= (const float*)d_in[24];
  const float* dec_cross_b= (const float*)d_in[25];
  const float* dec_ffn1_w = (const float*)d_in[26];
  const float* dec_ffn1_b = (const float*)d_in[27];
  const float* dec_ffn2_w = (const float*)d_in[28];
  const float* dec_ffn2_b = (const float*)d_in[29];
  const float* dec_ln_g   = (const float*)d_in[30];
  const float* dec_ln_b   = (const float*)d_in[31];
  const float* dec_norm_g = (const float*)d_in[32];
  const float* dec_norm_b = (const float*)d_in[33];
  const float* proj_w     = (const float*)d_in[34];
  const float* proj_b     = (const float*)d_in[35];

  // -------- workspace layout: split-only activations; Y sized by tier --------
  float* ws = (float*)d_ws;
  size_t off = 0;
  f16* Xh   = (f16*)(ws + off); off += 16777216;
  f16* Xl   = Xh + 16777216;
  f16* ENCh = (f16*)(ws + off); off += 4194304;
  f16* ENCl = ENCh + 4194304;
  float* PE = ws + off; off += 1048576;
  float* Mb = ws + off; off += 131072;
  float* PS = ws + off; off += 65536;
  f16* WSP  = (f16*)(ws + off); off += 2097152;
  int* IDXi = (int*)(ws + off); off += 84480;
  float* Y  = ws + off;
  int* MTi  = IDXi + 81920;
  size_t need4 = (off + 16777216ull) * 4;
  size_t need8 = (off + 33554432ull) * 4;
  int bs;
  if      (ws_size >= need8) bs = 8;
  else if (ws_size >= need4) bs = 4;
  else return;
  f16* Yh = (f16*)Y;
  f16* Yl = Yh + 16777216;
  float* WF  = (float*)WSP + 1048576;
  float* PPm = WF;
  float* PPs = WF + 16384;
  float* PPv = WF + 32768;

  auto ln = [&](const f16* xh, const f16* xl, const float* g, const float* b, int rows,
                float* of32, f16* oh, f16* ol) {
    k_ln<<<rows, 256, 0, stream>>>(xh, xl, g, b, of32, oh, ol);
  };
  auto wsplit = [&](const float* W, f16* Wh, f16* Wl, int K, int N, int nmat) {
    dim3 g(K >> 5, N >> 5, nmat);
    k_wsplit<<<g, 256, 0, stream>>>(W, Wh, Wl, K, N);
  };
  auto mgQ = [&](const f16* Ah, const f16* Al, const f16* Wh, const f16* Wl,
                 const float* bias, float* C, int M, int N, int K) {
    dim3 g(N >> 7, M >> 7);
    k_mgemm2<0,0,0,0><<<g, 256, 0, stream>>>(Ah, Al, Wh, Wl, bias, nullptr, nullptr,
        nullptr, nullptr, C, nullptr, nullptr, M, N, K, 0);
  };
  auto mgR = [&](const f16* Ah, const f16* Al, const f16* Wh, const f16* Wl,
                 const float* bias, const f16* Rh, const f16* Rl,
                 f16* Ch, f16* Cl, int M, int N, int K) {
    dim3 g(N >> 7, M >> 7);
    k_mgemm2<0,1,0,1><<<g, 256, 0, stream>>>(Ah, Al, Wh, Wl, bias, Rh, Rl,
        nullptr, nullptr, nullptr, Ch, Cl, M, N, K, 0);
  };
  auto mgG = [&](const f16* Ah, const f16* Al, const f16* Wh, const f16* Wl,
                 const float* bias, f16* Ch, f16* Cl, int M, int N, int K) {
    dim3 g(N >> 7, M >> 7);
    k_mgemm2<1,1,0,0><<<g, 256, 0, stream>>>(Ah, Al, Wh, Wl, bias, nullptr, nullptr,
        nullptr, nullptr, nullptr, Ch, Cl, M, N, K, 0);
  };
  auto Uof = [](int Lx) { int v = 5 * (int)ceil(log((double)Lx)); return v < Lx ? v : Lx; };

  auto attn = [&](f16* xqh, f16* xql, const f16* xkvh, const f16* xkvl,
                  int Lq, int Lk, const float* w, const float* bias,
                  bool masked, u32 fold, bool selfa) {
    int U = Uof(Lk), uu = Uof(Lq);
    u32 r0, r1, ka, kb2;
    tf_block(0u, 42u, 0u, fold, r0, r1);
    tf_block(r0, r1, 0u, 1u, ka, kb2);
    int n = Lq * U;
    k_idx<<<(n + 255) / 256, 256, 0, stream>>>(ka, kb2, n, Lk - 1, IDXi);

    f16 *Wqkvh = WSP,            *Wqkvl = WSP + 786432;
    f16 *WQh   = WSP,            *WQl   = WSP + 262144;
    f16 *WKVh  = WSP + 524288,   *WKVl  = WSP + 1048576;
    f16 *WOh   = WSP + 1572864,  *WOl   = WSP + 1835008;
    if (selfa) {
      wsplit(w, Wqkvh, Wqkvl, 512, 512, 3);
    } else {
      wsplit(w, WQh, WQl, 512, 512, 1);
      wsplit(w + 262144, WKVh, WKVl, 512, 512, 2);
    }
    wsplit(w + 786432, WOh, WOl, 512, 512, 1);

    int nsl = 16 / bs;
    int bhn = bs * 8;
    for (int s = 0; s < nsl; ++s) {
      size_t qoff = (size_t)s * bs * Lq * 512;
      size_t koff = (size_t)s * bs * Lk * 512;
      const float *qp, *kp, *vp;
      int qstr, kstr, vstr;
      f16 *AOh, *AOl;
      if (selfa) {
        float* QKV = Y;
        AOh = (f16*)(Y + (size_t)bs * Lq * 1536);
        AOl = AOh + (size_t)bs * Lq * 512;
        mgQ(xqh + qoff, xql + qoff, Wqkvh, Wqkvl, bias, QKV, bs * Lq, 1536, 512);
        qp = QKV; qstr = 1536; kp = QKV + 512; kstr = 1536; vp = QKV + 1024; vstr = 1536;
      } else {
        float* Qb  = Y;
        float* KVb = Y + (size_t)bs * Lq * 512;
        AOh = (f16*)(KVb + (size_t)bs * Lk * 1024);
        AOl = AOh + (size_t)bs * Lq * 512;
        mgQ(xqh + qoff, xql + qoff, WQh, WQl, bias, Qb, bs * Lq, 512, 512);
        mgQ(xkvh + koff, xkvl + koff, WKVh, WKVl, bias + 512, KVb, bs * Lk, 1024, 512);
        qp = Qb; qstr = 512; kp = KVb; kstr = 1024; vp = KVb + 512; vstr = 1024;
      }
      int wids = bhn * Lq;
      k_qkM<<<wids / 8, 256, 0, stream>>>(qp, qstr, kp, kstr, IDXi, Mb, Lq, Lk, U);
      k_topk64<<<bhn, 64, 0, stream>>>(Mb, MTi, Lq, uu);
      if (masked) {
        k_cs1<<<bhn * 8, 64, 0, stream>>>(vp, vstr, PS, Lq, Lq >> 3);
        k_cs3<<<bhn * 8, 64, 0, stream>>>(vp, vstr, PS, AOh, AOl, Lq, Lq >> 3);
      } else {
        k_cm1<<<bhn * 16, 64, 0, stream>>>(vp, vstr, PS, Lk, Lk >> 4);
        int tot = bs * Lq * 512;
        k_cm2<<<tot / 256, 256, 0, stream>>>(PS, AOh, AOl, 1.0f / (float)Lk, Lq, tot);
      }
      int chunk = (Lk >= 2048) ? 512 : ((Lk >= 1024) ? 256 : 128);
      int nch = Lk / chunk;
      dim3 gs(nch, bhn);
      k_sattnF<<<gs, 256, 0, stream>>>(qp, qstr, kp, kstr, vp, vstr, MTi,
                                       PPm, PPs, PPv, Lq, Lk, uu, masked ? 1 : 0, bhn, chunk);
      k_sattnc<<<bhn * uu, 64, 0, stream>>>(PPm, PPs, PPv, MTi, AOh, AOl, Lq, uu, nch, bhn);
      mgR(AOh, AOl, WOh, WOl, bias + 1536, xqh + qoff, xql + qoff,
          xqh + qoff, xql + qoff, bs * Lq, 512, 512);
    }
  };

  auto ffn = [&](f16* xh, f16* xl, const float* w1, const float* b1,
                 const float* w2, const float* b2, int Mtot) {
    f16 *W1h = WSP,           *W1l = WSP + 1048576,
        *W2h = WSP + 2097152, *W2l = WSP + 3145728;
    wsplit(w1, W1h, W1l, 512, 2048, 1);
    wsplit(w2, W2h, W2l, 2048, 512, 1);
    for (int c0 = 0; c0 < Mtot; c0 += 8192) {
      int rows = (Mtot - c0 < 8192) ? (Mtot - c0) : 8192;
      mgG(xh + (size_t)c0 * 512, xl + (size_t)c0 * 512, W1h, W1l, b1, Yh, Yl, rows, 2048, 512);
      mgR(Yh, Yl, W2h, W2l, b2, xh + (size_t)c0 * 512, xl + (size_t)c0 * 512,
          xh + (size_t)c0 * 512, xl + (size_t)c0 * 512, rows, 512, 2048);
    }
  };

  // ---------------- encoder ----------------
  k_pe<<<(2048 * 512) / 256, 256, 0, stream>>>(PE);
  k_embed<<<(16 * 2048 * 512) / 256, 256, 0, stream>>>(x_enc, x_mark_enc, enc_tok_w, enc_mark_w,
                                                       PE, Xh, Xl, 2048, 16 * 2048 * 512);
  int L = 2048;
  for (int l = 0; l < 3; ++l) {
    attn(Xh, Xl, Xh, Xl, L, L, enc_attn_w + (size_t)l * 4 * 262144,
         enc_attn_b + (size_t)l * 2048, false, (u32)l, true);
    ln(Xh, Xl, enc_ln_g + (size_t)(l * 2) * 512, enc_ln_b + (size_t)(l * 2) * 512, 16 * L,
       nullptr, Xh, Xl);
    ffn(Xh, Xl, enc_ffn1_w + (size_t)l * 512 * 2048, enc_ffn1_b + (size_t)l * 2048,
        enc_ffn2_w + (size_t)l * 2048 * 512, enc_ffn2_b + (size_t)l * 512, 16 * L);
    ln(Xh, Xl, enc_ln_g + (size_t)(l * 2 + 1) * 512, enc_ln_b + (size_t)(l * 2 + 1) * 512, 16 * L,
       nullptr, Xh, Xl);
    if (l < 2) {
      f16 *Dh = WSP, *Dl = WSP + 786432;
      k_wsplit_conv<<<(512 * 1536) / 256, 256, 0, stream>>>(distil_w + (size_t)l * 512 * 512 * 3, Dh, Dl);
      dim3 g(512 >> 7, (16 * L) >> 7);
      int lgL = (L == 2048) ? 11 : 10;
      k_mgemm2<2,0,1,0><<<g, 256, 0, stream>>>(Xh, Xl, Dh, Dl, distil_b + (size_t)l * 512,
          nullptr, nullptr, distil_bn_g + (size_t)l * 512, distil_bn_b + (size_t)l * 512,
          Y, nullptr, nullptr, 16 * L, 512, 1536, lgL);
      int Lo = L >> 1;
      k_maxpool<<<(16 * Lo * 512) / 256, 256, 0, stream>>>(Y, Xh, Xl, L);
      L = Lo;
    }
  }
  ln(Xh, Xl, enc_norm_g, enc_norm_b, 16 * 512, nullptr, ENCh, ENCl);

  // ---------------- decoder (in-place chain in Xh/Xl) ----------------
  k_embed<<<(16 * 1024 * 512) / 256, 256, 0, stream>>>(x_dec, x_mark_dec, dec_tok_w, dec_mark_w,
                                                       PE, Xh, Xl, 1024, 16 * 1024 * 512);
  for (int l = 0; l < 2; ++l) {
    attn(Xh, Xl, Xh, Xl, 1024, 1024, dec_self_w + (size_t)l * 4 * 262144,
         dec_self_b + (size_t)l * 2048, true, (u32)(100 + 2 * l), true);
    ln(Xh, Xl, dec_ln_g + (size_t)(l * 3) * 512, dec_ln_b + (size_t)(l * 3) * 512, 16384,
       nullptr, Xh, Xl);
    attn(Xh, Xl, ENCh, ENCl, 1024, 512, dec_cross_w + (size_t)l * 4 * 262144,
         dec_cross_b + (size_t)l * 2048, false, (u32)(101 + 2 * l), false);
    ln(Xh, Xl, dec_ln_g + (size_t)(l * 3 + 1) * 512, dec_ln_b + (size_t)(l * 3 + 1) * 512, 16384,
       nullptr, Xh, Xl);
    ffn(Xh, Xl, dec_ffn1_w + (size_t)l * 512 * 2048, dec_ffn1_b + (size_t)l * 2048,
        dec_ffn2_w + (size_t)l * 2048 * 512, dec_ffn2_b + (size_t)l * 512, 16384);
    ln(Xh, Xl, dec_ln_g + (size_t)(l * 3 + 2) * 512, dec_ln_b + (size_t)(l * 3 + 2) * 512, 16384,
       nullptr, Xh, Xl);
  }
  ln(Xh, Xl, dec_norm_g, dec_norm_b, 16384, Y, nullptr, nullptr);
  k_proj<<<(16 * 512 * 7 + 255) / 256, 256, 0, stream>>>(Y, proj_w, proj_b, (float*)d_out);
}

// Round 23
// 5838.903 us; speedup vs baseline: 3.4888x; 1.0554x over previous
//
#include <hip/hip_runtime.h>
#include <math.h>
#include <stdint.h>

typedef unsigned int u32;
typedef _Float16 f16;
typedef __attribute__((ext_vector_type(8))) _Float16 f16x8;
typedef __attribute__((ext_vector_type(4))) float f32x4;

// ---------------- Threefry-2x32 (20 rounds), matches JAX ----------------
__host__ __device__ __forceinline__ u32 rotl32(u32 x, int r) { return (x << r) | (x >> (32 - r)); }
__host__ __device__ __forceinline__ void tf_round(u32& x0, u32& x1, int r) {
  x0 += x1; x1 = rotl32(x1, r); x1 ^= x0;
}
__host__ __device__ __forceinline__ void tf_block(u32 k0, u32 k1, u32 x0, u32 x1, u32& o0, u32& o1) {
  u32 k2 = k0 ^ k1 ^ 0x1BD11BDAu;
  x0 += k0; x1 += k1;
  tf_round(x0,x1,13); tf_round(x0,x1,15); tf_round(x0,x1,26); tf_round(x0,x1,6);
  x0 += k1; x1 += k2 + 1u;
  tf_round(x0,x1,17); tf_round(x0,x1,29); tf_round(x0,x1,16); tf_round(x0,x1,24);
  x0 += k2; x1 += k0 + 2u;
  tf_round(x0,x1,13); tf_round(x0,x1,15); tf_round(x0,x1,26); tf_round(x0,x1,6);
  x0 += k0; x1 += k1 + 3u;
  tf_round(x0,x1,17); tf_round(x0,x1,29); tf_round(x0,x1,16); tf_round(x0,x1,24);
  x0 += k1; x1 += k2 + 4u;
  tf_round(x0,x1,13); tf_round(x0,x1,15); tf_round(x0,x1,26); tf_round(x0,x1,6);
  x0 += k2; x1 += k0 + 5u;
  o0 = x0; o1 = x1;
}

__global__ void k_idx(u32 ka, u32 kb, int n, int mask, int* __restrict__ idx) {
  int i = blockIdx.x * 256 + threadIdx.x;
  if (i >= n) return;
  u32 b1, b2; tf_block(ka, kb, 0u, (u32)i, b1, b2);
  idx[i] = (int)((b1 ^ b2) & (u32)mask);
}

__device__ __forceinline__ void emit_split(float v, f16* __restrict__ oh,
                                           f16* __restrict__ ol, size_t o) {
  f16 h = (f16)v;
  oh[o] = h;
  ol[o] = (f16)((v - (float)h) * 2048.0f);
}
__device__ __forceinline__ float rsplit(const f16* __restrict__ h,
                                        const f16* __restrict__ l, size_t o) {
  return (float)h[o] + (float)l[o] * (1.0f / 2048.0f);
}

// ---------------- positional embedding ----------------
__global__ void k_pe(float* __restrict__ pe) {
  int i = blockIdx.x * 256 + threadIdx.x;
  if (i >= 2048 * 512) return;
  int t = i >> 9, o = i & 511;
  float arg = (float)((o >> 1) * 2) * (float)(-(log(10000.0) / 512.0));
  float div = (float)exp((double)arg);
  float ang32 = (float)t * div;
  double ang = (double)ang32;
  pe[i] = (float)((o & 1) ? cos(ang) : sin(ang));
}

// ---------------- embedding (split-only output) ----------------
__global__ __launch_bounds__(256) void k_embed(
    const float* __restrict__ x, const float* __restrict__ mark,
    const float* __restrict__ tw, const float* __restrict__ mw,
    const float* __restrict__ pe, f16* __restrict__ oh, f16* __restrict__ ol,
    int L, int total) {
  int i = blockIdx.x * 256 + threadIdx.x;
  if (i >= total) return;
  int oo = i & 511;
  int bt = i >> 9;
  int t = bt % L;
  int b = bt / L;
  float acc = pe[(t << 9) + oo];
  #pragma unroll
  for (int k = 0; k < 3; ++k) {
    int st = t + k - 1; if (st < 0) st += L; else if (st >= L) st -= L;
    const float* xr = x + (size_t)(b * L + st) * 7;
    const float* wr = tw + oo * 21 + k;
    #pragma unroll
    for (int ii = 0; ii < 7; ++ii) acc += xr[ii] * wr[ii * 3];
  }
  const float* mr = mark + (size_t)bt * 4;
  #pragma unroll
  for (int m = 0; m < 4; ++m) acc += mr[m] * mw[(m << 9) + oo];
  emit_split(acc, oh, ol, ((size_t)bt << 9) + oo);
}

// ---------------- weight transpose + f16 split (z = matrix index) ----------------
__global__ __launch_bounds__(256) void k_wsplit(const float* __restrict__ W,
    f16* __restrict__ Wh, f16* __restrict__ Wl, int K, int N) {
  size_t zo = (size_t)blockIdx.z * K * N;
  W += zo; Wh += zo; Wl += zo;
  __shared__ float tile[32][33];
  int kb = blockIdx.x << 5, nb = blockIdx.y << 5;
  int t = threadIdx.x;
  int tr = t >> 5, tc = t & 31;
  #pragma unroll
  for (int p = 0; p < 4; ++p)
    tile[tr + p * 8][tc] = W[(size_t)(kb + tr + p * 8) * N + nb + tc];
  __syncthreads();
  #pragma unroll
  for (int p = 0; p < 4; ++p) {
    int n = tr + p * 8, k = tc;
    float v = tile[k][n];
    f16 h = (f16)v;
    size_t o = (size_t)(nb + n) * K + kb + k;
    Wh[o] = h;
    Wl[o] = (f16)((v - (float)h) * 2048.0f);
  }
}

__global__ void k_wsplit_conv(const float* __restrict__ w, f16* __restrict__ Wh, f16* __restrict__ Wl) {
  int i = blockIdx.x * 256 + threadIdx.x;
  if (i >= 512 * 1536) return;
  int o = i / 1536, k = i - o * 1536;
  float v = w[(size_t)o * 1536 + (k & 511) * 3 + (k >> 9)];
  f16 h = (f16)v;
  Wh[i] = h;
  Wl[i] = (f16)((v - (float)h) * 2048.0f);
}

__device__ __forceinline__ int swz_x(int r) { return ((((r >> 1) & 3) ^ ((r >> 3) & 3)) << 4); }

__device__ __forceinline__ void gload16(const void* g, void* l) {
  __builtin_amdgcn_global_load_lds(
      (const __attribute__((address_space(1))) void*)g,
      (__attribute__((address_space(3))) void*)l, 16, 0, 0);
}

// ---------------- MFMA GEMM v2: pre-split f16 A/B, async LDS, dbuf, 16x16x32 ----------------
template<int ACT, int OSPLIT, int GATHER, int RESID>
__global__ __launch_bounds__(256, 2) void k_mgemm2(
    const f16* __restrict__ Ah, const f16* __restrict__ Al,
    const f16* __restrict__ Bh, const f16* __restrict__ Bl,
    const float* __restrict__ bias,
    const f16* __restrict__ Rh, const f16* __restrict__ Rl,
    const float* __restrict__ bns, const float* __restrict__ bnb,
    float* __restrict__ C, f16* __restrict__ Ch, f16* __restrict__ Cl,
    int M, int N, int K, int lgL) {
  __shared__ char lds[65536];
  const int t = threadIdx.x;
  int nwg = gridDim.x * gridDim.y;
  int bid = blockIdx.y * gridDim.x + blockIdx.x;
  if ((nwg & 7) == 0) {
    int cpx = nwg >> 3;
    bid = (bid & 7) * cpx + (bid >> 3);
  }
  const int bm = (bid / gridDim.x) << 7, bn = (bid % gridDim.x) << 7;
  const int w = t >> 6, l = t & 63;
  const int lr = l >> 2;
  const int qx = (l & 3) << 4;
  const int wr = (w >> 1) << 6, wc = (w & 1) << 6;
  const int fr = l & 15;
  const int fkB = (l >> 4) << 4;
  const f32x4 zero = {0.f, 0.f, 0.f, 0.f};
  f32x4 acc1[4][4], acc2[4][4];
  #pragma unroll
  for (int i = 0; i < 4; ++i)
    #pragma unroll
    for (int j = 0; j < 4; ++j) { acc1[i][j] = zero; acc2[i][j] = zero; }

  auto stage = [&](int k0, int bufo) {
    #pragma unroll
    for (int c = 0; c < 2; ++c) {
      int r = w * 32 + c * 16 + lr;
      int sx = qx ^ swz_x(r);
      const char *gAh, *gAl;
      if (GATHER) {
        int m = bm + r;
        int Lm = 1 << lgL;
        int ab = m >> lgL, at = m & (Lm - 1);
        int ke = k0 + (sx >> 1);
        int tap = ke >> 9, ii = ke & 511;
        int st = at + tap - 1; if (st < 0) st += Lm; else if (st >= Lm) st -= Lm;
        size_t aoff = (((size_t)((ab << lgL) + st)) << 9) + ii;
        gAh = (const char*)(Ah + aoff);
        gAl = (const char*)(Al + aoff);
      } else {
        gAh = (const char*)(Ah + (size_t)(bm + r) * K + k0) + sx;
        gAl = (const char*)(Al + (size_t)(bm + r) * K + k0) + sx;
      }
      const char* gBh = (const char*)(Bh + (size_t)(bn + r) * K + k0) + sx;
      const char* gBl = (const char*)(Bl + (size_t)(bn + r) * K + k0) + sx;
      char* base = lds + bufo + w * 2048 + c * 1024;
      gload16(gAh, base);
      gload16(gAl, base + 8192);
      gload16(gBh, base + 16384);
      gload16(gBl, base + 24576);
    }
  };

  int nt = K >> 5;
  stage(0, 0);
  __syncthreads();
  int bufo = 0;
  for (int tt = 0; tt < nt; ++tt) {
    int nb = bufo ^ 32768;
    if (tt + 1 < nt) stage((tt + 1) << 5, nb);
    char* pAh = lds + bufo;
    char* pAl = pAh + 8192;
    char* pBh = pAh + 16384;
    char* pBl = pAh + 24576;
    f16x8 ah4[4], al4[4];
    #pragma unroll
    for (int i = 0; i < 4; ++i) {
      int r = wr + i * 16 + fr;
      int ob = r * 64 + (fkB ^ swz_x(r));
      ah4[i] = *(f16x8*)(pAh + ob);
      al4[i] = *(f16x8*)(pAl + ob);
    }
    #pragma unroll
    for (int j = 0; j < 4; ++j) {
      int r = wc + j * 16 + fr;
      int ob = r * 64 + (fkB ^ swz_x(r));
      f16x8 bh_ = *(f16x8*)(pBh + ob);
      f16x8 bl_ = *(f16x8*)(pBl + ob);
      #pragma unroll
      for (int i = 0; i < 4; ++i) {
        acc1[i][j] = __builtin_amdgcn_mfma_f32_16x16x32_f16(ah4[i], bh_, acc1[i][j], 0, 0, 0);
        acc2[i][j] = __builtin_amdgcn_mfma_f32_16x16x32_f16(ah4[i], bl_, acc2[i][j], 0, 0, 0);
        acc2[i][j] = __builtin_amdgcn_mfma_f32_16x16x32_f16(al4[i], bh_, acc2[i][j], 0, 0, 0);
      }
    }
    __syncthreads();
    bufo = nb;
  }
  #pragma unroll
  for (int j = 0; j < 4; ++j) {
    int col = bn + wc + j * 16 + fr;
    float bsv = bias[col];
    float g2 = 0.f, b2 = 0.f;
    if (ACT == 2) { g2 = bns[col] * 0.9999950000375f; b2 = bnb[col]; }
    #pragma unroll
    for (int i = 0; i < 4; ++i) {
      #pragma unroll
      for (int r = 0; r < 4; ++r) {
        int row = bm + wr + i * 16 + ((l >> 4) << 2) + r;
        float v = acc1[i][j][r] + acc2[i][j][r] * (1.0f / 2048.0f) + bsv;
        if (ACT == 1) v = 0.5f * v * (1.0f + erff(v * 0.70710678118654752f));
        if (ACT == 2) { v = v * g2 + b2; v = v > 0.f ? v : expm1f(v); }
        size_t oi = (size_t)row * N + col;
        if (RESID) v += rsplit(Rh, Rl, oi);
        if (OSPLIT) emit_split(v, Ch, Cl, oi);
        else        C[oi] = v;
      }
    }
  }
}

// ---------------- LayerNorm on split input; optional split / f32 outputs ----------------
__global__ __launch_bounds__(256) void k_ln(const f16* __restrict__ xh, const f16* __restrict__ xl,
    const float* __restrict__ g, const float* __restrict__ b,
    float* __restrict__ of32, f16* __restrict__ oh, f16* __restrict__ ol) {
  int row = blockIdx.x, t = threadIdx.x;
  size_t base = (size_t)row << 9;
  float v0 = rsplit(xh, xl, base + t);
  float v1 = rsplit(xh, xl, base + t + 256);
  float s = v0 + v1;
  #pragma unroll
  for (int off = 32; off; off >>= 1) s += __shfl_down(s, off);
  __shared__ float ls[4];
  if ((t & 63) == 0) ls[t >> 6] = s;
  __syncthreads();
  float mean = (ls[0] + ls[1] + ls[2] + ls[3]) * (1.f / 512.f);
  __syncthreads();
  float d0 = v0 - mean, d1 = v1 - mean;
  float q = d0 * d0 + d1 * d1;
  #pragma unroll
  for (int off = 32; off; off >>= 1) q += __shfl_down(q, off);
  if ((t & 63) == 0) ls[t >> 6] = q;
  __syncthreads();
  float var = (ls[0] + ls[1] + ls[2] + ls[3]) * (1.f / 512.f);
  float rs = rsqrtf(var + 1e-5f);
  float r0 = d0 * rs * g[t] + b[t];
  float r1 = d1 * rs * g[t + 256] + b[t + 256];
  if (of32) { of32[base + t] = r0; of32[base + t + 256] = r1; }
  if (oh) {
    emit_split(r0, oh, ol, base + t);
    emit_split(r1, oh, ol, base + t + 256);
  }
}

// ---------------- M[bh,l] scoring: 4 queries/wave, 4-lane cooperative gather ----------------
// 4 queries x U samples packed into ceil(4U/16) passes of 16 groups (U=40: 10 exact).
// q0 partials bit-identical to prior versions; q1-3 reassociate sm only (ulp-class).
__global__ __launch_bounds__(256) void k_qkM(const float* __restrict__ Q, int qstr,
    const float* __restrict__ Kp, int kstr, const int* __restrict__ idx,
    float* __restrict__ M, int Lq, int Lk, int U) {
  __shared__ float qsh[4][4][64];
  __shared__ int idxs[4][4][40];
  int nwg = gridDim.x;
  int bid = blockIdx.x;
  if ((nwg & 7) == 0) {
    int cpx = nwg >> 3;
    bid = (bid & 7) * cpx + (bid >> 3);   // same-bh blocks on one XCD -> K panel L2-resident
  }
  int wib = threadIdx.x >> 6;
  int wid = (bid << 2) + wib;
  int lane = threadIdx.x & 63;
  int Lh = Lq >> 2;
  int lp = wid & (Lh - 1);
  int bh = wid / Lh;
  int l0 = lp * 4;
  int h = bh & 7; int b = bh >> 3;
  {
    int q = lane >> 4, e = lane & 15;
    const float4* qr = (const float4*)(Q + (size_t)(b * Lq + l0 + q) * qstr + (h << 6));
    *(float4*)(&qsh[wib][q][e * 4]) = qr[e];
  }
  if (lane < U) {
    #pragma unroll
    for (int q = 0; q < 4; ++q)
      idxs[wib][q][lane] = idx[(l0 + q) * U + lane];
  }
  __syncthreads();
  int g = lane >> 2, j = lane & 3;
  float mx0 = -INFINITY, sm0 = 0.f, mx1 = -INFINITY, sm1 = 0.f;
  float mx2 = -INFINITY, sm2 = 0.f, mx3 = -INFINITY, sm3 = 0.f;
  int npass = (4 * U + 15) >> 4;
  for (int p = 0; p < npass; ++p) {
    int sp = p * 16 + g;
    bool act = sp < 4 * U;
    int q = act ? sp / U : 0;
    int s = act ? sp - q * U : 0;
    int kr = idxs[wib][q][s];
    const float* kb_ = Kp + (size_t)((size_t)b * Lk + kr) * kstr + (h << 6);
    // instruction i: lane j reads floats [16i+4j, 16i+4j+4) -> group covers line i
    float4 c0 = *(const float4*)(kb_ +  0 + 4 * j);
    float4 c1 = *(const float4*)(kb_ + 16 + 4 * j);
    float4 c2 = *(const float4*)(kb_ + 32 + 4 * j);
    float4 c3 = *(const float4*)(kb_ + 48 + 4 * j);
    const float* qs = qsh[wib][q];
    float pd = 0.f;
    pd += qs[ 0 + 4*j] * c0.x + qs[ 1 + 4*j] * c0.y + qs[ 2 + 4*j] * c0.z + qs[ 3 + 4*j] * c0.w;
    pd += qs[16 + 4*j] * c1.x + qs[17 + 4*j] * c1.y + qs[18 + 4*j] * c1.z + qs[19 + 4*j] * c1.w;
    pd += qs[32 + 4*j] * c2.x + qs[33 + 4*j] * c2.y + qs[34 + 4*j] * c2.z + qs[35 + 4*j] * c2.w;
    pd += qs[48 + 4*j] * c3.x + qs[49 + 4*j] * c3.y + qs[50 + 4*j] * c3.z + qs[51 + 4*j] * c3.w;
    pd += __shfl_xor(pd, 1);
    pd += __shfl_xor(pd, 2);    // all 4 lanes of group hold the full dot
    if (act) {
      if (q == 0)      { mx0 = fmaxf(mx0, pd); sm0 += pd; }
      else if (q == 1) { mx1 = fmaxf(mx1, pd); sm1 += pd; }
      else if (q == 2) { mx2 = fmaxf(mx2, pd); sm2 += pd; }
      else             { mx3 = fmaxf(mx3, pd); sm3 += pd; }
    }
  }
  // reduce across the 16 groups (j-slices are duplicates; strides >=4 keep them separate)
  #pragma unroll
  for (int off = 32; off >= 4; off >>= 1) {
    mx0 = fmaxf(mx0, __shfl_xor(mx0, off)); sm0 += __shfl_xor(sm0, off);
    mx1 = fmaxf(mx1, __shfl_xor(mx1, off)); sm1 += __shfl_xor(sm1, off);
    mx2 = fmaxf(mx2, __shfl_xor(mx2, off)); sm2 += __shfl_xor(sm2, off);
    mx3 = fmaxf(mx3, __shfl_xor(mx3, off)); sm3 += __shfl_xor(sm3, off);
  }
  if (lane == 0) {
    M[(size_t)bh * Lq + l0]     = mx0 - sm0 / (float)Lk;
    M[(size_t)bh * Lq + l0 + 1] = mx1 - sm1 / (float)Lk;
    M[(size_t)bh * Lq + l0 + 2] = mx2 - sm2 / (float)Lk;
    M[(size_t)bh * Lq + l0 + 3] = mx3 - sm3 / (float)Lk;
  }
}

// ---------------- single-wave top-u per (b,h), ties -> lower index ----------------
__global__ void k_topk64(const float* __restrict__ M, int* __restrict__ mtop, int Lq, int u) {
  __shared__ float vals[2048];
  int bh = blockIdx.x, l = threadIdx.x;
  const float* Mr = M + (size_t)bh * Lq;
  for (int i = l; i < Lq; i += 64) vals[i] = Mr[i];
  __syncthreads();
  for (int it = 0; it < u; ++it) {
    float bv = -INFINITY; int bi = 0x7fffffff;
    for (int i = l; i < Lq; i += 64) {
      float v = vals[i];
      if (v > bv || (v == bv && i < bi)) { bv = v; bi = i; }
    }
    #pragma unroll
    for (int off = 32; off; off >>= 1) {
      float vv = __shfl_xor(bv, off); int ii = __shfl_xor(bi, off);
      if (vv > bv || (vv == bv && ii < bi)) { bv = vv; bi = ii; }
    }
    if (l == 0) { mtop[bh * u + it] = bi; vals[bi] = -INFINITY; }
    __syncthreads();
  }
}

// ---------------- ctx mean (AO split) ----------------
__global__ void k_cm1(const float* __restrict__ V, int vstr, float* __restrict__ PS,
                      int Lk, int rows) {
  int bid = blockIdx.x;
  int bh = bid >> 4, seg = bid & 15, d = threadIdx.x;
  int b = bh >> 3, h = bh & 7;
  const float* vp = V + (size_t)(b * Lk + seg * rows) * vstr + (h << 6) + d;
  float acc = 0.f;
  for (int r = 0; r < rows; ++r) acc += vp[(size_t)r * vstr];
  PS[(bid << 6) + d] = acc;
}
__global__ void k_cm2(const float* __restrict__ PS, f16* __restrict__ AOh,
                      f16* __restrict__ AOl, float invLk, int Lq, int total) {
  int i = blockIdx.x * 256 + threadIdx.x;
  if (i >= total) return;
  int c = i & 511; int h = c >> 6; int d = c & 63;
  int r = i >> 9; int b = r / Lq;
  float acc = 0.f;
  #pragma unroll
  for (int s = 0; s < 16; ++s) acc += PS[(((((b << 3) + h) << 4) + s) << 6) + d];
  emit_split(acc * invLk, AOh, AOl, (size_t)i);
}

// ---------------- cumsum (masked ctx; 16 segments, AO split) ----------------
__global__ void k_cs1(const float* __restrict__ V, int vstr, float* __restrict__ PS,
                      int Lq, int rows) {
  int bid = blockIdx.x;
  int bh = bid >> 4, seg = bid & 15, d = threadIdx.x;
  int b = bh >> 3, h = bh & 7;
  const float* vp = V + (size_t)(b * Lq + seg * rows) * vstr + (h << 6) + d;
  float acc = 0.f;
  for (int r = 0; r < rows; ++r) acc += vp[(size_t)r * vstr];
  PS[(bid << 6) + d] = acc;
}
__global__ void k_cs3(const float* __restrict__ V, int vstr, const float* __restrict__ PS,
                      f16* __restrict__ AOh, f16* __restrict__ AOl, int Lq, int rows) {
  int bid = blockIdx.x;
  int bh = bid >> 4, seg = bid & 15, d = threadIdx.x;
  int b = bh >> 3, h = bh & 7;
  float acc = 0.f;
  for (int s2 = 0; s2 < seg; ++s2) acc += PS[(((bh << 4) + s2) << 6) + d];
  const float* vp = V + (size_t)(b * Lq + seg * rows) * vstr + (h << 6) + d;
  size_t ob = ((size_t)(b * Lq + seg * rows) << 9) + (h << 6) + d;
  for (int r = 0; r < rows; ++r) {
    acc += vp[(size_t)r * vstr];
    emit_split(acc, AOh, AOl, ob + ((size_t)r << 9));
  }
}

// ---------------- flash sparse attn: ALL u rows per (chunk, bh) block ----------------
// chunk sized so nch=4 (256 blocks) for every Lk -> full-CU utilization.
__global__ __launch_bounds__(256) void k_sattnF(
    const float* __restrict__ Q, int qstr, const float* __restrict__ Kp, int kstr,
    const float* __restrict__ Vp, int vstr, const int* __restrict__ mtop,
    float* __restrict__ PPm, float* __restrict__ PPs, float* __restrict__ PPv,
    int Lq, int Lk, int u, int masked, int bhn, int chunk) {
  __shared__ float Qs[40 * 64];
  __shared__ float Kt[64 * 65];
  __shared__ float Vs[64 * 65];
  __shared__ float els[40 * 64];
  __shared__ int rowsh[40];
  int ch = blockIdx.x, bh = blockIdx.y;
  int b = bh >> 3, h = bh & 7;
  int c0 = ch * chunk;
  int nkt = chunk >> 6;
  int t = threadIdx.x;
  int g = t >> 6, d = t & 63;
  if (t < 40) rowsh[t] = (t < u) ? mtop[bh * u + t] : -1;
  __syncthreads();
  for (int i = t; i < 40 * 16; i += 256) {
    int r = i >> 4, e4 = i & 15;
    int row = rowsh[r];
    float4 v;
    if (row >= 0) v = *(const float4*)(Q + (size_t)(b * Lq + row) * qstr + (h << 6) + e4 * 4);
    else          v = make_float4(0.f, 0.f, 0.f, 0.f);
    *(float4*)(Qs + r * 64 + e4 * 4) = v;
  }
  int rows_[10];
  __syncthreads();
  #pragma unroll
  for (int i = 0; i < 10; ++i) rows_[i] = rowsh[g + i * 4];
  float pv[10], m[10], sum[10];
  #pragma unroll
  for (int i = 0; i < 10; ++i) { pv[i] = 0.f; m[i] = -INFINITY; sum[i] = 0.f; }
  const int srow = t >> 2, seg = t & 3;
  for (int kt = 0; kt < nkt; ++kt) {
    __syncthreads();
    {
      int crow = c0 + (kt << 6) + srow;
      const float* kp2 = Kp + (size_t)(b * Lk + crow) * kstr + (h << 6) + seg * 16;
      const float* vp2 = Vp + (size_t)(b * Lk + crow) * vstr + (h << 6) + seg * 16;
      #pragma unroll
      for (int q4 = 0; q4 < 4; ++q4) {
        float4 kv = *(const float4*)(kp2 + q4 * 4);
        float4 vv = *(const float4*)(vp2 + q4 * 4);
        int e0 = seg * 16 + q4 * 4;
        Kt[(e0 + 0) * 65 + srow] = kv.x;
        Kt[(e0 + 1) * 65 + srow] = kv.y;
        Kt[(e0 + 2) * 65 + srow] = kv.z;
        Kt[(e0 + 3) * 65 + srow] = kv.w;
        Vs[srow * 65 + e0 + 0] = vv.x;
        Vs[srow * 65 + e0 + 1] = vv.y;
        Vs[srow * 65 + e0 + 2] = vv.z;
        Vs[srow * 65 + e0 + 3] = vv.w;
      }
    }
    __syncthreads();
    float dot[10];
    #pragma unroll
    for (int i = 0; i < 10; ++i) dot[i] = 0.f;
    for (int e = 0; e < 64; ++e) {
      float kv = Kt[e * 65 + d];
      #pragma unroll
      for (int i = 0; i < 10; ++i)
        dot[i] += Qs[(g + i * 4) * 64 + e] * kv;
    }
    int key = c0 + (kt << 6) + d;
    float scale_[10];
    #pragma unroll
    for (int i = 0; i < 10; ++i) {
      float s = dot[i] * 0.125f;
      if (masked && key > rows_[i]) s = -INFINITY;
      float tm = s;
      #pragma unroll
      for (int off = 32; off; off >>= 1) tm = fmaxf(tm, __shfl_xor(tm, off));
      float nm = fmaxf(m[i], tm);
      if (nm > -3e38f) {
        float scl = expf(m[i] - nm);
        float e_ = expf(s - nm);
        float ts = e_;
        #pragma unroll
        for (int off = 32; off; off >>= 1) ts += __shfl_xor(ts, off);
        sum[i] = sum[i] * scl + ts;
        m[i] = nm;
        scale_[i] = scl;
        els[(g + i * 4) * 64 + d] = e_;
      } else {
        scale_[i] = 1.f;
        els[(g + i * 4) * 64 + d] = 0.f;
      }
    }
    __syncthreads();
    float acc[10];
    #pragma unroll
    for (int i = 0; i < 10; ++i) acc[i] = 0.f;
    for (int k = 0; k < 64; ++k) {
      float vv = Vs[k * 65 + d];
      #pragma unroll
      for (int i = 0; i < 10; ++i)
        acc[i] += els[(g + i * 4) * 64 + k] * vv;
    }
    #pragma unroll
    for (int i = 0; i < 10; ++i) pv[i] = pv[i] * scale_[i] + acc[i];
  }
  #pragma unroll
  for (int i = 0; i < 10; ++i) {
    int r = g + i * 4;
    if (r < u) {
      size_t pidx = (size_t)(ch * bhn + bh) * u + r;
      if (d == 0) { PPm[pidx] = m[i]; PPs[pidx] = sum[i]; }
      PPv[pidx * 64 + d] = pv[i];
    }
  }
}

// ---------------- combine chunk partials -> AO (online softmax rescale) ----------------
__global__ void k_sattnc(const float* __restrict__ PPm, const float* __restrict__ PPs,
                         const float* __restrict__ PPv, const int* __restrict__ mtop,
                         f16* __restrict__ AOh, f16* __restrict__ AOl,
                         int Lq, int u, int nch, int bhn) {
  int rowid = blockIdx.x;
  int bh = rowid / u, ui = rowid % u;
  int d = threadIdx.x;
  int b = bh >> 3, h = bh & 7;
  int row = mtop[bh * u + ui];
  float M = -INFINITY;
  for (int c = 0; c < nch; ++c)
    M = fmaxf(M, PPm[(size_t)(c * bhn + bh) * u + ui]);
  float S = 0.f, o = 0.f;
  for (int c = 0; c < nch; ++c) {
    size_t pidx = (size_t)(c * bhn + bh) * u + ui;
    float pm = PPm[pidx];
    float sc = (pm > -3e38f) ? expf(pm - M) : 0.f;
    S += sc * PPs[pidx];
    o += sc * PPv[pidx * 64 + d];
  }
  emit_split(o / S, AOh, AOl, ((size_t)(b * Lq + row) << 9) + (h << 6) + d);
}

// ---------------- maxpool w3 s2 p1 along L (split-only output) ----------------
__global__ void k_maxpool(const float* __restrict__ y, f16* __restrict__ oh,
                          f16* __restrict__ ol, int L) {
  int Lo = L >> 1;
  int i = blockIdx.x * 256 + threadIdx.x;
  int c = i & 511; int bj = i >> 9;
  int j = bj % Lo; int b = bj / Lo;
  float m = -INFINITY;
  int t0 = 2 * j - 1;
  #pragma unroll
  for (int k = 0; k < 3; ++k) {
    int tt = t0 + k;
    if (tt >= 0 && tt < L) m = fmaxf(m, y[((size_t)(b * L + tt) << 9) + c]);
  }
  emit_split(m, oh, ol, ((size_t)(b * Lo + j) << 9) + c);
}

// ---------------- final projection 512->7 (reads f32 from Y) ----------------
__global__ void k_proj(const float* __restrict__ Xn, const float* __restrict__ pw,
                       const float* __restrict__ pb, float* __restrict__ out) {
  int i = blockIdx.x * 256 + threadIdx.x;
  if (i >= 16 * 512 * 7) return;
  int c = i % 7; int r = i / 7;
  int b = r >> 9; int j = r & 511;
  const float* xr = Xn + ((size_t)(b * 1024 + 512 + j) << 9);
  float acc = pb[c];
  for (int d2 = 0; d2 < 512; ++d2) acc += xr[d2] * pw[d2 * 7 + c];
  out[i] = acc;
}

// =====================================================================
extern "C" void kernel_launch(void* const* d_in, const int* in_sizes, int n_in,
                              void* d_out, int out_size, void* d_ws, size_t ws_size,
                              hipStream_t stream) {
  const float* x_enc      = (const float*)d_in[0];
  const float* x_mark_enc = (const float*)d_in[1];
  const float* x_dec      = (const float*)d_in[2];
  const float* x_mark_dec = (const float*)d_in[3];
  const float* enc_tok_w  = (const float*)d_in[4];
  const float* enc_mark_w = (const float*)d_in[5];
  const float* dec_tok_w  = (const float*)d_in[6];
  const float* dec_mark_w = (const float*)d_in[7];
  const float* enc_attn_w = (const float*)d_in[8];
  const float* enc_attn_b = (const float*)d_in[9];
  const float* enc_ffn1_w = (const float*)d_in[10];
  const float* enc_ffn1_b = (const float*)d_in[11];
  const float* enc_ffn2_w = (const float*)d_in[12];
  const float* enc_ffn2_b = (const float*)d_in[13];
  const float* enc_ln_g   = (const float*)d_in[14];
  const float* enc_ln_b   = (const float*)d_in[15];
  const float* distil_w   = (const float*)d_in[16];
  const float* distil_b   = (const float*)d_in[17];
  const float* distil_bn_g= (const float*)d_in[18];
  const float* distil_bn_b= (const float*)d_in[19];
  const float* enc_norm_g = (const float*)d_in[20];
  const float* enc_norm_b = (const float*)d_in[21];
  const float* dec_self_w = (const float*)d_in[22];
  const float* dec_self_b = (const float*)d_in[23];
  const float* dec_cross_w= (const float*)d_in[24];
  const float* dec_cross_b= (const float*)d_in[25];
  const float* dec_ffn1_w = (const float*)d_in[26];
  const float* dec_ffn1_b = (const float*)d_in[27];
  const float* dec_ffn2_w = (const float*)d_in[28];
  const float* dec_ffn2_b = (const float*)d_in[29];
  const float* dec_ln_g   = (const float*)d_in[30];
  const float* dec_ln_b   = (const float*)d_in[31];
  const float* dec_norm_g = (const float*)d_in[32];
  const float* dec_norm_b = (const float*)d_in[33];
  const float* proj_w     = (const float*)d_in[34];
  const float* proj_b     = (const float*)d_in[35];

  // -------- workspace layout: split-only activations; Y sized by tier --------
  float* ws = (float*)d_ws;
  size_t off = 0;
  f16* Xh   = (f16*)(ws + off); off += 16777216;
  f16* Xl   = Xh + 16777216;
  f16* ENCh = (f16*)(ws + off); off += 4194304;
  f16* ENCl = ENCh + 4194304;
  float* PE = ws + off; off += 1048576;
  float* Mb = ws + off; off += 131072;
  float* PS = ws + off; off += 65536;
  f16* WSP  = (f16*)(ws + off); off += 2097152;
  int* IDXi = (int*)(ws + off); off += 84480;
  float* Y  = ws + off;
  int* MTi  = IDXi + 81920;
  size_t need4 = (off + 16777216ull) * 4;
  size_t need8 = (off + 33554432ull) * 4;
  int bs;
  if      (ws_size >= need8) bs = 8;
  else if (ws_size >= need4) bs = 4;
  else return;
  f16* Yh = (f16*)Y;
  float* WF  = (float*)WSP + 1048576;
  float* PPm = WF;
  float* PPs = WF + 16384;
  float* PPv = WF + 32768;

  auto ln = [&](const f16* xh, const f16* xl, const float* g, const float* b, int rows,
                float* of32, f16* oh, f16* ol) {
    k_ln<<<rows, 256, 0, stream>>>(xh, xl, g, b, of32, oh, ol);
  };
  auto wsplit = [&](const float* W, f16* Wh, f16* Wl, int K, int N, int nmat) {
    dim3 g(K >> 5, N >> 5, nmat);
    k_wsplit<<<g, 256, 0, stream>>>(W, Wh, Wl, K, N);
  };
  auto mgQ = [&](const f16* Ah, const f16* Al, const f16* Wh, const f16* Wl,
                 const float* bias, float* C, int M, int N, int K) {
    dim3 g(N >> 7, M >> 7);
    k_mgemm2<0,0,0,0><<<g, 256, 0, stream>>>(Ah, Al, Wh, Wl, bias, nullptr, nullptr,
        nullptr, nullptr, C, nullptr, nullptr, M, N, K, 0);
  };
  auto mgR = [&](const f16* Ah, const f16* Al, const f16* Wh, const f16* Wl,
                 const float* bias, const f16* Rh, const f16* Rl,
                 f16* Ch, f16* Cl, int M, int N, int K) {
    dim3 g(N >> 7, M >> 7);
    k_mgemm2<0,1,0,1><<<g, 256, 0, stream>>>(Ah, Al, Wh, Wl, bias, Rh, Rl,
        nullptr, nullptr, nullptr, Ch, Cl, M, N, K, 0);
  };
  auto mgG = [&](const f16* Ah, const f16* Al, const f16* Wh, const f16* Wl,
                 const float* bias, f16* Ch, f16* Cl, int M, int N, int K) {
    dim3 g(N >> 7, M >> 7);
    k_mgemm2<1,1,0,0><<<g, 256, 0, stream>>>(Ah, Al, Wh, Wl, bias, nullptr, nullptr,
        nullptr, nullptr, nullptr, Ch, Cl, M, N, K, 0);
  };
  auto Uof = [](int Lx) { int v = 5 * (int)ceil(log((double)Lx)); return v < Lx ? v : Lx; };

  auto attn = [&](f16* xqh, f16* xql, const f16* xkvh, const f16* xkvl,
                  int Lq, int Lk, const float* w, const float* bias,
                  bool masked, u32 fold, bool selfa) {
    int U = Uof(Lk), uu = Uof(Lq);
    u32 r0, r1, ka, kb2;
    tf_block(0u, 42u, 0u, fold, r0, r1);
    tf_block(r0, r1, 0u, 1u, ka, kb2);
    int n = Lq * U;
    k_idx<<<(n + 255) / 256, 256, 0, stream>>>(ka, kb2, n, Lk - 1, IDXi);

    // one z=4 wsplit: Q,K,V,O (or QKV,O) are contiguous in w
    f16 *Wh = WSP, *Wl = WSP + 1048576;
    wsplit(w, Wh, Wl, 512, 512, 4);
    f16 *Wqkvh = Wh,           *Wqkvl = Wl;
    f16 *WQh   = Wh,           *WQl   = Wl;
    f16 *WKVh  = Wh + 262144,  *WKVl  = Wl + 262144;
    f16 *WOh   = Wh + 786432,  *WOl   = Wl + 786432;

    int nsl = 16 / bs;
    int bhn = bs * 8;
    for (int s = 0; s < nsl; ++s) {
      size_t qoff = (size_t)s * bs * Lq * 512;
      size_t koff = (size_t)s * bs * Lk * 512;
      const float *qp, *kp, *vp;
      int qstr, kstr, vstr;
      f16 *AOh, *AOl;
      if (selfa) {
        float* QKV = Y;
        AOh = (f16*)(Y + (size_t)bs * Lq * 1536);
        AOl = AOh + (size_t)bs * Lq * 512;
        mgQ(xqh + qoff, xql + qoff, Wqkvh, Wqkvl, bias, QKV, bs * Lq, 1536, 512);
        qp = QKV; qstr = 1536; kp = QKV + 512; kstr = 1536; vp = QKV + 1024; vstr = 1536;
      } else {
        float* Qb  = Y;
        float* KVb = Y + (size_t)bs * Lq * 512;
        AOh = (f16*)(KVb + (size_t)bs * Lk * 1024);
        AOl = AOh + (size_t)bs * Lq * 512;
        mgQ(xqh + qoff, xql + qoff, WQh, WQl, bias, Qb, bs * Lq, 512, 512);
        mgQ(xkvh + koff, xkvl + koff, WKVh, WKVl, bias + 512, KVb, bs * Lk, 1024, 512);
        qp = Qb; qstr = 512; kp = KVb; kstr = 1024; vp = KVb + 512; vstr = 1024;
      }
      int wids = bhn * Lq;
      k_qkM<<<wids / 16, 256, 0, stream>>>(qp, qstr, kp, kstr, IDXi, Mb, Lq, Lk, U);
      k_topk64<<<bhn, 64, 0, stream>>>(Mb, MTi, Lq, uu);
      if (masked) {
        k_cs1<<<bhn * 16, 64, 0, stream>>>(vp, vstr, PS, Lq, Lq >> 4);
        k_cs3<<<bhn * 16, 64, 0, stream>>>(vp, vstr, PS, AOh, AOl, Lq, Lq >> 4);
      } else {
        k_cm1<<<bhn * 16, 64, 0, stream>>>(vp, vstr, PS, Lk, Lk >> 4);
        int tot = bs * Lq * 512;
        k_cm2<<<tot / 256, 256, 0, stream>>>(PS, AOh, AOl, 1.0f / (float)Lk, Lq, tot);
      }
      int chunk = (Lk >= 2048) ? 512 : ((Lk >= 1024) ? 256 : 128);
      int nch = Lk / chunk;
      dim3 gs(nch, bhn);
      k_sattnF<<<gs, 256, 0, stream>>>(qp, qstr, kp, kstr, vp, vstr, MTi,
                                       PPm, PPs, PPv, Lq, Lk, uu, masked ? 1 : 0, bhn, chunk);
      k_sattnc<<<bhn * uu, 64, 0, stream>>>(PPm, PPs, PPv, MTi, AOh, AOl, Lq, uu, nch, bhn);
      mgR(AOh, AOl, WOh, WOl, bias + 1536, xqh + qoff, xql + qoff,
          xqh + qoff, xql + qoff, bs * Lq, 512, 512);
    }
  };

  auto ffn = [&](f16* xh, f16* xl, const float* w1, const float* b1,
                 const float* w2, const float* b2, int Mtot) {
    f16 *W1h = WSP,           *W1l = WSP + 1048576,
        *W2h = WSP + 2097152, *W2l = WSP + 3145728;
    wsplit(w1, W1h, W1l, 512, 2048, 1);
    wsplit(w2, W2h, W2l, 2048, 512, 1);
    int chunk = (bs == 8) ? 16384 : 8192;
    f16* Yl2 = Yh + (size_t)chunk * 2048;
    for (int c0 = 0; c0 < Mtot; c0 += chunk) {
      int rows = (Mtot - c0 < chunk) ? (Mtot - c0) : chunk;
      mgG(xh + (size_t)c0 * 512, xl + (size_t)c0 * 512, W1h, W1l, b1, Yh, Yl2, rows, 2048, 512);
      mgR(Yh, Yl2, W2h, W2l, b2, xh + (size_t)c0 * 512, xl + (size_t)c0 * 512,
          xh + (size_t)c0 * 512, xl + (size_t)c0 * 512, rows, 512, 2048);
    }
  };

  // ---------------- encoder ----------------
  k_pe<<<(2048 * 512) / 256, 256, 0, stream>>>(PE);
  k_embed<<<(16 * 2048 * 512) / 256, 256, 0, stream>>>(x_enc, x_mark_enc, enc_tok_w, enc_mark_w,
                                                       PE, Xh, Xl, 2048, 16 * 2048 * 512);
  int L = 2048;
  for (int l = 0; l < 3; ++l) {
    attn(Xh, Xl, Xh, Xl, L, L, enc_attn_w + (size_t)l * 4 * 262144,
         enc_attn_b + (size_t)l * 2048, false, (u32)l, true);
    ln(Xh, Xl, enc_ln_g + (size_t)(l * 2) * 512, enc_ln_b + (size_t)(l * 2) * 512, 16 * L,
       nullptr, Xh, Xl);
    ffn(Xh, Xl, enc_ffn1_w + (size_t)l * 512 * 2048, enc_ffn1_b + (size_t)l * 2048,
        enc_ffn2_w + (size_t)l * 2048 * 512, enc_ffn2_b + (size_t)l * 512, 16 * L);
    ln(Xh, Xl, enc_ln_g + (size_t)(l * 2 + 1) * 512, enc_ln_b + (size_t)(l * 2 + 1) * 512, 16 * L,
       nullptr, Xh, Xl);
    if (l < 2) {
      f16 *Dh = WSP, *Dl = WSP + 786432;
      k_wsplit_conv<<<(512 * 1536) / 256, 256, 0, stream>>>(distil_w + (size_t)l * 512 * 512 * 3, Dh, Dl);
      dim3 g(512 >> 7, (16 * L) >> 7);
      int lgL = (L == 2048) ? 11 : 10;
      k_mgemm2<2,0,1,0><<<g, 256, 0, stream>>>(Xh, Xl, Dh, Dl, distil_b + (size_t)l * 512,
          nullptr, nullptr, distil_bn_g + (size_t)l * 512, distil_bn_b + (size_t)l * 512,
          Y, nullptr, nullptr, 16 * L, 512, 1536, lgL);
      int Lo = L >> 1;
      k_maxpool<<<(16 * Lo * 512) / 256, 256, 0, stream>>>(Y, Xh, Xl, L);
      L = Lo;
    }
  }
  ln(Xh, Xl, enc_norm_g, enc_norm_b, 16 * 512, nullptr, ENCh, ENCl);

  // ---------------- decoder (in-place chain in Xh/Xl) ----------------
  k_embed<<<(16 * 1024 * 512) / 256, 256, 0, stream>>>(x_dec, x_mark_dec, dec_tok_w, dec_mark_w,
                                                       PE, Xh, Xl, 1024, 16 * 1024 * 512);
  for (int l = 0; l < 2; ++l) {
    attn(Xh, Xl, Xh, Xl, 1024, 1024, dec_self_w + (size_t)l * 4 * 262144,
         dec_self_b + (size_t)l * 2048, true, (u32)(100 + 2 * l), true);
    ln(Xh, Xl, dec_ln_g + (size_t)(l * 3) * 512, dec_ln_b + (size_t)(l * 3) * 512, 16384,
       nullptr, Xh, Xl);
    attn(Xh, Xl, ENCh, ENCl, 1024, 512, dec_cross_w + (size_t)l * 4 * 262144,
         dec_cross_b + (size_t)l * 2048, false, (u32)(101 + 2 * l), false);
    ln(Xh, Xl, dec_ln_g + (size_t)(l * 3 + 1) * 512, dec_ln_b + (size_t)(l * 3 + 1) * 512, 16384,
       nullptr, Xh, Xl);
    ffn(Xh, Xl, dec_ffn1_w + (size_t)l * 512 * 2048, dec_ffn1_b + (size_t)l * 2048,
        dec_ffn2_w + (size_t)l * 2048 * 512, dec_ffn2_b + (size_t)l * 512, 16384);
    ln(Xh, Xl, dec_ln_g + (size_t)(l * 3 + 2) * 512, dec_ln_b + (size_t)(l * 3 + 2) * 512, 16384,
       nullptr, Xh, Xl);
  }
  ln(Xh, Xl, dec_norm_g, dec_norm_b, 16384, Y, nullptr, nullptr);
  k_proj<<<(16 * 512 * 7 + 255) / 256, 256, 0, stream>>>(Y, proj_w, proj_b, (float*)d_out);
}